// Round 9
// baseline (1675.754 us; speedup 1.0000x reference)
//
#include <hip/hip_runtime.h>
#include <math.h>

// ---------------- problem constants ----------------
#define BATCH 2
#define TSEQ 1024
#define DIMD 1024
#define NPERS 16
#define NCH 8
#define NTOK 2064
#define ETA_C 0.9f
#define THETA_C 0.1f
#define ALPHA_C 0.02f

typedef __attribute__((ext_vector_type(4))) float f32x4;
typedef __attribute__((ext_vector_type(8))) short s16x8;
typedef unsigned short u16;

// ---------------- bf16 helpers ----------------
__device__ __forceinline__ u16 f2bf(float f) {
    unsigned int u = __float_as_uint(f);
    return (u16)((u + 0x7fffu + ((u >> 16) & 1u)) >> 16);
}
__device__ __forceinline__ float bf2f(u16 h) { return __uint_as_float(((unsigned)h) << 16); }
__device__ __forceinline__ void split2(float v, u16& h, u16& l) {
    h = f2bf(v); l = f2bf(v - bf2f(h));
}

// ---------------- workspace layout (byte offsets) ----------------
static const size_t oRA = 0;                       // 50,724,864 multiplexed
static const size_t oRB = 50724864;                // 16,908,288
static const size_t oRC = 67633152;                // 12,582,912
static const size_t oRD = 80216064;                // 16,777,216
static const size_t oRE = 96993280;                // 12,582,912 Wqkv h/l (persistent)
static const size_t oRF = 109576192;               //  4,194,304 parW h/l (persistent)
static const size_t oRG = 113770496;               //  4,200,448 par (persistent)
static const size_t oRH = 117970944;               //  8,388,608 outb f32 (Qs split during attn)
// total 126,359,552 bytes

static const size_t PW1 = 0, PB1 = 524288, PW2 = 524800, PB2 = 1049088, PSZ = 1050112;

// ---------------- async global->LDS ----------------
__device__ __forceinline__ void gload_lds16(const u16* g, u16* l) {
    __builtin_amdgcn_global_load_lds(
        (const __attribute__((address_space(1))) unsigned int*)g,
        (__attribute__((address_space(3))) unsigned int*)l, 16, 0, 0);
}

// XCD-chunked block swizzle (bijective when nwg % 8 == 0; identity fallback).
__device__ __forceinline__ void xcd_swizzle(int& bx, int& by) {
    int gx = gridDim.x, nwg = gx * gridDim.y;
    int lid = blockIdx.y * gx + blockIdx.x;
    int t = lid;
    if ((nwg & 7) == 0) {
        int q = nwg >> 3;
        t = (lid & 7) * q + (lid >> 3);
    }
    bx = t % gx; by = t / gx;
}

// stage one 128x32 bf16 tile (this wave's quarter) into buf + wid*4096
__device__ __forceinline__ void stage_tile(const u16* sp, u16* buf, int rbase,
                                           int M, int clampM, int K, int k0,
                                           int wid, int lane) {
    const int lr = lane >> 2, lc = lane & 3;
    #pragma unroll
    for (int i = 0; i < 8; ++i) {
        int r = i * 16 + lr;
        int gr = rbase + r;
        if (clampM && gr >= M) gr = M - 1;
        int g = lc ^ ((r >> 1) & 3);
        gload_lds16(sp + (size_t)gr * K + k0 + g * 8, buf + wid * 4096 + i * 512);
    }
}

// ---------------- split-bf16 MFMA GEMM:  C = act(A @ W^T + bias) ----------------
// Double-buffered K-loop, ONE barrier per K-step.  PARTIAL: gridDim.z = S K-slices.
template<int ACTF, int WF32, int WSPLIT, int PARTIAL>
__global__ __launch_bounds__(256)
void gemm_mfma_k(const u16* __restrict__ Ah, const u16* __restrict__ Al,
                 const u16* __restrict__ Wh, const u16* __restrict__ Wl,
                 float* __restrict__ C, u16* __restrict__ Chi, u16* __restrict__ Clo,
                 int M, int N, int K, const float* __restrict__ bias)
{
    __shared__ u16 lds[2][16384];
    const int tid = threadIdx.x;
    const int lane = tid & 63, wid = tid >> 6;
    const int wm = wid >> 1, wn = wid & 1;
    int bx, by; xcd_swizzle(bx, by);
    const int row0 = by * 128, col0 = bx * 128;

    const u16* sp = (wid == 0) ? Ah : (wid == 1) ? Al : (wid == 2) ? Wh : Wl;
    const int rbase = (wid < 2) ? row0 : col0;
    const int clampM = (wid < 2) ? 1 : 0;

    f32x4 acc[4][4] = {};
    const int frow = lane & 15, kblk = lane >> 4;

    int kbeg = 0, kend = K;
    if (PARTIAL) {
        int Kseg = K / gridDim.z;
        kbeg = blockIdx.z * Kseg;
        kend = kbeg + Kseg;
    }
    const int nt = (kend - kbeg) >> 5;

    stage_tile(sp, lds[0], rbase, M, clampM, K, kbeg, wid, lane);

    for (int t = 0; t < nt; ++t) {
        __syncthreads();
        if (t + 1 < nt)
            stage_tile(sp, lds[(t + 1) & 1], rbase, M, clampM, K, kbeg + ((t + 1) << 5), wid, lane);
        const u16* cb = lds[t & 1];

        s16x8 bh[4], bl[4];
        #pragma unroll
        for (int ni = 0; ni < 4; ++ni) {
            int br = wn * 64 + ni * 16 + frow;
            int pc = kblk ^ ((br >> 1) & 3);
            bh[ni] = *(const s16x8*)&cb[2 * 4096 + br * 32 + pc * 8];
            bl[ni] = *(const s16x8*)&cb[3 * 4096 + br * 32 + pc * 8];
        }
        #pragma unroll
        for (int mi = 0; mi < 4; ++mi) {
            int ar = wm * 64 + mi * 16 + frow;
            int pc = kblk ^ ((ar >> 1) & 3);
            s16x8 ah = *(const s16x8*)&cb[0 * 4096 + ar * 32 + pc * 8];
            s16x8 al = *(const s16x8*)&cb[1 * 4096 + ar * 32 + pc * 8];
            #pragma unroll
            for (int ni = 0; ni < 4; ++ni) {
                acc[mi][ni] = __builtin_amdgcn_mfma_f32_16x16x32_bf16(ah, bh[ni], acc[mi][ni], 0, 0, 0);
                acc[mi][ni] = __builtin_amdgcn_mfma_f32_16x16x32_bf16(ah, bl[ni], acc[mi][ni], 0, 0, 0);
                acc[mi][ni] = __builtin_amdgcn_mfma_f32_16x16x32_bf16(al, bh[ni], acc[mi][ni], 0, 0, 0);
            }
        }
    }

    const int erow = (lane >> 4) * 4, ecol = lane & 15;
    #pragma unroll
    for (int mi = 0; mi < 4; ++mi) {
        #pragma unroll
        for (int ni = 0; ni < 4; ++ni) {
            int c = col0 + wn * 64 + ni * 16 + ecol;
            float bv = (!PARTIAL && bias) ? bias[c] : 0.f;
            #pragma unroll
            for (int reg = 0; reg < 4; ++reg) {
                int r = row0 + wm * 64 + mi * 16 + erow + reg;
                if (r >= M) continue;
                float v = acc[mi][ni][reg] + bv;
                if (PARTIAL) {
                    C[((size_t)blockIdx.z * M + r) * N + c] = v;
                    continue;
                }
                if (ACTF == 1) v = v / (1.f + __expf(-v));
                else if (ACTF == 2) {
                    float u = 0.7978845608028654f * (v + 0.044715f * v * v * v);
                    v = 0.5f * v * (1.f + tanhf(u));
                }
                size_t o = (size_t)r * N + c;
                if (WF32) C[o] = v;
                if (WSPLIT) { u16 h, l; split2(v, h, l); Chi[o] = h; Clo[o] = l; }
            }
        }
    }
}

// split-K reduce + epilogue
template<int ACTF, int WF32, int WSPLIT>
__global__ __launch_bounds__(256)
void reduce_k(const float* __restrict__ Cp, int S,
              float* __restrict__ C, u16* __restrict__ Chi, u16* __restrict__ Clo,
              const float* __restrict__ bias, int M, int N)
{
    int i = blockIdx.x * 256 + threadIdx.x;
    int n4 = (int)((size_t)M * N / 4);
    if (i >= n4) return;
    size_t off = (size_t)i * 4;
    float4 v = *(const float4*)&Cp[off];
    for (int z = 1; z < S; ++z) {
        float4 u = *(const float4*)&Cp[(size_t)z * M * N + off];
        v.x += u.x; v.y += u.y; v.z += u.z; v.w += u.w;
    }
    int c = (int)(off % N);
    float vv[4] = {v.x, v.y, v.z, v.w};
    #pragma unroll
    for (int j = 0; j < 4; ++j) {
        float w = vv[j];
        if (bias) w += bias[c + j];
        if (ACTF == 1) w = w / (1.f + __expf(-w));
        else if (ACTF == 2) {
            float u = 0.7978845608028654f * (w + 0.044715f * w * w * w);
            w = 0.5f * w * (1.f + tanhf(u));
        }
        if (WF32) C[off + j] = w;
        if (WSPLIT) { u16 h, l; split2(w, h, l); Chi[off + j] = h; Clo[off + j] = l; }
    }
}

static void gemm_mfma(hipStream_t s, int act, int wf32, int wsplit,
                      const u16* Ah, const u16* Al, const u16* Wh, const u16* Wl,
                      float* C, u16* Ch, u16* Cl, int M, int N, int K, const float* bias)
{
    dim3 g(N / 128, (M + 127) / 128), b(256);
    if (act == 0 && wf32 == 1 && wsplit == 0)
        gemm_mfma_k<0,1,0,0><<<g,b,0,s>>>(Ah,Al,Wh,Wl,C,Ch,Cl,M,N,K,bias);
    else if (act == 0 && wf32 == 1 && wsplit == 1)
        gemm_mfma_k<0,1,1,0><<<g,b,0,s>>>(Ah,Al,Wh,Wl,C,Ch,Cl,M,N,K,bias);
    else if (act == 0 && wf32 == 0 && wsplit == 1)
        gemm_mfma_k<0,0,1,0><<<g,b,0,s>>>(Ah,Al,Wh,Wl,C,Ch,Cl,M,N,K,bias);
    else if (act == 1)
        gemm_mfma_k<1,0,1,0><<<g,b,0,s>>>(Ah,Al,Wh,Wl,C,Ch,Cl,M,N,K,bias);
    else
        gemm_mfma_k<2,0,1,0><<<g,b,0,s>>>(Ah,Al,Wh,Wl,C,Ch,Cl,M,N,K,bias);
}

static void gemm_mfma_sk(hipStream_t s, int act, int wf32, int wsplit,
                         const u16* Ah, const u16* Al, const u16* Wh, const u16* Wl,
                         float* C, u16* Ch, u16* Cl, int M, int N, int K,
                         const float* bias, int S, float* part)
{
    if (S <= 1) { gemm_mfma(s, act, wf32, wsplit, Ah, Al, Wh, Wl, C, Ch, Cl, M, N, K, bias); return; }
    dim3 g(N / 128, (M + 127) / 128, S), b(256);
    gemm_mfma_k<0,0,0,1><<<g,b,0,s>>>(Ah,Al,Wh,Wl,part,nullptr,nullptr,M,N,K,nullptr);
    int n4 = (int)((size_t)M * N / 4);
    dim3 rg((n4 + 255) / 256), rb(256);
    if (act == 0 && wf32 == 1 && wsplit == 0)
        reduce_k<0,1,0><<<rg,rb,0,s>>>(part, S, C, Ch, Cl, bias, M, N);
    else if (act == 0 && wf32 == 1 && wsplit == 1)
        reduce_k<0,1,1><<<rg,rb,0,s>>>(part, S, C, Ch, Cl, bias, M, N);
    else if (act == 0 && wf32 == 0 && wsplit == 1)
        reduce_k<0,0,1><<<rg,rb,0,s>>>(part, S, C, Ch, Cl, bias, M, N);
    else if (act == 1)
        reduce_k<1,0,1><<<rg,rb,0,s>>>(part, S, C, Ch, Cl, bias, M, N);
    else
        reduce_k<2,0,1><<<rg,rb,0,s>>>(part, S, C, Ch, Cl, bias, M, N);
}

// ---------------- scan-specialized split-bf16 MFMA GEMM (dbuf loop) -------
// MODE 1: z1 = A@B^T + bias (f32); h = silu(z1) -> split + splitT
// MODE 2: r = A@B^T + bias - add; split + splitT; col-partials CP (x alpha)
// MODE 4: dh = alpha*(A@B^T)*dsilu(Z); splitT; col-partials CP
template<int MODE>
__global__ __launch_bounds__(256)
void gemm_scan_k(const u16* __restrict__ Ah, const u16* __restrict__ Al,
                 const u16* __restrict__ Wh, const u16* __restrict__ Wl,
                 float* __restrict__ C, u16* __restrict__ Chi, u16* __restrict__ Clo,
                 u16* __restrict__ ChiT, u16* __restrict__ CloT,
                 const float* __restrict__ Zf, const float* __restrict__ add,
                 const float* __restrict__ bias, float* __restrict__ CP,
                 int M, int N, int K, float alpha)
{
    __shared__ u16 lds[2][16384];
    const int tid = threadIdx.x;
    const int lane = tid & 63, wid = tid >> 6;
    const int wm = wid >> 1, wn = wid & 1;
    int bx, by; xcd_swizzle(bx, by);
    const int row0 = by * 128, col0 = bx * 128;

    const u16* sp = (wid == 0) ? Ah : (wid == 1) ? Al : (wid == 2) ? Wh : Wl;
    const int rbase = (wid < 2) ? row0 : col0;

    f32x4 acc[4][4] = {};
    const int frow = lane & 15, kblk = lane >> 4;
    const int nt = K >> 5;

    stage_tile(sp, lds[0], rbase, M, 0, K, 0, wid, lane);

    for (int t = 0; t < nt; ++t) {
        __syncthreads();
        if (t + 1 < nt)
            stage_tile(sp, lds[(t + 1) & 1], rbase, M, 0, K, (t + 1) << 5, wid, lane);
        const u16* cb = lds[t & 1];

        s16x8 bh[4], bl[4];
        #pragma unroll
        for (int ni = 0; ni < 4; ++ni) {
            int br = wn * 64 + ni * 16 + frow;
            int pc = kblk ^ ((br >> 1) & 3);
            bh[ni] = *(const s16x8*)&cb[2 * 4096 + br * 32 + pc * 8];
            bl[ni] = *(const s16x8*)&cb[3 * 4096 + br * 32 + pc * 8];
        }
        #pragma unroll
        for (int mi = 0; mi < 4; ++mi) {
            int ar = wm * 64 + mi * 16 + frow;
            int pc = kblk ^ ((ar >> 1) & 3);
            s16x8 ah = *(const s16x8*)&cb[0 * 4096 + ar * 32 + pc * 8];
            s16x8 al = *(const s16x8*)&cb[1 * 4096 + ar * 32 + pc * 8];
            #pragma unroll
            for (int ni = 0; ni < 4; ++ni) {
                acc[mi][ni] = __builtin_amdgcn_mfma_f32_16x16x32_bf16(ah, bh[ni], acc[mi][ni], 0, 0, 0);
                acc[mi][ni] = __builtin_amdgcn_mfma_f32_16x16x32_bf16(ah, bl[ni], acc[mi][ni], 0, 0, 0);
                acc[mi][ni] = __builtin_amdgcn_mfma_f32_16x16x32_bf16(al, bh[ni], acc[mi][ni], 0, 0, 0);
            }
        }
    }

    const int erow = (lane >> 4) * 4, ecol = lane & 15;
    float csum[4] = {0.f, 0.f, 0.f, 0.f};
    #pragma unroll
    for (int mi = 0; mi < 4; ++mi) {
        #pragma unroll
        for (int ni = 0; ni < 4; ++ni) {
            int c = col0 + wn * 64 + ni * 16 + ecol;
            #pragma unroll
            for (int reg = 0; reg < 4; ++reg) {
                int r = row0 + wm * 64 + mi * 16 + erow + reg;
                float v = acc[mi][ni][reg];
                size_t o = (size_t)r * N + c;
                if (MODE == 1) {
                    v += bias[c];
                    C[o] = v;
                    float hv = v / (1.f + __expf(-v));
                    u16 h, l; split2(hv, h, l);
                    Chi[o] = h; Clo[o] = l;
                    size_t ot = (size_t)c * M + r;
                    ChiT[ot] = h; CloT[ot] = l;
                } else if (MODE == 2) {
                    v += bias[c] - add[o];
                    u16 h, l; split2(v, h, l);
                    Chi[o] = h; Clo[o] = l;
                    size_t ot = (size_t)c * M + r;
                    ChiT[ot] = h; CloT[ot] = l;
                    csum[ni] += v;
                } else {
                    v *= alpha;
                    float z = Zf[o];
                    float sg = 1.f / (1.f + __expf(-z));
                    v *= sg * (1.f + z * (1.f - sg));
                    u16 h, l; split2(v, h, l);
                    size_t ot = (size_t)c * M + r;
                    ChiT[ot] = h; CloT[ot] = l;
                    csum[ni] += v;
                }
            }
        }
    }
    if (MODE == 2 || MODE == 4) {
        #pragma unroll
        for (int ni = 0; ni < 4; ++ni) {
            float s = csum[ni];
            s += __shfl_xor(s, 16);
            s += __shfl_xor(s, 32);
            if ((lane >> 4) == 0) {
                int c = col0 + wn * 64 + ni * 16 + ecol;
                float w = (MODE == 2) ? alpha * s : s;
                CP[(size_t)(by * 2 + wm) * N + c] = w;
            }
        }
    }
}

// gradient GEMM + fused momentum/param update (deterministic, 1 thread/element).
// ISW1=0: gW2 = alpha*A@B^T -> update W2 [1024,512] + W2T split; bias b2 from cp.
// ISW1=1: gW1 = alpha*A@B^T -> update W1 [512,1024]; bias b1 from cp.
template<int ISW1>
__global__ __launch_bounds__(256)
void gemm_scan_upd_k(const u16* __restrict__ Ah, const u16* __restrict__ Al,
                     const u16* __restrict__ Wh, const u16* __restrict__ Wl,
                     float* __restrict__ par, float* __restrict__ mo,
                     u16* __restrict__ wh, u16* __restrict__ wl,
                     u16* __restrict__ wth, u16* __restrict__ wtl,
                     const float* __restrict__ cp, int M, int N, int K, float alpha)
{
    __shared__ u16 lds[2][16384];
    const int tid = threadIdx.x;
    const int lane = tid & 63, wid = tid >> 6;
    const int wm = wid >> 1, wn = wid & 1;
    int bx, by; xcd_swizzle(bx, by);
    const int row0 = by * 128, col0 = bx * 128;

    const u16* sp = (wid == 0) ? Ah : (wid == 1) ? Al : (wid == 2) ? Wh : Wl;
    const int rbase = (wid < 2) ? row0 : col0;

    f32x4 acc[4][4] = {};
    const int frow = lane & 15, kblk = lane >> 4;
    const int nt = K >> 5;

    stage_tile(sp, lds[0], rbase, M, 0, K, 0, wid, lane);

    for (int t = 0; t < nt; ++t) {
        __syncthreads();
        if (t + 1 < nt)
            stage_tile(sp, lds[(t + 1) & 1], rbase, M, 0, K, (t + 1) << 5, wid, lane);
        const u16* cb = lds[t & 1];

        s16x8 bh[4], bl[4];
        #pragma unroll
        for (int ni = 0; ni < 4; ++ni) {
            int br = wn * 64 + ni * 16 + frow;
            int pc = kblk ^ ((br >> 1) & 3);
            bh[ni] = *(const s16x8*)&cb[2 * 4096 + br * 32 + pc * 8];
            bl[ni] = *(const s16x8*)&cb[3 * 4096 + br * 32 + pc * 8];
        }
        #pragma unroll
        for (int mi = 0; mi < 4; ++mi) {
            int ar = wm * 64 + mi * 16 + frow;
            int pc = kblk ^ ((ar >> 1) & 3);
            s16x8 ah = *(const s16x8*)&cb[0 * 4096 + ar * 32 + pc * 8];
            s16x8 al = *(const s16x8*)&cb[1 * 4096 + ar * 32 + pc * 8];
            #pragma unroll
            for (int ni = 0; ni < 4; ++ni) {
                acc[mi][ni] = __builtin_amdgcn_mfma_f32_16x16x32_bf16(ah, bh[ni], acc[mi][ni], 0, 0, 0);
                acc[mi][ni] = __builtin_amdgcn_mfma_f32_16x16x32_bf16(ah, bl[ni], acc[mi][ni], 0, 0, 0);
                acc[mi][ni] = __builtin_amdgcn_mfma_f32_16x16x32_bf16(al, bh[ni], acc[mi][ni], 0, 0, 0);
            }
        }
    }

    const int erow = (lane >> 4) * 4, ecol = lane & 15;
    const size_t pw = ISW1 ? PW1 : PW2;
    #pragma unroll
    for (int mi = 0; mi < 4; ++mi) {
        #pragma unroll
        for (int ni = 0; ni < 4; ++ni) {
            int c = col0 + wn * 64 + ni * 16 + ecol;
            #pragma unroll
            for (int reg = 0; reg < 4; ++reg) {
                int r = row0 + wm * 64 + mi * 16 + erow + reg;
                float g = alpha * acc[mi][ni][reg];
                size_t o = (size_t)r * N + c;
                size_t po = pw + o;
                float m = ETA_C * mo[po] - THETA_C * g;
                mo[po] = m;
                float pv = (1.f - ALPHA_C) * par[po] + m;
                par[po] = pv;
                u16 h, l; split2(pv, h, l);
                wh[o] = h; wl[o] = l;
                if (!ISW1) { size_t ot = (size_t)c * 1024 + r; wth[ot] = h; wtl[ot] = l; }
            }
        }
    }
    // bias update (one block, after cp complete in the preceding kernel)
    if (blockIdx.x == 0 && blockIdx.y == 0) {
        const int nb = ISW1 ? 512 : 1024;
        const size_t pb = ISW1 ? PB1 : PB2;
        for (int j = tid; j < nb; j += 256) {
            float gi = cp[j] + cp[nb + j] + cp[2 * nb + j] + cp[3 * nb + j];
            float m = ETA_C * mo[pb + j] - THETA_C * gi;
            mo[pb + j] = m;
            par[pb + j] = (1.f - ALPHA_C) * par[pb + j] + m;
        }
    }
}

// ---------------- small kernels ----------------
__global__ void cvt_split_k(const float* __restrict__ in, u16* __restrict__ hi,
                            u16* __restrict__ lo, int n4) {
    int i = blockIdx.x * 256 + threadIdx.x;
    if (i >= n4) return;
    float4 v = *(const float4*)&in[(size_t)i * 4];
    u16 h0,l0,h1,l1,h2,l2,h3,l3;
    split2(v.x,h0,l0); split2(v.y,h1,l1); split2(v.z,h2,l2); split2(v.w,h3,l3);
    ushort4 hv = {h0,h1,h2,h3}, lv = {l0,l1,l2,l3};
    *(ushort4*)&hi[(size_t)i * 4] = hv;
    *(ushort4*)&lo[(size_t)i * 4] = lv;
}
__global__ void transpose_split_k(const float* __restrict__ in, u16* __restrict__ outh,
                                  u16* __restrict__ outl, int R, int C) {
    __shared__ float t[32][33];
    const int c0 = blockIdx.x * 32, r0 = blockIdx.y * 32;
    const size_t zoff = (size_t)blockIdx.z * R * C;
    const int tx = threadIdx.x & 31, ty = threadIdx.x >> 5;
    #pragma unroll
    for (int p = 0; p < 4; ++p) {
        int r = ty + p * 8;
        t[r][tx] = in[zoff + (size_t)(r0 + r) * C + c0 + tx];
    }
    __syncthreads();
    #pragma unroll
    for (int p = 0; p < 4; ++p) {
        int cc = ty + p * 8;
        float v = t[tx][cc];
        u16 h, l; split2(v, h, l);
        size_t o = zoff + (size_t)(c0 + cc) * R + r0 + tx;
        outh[o] = h; outl[o] = l;
    }
}
__global__ void extractqkv2_k(const float* __restrict__ qkv, u16* __restrict__ Qh,
                              u16* __restrict__ Ql, float* __restrict__ Kb,
                              float* __restrict__ Vb) {
    size_t idx = (size_t)blockIdx.x * 256 + threadIdx.x;
    int m = (int)(idx / 3072), col = (int)(idx % 3072);
    int b = m >> 10, t = m & 1023;
    float v = qkv[idx];
    if (col < 1024) {
        size_t o = (size_t)m * 1024 + col;
        u16 h, l; split2(v, h, l); Qh[o] = h; Ql[o] = l;
    } else {
        int d = col & 1023;
        int ch = t >> 7, r = t & 127;
        size_t o = ((size_t)((ch * 2 + b) * 128 + r)) * 1024 + d;
        if (col < 2048) Kb[o] = v; else Vb[o] = v;
    }
}
__global__ void tokens_split_k(const float* __restrict__ P, const float* __restrict__ memtok,
                               const float* __restrict__ x, u16* __restrict__ th,
                               u16* __restrict__ tl) {
    size_t idx = (size_t)blockIdx.x * 256 + threadIdx.x;
    int d = (int)(idx & 1023);
    int n = (int)((idx >> 10) % NTOK);
    int b = (int)(idx / ((size_t)NTOK * 1024));
    float v;
    if (n < NPERS)            v = P[(size_t)n * 1024 + d];
    else if (n < NPERS + TSEQ) v = memtok[((size_t)b * TSEQ + (n - NPERS)) * 1024 + d];
    else                      v = x[((size_t)b * TSEQ + (n - NPERS - TSEQ)) * 1024 + d];
    u16 h, l; split2(v, h, l); th[idx] = h; tl[idx] = l;
}
__global__ void mul_k(const float* __restrict__ a, const float* __restrict__ b,
                      float* __restrict__ o, int n) {
    int i = blockIdx.x * 256 + threadIdx.x;
    if (i < n) o[i] = a[i] * b[i];
}

// ---------------- attention prep ----------------
__global__ void prep_q_k(const float* __restrict__ aqkv, u16* __restrict__ Qh,
                         u16* __restrict__ Ql) {
    size_t idx = (size_t)blockIdx.x * 256 + threadIdx.x;
    int d = (int)(idx & 63);
    int row = (int)((idx >> 6) & 1023);
    int h = (int)((idx >> 16) & 15);
    int b = (int)(idx >> 20);
    float v = 0.125f * aqkv[((size_t)b * NTOK + NPERS + TSEQ + row) * 3072 + h * 64 + d];
    u16 hh, ll; split2(v, hh, ll);
    Qh[idx] = hh; Ql[idx] = ll;
}
__global__ void prep_kk_k(const float* __restrict__ aqkv, u16* __restrict__ Kh,
                          u16* __restrict__ Kl) {
    size_t idx = (size_t)blockIdx.x * 256 + threadIdx.x;
    int d = (int)(idx & 63);
    int n = (int)((idx >> 6) % NTOK);
    int t = (int)(idx / (64 * NTOK));
    int h = t & 15, b = t >> 4;
    float v = aqkv[((size_t)b * NTOK + n) * 3072 + 1024 + h * 64 + d];
    u16 hh, ll; split2(v, hh, ll);
    Kh[idx] = hh; Kl[idx] = ll;
}
__global__ void prep_vt_k(const float* __restrict__ aqkv, u16* __restrict__ Vt) {
    __shared__ float t[64][65];
    const int nt = blockIdx.x, h = blockIdx.y, b = blockIdx.z;
    const int j0 = nt * 64;
    const int lx = threadIdx.x & 63, rg = threadIdx.x >> 6;
    #pragma unroll
    for (int p = 0; p < 16; ++p) {
        int r = rg * 16 + p;
        int n = j0 + r;
        t[r][lx] = (n < NTOK) ? aqkv[((size_t)b * NTOK + n) * 3072 + 2048 + h * 64 + lx] : 0.f;
    }
    __syncthreads();
    #pragma unroll
    for (int p = 0; p < 16; ++p) {
        int d = rg * 16 + p;
        int n = j0 + lx;
        if (n < NTOK)
            Vt[((size_t)(b * 16 + h) * 64 + d) * NTOK + n] = f2bf(t[lx][d]);
    }
}

// ---------------- MFMA flash attention (KV dbuf, Q in regs, 64KB LDS) ----------
__global__ __launch_bounds__(256)
void flash_mfma_k(const u16* __restrict__ Qsh, const u16* __restrict__ Qsl,
                  const u16* __restrict__ Ksh, const u16* __restrict__ Ksl,
                  const u16* __restrict__ Vts, u16* __restrict__ oh, u16* __restrict__ ol)
{
    __shared__ u16 lds[32768];             // kv0{KH KL VT} | kv1{...} | PH PL = 64 KB
    u16* KV0 = lds;           u16* KV1 = lds + 12288;
    u16* PH = lds + 24576;    u16* PL = lds + 28672;

    const int qt = blockIdx.x, h = blockIdx.y, b = blockIdx.z;
    const int tid = threadIdx.x;
    const int lane = tid & 63, wid = tid >> 6;
    const int fr = lane & 15, kq = lane >> 4;
    const int bh = b * 16 + h;
    const int q0c = qt * 64;
    const int q0a = NPERS + TSEQ + q0c;
    const int jtmax = (q0a + 63) >> 6;
    const int l8 = lane & 7, lr8 = lane >> 3;

    auto stageKV = [&](int jt, u16* kvb) {
        const int j0 = jt * 64;
        #pragma unroll
        for (int jj = 0; jj < 6; ++jj) {
            int j = wid * 6 + jj;
            int buf = j >> 3, i8 = j & 7;
            if (buf < 2) {
                int row = i8 * 8 + lr8;
                int grow = j0 + row; if (grow > NTOK - 1) grow = NTOK - 1;
                int c = l8 ^ (row & 7);
                const u16* src = (buf == 0 ? Ksh : Ksl) +
                                 (((size_t)bh * NTOK + grow) << 6) + c * 8;
                gload_lds16(src, kvb + buf * 4096 + i8 * 512);
            } else {
                int d = i8 * 8 + lr8;
                int c = l8 ^ (d & 7);
                int col = j0 + c * 8; if (col > NTOK - 8) col = NTOK - 8;
                const u16* src = Vts + ((size_t)bh * 64 + d) * NTOK + col;
                gload_lds16(src, kvb + 8192 + i8 * 512);
            }
        }
    };

    // Q fragments direct from global (read once; chunk kb*4+kq is swizzle-free)
    s16x8 qh[2], ql[2];
    {
        const size_t qrow = ((size_t)bh * 1024 + q0c + wid * 16 + fr) << 6;
        #pragma unroll
        for (int kb = 0; kb < 2; ++kb) {
            qh[kb] = *(const s16x8*)&Qsh[qrow + (size_t)(kb * 4 + kq) * 8];
            ql[kb] = *(const s16x8*)&Qsl[qrow + (size_t)(kb * 4 + kq) * 8];
        }
    }
    stageKV(0, KV0);
    __syncthreads();

    f32x4 Oa[4] = {};
    float mrow[4], lrow[4];
    #pragma unroll
    for (int r = 0; r < 4; ++r) { mrow[r] = -INFINITY; lrow[r] = 0.f; }

    for (int jt = 0; jt <= jtmax; ++jt) {
        const int j0 = jt * 64;
        if (jt) __syncthreads();
        if (jt + 1 <= jtmax) stageKV(jt + 1, (jt & 1) ? KV0 : KV1);
        u16* kvb = (jt & 1) ? KV1 : KV0;
        u16* KH = kvb; u16* KL = kvb + 4096; u16* VT = kvb + 8192;

        f32x4 sacc[4] = {};
        #pragma unroll
        for (int nt = 0; nt < 4; ++nt) {
            #pragma unroll
            for (int kb = 0; kb < 2; ++kb) {
                int br = nt * 16 + fr;
                int sl = (kb * 4 + kq) ^ (fr & 7);
                s16x8 kh = *(const s16x8*)&KH[br * 64 + sl * 8];
                s16x8 kl = *(const s16x8*)&KL[br * 64 + sl * 8];
                sacc[nt] = __builtin_amdgcn_mfma_f32_16x16x32_bf16(qh[kb], kh, sacc[nt], 0, 0, 0);
                sacc[nt] = __builtin_amdgcn_mfma_f32_16x16x32_bf16(ql[kb], kh, sacc[nt], 0, 0, 0);
                sacc[nt] = __builtin_amdgcn_mfma_f32_16x16x32_bf16(qh[kb], kl, sacc[nt], 0, 0, 0);
            }
        }

        #pragma unroll
        for (int r = 0; r < 4; ++r) {
            const int qloc = kq * 4 + r;
            const int qi = q0a + wid * 16 + qloc;
            float sv[4], tmax = -INFINITY;
            #pragma unroll
            for (int nt = 0; nt < 4; ++nt) {
                int kj = j0 + nt * 16 + fr;
                sv[nt] = (kj <= qi) ? sacc[nt][r] : -INFINITY;
                tmax = fmaxf(tmax, sv[nt]);
            }
            #pragma unroll
            for (int off = 1; off < 16; off <<= 1)
                tmax = fmaxf(tmax, __shfl_xor(tmax, off));
            float mnew = fmaxf(mrow[r], tmax);
            float scale = __expf(mrow[r] - mnew);
            float psum = 0.f;
            float p4[4];
            #pragma unroll
            for (int nt = 0; nt < 4; ++nt) { p4[nt] = __expf(sv[nt] - mnew); psum += p4[nt]; }
            #pragma unroll
            for (int off = 1; off < 16; off <<= 1)
                psum += __shfl_xor(psum, off);
            lrow[r] = lrow[r] * scale + psum;
            mrow[r] = mnew;
            #pragma unroll
            for (int dt = 0; dt < 4; ++dt) Oa[dt][r] *= scale;
            const int prow = wid * 16 + qloc;
            #pragma unroll
            for (int nt = 0; nt < 4; ++nt) {
                u16 ph, pl; split2(p4[nt], ph, pl);
                int col = nt * 16 + fr;
                int sl = (col >> 3) ^ (qloc & 7);
                int off = prow * 64 + sl * 8 + (col & 7);
                PH[off] = ph; PL[off] = pl;
            }
        }

        #pragma unroll
        for (int kb = 0; kb < 2; ++kb) {
            int pr = wid * 16 + fr;
            int sl = (kb * 4 + kq) ^ (fr & 7);
            s16x8 pa = *(const s16x8*)&PH[pr * 64 + sl * 8];
            s16x8 pb = *(const s16x8*)&PL[pr * 64 + sl * 8];
            #pragma unroll
            for (int dt = 0; dt < 4; ++dt) {
                int vr = dt * 16 + fr;
                s16x8 vb = *(const s16x8*)&VT[vr * 64 + sl * 8];
                Oa[dt] = __builtin_amdgcn_mfma_f32_16x16x32_bf16(pa, vb, Oa[dt], 0, 0, 0);
                Oa[dt] = __builtin_amdgcn_mfma_f32_16x16x32_bf16(pb, vb, Oa[dt], 0, 0, 0);
            }
        }
    }

    #pragma unroll
    for (int r = 0; r < 4; ++r) {
        float inv = 1.f / lrow[r];
        int row = b * 1024 + q0c + wid * 16 + kq * 4 + r;
        #pragma unroll
        for (int dt = 0; dt < 4; ++dt) {
            float v = Oa[dt][r] * inv;
            size_t o = (size_t)row * 1024 + h * 64 + dt * 16 + fr;
            u16 hh, ll; split2(v, hh, ll);
            oh[o] = hh; ol[o] = ll;
        }
    }
}

// ---------------- launch ----------------
extern "C" void kernel_launch(void* const* d_in, const int* in_sizes, int n_in,
                              void* d_out, int out_size, void* d_ws, size_t ws_size,
                              hipStream_t stream)
{
    const float* x     = (const float*)d_in[0];
    const float* Wqkv  = (const float*)d_in[1];
    const float* mW1   = (const float*)d_in[2];
    const float* mb1   = (const float*)d_in[3];
    const float* mW2   = (const float*)d_in[4];
    const float* mb2   = (const float*)d_in[5];
    const float* Pp    = (const float*)d_in[6];
    const float* Wqa   = (const float*)d_in[7];
    const float* Wo    = (const float*)d_in[8];
    const float* ffW1  = (const float*)d_in[9];
    const float* ffb1  = (const float*)d_in[10];
    const float* ffW2  = (const float*)d_in[11];
    const float* ffb2  = (const float*)d_in[12];
    char* wsb = (char*)d_ws;
    float* outp = (float*)d_out;

    // region A (multiplexed)
    float* qkv   = (float*)(wsb + oRA);
    float* z1    = (float*)(wsb + oRA);
    float* cp2   = (float*)(wsb + oRA + 7346176);
    float* cp1   = (float*)(wsb + oRA + 7362560);
    u16* hh_     = (u16*)(wsb + oRA + 8388608);
    u16* hl_     = (u16*)(wsb + oRA + 8650752);
    u16* hTh     = (u16*)(wsb + oRA + 9437184);
    u16* hTl     = (u16*)(wsb + oRA + 9699328);
    u16* rh_     = (u16*)(wsb + oRA + 10485760);
    u16* rl_     = (u16*)(wsb + oRA + 11010048);
    u16* rTh     = (u16*)(wsb + oRA + 11534336);
    u16* rTl     = (u16*)(wsb + oRA + 12058624);
    u16* dhTh    = (u16*)(wsb + oRA + 12582912);
    u16* dhTl    = (u16*)(wsb + oRA + 12845056);
    u16* kcTh    = (u16*)(wsb + oRA + 16777216);
    u16* kcTl    = (u16*)(wsb + oRA + 20971520);
    float* aqkv  = (float*)(wsb + oRA);
    u16* Woh     = (u16*)(wsb + oRA);
    u16* Wol     = (u16*)(wsb + oRA + 2097152);
    u16* ffhh    = (u16*)(wsb + oRA);
    u16* ffhl    = (u16*)(wsb + oRA + 16777216);
    u16* outbh   = (u16*)(wsb + oRA + 33554432);
    u16* outbl   = (u16*)(wsb + oRA + 37748736);
    u16* newQh   = (u16*)(wsb + oRA);
    u16* newQl   = (u16*)(wsb + oRA + 4194304);
    u16* hzh     = (u16*)(wsb + oRA + 8388608);
    u16* hzl     = (u16*)(wsb + oRA + 10485760);
    float* memq  = (float*)(wsb + oRA + 12582912);
    float* partA0 = (float*)(wsb + oRA);
    float* partA1 = (float*)(wsb + oRA + 4194304);
    float* partA2 = (float*)(wsb + oRA + 16777216);
    // region B
    float* Kb    = (float*)(wsb + oRB);
    float* Vb    = (float*)(wsb + oRB + 8388608);
    u16* tokh    = (u16*)(wsb + oRB);
    u16* tokl    = (u16*)(wsb + oRB + 8454144);
    u16* oh      = (u16*)(wsb + oRB);
    u16* ol      = (u16*)(wsb + oRB + 4194304);
    u16* fVth    = (u16*)(wsb + oRB + 8388608);
    u16* y1h     = (u16*)(wsb + oRB + 8388608);
    u16* y1l     = (u16*)(wsb + oRB + 12582912);
    float* partB = (float*)(wsb + oRB);
    // region C
    u16* xh      = (u16*)(wsb + oRC);
    u16* xl      = (u16*)(wsb + oRC + 4194304);
    float* mom   = (float*)(wsb + oRC);
    u16* pW2Th   = (u16*)(wsb + oRC + 5242880);
    u16* pW2Tl   = (u16*)(wsb + oRC + 6291456);
    u16* Wqah    = (u16*)(wsb + oRC);
    u16* Wqal    = (u16*)(wsb + oRC + 6291456);
    u16* fKl     = (u16*)(wsb + oRC);
    // region D
    u16* Qh      = (u16*)(wsb + oRD);
    u16* Ql      = (u16*)(wsb + oRD + 4194304);
    u16* kchh    = (u16*)(wsb + oRD + 8388608);
    u16* kchl    = (u16*)(wsb + oRD + 12582912);
    u16* t1h     = (u16*)(wsb + oRD + 8388608);
    u16* t1l     = (u16*)(wsb + oRD + 10485760);
    float* memtok= (float*)(wsb + oRD);
    u16* fKh     = (u16*)(wsb + oRD);
    u16* ffW1h   = (u16*)(wsb + oRD);
    u16* ffW1l   = (u16*)(wsb + oRD + 8388608);
    u16* ffW2h   = (u16*)(wsb + oRD);
    u16* ffW2l   = (u16*)(wsb + oRD + 8388608);
    // persistent
    u16* Wqkvh   = (u16*)(wsb + oRE);
    u16* Wqkvl   = (u16*)(wsb + oRE + 6291456);
    u16* pW1h    = (u16*)(wsb + oRF);
    u16* pW1l    = (u16*)(wsb + oRF + 1048576);
    u16* pW2h    = (u16*)(wsb + oRF + 2097152);
    u16* pW2l    = (u16*)(wsb + oRF + 3145728);
    float* par   = (float*)(wsb + oRG);
    float* outb  = (float*)(wsb + oRH);
    u16* fQh     = (u16*)(wsb + oRH);
    u16* fQl     = (u16*)(wsb + oRH + 4194304);

    // init memory-MLP params
    hipMemcpyAsync(par + PW1, mW1, 524288 * sizeof(float), hipMemcpyDeviceToDevice, stream);
    hipMemcpyAsync(par + PB1, mb1, 512 * sizeof(float), hipMemcpyDeviceToDevice, stream);
    hipMemcpyAsync(par + PW2, mW2, 524288 * sizeof(float), hipMemcpyDeviceToDevice, stream);
    hipMemcpyAsync(par + PB2, mb2, 1024 * sizeof(float), hipMemcpyDeviceToDevice, stream);

    // qkv = x @ Wqkv^T
    cvt_split_k<<<2048, 256, 0, stream>>>(x, xh, xl, 524288);
    cvt_split_k<<<3072, 256, 0, stream>>>(Wqkv, Wqkvh, Wqkvl, 786432);
    gemm_mfma(stream, 0, 1, 0, xh, xl, Wqkvh, Wqkvl, qkv, nullptr, nullptr, 2048, 3072, 1024, nullptr);
    extractqkv2_k<<<24576, 256, 0, stream>>>(qkv, Qh, Ql, Kb, Vb);

    // scan prep
    hipMemsetAsync(mom, 0, PSZ * sizeof(float), stream);
    cvt_split_k<<<2048, 256, 0, stream>>>(Kb, kchh, kchl, 524288);
    transpose_split_k<<<dim3(32, 8, 8), 256, 0, stream>>>(Kb, kcTh, kcTl, 256, 1024);
    cvt_split_k<<<512, 256, 0, stream>>>(par + PW1, pW1h, pW1l, 131072);
    cvt_split_k<<<512, 256, 0, stream>>>(par + PW2, pW2h, pW2l, 131072);
    transpose_split_k<<<dim3(16, 32, 1), 256, 0, stream>>>(par + PW2, pW2Th, pW2Tl, 1024, 512);

    // memory scan: z1 -> r(+cp2) -> dh(+cp1) -> gW2+update -> gW1+update
    const float cs = 2.f / (float)(BATCH * 128 * DIMD);
    for (int c = 0; c < NCH; ++c) {
        const u16* kch = kchh + (size_t)c * 262144;
        const u16* kcl = kchl + (size_t)c * 262144;
        const u16* kth = kcTh + (size_t)c * 262144;
        const u16* ktl = kcTl + (size_t)c * 262144;
        const float* vc = Vb + (size_t)c * 262144;
        gemm_scan_k<1><<<dim3(4, 2), 256, 0, stream>>>(kch, kcl, pW1h, pW1l,
            z1, hh_, hl_, hTh, hTl, nullptr, nullptr, par + PB1, nullptr, 256, 512, 1024, 1.f);
        gemm_scan_k<2><<<dim3(8, 2), 256, 0, stream>>>(hh_, hl_, pW2h, pW2l,
            nullptr, rh_, rl_, rTh, rTl, nullptr, vc, par + PB2, cp2, 256, 1024, 512, cs);
        gemm_scan_k<4><<<dim3(4, 2), 256, 0, stream>>>(rh_, rl_, pW2Th, pW2Tl,
            nullptr, nullptr, nullptr, dhTh, dhTl, z1, nullptr, nullptr, cp1, 256, 512, 1024, cs);
        // gW2 = cs * rT @ hT^T  -> W2 update (also refreshes W2T; dh above used OLD W2T)
        gemm_scan_upd_k<0><<<dim3(4, 8), 256, 0, stream>>>(rTh, rTl, hTh, hTl,
            par, mom, pW2h, pW2l, pW2Th, pW2Tl, cp2, 1024, 512, 256, cs);
        // gW1 = dhT @ kcT^T -> W1 update
        gemm_scan_upd_k<1><<<dim3(8, 4), 256, 0, stream>>>(dhTh, dhTl, kth, ktl,
            par, mom, pW1h, pW1l, nullptr, nullptr, cp1, 512, 1024, 256, 1.f);
    }

    // memory readout (split-K: t1 S=4 part@A2, memtok S=2 part@A0)
    gemm_mfma_sk(stream, 1, 0, 1, Qh, Ql, pW1h, pW1l, nullptr, t1h, t1l,
                 2048, 512, 1024, par + PB1, 4, partA2);
    gemm_mfma_sk(stream, 0, 1, 0, t1h, t1l, pW2h, pW2l, memtok, nullptr, nullptr,
                 2048, 1024, 512, par + PB2, 2, partA0);

    // tokens + attention qkv
    tokens_split_k<<<16512, 256, 0, stream>>>(Pp, memtok, x, tokh, tokl);
    cvt_split_k<<<3072, 256, 0, stream>>>(Wqa, Wqah, Wqal, 786432);
    gemm_mfma(stream, 0, 1, 0, tokh, tokl, Wqah, Wqal, aqkv, nullptr, nullptr, 4128, 3072, 1024, nullptr);

    // attention prep
    prep_q_k<<<8192, 256, 0, stream>>>(aqkv, fQh, fQl);
    prep_kk_k<<<16512, 256, 0, stream>>>(aqkv, fKh, fKl);
    prep_vt_k<<<dim3(33, 16, 2), 256, 0, stream>>>(aqkv, fVth);

    // MFMA flash attention
    flash_mfma_k<<<dim3(16, 16, 2), 256, 0, stream>>>(fQh, fQl, fKh, fKl, fVth, oh, ol);

    // Wo projection + FFN (split-K on grid-starved GEMMs)
    cvt_split_k<<<1024, 256, 0, stream>>>(Wo, Woh, Wol, 262144);
    gemm_mfma_sk(stream, 0, 0, 1, oh, ol, Woh, Wol, nullptr, y1h, y1l,
                 2048, 1024, 1024, nullptr, 2, partA1);
    cvt_split_k<<<4096, 256, 0, stream>>>(ffW1, ffW1h, ffW1l, 1048576);
    gemm_mfma(stream, 2, 0, 1, y1h, y1l, ffW1h, ffW1l, nullptr, ffhh, ffhl, 2048, 4096, 1024, ffb1);
    cvt_split_k<<<4096, 256, 0, stream>>>(ffW2, ffW2h, ffW2l, 1048576);
    gemm_mfma_sk(stream, 0, 1, 1, ffhh, ffhl, ffW2h, ffW2l, outb, outbh, outbl,
                 2048, 1024, 4096, ffb2, 2, partB);

    // gate
    gemm_mfma_sk(stream, 0, 0, 1, outbh, outbl, Wqkvh, Wqkvl, nullptr, newQh, newQl,
                 2048, 1024, 1024, nullptr, 2, partB);
    gemm_mfma_sk(stream, 1, 0, 1, newQh, newQl, pW1h, pW1l, nullptr, hzh, hzl,
                 2048, 512, 1024, par + PB1, 4, partB);
    gemm_mfma_sk(stream, 0, 1, 0, hzh, hzl, pW2h, pW2l, memq, nullptr, nullptr,
                 2048, 1024, 512, par + PB2, 2, partB);
    mul_k<<<8192, 256, 0, stream>>>(outb, memq, outp, 2097152);
}

// Round 10
// 1508.205 us; speedup vs baseline: 1.1111x; 1.1111x over previous
//
#include <hip/hip_runtime.h>
#include <math.h>

// ---------------- problem constants ----------------
#define BATCH 2
#define TSEQ 1024
#define DIMD 1024
#define NPERS 16
#define NCH 8
#define NTOK 2064
#define ETA_C 0.9f
#define THETA_C 0.1f
#define ALPHA_C 0.02f

typedef __attribute__((ext_vector_type(4))) float f32x4;
typedef __attribute__((ext_vector_type(8))) short s16x8;
typedef unsigned short u16;

// ---------------- bf16 helpers ----------------
__device__ __forceinline__ u16 f2bf(float f) {
    unsigned int u = __float_as_uint(f);
    return (u16)((u + 0x7fffu + ((u >> 16) & 1u)) >> 16);
}
__device__ __forceinline__ float bf2f(u16 h) { return __uint_as_float(((unsigned)h) << 16); }
__device__ __forceinline__ void split2(float v, u16& h, u16& l) {
    h = f2bf(v); l = f2bf(v - bf2f(h));
}

// ---------------- workspace layout (byte offsets) ----------------
static const size_t oRA = 0;                       // 50,724,864 multiplexed
static const size_t oRB = 50724864;                // 16,908,288
static const size_t oRC = 67633152;                // 12,582,912
static const size_t oRD = 80216064;                // 16,777,216
static const size_t oRE = 96993280;                // 12,582,912 Wqkv h/l (persistent)
static const size_t oRF = 109576192;               //  4,194,304 parW h/l (persistent)
static const size_t oRG = 113770496;               //  4,200,448 par (persistent)
static const size_t oRH = 117970944;               //  8,388,608 outb f32 (Qs split during attn)
// total 126,359,552 bytes

static const size_t PW1 = 0, PB1 = 524288, PW2 = 524800, PB2 = 1049088, PSZ = 1050112;

// ---------------- async global->LDS ----------------
__device__ __forceinline__ void gload_lds16(const u16* g, u16* l) {
    __builtin_amdgcn_global_load_lds(
        (const __attribute__((address_space(1))) unsigned int*)g,
        (__attribute__((address_space(3))) unsigned int*)l, 16, 0, 0);
}

// XCD-chunked block swizzle (bijective when nwg % 8 == 0; identity fallback).
__device__ __forceinline__ void xcd_swizzle(int& bx, int& by) {
    int gx = gridDim.x, nwg = gx * gridDim.y;
    int lid = blockIdx.y * gx + blockIdx.x;
    int t = lid;
    if ((nwg & 7) == 0) {
        int q = nwg >> 3;
        t = (lid & 7) * q + (lid >> 3);
    }
    bx = t % gx; by = t / gx;
}

// stage one 128x32 bf16 tile (this wave's quarter) into buf + wid*4096
__device__ __forceinline__ void stage_tile(const u16* sp, u16* buf, int rbase,
                                           int M, int clampM, int K, int k0,
                                           int wid, int lane) {
    const int lr = lane >> 2, lc = lane & 3;
    #pragma unroll
    for (int i = 0; i < 8; ++i) {
        int r = i * 16 + lr;
        int gr = rbase + r;
        if (clampM && gr >= M) gr = M - 1;
        int g = lc ^ ((r >> 1) & 3);
        gload_lds16(sp + (size_t)gr * K + k0 + g * 8, buf + wid * 4096 + i * 512);
    }
}

// ---------------- split-bf16 MFMA GEMM:  C = act(A @ W^T + bias) ----------------
// Double-buffered K-loop, ONE barrier per K-step.  PARTIAL: gridDim.z = S K-slices.
template<int ACTF, int WF32, int WSPLIT, int PARTIAL>
__global__ __launch_bounds__(256)
void gemm_mfma_k(const u16* __restrict__ Ah, const u16* __restrict__ Al,
                 const u16* __restrict__ Wh, const u16* __restrict__ Wl,
                 float* __restrict__ C, u16* __restrict__ Chi, u16* __restrict__ Clo,
                 int M, int N, int K, const float* __restrict__ bias)
{
    __shared__ u16 lds[2][16384];
    const int tid = threadIdx.x;
    const int lane = tid & 63, wid = tid >> 6;
    const int wm = wid >> 1, wn = wid & 1;
    int bx, by; xcd_swizzle(bx, by);
    const int row0 = by * 128, col0 = bx * 128;

    const u16* sp = (wid == 0) ? Ah : (wid == 1) ? Al : (wid == 2) ? Wh : Wl;
    const int rbase = (wid < 2) ? row0 : col0;
    const int clampM = (wid < 2) ? 1 : 0;

    f32x4 acc[4][4] = {};
    const int frow = lane & 15, kblk = lane >> 4;

    int kbeg = 0, kend = K;
    if (PARTIAL) {
        int Kseg = K / gridDim.z;
        kbeg = blockIdx.z * Kseg;
        kend = kbeg + Kseg;
    }
    const int nt = (kend - kbeg) >> 5;

    stage_tile(sp, lds[0], rbase, M, clampM, K, kbeg, wid, lane);

    for (int t = 0; t < nt; ++t) {
        __syncthreads();
        if (t + 1 < nt)
            stage_tile(sp, lds[(t + 1) & 1], rbase, M, clampM, K, kbeg + ((t + 1) << 5), wid, lane);
        const u16* cb = lds[t & 1];

        s16x8 bh[4], bl[4];
        #pragma unroll
        for (int ni = 0; ni < 4; ++ni) {
            int br = wn * 64 + ni * 16 + frow;
            int pc = kblk ^ ((br >> 1) & 3);
            bh[ni] = *(const s16x8*)&cb[2 * 4096 + br * 32 + pc * 8];
            bl[ni] = *(const s16x8*)&cb[3 * 4096 + br * 32 + pc * 8];
        }
        #pragma unroll
        for (int mi = 0; mi < 4; ++mi) {
            int ar = wm * 64 + mi * 16 + frow;
            int pc = kblk ^ ((ar >> 1) & 3);
            s16x8 ah = *(const s16x8*)&cb[0 * 4096 + ar * 32 + pc * 8];
            s16x8 al = *(const s16x8*)&cb[1 * 4096 + ar * 32 + pc * 8];
            #pragma unroll
            for (int ni = 0; ni < 4; ++ni) {
                acc[mi][ni] = __builtin_amdgcn_mfma_f32_16x16x32_bf16(ah, bh[ni], acc[mi][ni], 0, 0, 0);
                acc[mi][ni] = __builtin_amdgcn_mfma_f32_16x16x32_bf16(ah, bl[ni], acc[mi][ni], 0, 0, 0);
                acc[mi][ni] = __builtin_amdgcn_mfma_f32_16x16x32_bf16(al, bh[ni], acc[mi][ni], 0, 0, 0);
            }
        }
    }

    const int erow = (lane >> 4) * 4, ecol = lane & 15;
    #pragma unroll
    for (int mi = 0; mi < 4; ++mi) {
        #pragma unroll
        for (int ni = 0; ni < 4; ++ni) {
            int c = col0 + wn * 64 + ni * 16 + ecol;
            float bv = (!PARTIAL && bias) ? bias[c] : 0.f;
            #pragma unroll
            for (int reg = 0; reg < 4; ++reg) {
                int r = row0 + wm * 64 + mi * 16 + erow + reg;
                if (r >= M) continue;
                float v = acc[mi][ni][reg] + bv;
                if (PARTIAL) {
                    C[((size_t)blockIdx.z * M + r) * N + c] = v;
                    continue;
                }
                if (ACTF == 1) v = v / (1.f + __expf(-v));
                else if (ACTF == 2) {
                    float u = 0.7978845608028654f * (v + 0.044715f * v * v * v);
                    v = 0.5f * v * (1.f + tanhf(u));
                }
                size_t o = (size_t)r * N + c;
                if (WF32) C[o] = v;
                if (WSPLIT) { u16 h, l; split2(v, h, l); Chi[o] = h; Clo[o] = l; }
            }
        }
    }
}

// split-K reduce + epilogue
template<int ACTF, int WF32, int WSPLIT>
__global__ __launch_bounds__(256)
void reduce_k(const float* __restrict__ Cp, int S,
              float* __restrict__ C, u16* __restrict__ Chi, u16* __restrict__ Clo,
              const float* __restrict__ bias, int M, int N)
{
    int i = blockIdx.x * 256 + threadIdx.x;
    int n4 = (int)((size_t)M * N / 4);
    if (i >= n4) return;
    size_t off = (size_t)i * 4;
    float4 v = *(const float4*)&Cp[off];
    for (int z = 1; z < S; ++z) {
        float4 u = *(const float4*)&Cp[(size_t)z * M * N + off];
        v.x += u.x; v.y += u.y; v.z += u.z; v.w += u.w;
    }
    int c = (int)(off % N);
    float vv[4] = {v.x, v.y, v.z, v.w};
    #pragma unroll
    for (int j = 0; j < 4; ++j) {
        float w = vv[j];
        if (bias) w += bias[c + j];
        if (ACTF == 1) w = w / (1.f + __expf(-w));
        else if (ACTF == 2) {
            float u = 0.7978845608028654f * (w + 0.044715f * w * w * w);
            w = 0.5f * w * (1.f + tanhf(u));
        }
        if (WF32) C[off + j] = w;
        if (WSPLIT) { u16 h, l; split2(w, h, l); Chi[off + j] = h; Clo[off + j] = l; }
    }
}

static void gemm_mfma(hipStream_t s, int act, int wf32, int wsplit,
                      const u16* Ah, const u16* Al, const u16* Wh, const u16* Wl,
                      float* C, u16* Ch, u16* Cl, int M, int N, int K, const float* bias)
{
    dim3 g(N / 128, (M + 127) / 128), b(256);
    if (act == 0 && wf32 == 1 && wsplit == 0)
        gemm_mfma_k<0,1,0,0><<<g,b,0,s>>>(Ah,Al,Wh,Wl,C,Ch,Cl,M,N,K,bias);
    else if (act == 0 && wf32 == 1 && wsplit == 1)
        gemm_mfma_k<0,1,1,0><<<g,b,0,s>>>(Ah,Al,Wh,Wl,C,Ch,Cl,M,N,K,bias);
    else if (act == 0 && wf32 == 0 && wsplit == 1)
        gemm_mfma_k<0,0,1,0><<<g,b,0,s>>>(Ah,Al,Wh,Wl,C,Ch,Cl,M,N,K,bias);
    else if (act == 1)
        gemm_mfma_k<1,0,1,0><<<g,b,0,s>>>(Ah,Al,Wh,Wl,C,Ch,Cl,M,N,K,bias);
    else
        gemm_mfma_k<2,0,1,0><<<g,b,0,s>>>(Ah,Al,Wh,Wl,C,Ch,Cl,M,N,K,bias);
}

static void gemm_mfma_sk(hipStream_t s, int act, int wf32, int wsplit,
                         const u16* Ah, const u16* Al, const u16* Wh, const u16* Wl,
                         float* C, u16* Ch, u16* Cl, int M, int N, int K,
                         const float* bias, int S, float* part)
{
    if (S <= 1) { gemm_mfma(s, act, wf32, wsplit, Ah, Al, Wh, Wl, C, Ch, Cl, M, N, K, bias); return; }
    dim3 g(N / 128, (M + 127) / 128, S), b(256);
    gemm_mfma_k<0,0,0,1><<<g,b,0,s>>>(Ah,Al,Wh,Wl,part,nullptr,nullptr,M,N,K,nullptr);
    int n4 = (int)((size_t)M * N / 4);
    dim3 rg((n4 + 255) / 256), rb(256);
    if (act == 0 && wf32 == 1 && wsplit == 0)
        reduce_k<0,1,0><<<rg,rb,0,s>>>(part, S, C, Ch, Cl, bias, M, N);
    else if (act == 0 && wf32 == 1 && wsplit == 1)
        reduce_k<0,1,1><<<rg,rb,0,s>>>(part, S, C, Ch, Cl, bias, M, N);
    else if (act == 0 && wf32 == 0 && wsplit == 1)
        reduce_k<0,0,1><<<rg,rb,0,s>>>(part, S, C, Ch, Cl, bias, M, N);
    else if (act == 1)
        reduce_k<1,0,1><<<rg,rb,0,s>>>(part, S, C, Ch, Cl, bias, M, N);
    else
        reduce_k<2,0,1><<<rg,rb,0,s>>>(part, S, C, Ch, Cl, bias, M, N);
}

// ---------------- scan-specialized split-bf16 MFMA GEMM (dbuf loop) -------
// MODE 1: z1 = A@B^T + bias (f32); h = silu(z1) -> split + splitT
// MODE 2: r = A@B^T + bias - add; split + splitT; col-partials CP (x alpha)
// MODE 3: C = alpha * A@B^T (f32)
// MODE 4: dh = alpha*(A@B^T)*dsilu(Z); splitT; col-partials CP
template<int MODE>
__global__ __launch_bounds__(256)
void gemm_scan_k(const u16* __restrict__ Ah, const u16* __restrict__ Al,
                 const u16* __restrict__ Wh, const u16* __restrict__ Wl,
                 float* __restrict__ C, u16* __restrict__ Chi, u16* __restrict__ Clo,
                 u16* __restrict__ ChiT, u16* __restrict__ CloT,
                 const float* __restrict__ Zf, const float* __restrict__ add,
                 const float* __restrict__ bias, float* __restrict__ CP,
                 int M, int N, int K, float alpha)
{
    __shared__ u16 lds[2][16384];
    const int tid = threadIdx.x;
    const int lane = tid & 63, wid = tid >> 6;
    const int wm = wid >> 1, wn = wid & 1;
    int bx, by; xcd_swizzle(bx, by);
    const int row0 = by * 128, col0 = bx * 128;

    const u16* sp = (wid == 0) ? Ah : (wid == 1) ? Al : (wid == 2) ? Wh : Wl;
    const int rbase = (wid < 2) ? row0 : col0;

    f32x4 acc[4][4] = {};
    const int frow = lane & 15, kblk = lane >> 4;
    const int nt = K >> 5;

    stage_tile(sp, lds[0], rbase, M, 0, K, 0, wid, lane);

    for (int t = 0; t < nt; ++t) {
        __syncthreads();
        if (t + 1 < nt)
            stage_tile(sp, lds[(t + 1) & 1], rbase, M, 0, K, (t + 1) << 5, wid, lane);
        const u16* cb = lds[t & 1];

        s16x8 bh[4], bl[4];
        #pragma unroll
        for (int ni = 0; ni < 4; ++ni) {
            int br = wn * 64 + ni * 16 + frow;
            int pc = kblk ^ ((br >> 1) & 3);
            bh[ni] = *(const s16x8*)&cb[2 * 4096 + br * 32 + pc * 8];
            bl[ni] = *(const s16x8*)&cb[3 * 4096 + br * 32 + pc * 8];
        }
        #pragma unroll
        for (int mi = 0; mi < 4; ++mi) {
            int ar = wm * 64 + mi * 16 + frow;
            int pc = kblk ^ ((ar >> 1) & 3);
            s16x8 ah = *(const s16x8*)&cb[0 * 4096 + ar * 32 + pc * 8];
            s16x8 al = *(const s16x8*)&cb[1 * 4096 + ar * 32 + pc * 8];
            #pragma unroll
            for (int ni = 0; ni < 4; ++ni) {
                acc[mi][ni] = __builtin_amdgcn_mfma_f32_16x16x32_bf16(ah, bh[ni], acc[mi][ni], 0, 0, 0);
                acc[mi][ni] = __builtin_amdgcn_mfma_f32_16x16x32_bf16(ah, bl[ni], acc[mi][ni], 0, 0, 0);
                acc[mi][ni] = __builtin_amdgcn_mfma_f32_16x16x32_bf16(al, bh[ni], acc[mi][ni], 0, 0, 0);
            }
        }
    }

    const int erow = (lane >> 4) * 4, ecol = lane & 15;
    float csum[4] = {0.f, 0.f, 0.f, 0.f};
    #pragma unroll
    for (int mi = 0; mi < 4; ++mi) {
        #pragma unroll
        for (int ni = 0; ni < 4; ++ni) {
            int c = col0 + wn * 64 + ni * 16 + ecol;
            #pragma unroll
            for (int reg = 0; reg < 4; ++reg) {
                int r = row0 + wm * 64 + mi * 16 + erow + reg;
                float v = acc[mi][ni][reg];
                size_t o = (size_t)r * N + c;
                if (MODE == 1) {
                    v += bias[c];
                    C[o] = v;
                    float hv = v / (1.f + __expf(-v));
                    u16 h, l; split2(hv, h, l);
                    Chi[o] = h; Clo[o] = l;
                    size_t ot = (size_t)c * M + r;
                    ChiT[ot] = h; CloT[ot] = l;
                } else if (MODE == 2) {
                    v += bias[c] - add[o];
                    u16 h, l; split2(v, h, l);
                    Chi[o] = h; Clo[o] = l;
                    size_t ot = (size_t)c * M + r;
                    ChiT[ot] = h; CloT[ot] = l;
                    csum[ni] += v;
                } else if (MODE == 3) {
                    C[o] = alpha * v;
                } else {
                    v *= alpha;
                    float z = Zf[o];
                    float sg = 1.f / (1.f + __expf(-z));
                    v *= sg * (1.f + z * (1.f - sg));
                    u16 h, l; split2(v, h, l);
                    size_t ot = (size_t)c * M + r;
                    ChiT[ot] = h; CloT[ot] = l;
                    csum[ni] += v;
                }
            }
        }
    }
    if (MODE == 2 || MODE == 4) {
        #pragma unroll
        for (int ni = 0; ni < 4; ++ni) {
            float s = csum[ni];
            s += __shfl_xor(s, 16);
            s += __shfl_xor(s, 32);
            if ((lane >> 4) == 0) {
                int c = col0 + wn * 64 + ni * 16 + ecol;
                float w = (MODE == 2) ? alpha * s : s;
                CP[(size_t)(by * 2 + wm) * N + c] = w;
            }
        }
    }
}

// ---------------- small kernels ----------------
__global__ void cvt_split_k(const float* __restrict__ in, u16* __restrict__ hi,
                            u16* __restrict__ lo, int n4) {
    int i = blockIdx.x * 256 + threadIdx.x;
    if (i >= n4) return;
    float4 v = *(const float4*)&in[(size_t)i * 4];
    u16 h0,l0,h1,l1,h2,l2,h3,l3;
    split2(v.x,h0,l0); split2(v.y,h1,l1); split2(v.z,h2,l2); split2(v.w,h3,l3);
    ushort4 hv = {h0,h1,h2,h3}, lv = {l0,l1,l2,l3};
    *(ushort4*)&hi[(size_t)i * 4] = hv;
    *(ushort4*)&lo[(size_t)i * 4] = lv;
}
__global__ void transpose_split_k(const float* __restrict__ in, u16* __restrict__ outh,
                                  u16* __restrict__ outl, int R, int C) {
    __shared__ float t[32][33];
    const int c0 = blockIdx.x * 32, r0 = blockIdx.y * 32;
    const size_t zoff = (size_t)blockIdx.z * R * C;
    const int tx = threadIdx.x & 31, ty = threadIdx.x >> 5;
    #pragma unroll
    for (int p = 0; p < 4; ++p) {
        int r = ty + p * 8;
        t[r][tx] = in[zoff + (size_t)(r0 + r) * C + c0 + tx];
    }
    __syncthreads();
    #pragma unroll
    for (int p = 0; p < 4; ++p) {
        int cc = ty + p * 8;
        float v = t[tx][cc];
        u16 h, l; split2(v, h, l);
        size_t o = zoff + (size_t)(c0 + cc) * R + r0 + tx;
        outh[o] = h; outl[o] = l;
    }
}
// momentum update; bias grads from col-partials; maintain W1/W2/W2T split forms
__global__ void update3_k(float* __restrict__ p, float* __restrict__ mo,
                          const float* __restrict__ g,
                          const float* __restrict__ cp1, const float* __restrict__ cp2,
                          u16* __restrict__ w1h, u16* __restrict__ w1l,
                          u16* __restrict__ w2h, u16* __restrict__ w2l,
                          u16* __restrict__ w2th, u16* __restrict__ w2tl, int n) {
    int i = blockIdx.x * 256 + threadIdx.x;
    if (i >= n) return;
    float gi;
    if (i < 524288) gi = g[i];
    else if (i < 524800) {
        int j = i - 524288;
        gi = cp1[j] + cp1[512 + j] + cp1[1024 + j] + cp1[1536 + j];
    } else if (i < 1049088) gi = g[i];
    else {
        int j = i - 1049088;
        gi = cp2[j] + cp2[1024 + j] + cp2[2048 + j] + cp2[3072 + j];
    }
    float m = ETA_C * mo[i] - THETA_C * gi;
    mo[i] = m;
    float pv = (1.f - ALPHA_C) * p[i] + m;
    p[i] = pv;
    if (i < 524288) {
        u16 h, l; split2(pv, h, l); w1h[i] = h; w1l[i] = l;
    } else if (i >= 524800 && i < 1049088) {
        int j = i - 524800;
        u16 h, l; split2(pv, h, l);
        w2h[j] = h; w2l[j] = l;
        int tj = (j & 511) * 1024 + (j >> 9);
        w2th[tj] = h; w2tl[tj] = l;
    }
}
__global__ void extractqkv2_k(const float* __restrict__ qkv, u16* __restrict__ Qh,
                              u16* __restrict__ Ql, float* __restrict__ Kb,
                              float* __restrict__ Vb) {
    size_t idx = (size_t)blockIdx.x * 256 + threadIdx.x;
    int m = (int)(idx / 3072), col = (int)(idx % 3072);
    int b = m >> 10, t = m & 1023;
    float v = qkv[idx];
    if (col < 1024) {
        size_t o = (size_t)m * 1024 + col;
        u16 h, l; split2(v, h, l); Qh[o] = h; Ql[o] = l;
    } else {
        int d = col & 1023;
        int ch = t >> 7, r = t & 127;
        size_t o = ((size_t)((ch * 2 + b) * 128 + r)) * 1024 + d;
        if (col < 2048) Kb[o] = v; else Vb[o] = v;
    }
}
__global__ void tokens_split_k(const float* __restrict__ P, const float* __restrict__ memtok,
                               const float* __restrict__ x, u16* __restrict__ th,
                               u16* __restrict__ tl) {
    size_t idx = (size_t)blockIdx.x * 256 + threadIdx.x;
    int d = (int)(idx & 1023);
    int n = (int)((idx >> 10) % NTOK);
    int b = (int)(idx / ((size_t)NTOK * 1024));
    float v;
    if (n < NPERS)            v = P[(size_t)n * 1024 + d];
    else if (n < NPERS + TSEQ) v = memtok[((size_t)b * TSEQ + (n - NPERS)) * 1024 + d];
    else                      v = x[((size_t)b * TSEQ + (n - NPERS - TSEQ)) * 1024 + d];
    u16 h, l; split2(v, h, l); th[idx] = h; tl[idx] = l;
}
__global__ void mul_k(const float* __restrict__ a, const float* __restrict__ b,
                      float* __restrict__ o, int n) {
    int i = blockIdx.x * 256 + threadIdx.x;
    if (i < n) o[i] = a[i] * b[i];
}

// ---------------- attention prep ----------------
__global__ void prep_q_k(const float* __restrict__ aqkv, u16* __restrict__ Qh,
                         u16* __restrict__ Ql) {
    size_t idx = (size_t)blockIdx.x * 256 + threadIdx.x;
    int d = (int)(idx & 63);
    int row = (int)((idx >> 6) & 1023);
    int h = (int)((idx >> 16) & 15);
    int b = (int)(idx >> 20);
    float v = 0.125f * aqkv[((size_t)b * NTOK + NPERS + TSEQ + row) * 3072 + h * 64 + d];
    u16 hh, ll; split2(v, hh, ll);
    Qh[idx] = hh; Ql[idx] = ll;
}
__global__ void prep_kk_k(const float* __restrict__ aqkv, u16* __restrict__ Kh,
                          u16* __restrict__ Kl) {
    size_t idx = (size_t)blockIdx.x * 256 + threadIdx.x;
    int d = (int)(idx & 63);
    int n = (int)((idx >> 6) % NTOK);
    int t = (int)(idx / (64 * NTOK));
    int h = t & 15, b = t >> 4;
    float v = aqkv[((size_t)b * NTOK + n) * 3072 + 1024 + h * 64 + d];
    u16 hh, ll; split2(v, hh, ll);
    Kh[idx] = hh; Kl[idx] = ll;
}
__global__ void prep_vt_k(const float* __restrict__ aqkv, u16* __restrict__ Vt) {
    __shared__ float t[64][65];
    const int nt = blockIdx.x, h = blockIdx.y, b = blockIdx.z;
    const int j0 = nt * 64;
    const int lx = threadIdx.x & 63, rg = threadIdx.x >> 6;
    #pragma unroll
    for (int p = 0; p < 16; ++p) {
        int r = rg * 16 + p;
        int n = j0 + r;
        t[r][lx] = (n < NTOK) ? aqkv[((size_t)b * NTOK + n) * 3072 + 2048 + h * 64 + lx] : 0.f;
    }
    __syncthreads();
    #pragma unroll
    for (int p = 0; p < 16; ++p) {
        int d = rg * 16 + p;
        int n = j0 + lx;
        if (n < NTOK)
            Vt[((size_t)(b * 16 + h) * 64 + d) * NTOK + n] = f2bf(t[lx][d]);
    }
}

// ---------------- MFMA flash attention (KV dbuf, Q in regs, XCD-chunked) --------
__global__ __launch_bounds__(256)
void flash_mfma_k(const u16* __restrict__ Qsh, const u16* __restrict__ Qsl,
                  const u16* __restrict__ Ksh, const u16* __restrict__ Ksl,
                  const u16* __restrict__ Vts, u16* __restrict__ oh, u16* __restrict__ ol)
{
    __shared__ u16 lds[32768];             // kv0{KH KL VT} | kv1{...} | PH PL = 64 KB
    u16* KV0 = lds;           u16* KV1 = lds + 12288;
    u16* PH = lds + 24576;    u16* PL = lds + 28672;

    // XCD-chunked swizzle over the 512-block grid: each XCD owns 4 complete
    // (b,h) K/V panels (contiguous groups of 16 qt-blocks) -> L2 locality.
    int lid = blockIdx.x + (blockIdx.y << 4) + (blockIdx.z << 8);
    int t512 = ((lid & 7) << 6) + (lid >> 3);
    const int qt = t512 & 15, h = (t512 >> 4) & 15, b = t512 >> 8;

    const int tid = threadIdx.x;
    const int lane = tid & 63, wid = tid >> 6;
    const int fr = lane & 15, kq = lane >> 4;
    const int bh = b * 16 + h;
    const int q0c = qt * 64;
    const int q0a = NPERS + TSEQ + q0c;
    const int jtmax = (q0a + 63) >> 6;
    const int l8 = lane & 7, lr8 = lane >> 3;

    auto stageKV = [&](int jt, u16* kvb) {
        const int j0 = jt * 64;
        #pragma unroll
        for (int jj = 0; jj < 6; ++jj) {
            int j = wid * 6 + jj;
            int buf = j >> 3, i8 = j & 7;
            if (buf < 2) {
                int row = i8 * 8 + lr8;
                int grow = j0 + row; if (grow > NTOK - 1) grow = NTOK - 1;
                int c = l8 ^ (row & 7);
                const u16* src = (buf == 0 ? Ksh : Ksl) +
                                 (((size_t)bh * NTOK + grow) << 6) + c * 8;
                gload_lds16(src, kvb + buf * 4096 + i8 * 512);
            } else {
                int d = i8 * 8 + lr8;
                int c = l8 ^ (d & 7);
                int col = j0 + c * 8; if (col > NTOK - 8) col = NTOK - 8;
                const u16* src = Vts + ((size_t)bh * 64 + d) * NTOK + col;
                gload_lds16(src, kvb + 8192 + i8 * 512);
            }
        }
    };

    // Q fragments direct from global (read once; chunk kb*4+kq is swizzle-free)
    s16x8 qh[2], ql[2];
    {
        const size_t qrow = ((size_t)bh * 1024 + q0c + wid * 16 + fr) << 6;
        #pragma unroll
        for (int kb = 0; kb < 2; ++kb) {
            qh[kb] = *(const s16x8*)&Qsh[qrow + (size_t)(kb * 4 + kq) * 8];
            ql[kb] = *(const s16x8*)&Qsl[qrow + (size_t)(kb * 4 + kq) * 8];
        }
    }
    stageKV(0, KV0);
    __syncthreads();

    f32x4 Oa[4] = {};
    float mrow[4], lrow[4];
    #pragma unroll
    for (int r = 0; r < 4; ++r) { mrow[r] = -INFINITY; lrow[r] = 0.f; }

    for (int jt = 0; jt <= jtmax; ++jt) {
        const int j0 = jt * 64;
        if (jt) __syncthreads();
        if (jt + 1 <= jtmax) stageKV(jt + 1, (jt & 1) ? KV0 : KV1);
        u16* kvb = (jt & 1) ? KV1 : KV0;
        u16* KH = kvb; u16* KL = kvb + 4096; u16* VT = kvb + 8192;

        f32x4 sacc[4] = {};
        __builtin_amdgcn_s_setprio(1);
        #pragma unroll
        for (int nt = 0; nt < 4; ++nt) {
            #pragma unroll
            for (int kb = 0; kb < 2; ++kb) {
                int br = nt * 16 + fr;
                int sl = (kb * 4 + kq) ^ (fr & 7);
                s16x8 kh = *(const s16x8*)&KH[br * 64 + sl * 8];
                s16x8 kl = *(const s16x8*)&KL[br * 64 + sl * 8];
                sacc[nt] = __builtin_amdgcn_mfma_f32_16x16x32_bf16(qh[kb], kh, sacc[nt], 0, 0, 0);
                sacc[nt] = __builtin_amdgcn_mfma_f32_16x16x32_bf16(ql[kb], kh, sacc[nt], 0, 0, 0);
                sacc[nt] = __builtin_amdgcn_mfma_f32_16x16x32_bf16(qh[kb], kl, sacc[nt], 0, 0, 0);
            }
        }
        __builtin_amdgcn_s_setprio(0);

        #pragma unroll
        for (int r = 0; r < 4; ++r) {
            const int qloc = kq * 4 + r;
            const int qi = q0a + wid * 16 + qloc;
            float sv[4], tmax = -INFINITY;
            #pragma unroll
            for (int nt = 0; nt < 4; ++nt) {
                int kj = j0 + nt * 16 + fr;
                sv[nt] = (kj <= qi) ? sacc[nt][r] : -INFINITY;
                tmax = fmaxf(tmax, sv[nt]);
            }
            #pragma unroll
            for (int off = 1; off < 16; off <<= 1)
                tmax = fmaxf(tmax, __shfl_xor(tmax, off));
            float mnew = fmaxf(mrow[r], tmax);
            float scale = __expf(mrow[r] - mnew);
            float psum = 0.f;
            float p4[4];
            #pragma unroll
            for (int nt = 0; nt < 4; ++nt) { p4[nt] = __expf(sv[nt] - mnew); psum += p4[nt]; }
            #pragma unroll
            for (int off = 1; off < 16; off <<= 1)
                psum += __shfl_xor(psum, off);
            lrow[r] = lrow[r] * scale + psum;
            mrow[r] = mnew;
            #pragma unroll
            for (int dt = 0; dt < 4; ++dt) Oa[dt][r] *= scale;
            const int prow = wid * 16 + qloc;
            #pragma unroll
            for (int nt = 0; nt < 4; ++nt) {
                u16 ph, pl; split2(p4[nt], ph, pl);
                int col = nt * 16 + fr;
                int sl = (col >> 3) ^ (qloc & 7);
                int off = prow * 64 + sl * 8 + (col & 7);
                PH[off] = ph; PL[off] = pl;
            }
        }

        __builtin_amdgcn_s_setprio(1);
        #pragma unroll
        for (int kb = 0; kb < 2; ++kb) {
            int pr = wid * 16 + fr;
            int sl = (kb * 4 + kq) ^ (fr & 7);
            s16x8 pa = *(const s16x8*)&PH[pr * 64 + sl * 8];
            s16x8 pb = *(const s16x8*)&PL[pr * 64 + sl * 8];
            #pragma unroll
            for (int dt = 0; dt < 4; ++dt) {
                int vr = dt * 16 + fr;
                s16x8 vb = *(const s16x8*)&VT[vr * 64 + sl * 8];
                Oa[dt] = __builtin_amdgcn_mfma_f32_16x16x32_bf16(pa, vb, Oa[dt], 0, 0, 0);
                Oa[dt] = __builtin_amdgcn_mfma_f32_16x16x32_bf16(pb, vb, Oa[dt], 0, 0, 0);
            }
        }
        __builtin_amdgcn_s_setprio(0);
    }

    #pragma unroll
    for (int r = 0; r < 4; ++r) {
        float inv = 1.f / lrow[r];
        int row = b * 1024 + q0c + wid * 16 + kq * 4 + r;
        #pragma unroll
        for (int dt = 0; dt < 4; ++dt) {
            float v = Oa[dt][r] * inv;
            size_t o = (size_t)row * 1024 + h * 64 + dt * 16 + fr;
            u16 hh, ll; split2(v, hh, ll);
            oh[o] = hh; ol[o] = ll;
        }
    }
}

// ---------------- launch ----------------
extern "C" void kernel_launch(void* const* d_in, const int* in_sizes, int n_in,
                              void* d_out, int out_size, void* d_ws, size_t ws_size,
                              hipStream_t stream)
{
    const float* x     = (const float*)d_in[0];
    const float* Wqkv  = (const float*)d_in[1];
    const float* mW1   = (const float*)d_in[2];
    const float* mb1   = (const float*)d_in[3];
    const float* mW2   = (const float*)d_in[4];
    const float* mb2   = (const float*)d_in[5];
    const float* Pp    = (const float*)d_in[6];
    const float* Wqa   = (const float*)d_in[7];
    const float* Wo    = (const float*)d_in[8];
    const float* ffW1  = (const float*)d_in[9];
    const float* ffb1  = (const float*)d_in[10];
    const float* ffW2  = (const float*)d_in[11];
    const float* ffb2  = (const float*)d_in[12];
    char* wsb = (char*)d_ws;
    float* outp = (float*)d_out;

    // region A (multiplexed)
    float* qkv   = (float*)(wsb + oRA);
    float* z1    = (float*)(wsb + oRA);
    float* grd   = (float*)(wsb + oRA + 3145728);
    float* cp2   = (float*)(wsb + oRA + 7346176);
    float* cp1   = (float*)(wsb + oRA + 7362560);
    u16* hh_     = (u16*)(wsb + oRA + 8388608);
    u16* hl_     = (u16*)(wsb + oRA + 8650752);
    u16* hTh     = (u16*)(wsb + oRA + 9437184);
    u16* hTl     = (u16*)(wsb + oRA + 9699328);
    u16* rh_     = (u16*)(wsb + oRA + 10485760);
    u16* rl_     = (u16*)(wsb + oRA + 11010048);
    u16* rTh     = (u16*)(wsb + oRA + 11534336);
    u16* rTl     = (u16*)(wsb + oRA + 12058624);
    u16* dhTh    = (u16*)(wsb + oRA + 12582912);
    u16* dhTl    = (u16*)(wsb + oRA + 12845056);
    u16* kcTh    = (u16*)(wsb + oRA + 16777216);
    u16* kcTl    = (u16*)(wsb + oRA + 20971520);
    float* aqkv  = (float*)(wsb + oRA);
    u16* Woh     = (u16*)(wsb + oRA);
    u16* Wol     = (u16*)(wsb + oRA + 2097152);
    u16* ffhh    = (u16*)(wsb + oRA);
    u16* ffhl    = (u16*)(wsb + oRA + 16777216);
    u16* outbh   = (u16*)(wsb + oRA + 33554432);
    u16* outbl   = (u16*)(wsb + oRA + 37748736);
    u16* newQh   = (u16*)(wsb + oRA);
    u16* newQl   = (u16*)(wsb + oRA + 4194304);
    u16* hzh     = (u16*)(wsb + oRA + 8388608);
    u16* hzl     = (u16*)(wsb + oRA + 10485760);
    float* memq  = (float*)(wsb + oRA + 12582912);
    float* partA0 = (float*)(wsb + oRA);
    float* partA1 = (float*)(wsb + oRA + 4194304);
    float* partA2 = (float*)(wsb + oRA + 16777216);
    // region B
    float* Kb    = (float*)(wsb + oRB);
    float* Vb    = (float*)(wsb + oRB + 8388608);
    u16* tokh    = (u16*)(wsb + oRB);
    u16* tokl    = (u16*)(wsb + oRB + 8454144);
    u16* oh      = (u16*)(wsb + oRB);
    u16* ol      = (u16*)(wsb + oRB + 4194304);
    u16* fVth    = (u16*)(wsb + oRB + 8388608);
    u16* y1h     = (u16*)(wsb + oRB + 8388608);
    u16* y1l     = (u16*)(wsb + oRB + 12582912);
    float* partB = (float*)(wsb + oRB);
    // region C
    u16* xh      = (u16*)(wsb + oRC);
    u16* xl      = (u16*)(wsb + oRC + 4194304);
    float* mom   = (float*)(wsb + oRC);
    u16* pW2Th   = (u16*)(wsb + oRC + 5242880);
    u16* pW2Tl   = (u16*)(wsb + oRC + 6291456);
    u16* Wqah    = (u16*)(wsb + oRC);
    u16* Wqal    = (u16*)(wsb + oRC + 6291456);
    u16* fKl     = (u16*)(wsb + oRC);
    // region D
    u16* Qh      = (u16*)(wsb + oRD);
    u16* Ql      = (u16*)(wsb + oRD + 4194304);
    u16* kchh    = (u16*)(wsb + oRD + 8388608);
    u16* kchl    = (u16*)(wsb + oRD + 12582912);
    u16* t1h     = (u16*)(wsb + oRD + 8388608);
    u16* t1l     = (u16*)(wsb + oRD + 10485760);
    float* memtok= (float*)(wsb + oRD);
    u16* fKh     = (u16*)(wsb + oRD);
    u16* ffW1h   = (u16*)(wsb + oRD);
    u16* ffW1l   = (u16*)(wsb + oRD + 8388608);
    u16* ffW2h   = (u16*)(wsb + oRD);
    u16* ffW2l   = (u16*)(wsb + oRD + 8388608);
    // persistent
    u16* Wqkvh   = (u16*)(wsb + oRE);
    u16* Wqkvl   = (u16*)(wsb + oRE + 6291456);
    u16* pW1h    = (u16*)(wsb + oRF);
    u16* pW1l    = (u16*)(wsb + oRF + 1048576);
    u16* pW2h    = (u16*)(wsb + oRF + 2097152);
    u16* pW2l    = (u16*)(wsb + oRF + 3145728);
    float* par   = (float*)(wsb + oRG);
    float* outb  = (float*)(wsb + oRH);
    u16* fQh     = (u16*)(wsb + oRH);
    u16* fQl     = (u16*)(wsb + oRH + 4194304);

    // init memory-MLP params
    hipMemcpyAsync(par + PW1, mW1, 524288 * sizeof(float), hipMemcpyDeviceToDevice, stream);
    hipMemcpyAsync(par + PB1, mb1, 512 * sizeof(float), hipMemcpyDeviceToDevice, stream);
    hipMemcpyAsync(par + PW2, mW2, 524288 * sizeof(float), hipMemcpyDeviceToDevice, stream);
    hipMemcpyAsync(par + PB2, mb2, 1024 * sizeof(float), hipMemcpyDeviceToDevice, stream);

    // qkv = x @ Wqkv^T
    cvt_split_k<<<2048, 256, 0, stream>>>(x, xh, xl, 524288);
    cvt_split_k<<<3072, 256, 0, stream>>>(Wqkv, Wqkvh, Wqkvl, 786432);
    gemm_mfma(stream, 0, 1, 0, xh, xl, Wqkvh, Wqkvl, qkv, nullptr, nullptr, 2048, 3072, 1024, nullptr);
    extractqkv2_k<<<24576, 256, 0, stream>>>(qkv, Qh, Ql, Kb, Vb);

    // scan prep
    hipMemsetAsync(mom, 0, PSZ * sizeof(float), stream);
    cvt_split_k<<<2048, 256, 0, stream>>>(Kb, kchh, kchl, 524288);
    transpose_split_k<<<dim3(32, 8, 8), 256, 0, stream>>>(Kb, kcTh, kcTl, 256, 1024);
    cvt_split_k<<<512, 256, 0, stream>>>(par + PW1, pW1h, pW1l, 131072);
    cvt_split_k<<<512, 256, 0, stream>>>(par + PW2, pW2h, pW2l, 131072);
    transpose_split_k<<<dim3(16, 32, 1), 256, 0, stream>>>(par + PW2, pW2Th, pW2Tl, 1024, 512);

    // memory scan (round-8 proven structure)
    const float cs = 2.f / (float)(BATCH * 128 * DIMD);
    for (int c = 0; c < NCH; ++c) {
        const u16* kch = kchh + (size_t)c * 262144;
        const u16* kcl = kchl + (size_t)c * 262144;
        const u16* kth = kcTh + (size_t)c * 262144;
        const u16* ktl = kcTl + (size_t)c * 262144;
        const float* vc = Vb + (size_t)c * 262144;
        gemm_scan_k<1><<<dim3(4, 2), 256, 0, stream>>>(kch, kcl, pW1h, pW1l,
            z1, hh_, hl_, hTh, hTl, nullptr, nullptr, par + PB1, nullptr, 256, 512, 1024, 1.f);
        gemm_scan_k<2><<<dim3(8, 2), 256, 0, stream>>>(hh_, hl_, pW2h, pW2l,
            nullptr, rh_, rl_, rTh, rTl, nullptr, vc, par + PB2, cp2, 256, 1024, 512, cs);
        gemm_scan_k<3><<<dim3(4, 8), 256, 0, stream>>>(rTh, rTl, hTh, hTl,
            grd + PW2, nullptr, nullptr, nullptr, nullptr, nullptr, nullptr, nullptr, nullptr,
            1024, 512, 256, cs);
        gemm_scan_k<4><<<dim3(4, 2), 256, 0, stream>>>(rh_, rl_, pW2Th, pW2Tl,
            nullptr, nullptr, nullptr, dhTh, dhTl, z1, nullptr, nullptr, cp1, 256, 512, 1024, cs);
        gemm_scan_k<3><<<dim3(8, 4), 256, 0, stream>>>(dhTh, dhTl, kth, ktl,
            grd + PW1, nullptr, nullptr, nullptr, nullptr, nullptr, nullptr, nullptr, nullptr,
            512, 1024, 256, 1.f);
        update3_k<<<4102, 256, 0, stream>>>(par, mom, grd, cp1, cp2,
            pW1h, pW1l, pW2h, pW2l, pW2Th, pW2Tl, (int)PSZ);
    }

    // memory readout (split-K: t1 S=4 part@A2, memtok S=2 part@A0)
    gemm_mfma_sk(stream, 1, 0, 1, Qh, Ql, pW1h, pW1l, nullptr, t1h, t1l,
                 2048, 512, 1024, par + PB1, 4, partA2);
    gemm_mfma_sk(stream, 0, 1, 0, t1h, t1l, pW2h, pW2l, memtok, nullptr, nullptr,
                 2048, 1024, 512, par + PB2, 2, partA0);

    // tokens + attention qkv
    tokens_split_k<<<16512, 256, 0, stream>>>(Pp, memtok, x, tokh, tokl);
    cvt_split_k<<<3072, 256, 0, stream>>>(Wqa, Wqah, Wqal, 786432);
    gemm_mfma(stream, 0, 1, 0, tokh, tokl, Wqah, Wqal, aqkv, nullptr, nullptr, 4128, 3072, 1024, nullptr);

    // attention prep
    prep_q_k<<<8192, 256, 0, stream>>>(aqkv, fQh, fQl);
    prep_kk_k<<<16512, 256, 0, stream>>>(aqkv, fKh, fKl);
    prep_vt_k<<<dim3(33, 16, 2), 256, 0, stream>>>(aqkv, fVth);

    // MFMA flash attention (XCD-chunked, setprio)
    flash_mfma_k<<<dim3(16, 16, 2), 256, 0, stream>>>(fQh, fQl, fKh, fKl, fVth, oh, ol);

    // Wo projection + FFN (split-K on grid-starved GEMMs)
    cvt_split_k<<<1024, 256, 0, stream>>>(Wo, Woh, Wol, 262144);
    gemm_mfma_sk(stream, 0, 0, 1, oh, ol, Woh, Wol, nullptr, y1h, y1l,
                 2048, 1024, 1024, nullptr, 2, partA1);
    cvt_split_k<<<4096, 256, 0, stream>>>(ffW1, ffW1h, ffW1l, 1048576);
    gemm_mfma(stream, 2, 0, 1, y1h, y1l, ffW1h, ffW1l, nullptr, ffhh, ffhl, 2048, 4096, 1024, ffb1);
    cvt_split_k<<<4096, 256, 0, stream>>>(ffW2, ffW2h, ffW2l, 1048576);
    gemm_mfma_sk(stream, 0, 1, 1, ffhh, ffhl, ffW2h, ffW2l, outb, outbh, outbl,
                 2048, 1024, 4096, ffb2, 2, partB);

    // gate
    gemm_mfma_sk(stream, 0, 0, 1, outbh, outbl, Wqkvh, Wqkvl, nullptr, newQh, newQl,
                 2048, 1024, 1024, nullptr, 2, partB);
    gemm_mfma_sk(stream, 1, 0, 1, newQh, newQl, pW1h, pW1l, nullptr, hzh, hzl,
                 2048, 512, 1024, par + PB1, 4, partB);
    gemm_mfma_sk(stream, 0, 1, 0, hzh, hzl, pW2h, pW2l, memq, nullptr, nullptr,
                 2048, 1024, 512, par + PB2, 2, partB);
    mul_k<<<8192, 256, 0, stream>>>(outb, memq, outp, 2097152);
}

// Round 11
// 1470.063 us; speedup vs baseline: 1.1399x; 1.0259x over previous
//
#include <hip/hip_runtime.h>
#include <math.h>

// ---------------- problem constants ----------------
#define BATCH 2
#define TSEQ 1024
#define DIMD 1024
#define NPERS 16
#define NCH 8
#define NTOK 2064
#define ETA_C 0.9f
#define THETA_C 0.1f
#define ALPHA_C 0.02f

typedef __attribute__((ext_vector_type(4))) float f32x4;
typedef __attribute__((ext_vector_type(8))) short s16x8;
typedef unsigned short u16;

// ---------------- bf16 helpers ----------------
__device__ __forceinline__ u16 f2bf(float f) {
    unsigned int u = __float_as_uint(f);
    return (u16)((u + 0x7fffu + ((u >> 16) & 1u)) >> 16);
}
__device__ __forceinline__ float bf2f(u16 h) { return __uint_as_float(((unsigned)h) << 16); }
__device__ __forceinline__ void split2(float v, u16& h, u16& l) {
    h = f2bf(v); l = f2bf(v - bf2f(h));
}

// ---------------- workspace layout (byte offsets) ----------------
static const size_t oRA = 0;                       // 50,724,864 multiplexed
static const size_t oRB = 50724864;                // 16,908,288
static const size_t oRC = 67633152;                // 12,582,912
static const size_t oRD = 80216064;                // 16,777,216
static const size_t oRE = 96993280;                // 12,582,912 Wqkv h/l (persistent)
static const size_t oRF = 109576192;               //  4,194,304 parW h/l (persistent)
static const size_t oRG = 113770496;               //  4,200,448 par (persistent)
static const size_t oRH = 117970944;               //  8,388,608 outb f32 (Qs split during attn)
// total 126,359,552 bytes

static const size_t PW1 = 0, PB1 = 524288, PW2 = 524800, PB2 = 1049088, PSZ = 1050112;

// ---------------- async global->LDS ----------------
__device__ __forceinline__ void gload_lds16(const u16* g, u16* l) {
    __builtin_amdgcn_global_load_lds(
        (const __attribute__((address_space(1))) unsigned int*)g,
        (__attribute__((address_space(3))) unsigned int*)l, 16, 0, 0);
}

// XCD-chunked block swizzle (bijective when nwg % 8 == 0; identity fallback).
__device__ __forceinline__ void xcd_swizzle(int& bx, int& by) {
    int gx = gridDim.x, nwg = gx * gridDim.y;
    int lid = blockIdx.y * gx + blockIdx.x;
    int t = lid;
    if ((nwg & 7) == 0) {
        int q = nwg >> 3;
        t = (lid & 7) * q + (lid >> 3);
    }
    bx = t % gx; by = t / gx;
}

// stage one 128x32 bf16 tile (this wave's quarter) into buf + wid*4096
__device__ __forceinline__ void stage_tile(const u16* sp, u16* buf, int rbase,
                                           int M, int clampM, int K, int k0,
                                           int wid, int lane) {
    const int lr = lane >> 2, lc = lane & 3;
    #pragma unroll
    for (int i = 0; i < 8; ++i) {
        int r = i * 16 + lr;
        int gr = rbase + r;
        if (clampM && gr >= M) gr = M - 1;
        int g = lc ^ ((r >> 1) & 3);
        gload_lds16(sp + (size_t)gr * K + k0 + g * 8, buf + wid * 4096 + i * 512);
    }
}

// ---------------- split-bf16 MFMA GEMM:  C = act(A @ W^T + bias) ----------------
// Double-buffered K-loop, ONE barrier per K-step.  PARTIAL: gridDim.z = S K-slices.
template<int ACTF, int WF32, int WSPLIT, int PARTIAL>
__global__ __launch_bounds__(256)
void gemm_mfma_k(const u16* __restrict__ Ah, const u16* __restrict__ Al,
                 const u16* __restrict__ Wh, const u16* __restrict__ Wl,
                 float* __restrict__ C, u16* __restrict__ Chi, u16* __restrict__ Clo,
                 int M, int N, int K, const float* __restrict__ bias)
{
    __shared__ u16 lds[2][16384];
    const int tid = threadIdx.x;
    const int lane = tid & 63, wid = tid >> 6;
    const int wm = wid >> 1, wn = wid & 1;
    int bx, by; xcd_swizzle(bx, by);
    const int row0 = by * 128, col0 = bx * 128;

    const u16* sp = (wid == 0) ? Ah : (wid == 1) ? Al : (wid == 2) ? Wh : Wl;
    const int rbase = (wid < 2) ? row0 : col0;
    const int clampM = (wid < 2) ? 1 : 0;

    f32x4 acc[4][4] = {};
    const int frow = lane & 15, kblk = lane >> 4;

    int kbeg = 0, kend = K;
    if (PARTIAL) {
        int Kseg = K / gridDim.z;
        kbeg = blockIdx.z * Kseg;
        kend = kbeg + Kseg;
    }
    const int nt = (kend - kbeg) >> 5;

    stage_tile(sp, lds[0], rbase, M, clampM, K, kbeg, wid, lane);

    for (int t = 0; t < nt; ++t) {
        __syncthreads();
        if (t + 1 < nt)
            stage_tile(sp, lds[(t + 1) & 1], rbase, M, clampM, K, kbeg + ((t + 1) << 5), wid, lane);
        const u16* cb = lds[t & 1];

        s16x8 bh[4], bl[4];
        #pragma unroll
        for (int ni = 0; ni < 4; ++ni) {
            int br = wn * 64 + ni * 16 + frow;
            int pc = kblk ^ ((br >> 1) & 3);
            bh[ni] = *(const s16x8*)&cb[2 * 4096 + br * 32 + pc * 8];
            bl[ni] = *(const s16x8*)&cb[3 * 4096 + br * 32 + pc * 8];
        }
        #pragma unroll
        for (int mi = 0; mi < 4; ++mi) {
            int ar = wm * 64 + mi * 16 + frow;
            int pc = kblk ^ ((ar >> 1) & 3);
            s16x8 ah = *(const s16x8*)&cb[0 * 4096 + ar * 32 + pc * 8];
            s16x8 al = *(const s16x8*)&cb[1 * 4096 + ar * 32 + pc * 8];
            #pragma unroll
            for (int ni = 0; ni < 4; ++ni) {
                acc[mi][ni] = __builtin_amdgcn_mfma_f32_16x16x32_bf16(ah, bh[ni], acc[mi][ni], 0, 0, 0);
                acc[mi][ni] = __builtin_amdgcn_mfma_f32_16x16x32_bf16(ah, bl[ni], acc[mi][ni], 0, 0, 0);
                acc[mi][ni] = __builtin_amdgcn_mfma_f32_16x16x32_bf16(al, bh[ni], acc[mi][ni], 0, 0, 0);
            }
        }
    }

    const int erow = (lane >> 4) * 4, ecol = lane & 15;
    #pragma unroll
    for (int mi = 0; mi < 4; ++mi) {
        #pragma unroll
        for (int ni = 0; ni < 4; ++ni) {
            int c = col0 + wn * 64 + ni * 16 + ecol;
            float bv = (!PARTIAL && bias) ? bias[c] : 0.f;
            #pragma unroll
            for (int reg = 0; reg < 4; ++reg) {
                int r = row0 + wm * 64 + mi * 16 + erow + reg;
                if (r >= M) continue;
                float v = acc[mi][ni][reg] + bv;
                if (PARTIAL) {
                    C[((size_t)blockIdx.z * M + r) * N + c] = v;
                    continue;
                }
                if (ACTF == 1) v = v / (1.f + __expf(-v));
                else if (ACTF == 2) {
                    float u = 0.7978845608028654f * (v + 0.044715f * v * v * v);
                    v = 0.5f * v * (1.f + tanhf(u));
                }
                size_t o = (size_t)r * N + c;
                if (WF32) C[o] = v;
                if (WSPLIT) { u16 h, l; split2(v, h, l); Chi[o] = h; Clo[o] = l; }
            }
        }
    }
}

// split-K reduce + epilogue
template<int ACTF, int WF32, int WSPLIT>
__global__ __launch_bounds__(256)
void reduce_k(const float* __restrict__ Cp, int S,
              float* __restrict__ C, u16* __restrict__ Chi, u16* __restrict__ Clo,
              const float* __restrict__ bias, int M, int N)
{
    int i = blockIdx.x * 256 + threadIdx.x;
    int n4 = (int)((size_t)M * N / 4);
    if (i >= n4) return;
    size_t off = (size_t)i * 4;
    float4 v = *(const float4*)&Cp[off];
    for (int z = 1; z < S; ++z) {
        float4 u = *(const float4*)&Cp[(size_t)z * M * N + off];
        v.x += u.x; v.y += u.y; v.z += u.z; v.w += u.w;
    }
    int c = (int)(off % N);
    float vv[4] = {v.x, v.y, v.z, v.w};
    #pragma unroll
    for (int j = 0; j < 4; ++j) {
        float w = vv[j];
        if (bias) w += bias[c + j];
        if (ACTF == 1) w = w / (1.f + __expf(-w));
        else if (ACTF == 2) {
            float u = 0.7978845608028654f * (w + 0.044715f * w * w * w);
            w = 0.5f * w * (1.f + tanhf(u));
        }
        if (WF32) C[off + j] = w;
        if (WSPLIT) { u16 h, l; split2(w, h, l); Chi[off + j] = h; Clo[off + j] = l; }
    }
}

static void gemm_mfma(hipStream_t s, int act, int wf32, int wsplit,
                      const u16* Ah, const u16* Al, const u16* Wh, const u16* Wl,
                      float* C, u16* Ch, u16* Cl, int M, int N, int K, const float* bias)
{
    dim3 g(N / 128, (M + 127) / 128), b(256);
    if (act == 0 && wf32 == 1 && wsplit == 0)
        gemm_mfma_k<0,1,0,0><<<g,b,0,s>>>(Ah,Al,Wh,Wl,C,Ch,Cl,M,N,K,bias);
    else if (act == 0 && wf32 == 1 && wsplit == 1)
        gemm_mfma_k<0,1,1,0><<<g,b,0,s>>>(Ah,Al,Wh,Wl,C,Ch,Cl,M,N,K,bias);
    else if (act == 0 && wf32 == 0 && wsplit == 1)
        gemm_mfma_k<0,0,1,0><<<g,b,0,s>>>(Ah,Al,Wh,Wl,C,Ch,Cl,M,N,K,bias);
    else if (act == 1)
        gemm_mfma_k<1,0,1,0><<<g,b,0,s>>>(Ah,Al,Wh,Wl,C,Ch,Cl,M,N,K,bias);
    else
        gemm_mfma_k<2,0,1,0><<<g,b,0,s>>>(Ah,Al,Wh,Wl,C,Ch,Cl,M,N,K,bias);
}

static void gemm_mfma_sk(hipStream_t s, int act, int wf32, int wsplit,
                         const u16* Ah, const u16* Al, const u16* Wh, const u16* Wl,
                         float* C, u16* Ch, u16* Cl, int M, int N, int K,
                         const float* bias, int S, float* part)
{
    if (S <= 1) { gemm_mfma(s, act, wf32, wsplit, Ah, Al, Wh, Wl, C, Ch, Cl, M, N, K, bias); return; }
    dim3 g(N / 128, (M + 127) / 128, S), b(256);
    gemm_mfma_k<0,0,0,1><<<g,b,0,s>>>(Ah,Al,Wh,Wl,part,nullptr,nullptr,M,N,K,nullptr);
    int n4 = (int)((size_t)M * N / 4);
    dim3 rg((n4 + 255) / 256), rb(256);
    if (act == 0 && wf32 == 1 && wsplit == 0)
        reduce_k<0,1,0><<<rg,rb,0,s>>>(part, S, C, Ch, Cl, bias, M, N);
    else if (act == 0 && wf32 == 1 && wsplit == 1)
        reduce_k<0,1,1><<<rg,rb,0,s>>>(part, S, C, Ch, Cl, bias, M, N);
    else if (act == 0 && wf32 == 0 && wsplit == 1)
        reduce_k<0,0,1><<<rg,rb,0,s>>>(part, S, C, Ch, Cl, bias, M, N);
    else if (act == 1)
        reduce_k<1,0,1><<<rg,rb,0,s>>>(part, S, C, Ch, Cl, bias, M, N);
    else
        reduce_k<2,0,1><<<rg,rb,0,s>>>(part, S, C, Ch, Cl, bias, M, N);
}

// ---------------- scan-specialized split-bf16 MFMA GEMM body ----------------
// MODE 1: z1 = A@B^T + bias (f32); h = silu(z1) -> split + splitT
// MODE 2: r = A@B^T + bias - add; split + splitT; col-partials CP (x alpha)
// MODE 3: C = alpha * A@B^T (f32)
// MODE 4: dh = alpha*(A@B^T)*dsilu(Z); splitT; col-partials CP
template<int MODE>
__device__ __forceinline__ void scan_body(u16* lds, int bx, int by,
                 const u16* __restrict__ Ah, const u16* __restrict__ Al,
                 const u16* __restrict__ Wh, const u16* __restrict__ Wl,
                 float* __restrict__ C, u16* __restrict__ Chi, u16* __restrict__ Clo,
                 u16* __restrict__ ChiT, u16* __restrict__ CloT,
                 const float* __restrict__ Zf, const float* __restrict__ add,
                 const float* __restrict__ bias, float* __restrict__ CP,
                 int M, int N, int K, float alpha)
{
    const int tid = threadIdx.x;
    const int lane = tid & 63, wid = tid >> 6;
    const int wm = wid >> 1, wn = wid & 1;
    const int row0 = by * 128, col0 = bx * 128;

    const u16* sp = (wid == 0) ? Ah : (wid == 1) ? Al : (wid == 2) ? Wh : Wl;
    const int rbase = (wid < 2) ? row0 : col0;

    f32x4 acc[4][4] = {};
    const int frow = lane & 15, kblk = lane >> 4;
    const int nt = K >> 5;

    stage_tile(sp, lds, rbase, M, 0, K, 0, wid, lane);

    for (int t = 0; t < nt; ++t) {
        __syncthreads();
        if (t + 1 < nt)
            stage_tile(sp, lds + (((t + 1) & 1) << 14), rbase, M, 0, K, (t + 1) << 5, wid, lane);
        const u16* cb = lds + ((t & 1) << 14);

        s16x8 bh[4], bl[4];
        #pragma unroll
        for (int ni = 0; ni < 4; ++ni) {
            int br = wn * 64 + ni * 16 + frow;
            int pc = kblk ^ ((br >> 1) & 3);
            bh[ni] = *(const s16x8*)&cb[2 * 4096 + br * 32 + pc * 8];
            bl[ni] = *(const s16x8*)&cb[3 * 4096 + br * 32 + pc * 8];
        }
        #pragma unroll
        for (int mi = 0; mi < 4; ++mi) {
            int ar = wm * 64 + mi * 16 + frow;
            int pc = kblk ^ ((ar >> 1) & 3);
            s16x8 ah = *(const s16x8*)&cb[0 * 4096 + ar * 32 + pc * 8];
            s16x8 al = *(const s16x8*)&cb[1 * 4096 + ar * 32 + pc * 8];
            #pragma unroll
            for (int ni = 0; ni < 4; ++ni) {
                acc[mi][ni] = __builtin_amdgcn_mfma_f32_16x16x32_bf16(ah, bh[ni], acc[mi][ni], 0, 0, 0);
                acc[mi][ni] = __builtin_amdgcn_mfma_f32_16x16x32_bf16(ah, bl[ni], acc[mi][ni], 0, 0, 0);
                acc[mi][ni] = __builtin_amdgcn_mfma_f32_16x16x32_bf16(al, bh[ni], acc[mi][ni], 0, 0, 0);
            }
        }
    }

    const int erow = (lane >> 4) * 4, ecol = lane & 15;
    float csum[4] = {0.f, 0.f, 0.f, 0.f};
    #pragma unroll
    for (int mi = 0; mi < 4; ++mi) {
        #pragma unroll
        for (int ni = 0; ni < 4; ++ni) {
            int c = col0 + wn * 64 + ni * 16 + ecol;
            #pragma unroll
            for (int reg = 0; reg < 4; ++reg) {
                int r = row0 + wm * 64 + mi * 16 + erow + reg;
                float v = acc[mi][ni][reg];
                size_t o = (size_t)r * N + c;
                if (MODE == 1) {
                    v += bias[c];
                    C[o] = v;
                    float hv = v / (1.f + __expf(-v));
                    u16 h, l; split2(hv, h, l);
                    Chi[o] = h; Clo[o] = l;
                    size_t ot = (size_t)c * M + r;
                    ChiT[ot] = h; CloT[ot] = l;
                } else if (MODE == 2) {
                    v += bias[c] - add[o];
                    u16 h, l; split2(v, h, l);
                    Chi[o] = h; Clo[o] = l;
                    size_t ot = (size_t)c * M + r;
                    ChiT[ot] = h; CloT[ot] = l;
                    csum[ni] += v;
                } else if (MODE == 3) {
                    C[o] = alpha * v;
                } else {
                    v *= alpha;
                    float z = Zf[o];
                    float sg = 1.f / (1.f + __expf(-z));
                    v *= sg * (1.f + z * (1.f - sg));
                    u16 h, l; split2(v, h, l);
                    size_t ot = (size_t)c * M + r;
                    ChiT[ot] = h; CloT[ot] = l;
                    csum[ni] += v;
                }
            }
        }
    }
    if (MODE == 2 || MODE == 4) {
        #pragma unroll
        for (int ni = 0; ni < 4; ++ni) {
            float s = csum[ni];
            s += __shfl_xor(s, 16);
            s += __shfl_xor(s, 32);
            if ((lane >> 4) == 0) {
                int c = col0 + wn * 64 + ni * 16 + ecol;
                float w = (MODE == 2) ? alpha * s : s;
                CP[(size_t)(by * 2 + wm) * N + c] = w;
            }
        }
    }
}

template<int MODE>
__global__ __launch_bounds__(256)
void gemm_scan_k(const u16* __restrict__ Ah, const u16* __restrict__ Al,
                 const u16* __restrict__ Wh, const u16* __restrict__ Wl,
                 float* __restrict__ C, u16* __restrict__ Chi, u16* __restrict__ Clo,
                 u16* __restrict__ ChiT, u16* __restrict__ CloT,
                 const float* __restrict__ Zf, const float* __restrict__ add,
                 const float* __restrict__ bias, float* __restrict__ CP,
                 int M, int N, int K, float alpha)
{
    __shared__ u16 lds[2][16384];
    int bx, by; xcd_swizzle(bx, by);
    scan_body<MODE>(&lds[0][0], bx, by, Ah, Al, Wh, Wl, C, Chi, Clo, ChiT, CloT,
                    Zf, add, bias, CP, M, N, K, alpha);
}

// merged launch: gW2 (MODE3, 4x8 tiles at by<8) || dh (MODE4, 4x2 tiles at by>=8)
__global__ __launch_bounds__(256)
void gemm_scan_pair_k(const u16* __restrict__ rTh, const u16* __restrict__ rTl,
                      const u16* __restrict__ hTh, const u16* __restrict__ hTl,
                      float* __restrict__ gW2,
                      const u16* __restrict__ rh_, const u16* __restrict__ rl_,
                      const u16* __restrict__ w2th, const u16* __restrict__ w2tl,
                      u16* __restrict__ dhTh, u16* __restrict__ dhTl,
                      const float* __restrict__ z1, float* __restrict__ cp1, float cs)
{
    __shared__ u16 lds[2][16384];
    if (blockIdx.y < 8) {
        scan_body<3>(&lds[0][0], blockIdx.x, blockIdx.y, rTh, rTl, hTh, hTl,
                     gW2, nullptr, nullptr, nullptr, nullptr, nullptr, nullptr,
                     nullptr, nullptr, 1024, 512, 256, cs);
    } else {
        scan_body<4>(&lds[0][0], blockIdx.x, blockIdx.y - 8, rh_, rl_, w2th, w2tl,
                     nullptr, nullptr, nullptr, dhTh, dhTl, z1, nullptr,
                     nullptr, cp1, 256, 512, 1024, cs);
    }
}

// ---------------- small kernels ----------------
__global__ void cvt_split_k(const float* __restrict__ in, u16* __restrict__ hi,
                            u16* __restrict__ lo, int n4) {
    int i = blockIdx.x * 256 + threadIdx.x;
    if (i >= n4) return;
    float4 v = *(const float4*)&in[(size_t)i * 4];
    u16 h0,l0,h1,l1,h2,l2,h3,l3;
    split2(v.x,h0,l0); split2(v.y,h1,l1); split2(v.z,h2,l2); split2(v.w,h3,l3);
    ushort4 hv = {h0,h1,h2,h3}, lv = {l0,l1,l2,l3};
    *(ushort4*)&hi[(size_t)i * 4] = hv;
    *(ushort4*)&lo[(size_t)i * 4] = lv;
}
__global__ void transpose_split_k(const float* __restrict__ in, u16* __restrict__ outh,
                                  u16* __restrict__ outl, int R, int C) {
    __shared__ float t[32][33];
    const int c0 = blockIdx.x * 32, r0 = blockIdx.y * 32;
    const size_t zoff = (size_t)blockIdx.z * R * C;
    const int tx = threadIdx.x & 31, ty = threadIdx.x >> 5;
    #pragma unroll
    for (int p = 0; p < 4; ++p) {
        int r = ty + p * 8;
        t[r][tx] = in[zoff + (size_t)(r0 + r) * C + c0 + tx];
    }
    __syncthreads();
    #pragma unroll
    for (int p = 0; p < 4; ++p) {
        int cc = ty + p * 8;
        float v = t[tx][cc];
        u16 h, l; split2(v, h, l);
        size_t o = zoff + (size_t)(c0 + cc) * R + r0 + tx;
        outh[o] = h; outl[o] = l;
    }
}
// momentum update; bias grads from col-partials; maintain W1/W2/W2T split forms
__global__ void update3_k(float* __restrict__ p, float* __restrict__ mo,
                          const float* __restrict__ g,
                          const float* __restrict__ cp1, const float* __restrict__ cp2,
                          u16* __restrict__ w1h, u16* __restrict__ w1l,
                          u16* __restrict__ w2h, u16* __restrict__ w2l,
                          u16* __restrict__ w2th, u16* __restrict__ w2tl, int n) {
    int i = blockIdx.x * 256 + threadIdx.x;
    if (i >= n) return;
    float gi;
    if (i < 524288) gi = g[i];
    else if (i < 524800) {
        int j = i - 524288;
        gi = cp1[j] + cp1[512 + j] + cp1[1024 + j] + cp1[1536 + j];
    } else if (i < 1049088) gi = g[i];
    else {
        int j = i - 1049088;
        gi = cp2[j] + cp2[1024 + j] + cp2[2048 + j] + cp2[3072 + j];
    }
    float m = ETA_C * mo[i] - THETA_C * gi;
    mo[i] = m;
    float pv = (1.f - ALPHA_C) * p[i] + m;
    p[i] = pv;
    if (i < 524288) {
        u16 h, l; split2(pv, h, l); w1h[i] = h; w1l[i] = l;
    } else if (i >= 524800 && i < 1049088) {
        int j = i - 524800;
        u16 h, l; split2(pv, h, l);
        w2h[j] = h; w2l[j] = l;
        int tj = (j & 511) * 1024 + (j >> 9);
        w2th[tj] = h; w2tl[tj] = l;
    }
}
__global__ void extractqkv2_k(const float* __restrict__ qkv, u16* __restrict__ Qh,
                              u16* __restrict__ Ql, float* __restrict__ Kb,
                              float* __restrict__ Vb) {
    size_t idx = (size_t)blockIdx.x * 256 + threadIdx.x;
    int m = (int)(idx / 3072), col = (int)(idx % 3072);
    int b = m >> 10, t = m & 1023;
    float v = qkv[idx];
    if (col < 1024) {
        size_t o = (size_t)m * 1024 + col;
        u16 h, l; split2(v, h, l); Qh[o] = h; Ql[o] = l;
    } else {
        int d = col & 1023;
        int ch = t >> 7, r = t & 127;
        size_t o = ((size_t)((ch * 2 + b) * 128 + r)) * 1024 + d;
        if (col < 2048) Kb[o] = v; else Vb[o] = v;
    }
}
__global__ void tokens_split_k(const float* __restrict__ P, const float* __restrict__ memtok,
                               const float* __restrict__ x, u16* __restrict__ th,
                               u16* __restrict__ tl) {
    size_t idx = (size_t)blockIdx.x * 256 + threadIdx.x;
    int d = (int)(idx & 1023);
    int n = (int)((idx >> 10) % NTOK);
    int b = (int)(idx / ((size_t)NTOK * 1024));
    float v;
    if (n < NPERS)            v = P[(size_t)n * 1024 + d];
    else if (n < NPERS + TSEQ) v = memtok[((size_t)b * TSEQ + (n - NPERS)) * 1024 + d];
    else                      v = x[((size_t)b * TSEQ + (n - NPERS - TSEQ)) * 1024 + d];
    u16 h, l; split2(v, h, l); th[idx] = h; tl[idx] = l;
}
__global__ void mul_k(const float* __restrict__ a, const float* __restrict__ b,
                      float* __restrict__ o, int n) {
    int i = blockIdx.x * 256 + threadIdx.x;
    if (i < n) o[i] = a[i] * b[i];
}

// ---------------- attention prep ----------------
__global__ void prep_q_k(const float* __restrict__ aqkv, u16* __restrict__ Qh,
                         u16* __restrict__ Ql) {
    size_t idx = (size_t)blockIdx.x * 256 + threadIdx.x;
    int d = (int)(idx & 63);
    int row = (int)((idx >> 6) & 1023);
    int h = (int)((idx >> 16) & 15);
    int b = (int)(idx >> 20);
    float v = 0.125f * aqkv[((size_t)b * NTOK + NPERS + TSEQ + row) * 3072 + h * 64 + d];
    u16 hh, ll; split2(v, hh, ll);
    Qh[idx] = hh; Ql[idx] = ll;
}
__global__ void prep_kk_k(const float* __restrict__ aqkv, u16* __restrict__ Kh,
                          u16* __restrict__ Kl) {
    size_t idx = (size_t)blockIdx.x * 256 + threadIdx.x;
    int d = (int)(idx & 63);
    int n = (int)((idx >> 6) % NTOK);
    int t = (int)(idx / (64 * NTOK));
    int h = t & 15, b = t >> 4;
    float v = aqkv[((size_t)b * NTOK + n) * 3072 + 1024 + h * 64 + d];
    u16 hh, ll; split2(v, hh, ll);
    Kh[idx] = hh; Kl[idx] = ll;
}
__global__ void prep_vt_k(const float* __restrict__ aqkv, u16* __restrict__ Vt) {
    __shared__ float t[64][65];
    const int nt = blockIdx.x, h = blockIdx.y, b = blockIdx.z;
    const int j0 = nt * 64;
    const int lx = threadIdx.x & 63, rg = threadIdx.x >> 6;
    #pragma unroll
    for (int p = 0; p < 16; ++p) {
        int r = rg * 16 + p;
        int n = j0 + r;
        t[r][lx] = (n < NTOK) ? aqkv[((size_t)b * NTOK + n) * 3072 + 2048 + h * 64 + lx] : 0.f;
    }
    __syncthreads();
    #pragma unroll
    for (int p = 0; p < 16; ++p) {
        int d = rg * 16 + p;
        int n = j0 + lx;
        if (n < NTOK)
            Vt[((size_t)(b * 16 + h) * 64 + d) * NTOK + n] = f2bf(t[lx][d]);
    }
}

// ---------------- MFMA flash attention: split-KV partial + merge ----------------
// partial: grid 1024 blocks = (qt, h, b, z); single KV buffer, 40KB LDS -> 4 blk/CU.
__global__ __launch_bounds__(256)
void flash_part_k(const u16* __restrict__ Qsh, const u16* __restrict__ Qsl,
                  const u16* __restrict__ Ksh, const u16* __restrict__ Ksl,
                  const u16* __restrict__ Vts, float* __restrict__ Of,
                  float* __restrict__ Mf, float* __restrict__ Lf)
{
    __shared__ u16 lds[20480];             // KH KL VT | PH PL = 40 KB
    u16* KH = lds;            u16* KL = lds + 4096;
    u16* VT = lds + 8192;
    u16* PH = lds + 12288;    u16* PL = lds + 16384;

    // XCD-chunked swizzle over 1024 blocks (8 x 128); consecutive t share (h,b,z)
    int lid = blockIdx.x + (blockIdx.y << 4) + (blockIdx.z << 8);
    int t1024 = ((lid & 7) << 7) | (lid >> 3);
    const int qt = t1024 & 15, h = (t1024 >> 4) & 15;
    const int zb = t1024 >> 8;
    const int b = zb >> 1, z = zb & 1;

    const int tid = threadIdx.x;
    const int lane = tid & 63, wid = tid >> 6;
    const int fr = lane & 15, kq = lane >> 4;
    const int bh = b * 16 + h;
    const int q0c = qt * 64;
    const int q0a = NPERS + TSEQ + q0c;
    const int ntile = ((q0a + 63) >> 6) + 1;
    const int half = ntile >> 1;
    const int jt0 = z ? half : 0;
    const int jt1 = z ? ntile : half;
    const int l8 = lane & 7, lr8 = lane >> 3;

    auto stageKV = [&](int jt) {
        const int j0 = jt * 64;
        #pragma unroll
        for (int jj = 0; jj < 6; ++jj) {
            int j = wid * 6 + jj;
            int buf = j >> 3, i8 = j & 7;
            if (buf < 2) {
                int row = i8 * 8 + lr8;
                int grow = j0 + row; if (grow > NTOK - 1) grow = NTOK - 1;
                int c = l8 ^ (row & 7);
                const u16* src = (buf == 0 ? Ksh : Ksl) +
                                 (((size_t)bh * NTOK + grow) << 6) + c * 8;
                gload_lds16(src, (buf == 0 ? KH : KL) + i8 * 512);
            } else {
                int d = i8 * 8 + lr8;
                int c = l8 ^ (d & 7);
                int col = j0 + c * 8; if (col > NTOK - 8) col = NTOK - 8;
                const u16* src = Vts + ((size_t)bh * 64 + d) * NTOK + col;
                gload_lds16(src, VT + i8 * 512);
            }
        }
    };

    // Q fragments direct from global
    s16x8 qh[2], ql[2];
    {
        const size_t qrow = ((size_t)bh * 1024 + q0c + wid * 16 + fr) << 6;
        #pragma unroll
        for (int kb = 0; kb < 2; ++kb) {
            qh[kb] = *(const s16x8*)&Qsh[qrow + (size_t)(kb * 4 + kq) * 8];
            ql[kb] = *(const s16x8*)&Qsl[qrow + (size_t)(kb * 4 + kq) * 8];
        }
    }

    f32x4 Oa[4] = {};
    float mrow[4], lrow[4];
    #pragma unroll
    for (int r = 0; r < 4; ++r) { mrow[r] = -INFINITY; lrow[r] = 0.f; }

    for (int jt = jt0; jt < jt1; ++jt) {
        const int j0 = jt * 64;
        stageKV(jt);
        __syncthreads();                    // KV landed

        f32x4 sacc[4] = {};
        __builtin_amdgcn_s_setprio(1);
        #pragma unroll
        for (int nt = 0; nt < 4; ++nt) {
            #pragma unroll
            for (int kb = 0; kb < 2; ++kb) {
                int br = nt * 16 + fr;
                int sl = (kb * 4 + kq) ^ (fr & 7);
                s16x8 kh = *(const s16x8*)&KH[br * 64 + sl * 8];
                s16x8 kl = *(const s16x8*)&KL[br * 64 + sl * 8];
                sacc[nt] = __builtin_amdgcn_mfma_f32_16x16x32_bf16(qh[kb], kh, sacc[nt], 0, 0, 0);
                sacc[nt] = __builtin_amdgcn_mfma_f32_16x16x32_bf16(ql[kb], kh, sacc[nt], 0, 0, 0);
                sacc[nt] = __builtin_amdgcn_mfma_f32_16x16x32_bf16(qh[kb], kl, sacc[nt], 0, 0, 0);
            }
        }
        __builtin_amdgcn_s_setprio(0);

        #pragma unroll
        for (int r = 0; r < 4; ++r) {
            const int qloc = kq * 4 + r;
            const int qi = q0a + wid * 16 + qloc;
            float sv[4], tmax = -INFINITY;
            #pragma unroll
            for (int nt = 0; nt < 4; ++nt) {
                int kj = j0 + nt * 16 + fr;
                sv[nt] = (kj <= qi) ? sacc[nt][r] : -INFINITY;
                tmax = fmaxf(tmax, sv[nt]);
            }
            #pragma unroll
            for (int off = 1; off < 16; off <<= 1)
                tmax = fmaxf(tmax, __shfl_xor(tmax, off));
            float mnew = fmaxf(mrow[r], tmax);
            float scale = __expf(mrow[r] - mnew);
            float psum = 0.f;
            float p4[4];
            #pragma unroll
            for (int nt = 0; nt < 4; ++nt) { p4[nt] = __expf(sv[nt] - mnew); psum += p4[nt]; }
            #pragma unroll
            for (int off = 1; off < 16; off <<= 1)
                psum += __shfl_xor(psum, off);
            lrow[r] = lrow[r] * scale + psum;
            mrow[r] = mnew;
            #pragma unroll
            for (int dt = 0; dt < 4; ++dt) Oa[dt][r] *= scale;
            const int prow = wid * 16 + qloc;
            #pragma unroll
            for (int nt = 0; nt < 4; ++nt) {
                u16 ph, pl; split2(p4[nt], ph, pl);
                int col = nt * 16 + fr;
                int sl = (col >> 3) ^ (qloc & 7);
                int off = prow * 64 + sl * 8 + (col & 7);
                PH[off] = ph; PL[off] = pl;
            }
        }

        __builtin_amdgcn_s_setprio(1);
        #pragma unroll
        for (int kb = 0; kb < 2; ++kb) {
            int pr = wid * 16 + fr;
            int sl = (kb * 4 + kq) ^ (fr & 7);
            s16x8 pa = *(const s16x8*)&PH[pr * 64 + sl * 8];
            s16x8 pb = *(const s16x8*)&PL[pr * 64 + sl * 8];
            #pragma unroll
            for (int dt = 0; dt < 4; ++dt) {
                int vr = dt * 16 + fr;
                s16x8 vb = *(const s16x8*)&VT[vr * 64 + sl * 8];
                Oa[dt] = __builtin_amdgcn_mfma_f32_16x16x32_bf16(pa, vb, Oa[dt], 0, 0, 0);
                Oa[dt] = __builtin_amdgcn_mfma_f32_16x16x32_bf16(pb, vb, Oa[dt], 0, 0, 0);
            }
        }
        __builtin_amdgcn_s_setprio(0);
        __syncthreads();                    // compute done before next stage overwrites
    }

    // write unnormalized partial O + (m, l)
    const size_t obase = ((((size_t)z * 2 + b) * 16 + h) * 16 + qt) * 4096;
    const size_t mlb   = ((((size_t)z * 2 + b) * 16 + h) * 16 + qt) * 64;
    #pragma unroll
    for (int r = 0; r < 4; ++r) {
        int rl = wid * 16 + kq * 4 + r;
        if (fr == 0) { Mf[mlb + rl] = mrow[r]; Lf[mlb + rl] = lrow[r]; }
        #pragma unroll
        for (int dt = 0; dt < 4; ++dt)
            Of[obase + (size_t)rl * 64 + dt * 16 + fr] = Oa[dt][r];
    }
}

// merge: O = (O0 e0 + O1 e1) / (l0 e0 + l1 e1), e_z = exp(m_z - max)
__global__ __launch_bounds__(256)
void flash_merge_k(const float* __restrict__ Of, const float* __restrict__ Mf,
                   const float* __restrict__ Lf, u16* __restrict__ oh, u16* __restrict__ ol)
{
    const int qt = blockIdx.x, h = blockIdx.y, b = blockIdx.z;
    const int tid = threadIdx.x;
    const int row = tid >> 2, quad = tid & 3;
    const size_t b0 = ((((size_t)0 * 2 + b) * 16 + h) * 16 + qt) * 4096 + (size_t)row * 64;
    const size_t b1 = ((((size_t)1 * 2 + b) * 16 + h) * 16 + qt) * 4096 + (size_t)row * 64;
    const size_t m0i = ((((size_t)0 * 2 + b) * 16 + h) * 16 + qt) * 64 + row;
    const size_t m1i = ((((size_t)1 * 2 + b) * 16 + h) * 16 + qt) * 64 + row;
    float m0 = Mf[m0i], m1 = Mf[m1i], l0 = Lf[m0i], l1 = Lf[m1i];
    float m = fmaxf(m0, m1);
    float e0 = __expf(m0 - m), e1 = __expf(m1 - m);
    float inv = 1.f / (l0 * e0 + l1 * e1);
    const size_t orow = ((size_t)(b * 1024 + qt * 64 + row)) * 1024 + h * 64;
    #pragma unroll
    for (int i = 0; i < 4; ++i) {
        int col = quad * 16 + i * 4;
        float4 v0 = *(const float4*)&Of[b0 + col];
        float4 v1 = *(const float4*)&Of[b1 + col];
        float o0 = (v0.x * e0 + v1.x * e1) * inv;
        float o1 = (v0.y * e0 + v1.y * e1) * inv;
        float o2 = (v0.z * e0 + v1.z * e1) * inv;
        float o3 = (v0.w * e0 + v1.w * e1) * inv;
        u16 h0,l0_,h1,l1_,h2,l2_,h3,l3_;
        split2(o0,h0,l0_); split2(o1,h1,l1_); split2(o2,h2,l2_); split2(o3,h3,l3_);
        ushort4 hv = {h0,h1,h2,h3}, lv = {l0_,l1_,l2_,l3_};
        *(ushort4*)&oh[orow + col] = hv;
        *(ushort4*)&ol[orow + col] = lv;
    }
}

// ---------------- launch ----------------
extern "C" void kernel_launch(void* const* d_in, const int* in_sizes, int n_in,
                              void* d_out, int out_size, void* d_ws, size_t ws_size,
                              hipStream_t stream)
{
    const float* x     = (const float*)d_in[0];
    const float* Wqkv  = (const float*)d_in[1];
    const float* mW1   = (const float*)d_in[2];
    const float* mb1   = (const float*)d_in[3];
    const float* mW2   = (const float*)d_in[4];
    const float* mb2   = (const float*)d_in[5];
    const float* Pp    = (const float*)d_in[6];
    const float* Wqa   = (const float*)d_in[7];
    const float* Wo    = (const float*)d_in[8];
    const float* ffW1  = (const float*)d_in[9];
    const float* ffb1  = (const float*)d_in[10];
    const float* ffW2  = (const float*)d_in[11];
    const float* ffb2  = (const float*)d_in[12];
    char* wsb = (char*)d_ws;
    float* outp = (float*)d_out;

    // region A (multiplexed)
    float* qkv   = (float*)(wsb + oRA);
    float* z1    = (float*)(wsb + oRA);
    float* grd   = (float*)(wsb + oRA + 3145728);
    float* cp2   = (float*)(wsb + oRA + 7346176);
    float* cp1   = (float*)(wsb + oRA + 7362560);
    u16* hh_     = (u16*)(wsb + oRA + 8388608);
    u16* hl_     = (u16*)(wsb + oRA + 8650752);
    u16* hTh     = (u16*)(wsb + oRA + 9437184);
    u16* hTl     = (u16*)(wsb + oRA + 9699328);
    u16* rh_     = (u16*)(wsb + oRA + 10485760);
    u16* rl_     = (u16*)(wsb + oRA + 11010048);
    u16* rTh     = (u16*)(wsb + oRA + 11534336);
    u16* rTl     = (u16*)(wsb + oRA + 12058624);
    u16* dhTh    = (u16*)(wsb + oRA + 12582912);
    u16* dhTl    = (u16*)(wsb + oRA + 12845056);
    u16* kcTh    = (u16*)(wsb + oRA + 16777216);
    u16* kcTl    = (u16*)(wsb + oRA + 20971520);
    float* aqkv  = (float*)(wsb + oRA);
    float* Of    = (float*)(wsb + oRA);                  // flash partials 33.5 MB
    float* Mf    = (float*)(wsb + oRA + 33554432);
    float* Lf    = (float*)(wsb + oRA + 34078720);
    u16* Woh     = (u16*)(wsb + oRA);
    u16* Wol     = (u16*)(wsb + oRA + 2097152);
    u16* ffhh    = (u16*)(wsb + oRA);
    u16* ffhl    = (u16*)(wsb + oRA + 16777216);
    u16* outbh   = (u16*)(wsb + oRA + 33554432);
    u16* outbl   = (u16*)(wsb + oRA + 37748736);
    u16* newQh   = (u16*)(wsb + oRA);
    u16* newQl   = (u16*)(wsb + oRA + 4194304);
    u16* hzh     = (u16*)(wsb + oRA + 8388608);
    u16* hzl     = (u16*)(wsb + oRA + 10485760);
    float* memq  = (float*)(wsb + oRA + 12582912);
    float* partA0 = (float*)(wsb + oRA);
    float* partA1 = (float*)(wsb + oRA + 4194304);
    float* partA2 = (float*)(wsb + oRA + 16777216);
    // region B
    float* Kb    = (float*)(wsb + oRB);
    float* Vb    = (float*)(wsb + oRB + 8388608);
    u16* tokh    = (u16*)(wsb + oRB);
    u16* tokl    = (u16*)(wsb + oRB + 8454144);
    u16* oh      = (u16*)(wsb + oRB);
    u16* ol      = (u16*)(wsb + oRB + 4194304);
    u16* fVth    = (u16*)(wsb + oRB + 8388608);
    u16* y1h     = (u16*)(wsb + oRB + 8388608);
    u16* y1l     = (u16*)(wsb + oRB + 12582912);
    float* partB = (float*)(wsb + oRB);
    // region C
    u16* xh      = (u16*)(wsb + oRC);
    u16* xl      = (u16*)(wsb + oRC + 4194304);
    float* mom   = (float*)(wsb + oRC);
    u16* pW2Th   = (u16*)(wsb + oRC + 5242880);
    u16* pW2Tl   = (u16*)(wsb + oRC + 6291456);
    u16* Wqah    = (u16*)(wsb + oRC);
    u16* Wqal    = (u16*)(wsb + oRC + 6291456);
    u16* fKl     = (u16*)(wsb + oRC);
    // region D
    u16* Qh      = (u16*)(wsb + oRD);
    u16* Ql      = (u16*)(wsb + oRD + 4194304);
    u16* kchh    = (u16*)(wsb + oRD + 8388608);
    u16* kchl    = (u16*)(wsb + oRD + 12582912);
    u16* t1h     = (u16*)(wsb + oRD + 8388608);
    u16* t1l     = (u16*)(wsb + oRD + 10485760);
    float* memtok= (float*)(wsb + oRD);
    u16* fKh     = (u16*)(wsb + oRD);
    u16* ffW1h   = (u16*)(wsb + oRD);
    u16* ffW1l   = (u16*)(wsb + oRD + 8388608);
    u16* ffW2h   = (u16*)(wsb + oRD);
    u16* ffW2l   = (u16*)(wsb + oRD + 8388608);
    // persistent
    u16* Wqkvh   = (u16*)(wsb + oRE);
    u16* Wqkvl   = (u16*)(wsb + oRE + 6291456);
    u16* pW1h    = (u16*)(wsb + oRF);
    u16* pW1l    = (u16*)(wsb + oRF + 1048576);
    u16* pW2h    = (u16*)(wsb + oRF + 2097152);
    u16* pW2l    = (u16*)(wsb + oRF + 3145728);
    float* par   = (float*)(wsb + oRG);
    float* outb  = (float*)(wsb + oRH);
    u16* fQh     = (u16*)(wsb + oRH);
    u16* fQl     = (u16*)(wsb + oRH + 4194304);

    // init memory-MLP params
    hipMemcpyAsync(par + PW1, mW1, 524288 * sizeof(float), hipMemcpyDeviceToDevice, stream);
    hipMemcpyAsync(par + PB1, mb1, 512 * sizeof(float), hipMemcpyDeviceToDevice, stream);
    hipMemcpyAsync(par + PW2, mW2, 524288 * sizeof(float), hipMemcpyDeviceToDevice, stream);
    hipMemcpyAsync(par + PB2, mb2, 1024 * sizeof(float), hipMemcpyDeviceToDevice, stream);

    // qkv = x @ Wqkv^T
    cvt_split_k<<<2048, 256, 0, stream>>>(x, xh, xl, 524288);
    cvt_split_k<<<3072, 256, 0, stream>>>(Wqkv, Wqkvh, Wqkvl, 786432);
    gemm_mfma(stream, 0, 1, 0, xh, xl, Wqkvh, Wqkvl, qkv, nullptr, nullptr, 2048, 3072, 1024, nullptr);
    extractqkv2_k<<<24576, 256, 0, stream>>>(qkv, Qh, Ql, Kb, Vb);

    // scan prep
    hipMemsetAsync(mom, 0, PSZ * sizeof(float), stream);
    cvt_split_k<<<2048, 256, 0, stream>>>(Kb, kchh, kchl, 524288);
    transpose_split_k<<<dim3(32, 8, 8), 256, 0, stream>>>(Kb, kcTh, kcTl, 256, 1024);
    cvt_split_k<<<512, 256, 0, stream>>>(par + PW1, pW1h, pW1l, 131072);
    cvt_split_k<<<512, 256, 0, stream>>>(par + PW2, pW2h, pW2l, 131072);
    transpose_split_k<<<dim3(16, 32, 1), 256, 0, stream>>>(par + PW2, pW2Th, pW2Tl, 1024, 512);

    // memory scan: z1 -> r -> {gW2 || dh} -> gW1 -> update
    const float cs = 2.f / (float)(BATCH * 128 * DIMD);
    for (int c = 0; c < NCH; ++c) {
        const u16* kch = kchh + (size_t)c * 262144;
        const u16* kcl = kchl + (size_t)c * 262144;
        const u16* kth = kcTh + (size_t)c * 262144;
        const u16* ktl = kcTl + (size_t)c * 262144;
        const float* vc = Vb + (size_t)c * 262144;
        gemm_scan_k<1><<<dim3(4, 2), 256, 0, stream>>>(kch, kcl, pW1h, pW1l,
            z1, hh_, hl_, hTh, hTl, nullptr, nullptr, par + PB1, nullptr, 256, 512, 1024, 1.f);
        gemm_scan_k<2><<<dim3(8, 2), 256, 0, stream>>>(hh_, hl_, pW2h, pW2l,
            nullptr, rh_, rl_, rTh, rTl, nullptr, vc, par + PB2, cp2, 256, 1024, 512, cs);
        gemm_scan_pair_k<<<dim3(4, 10), 256, 0, stream>>>(rTh, rTl, hTh, hTl, grd + PW2,
            rh_, rl_, pW2Th, pW2Tl, dhTh, dhTl, z1, cp1, cs);
        gemm_scan_k<3><<<dim3(8, 4), 256, 0, stream>>>(dhTh, dhTl, kth, ktl,
            grd + PW1, nullptr, nullptr, nullptr, nullptr, nullptr, nullptr, nullptr, nullptr,
            512, 1024, 256, 1.f);
        update3_k<<<4102, 256, 0, stream>>>(par, mom, grd, cp1, cp2,
            pW1h, pW1l, pW2h, pW2l, pW2Th, pW2Tl, (int)PSZ);
    }

    // memory readout (split-K: t1 S=4 part@A2, memtok S=2 part@A0)
    gemm_mfma_sk(stream, 1, 0, 1, Qh, Ql, pW1h, pW1l, nullptr, t1h, t1l,
                 2048, 512, 1024, par + PB1, 4, partA2);
    gemm_mfma_sk(stream, 0, 1, 0, t1h, t1l, pW2h, pW2l, memtok, nullptr, nullptr,
                 2048, 1024, 512, par + PB2, 2, partA0);

    // tokens + attention qkv
    tokens_split_k<<<16512, 256, 0, stream>>>(Pp, memtok, x, tokh, tokl);
    cvt_split_k<<<3072, 256, 0, stream>>>(Wqa, Wqah, Wqal, 786432);
    gemm_mfma(stream, 0, 1, 0, tokh, tokl, Wqah, Wqal, aqkv, nullptr, nullptr, 4128, 3072, 1024, nullptr);

    // attention prep
    prep_q_k<<<8192, 256, 0, stream>>>(aqkv, fQh, fQl);
    prep_kk_k<<<16512, 256, 0, stream>>>(aqkv, fKh, fKl);
    prep_vt_k<<<dim3(33, 16, 2), 256, 0, stream>>>(aqkv, fVth);

    // MFMA flash attention: split-KV partials + merge
    flash_part_k<<<dim3(16, 16, 4), 256, 0, stream>>>(fQh, fQl, fKh, fKl, fVth, Of, Mf, Lf);
    flash_merge_k<<<dim3(16, 16, 2), 256, 0, stream>>>(Of, Mf, Lf, oh, ol);

    // Wo projection + FFN (split-K on grid-starved GEMMs)
    cvt_split_k<<<1024, 256, 0, stream>>>(Wo, Woh, Wol, 262144);
    gemm_mfma_sk(stream, 0, 0, 1, oh, ol, Woh, Wol, nullptr, y1h, y1l,
                 2048, 1024, 1024, nullptr, 2, partA1);
    cvt_split_k<<<4096, 256, 0, stream>>>(ffW1, ffW1h, ffW1l, 1048576);
    gemm_mfma(stream, 2, 0, 1, y1h, y1l, ffW1h, ffW1l, nullptr, ffhh, ffhl, 2048, 4096, 1024, ffb1);
    cvt_split_k<<<4096, 256, 0, stream>>>(ffW2, ffW2h, ffW2l, 1048576);
    gemm_mfma_sk(stream, 0, 1, 1, ffhh, ffhl, ffW2h, ffW2l, outb, outbh, outbl,
                 2048, 1024, 4096, ffb2, 2, partB);

    // gate
    gemm_mfma_sk(stream, 0, 0, 1, outbh, outbl, Wqkvh, Wqkvl, nullptr, newQh, newQl,
                 2048, 1024, 1024, nullptr, 2, partB);
    gemm_mfma_sk(stream, 1, 0, 1, newQh, newQl, pW1h, pW1l, nullptr, hzh, hzl,
                 2048, 512, 1024, par + PB1, 4, partB);
    gemm_mfma_sk(stream, 0, 1, 0, hzh, hzl, pW2h, pW2l, memq, nullptr, nullptr,
                 2048, 1024, 512, par + PB2, 2, partB);
    mul_k<<<8192, 256, 0, stream>>>(outb, memq, outp, 2097152);
}

// Round 12
// 1427.318 us; speedup vs baseline: 1.1741x; 1.0299x over previous
//
#include <hip/hip_runtime.h>
#include <math.h>

// ---------------- problem constants ----------------
#define BATCH 2
#define TSEQ 1024
#define DIMD 1024
#define NPERS 16
#define NCH 8
#define NTOK 2064
#define ETA_C 0.9f
#define THETA_C 0.1f
#define ALPHA_C 0.02f

typedef __attribute__((ext_vector_type(4))) float f32x4;
typedef __attribute__((ext_vector_type(8))) short s16x8;
typedef unsigned short u16;

// ---------------- bf16 helpers ----------------
__device__ __forceinline__ u16 f2bf(float f) {
    unsigned int u = __float_as_uint(f);
    return (u16)((u + 0x7fffu + ((u >> 16) & 1u)) >> 16);
}
__device__ __forceinline__ float bf2f(u16 h) { return __uint_as_float(((unsigned)h) << 16); }
__device__ __forceinline__ void split2(float v, u16& h, u16& l) {
    h = f2bf(v); l = f2bf(v - bf2f(h));
}

// ---------------- workspace layout (byte offsets) ----------------
static const size_t oRA = 0;                       // 50,724,864 multiplexed
static const size_t oRB = 50724864;                // 16,908,288
static const size_t oRC = 67633152;                // 12,582,912
static const size_t oRD = 80216064;                // 16,777,216
static const size_t oRE = 96993280;                // 12,582,912 Wqkv h/l (persistent)
static const size_t oRF = 109576192;               //  4,194,304 parW h/l (persistent)
static const size_t oRG = 113770496;               //  4,200,448 par (persistent)
static const size_t oRH = 117970944;               //  8,388,608 outb f32 (Qs split during attn)
// total 126,359,552 bytes

static const size_t PW1 = 0, PB1 = 524288, PW2 = 524800, PB2 = 1049088, PSZ = 1050112;

// ---------------- async global->LDS ----------------
__device__ __forceinline__ void gload_lds16(const u16* g, u16* l) {
    __builtin_amdgcn_global_load_lds(
        (const __attribute__((address_space(1))) unsigned int*)g,
        (__attribute__((address_space(3))) unsigned int*)l, 16, 0, 0);
}

// XCD-chunked block swizzle (bijective when nwg % 8 == 0; identity fallback).
__device__ __forceinline__ void xcd_swizzle(int& bx, int& by) {
    int gx = gridDim.x, nwg = gx * gridDim.y;
    int lid = blockIdx.y * gx + blockIdx.x;
    int t = lid;
    if ((nwg & 7) == 0) {
        int q = nwg >> 3;
        t = (lid & 7) * q + (lid >> 3);
    }
    bx = t % gx; by = t / gx;
}

// stage one 128x32 bf16 tile (this wave's quarter) into buf + wid*4096
__device__ __forceinline__ void stage_tile(const u16* sp, u16* buf, int rbase,
                                           int M, int clampM, int K, int k0,
                                           int wid, int lane) {
    const int lr = lane >> 2, lc = lane & 3;
    #pragma unroll
    for (int i = 0; i < 8; ++i) {
        int r = i * 16 + lr;
        int gr = rbase + r;
        if (clampM && gr >= M) gr = M - 1;
        int g = lc ^ ((r >> 1) & 3);
        gload_lds16(sp + (size_t)gr * K + k0 + g * 8, buf + wid * 4096 + i * 512);
    }
}

// stage one 128x64 bf16 tile into buf + wid*8192 (scan path, BK=64)
__device__ __forceinline__ void stage_tile64(const u16* sp, u16* buf, int rbase,
                                             int K, int k0, int wid, int lane) {
    const int lr = lane >> 3, lc = lane & 7;
    #pragma unroll
    for (int i = 0; i < 16; ++i) {
        int r = i * 8 + lr;
        int gr = rbase + r;
        int g = lc ^ (r & 7);                          // swizzled source chunk
        gload_lds16(sp + (size_t)gr * K + k0 + g * 8, buf + wid * 8192 + i * 512);
    }
}

// ---------------- split-bf16 MFMA GEMM:  C = act(A @ W^T + bias) ----------------
// Double-buffered K-loop, ONE barrier per K-step.  PARTIAL: gridDim.z = S K-slices.
template<int ACTF, int WF32, int WSPLIT, int PARTIAL>
__global__ __launch_bounds__(256)
void gemm_mfma_k(const u16* __restrict__ Ah, const u16* __restrict__ Al,
                 const u16* __restrict__ Wh, const u16* __restrict__ Wl,
                 float* __restrict__ C, u16* __restrict__ Chi, u16* __restrict__ Clo,
                 int M, int N, int K, const float* __restrict__ bias)
{
    __shared__ u16 lds[2][16384];
    const int tid = threadIdx.x;
    const int lane = tid & 63, wid = tid >> 6;
    const int wm = wid >> 1, wn = wid & 1;
    int bx, by; xcd_swizzle(bx, by);
    const int row0 = by * 128, col0 = bx * 128;

    const u16* sp = (wid == 0) ? Ah : (wid == 1) ? Al : (wid == 2) ? Wh : Wl;
    const int rbase = (wid < 2) ? row0 : col0;
    const int clampM = (wid < 2) ? 1 : 0;

    f32x4 acc[4][4] = {};
    const int frow = lane & 15, kblk = lane >> 4;

    int kbeg = 0, kend = K;
    if (PARTIAL) {
        int Kseg = K / gridDim.z;
        kbeg = blockIdx.z * Kseg;
        kend = kbeg + Kseg;
    }
    const int nt = (kend - kbeg) >> 5;

    stage_tile(sp, lds[0], rbase, M, clampM, K, kbeg, wid, lane);

    for (int t = 0; t < nt; ++t) {
        __syncthreads();
        if (t + 1 < nt)
            stage_tile(sp, lds[(t + 1) & 1], rbase, M, clampM, K, kbeg + ((t + 1) << 5), wid, lane);
        const u16* cb = lds[t & 1];

        s16x8 bh[4], bl[4];
        #pragma unroll
        for (int ni = 0; ni < 4; ++ni) {
            int br = wn * 64 + ni * 16 + frow;
            int pc = kblk ^ ((br >> 1) & 3);
            bh[ni] = *(const s16x8*)&cb[2 * 4096 + br * 32 + pc * 8];
            bl[ni] = *(const s16x8*)&cb[3 * 4096 + br * 32 + pc * 8];
        }
        #pragma unroll
        for (int mi = 0; mi < 4; ++mi) {
            int ar = wm * 64 + mi * 16 + frow;
            int pc = kblk ^ ((ar >> 1) & 3);
            s16x8 ah = *(const s16x8*)&cb[0 * 4096 + ar * 32 + pc * 8];
            s16x8 al = *(const s16x8*)&cb[1 * 4096 + ar * 32 + pc * 8];
            #pragma unroll
            for (int ni = 0; ni < 4; ++ni) {
                acc[mi][ni] = __builtin_amdgcn_mfma_f32_16x16x32_bf16(ah, bh[ni], acc[mi][ni], 0, 0, 0);
                acc[mi][ni] = __builtin_amdgcn_mfma_f32_16x16x32_bf16(ah, bl[ni], acc[mi][ni], 0, 0, 0);
                acc[mi][ni] = __builtin_amdgcn_mfma_f32_16x16x32_bf16(al, bh[ni], acc[mi][ni], 0, 0, 0);
            }
        }
    }

    const int erow = (lane >> 4) * 4, ecol = lane & 15;
    #pragma unroll
    for (int mi = 0; mi < 4; ++mi) {
        #pragma unroll
        for (int ni = 0; ni < 4; ++ni) {
            int c = col0 + wn * 64 + ni * 16 + ecol;
            float bv = (!PARTIAL && bias) ? bias[c] : 0.f;
            #pragma unroll
            for (int reg = 0; reg < 4; ++reg) {
                int r = row0 + wm * 64 + mi * 16 + erow + reg;
                if (r >= M) continue;
                float v = acc[mi][ni][reg] + bv;
                if (PARTIAL) {
                    C[((size_t)blockIdx.z * M + r) * N + c] = v;
                    continue;
                }
                if (ACTF == 1) v = v / (1.f + __expf(-v));
                else if (ACTF == 2) {
                    float u = 0.7978845608028654f * (v + 0.044715f * v * v * v);
                    v = 0.5f * v * (1.f + tanhf(u));
                }
                size_t o = (size_t)r * N + c;
                if (WF32) C[o] = v;
                if (WSPLIT) { u16 h, l; split2(v, h, l); Chi[o] = h; Clo[o] = l; }
            }
        }
    }
}

// split-K reduce + epilogue
template<int ACTF, int WF32, int WSPLIT>
__global__ __launch_bounds__(256)
void reduce_k(const float* __restrict__ Cp, int S,
              float* __restrict__ C, u16* __restrict__ Chi, u16* __restrict__ Clo,
              const float* __restrict__ bias, int M, int N)
{
    int i = blockIdx.x * 256 + threadIdx.x;
    int n4 = (int)((size_t)M * N / 4);
    if (i >= n4) return;
    size_t off = (size_t)i * 4;
    float4 v = *(const float4*)&Cp[off];
    for (int z = 1; z < S; ++z) {
        float4 u = *(const float4*)&Cp[(size_t)z * M * N + off];
        v.x += u.x; v.y += u.y; v.z += u.z; v.w += u.w;
    }
    int c = (int)(off % N);
    float vv[4] = {v.x, v.y, v.z, v.w};
    #pragma unroll
    for (int j = 0; j < 4; ++j) {
        float w = vv[j];
        if (bias) w += bias[c + j];
        if (ACTF == 1) w = w / (1.f + __expf(-w));
        else if (ACTF == 2) {
            float u = 0.7978845608028654f * (w + 0.044715f * w * w * w);
            w = 0.5f * w * (1.f + tanhf(u));
        }
        if (WF32) C[off + j] = w;
        if (WSPLIT) { u16 h, l; split2(w, h, l); Chi[off + j] = h; Clo[off + j] = l; }
    }
}

static void gemm_mfma(hipStream_t s, int act, int wf32, int wsplit,
                      const u16* Ah, const u16* Al, const u16* Wh, const u16* Wl,
                      float* C, u16* Ch, u16* Cl, int M, int N, int K, const float* bias)
{
    dim3 g(N / 128, (M + 127) / 128), b(256);
    if (act == 0 && wf32 == 1 && wsplit == 0)
        gemm_mfma_k<0,1,0,0><<<g,b,0,s>>>(Ah,Al,Wh,Wl,C,Ch,Cl,M,N,K,bias);
    else if (act == 0 && wf32 == 1 && wsplit == 1)
        gemm_mfma_k<0,1,1,0><<<g,b,0,s>>>(Ah,Al,Wh,Wl,C,Ch,Cl,M,N,K,bias);
    else if (act == 0 && wf32 == 0 && wsplit == 1)
        gemm_mfma_k<0,0,1,0><<<g,b,0,s>>>(Ah,Al,Wh,Wl,C,Ch,Cl,M,N,K,bias);
    else if (act == 1)
        gemm_mfma_k<1,0,1,0><<<g,b,0,s>>>(Ah,Al,Wh,Wl,C,Ch,Cl,M,N,K,bias);
    else
        gemm_mfma_k<2,0,1,0><<<g,b,0,s>>>(Ah,Al,Wh,Wl,C,Ch,Cl,M,N,K,bias);
}

static void gemm_mfma_sk(hipStream_t s, int act, int wf32, int wsplit,
                         const u16* Ah, const u16* Al, const u16* Wh, const u16* Wl,
                         float* C, u16* Ch, u16* Cl, int M, int N, int K,
                         const float* bias, int S, float* part)
{
    if (S <= 1) { gemm_mfma(s, act, wf32, wsplit, Ah, Al, Wh, Wl, C, Ch, Cl, M, N, K, bias); return; }
    dim3 g(N / 128, (M + 127) / 128, S), b(256);
    gemm_mfma_k<0,0,0,1><<<g,b,0,s>>>(Ah,Al,Wh,Wl,part,nullptr,nullptr,M,N,K,nullptr);
    int n4 = (int)((size_t)M * N / 4);
    dim3 rg((n4 + 255) / 256), rb(256);
    if (act == 0 && wf32 == 1 && wsplit == 0)
        reduce_k<0,1,0><<<rg,rb,0,s>>>(part, S, C, Ch, Cl, bias, M, N);
    else if (act == 0 && wf32 == 1 && wsplit == 1)
        reduce_k<0,1,1><<<rg,rb,0,s>>>(part, S, C, Ch, Cl, bias, M, N);
    else if (act == 0 && wf32 == 0 && wsplit == 1)
        reduce_k<0,0,1><<<rg,rb,0,s>>>(part, S, C, Ch, Cl, bias, M, N);
    else if (act == 1)
        reduce_k<1,0,1><<<rg,rb,0,s>>>(part, S, C, Ch, Cl, bias, M, N);
    else
        reduce_k<2,0,1><<<rg,rb,0,s>>>(part, S, C, Ch, Cl, bias, M, N);
}

// ---------------- scan-specialized split-bf16 MFMA GEMM body (BK=64 dbuf) -------
// MODE 1: z1 = A@B^T + bias (f32); h = silu(z1) -> split + splitT
// MODE 2: r = A@B^T + bias - add; split + splitT; col-partials CP (x alpha)
// MODE 3: C = alpha * A@B^T (f32)
// MODE 4: dh = alpha*(A@B^T)*dsilu(Z); splitT; col-partials CP
// lds: 2 buffers of 32768 u16 (4 tiles x [128][64]); K % 64 == 0; M,N % 128 == 0.
template<int MODE>
__device__ __forceinline__ void scan_body(u16* lds, int bx, int by,
                 const u16* __restrict__ Ah, const u16* __restrict__ Al,
                 const u16* __restrict__ Wh, const u16* __restrict__ Wl,
                 float* __restrict__ C, u16* __restrict__ Chi, u16* __restrict__ Clo,
                 u16* __restrict__ ChiT, u16* __restrict__ CloT,
                 const float* __restrict__ Zf, const float* __restrict__ add,
                 const float* __restrict__ bias, float* __restrict__ CP,
                 int M, int N, int K, float alpha)
{
    const int tid = threadIdx.x;
    const int lane = tid & 63, wid = tid >> 6;
    const int wm = wid >> 1, wn = wid & 1;
    const int row0 = by * 128, col0 = bx * 128;

    const u16* sp = (wid == 0) ? Ah : (wid == 1) ? Al : (wid == 2) ? Wh : Wl;
    const int rbase = (wid < 2) ? row0 : col0;

    f32x4 acc[4][4] = {};
    const int frow = lane & 15, kblk = lane >> 4;
    const int nt = K >> 6;

    stage_tile64(sp, lds, rbase, K, 0, wid, lane);

    for (int t = 0; t < nt; ++t) {
        __syncthreads();
        if (t + 1 < nt)
            stage_tile64(sp, lds + (((t + 1) & 1) << 15), rbase, K, (t + 1) << 6, wid, lane);
        const u16* cb = lds + ((t & 1) << 15);

        #pragma unroll
        for (int s = 0; s < 2; ++s) {
            s16x8 bh[4], bl[4];
            #pragma unroll
            for (int ni = 0; ni < 4; ++ni) {
                int br = wn * 64 + ni * 16 + frow;
                int pc = (s * 4 + kblk) ^ (br & 7);
                bh[ni] = *(const s16x8*)&cb[2 * 8192 + br * 64 + pc * 8];
                bl[ni] = *(const s16x8*)&cb[3 * 8192 + br * 64 + pc * 8];
            }
            #pragma unroll
            for (int mi = 0; mi < 4; ++mi) {
                int ar = wm * 64 + mi * 16 + frow;
                int pc = (s * 4 + kblk) ^ (ar & 7);
                s16x8 ah = *(const s16x8*)&cb[0 * 8192 + ar * 64 + pc * 8];
                s16x8 al = *(const s16x8*)&cb[1 * 8192 + ar * 64 + pc * 8];
                #pragma unroll
                for (int ni = 0; ni < 4; ++ni) {
                    acc[mi][ni] = __builtin_amdgcn_mfma_f32_16x16x32_bf16(ah, bh[ni], acc[mi][ni], 0, 0, 0);
                    acc[mi][ni] = __builtin_amdgcn_mfma_f32_16x16x32_bf16(ah, bl[ni], acc[mi][ni], 0, 0, 0);
                    acc[mi][ni] = __builtin_amdgcn_mfma_f32_16x16x32_bf16(al, bh[ni], acc[mi][ni], 0, 0, 0);
                }
            }
        }
    }

    const int erow = (lane >> 4) * 4, ecol = lane & 15;
    float csum[4] = {0.f, 0.f, 0.f, 0.f};
    #pragma unroll
    for (int mi = 0; mi < 4; ++mi) {
        #pragma unroll
        for (int ni = 0; ni < 4; ++ni) {
            int c = col0 + wn * 64 + ni * 16 + ecol;
            #pragma unroll
            for (int reg = 0; reg < 4; ++reg) {
                int r = row0 + wm * 64 + mi * 16 + erow + reg;
                float v = acc[mi][ni][reg];
                size_t o = (size_t)r * N + c;
                if (MODE == 1) {
                    v += bias[c];
                    C[o] = v;
                    float hv = v / (1.f + __expf(-v));
                    u16 h, l; split2(hv, h, l);
                    Chi[o] = h; Clo[o] = l;
                    size_t ot = (size_t)c * M + r;
                    ChiT[ot] = h; CloT[ot] = l;
                } else if (MODE == 2) {
                    v += bias[c] - add[o];
                    u16 h, l; split2(v, h, l);
                    Chi[o] = h; Clo[o] = l;
                    size_t ot = (size_t)c * M + r;
                    ChiT[ot] = h; CloT[ot] = l;
                    csum[ni] += v;
                } else if (MODE == 3) {
                    C[o] = alpha * v;
                } else {
                    v *= alpha;
                    float z = Zf[o];
                    float sg = 1.f / (1.f + __expf(-z));
                    v *= sg * (1.f + z * (1.f - sg));
                    u16 h, l; split2(v, h, l);
                    size_t ot = (size_t)c * M + r;
                    ChiT[ot] = h; CloT[ot] = l;
                    csum[ni] += v;
                }
            }
        }
    }
    if (MODE == 2 || MODE == 4) {
        #pragma unroll
        for (int ni = 0; ni < 4; ++ni) {
            float s = csum[ni];
            s += __shfl_xor(s, 16);
            s += __shfl_xor(s, 32);
            if ((lane >> 4) == 0) {
                int c = col0 + wn * 64 + ni * 16 + ecol;
                float w = (MODE == 2) ? alpha * s : s;
                CP[(size_t)(by * 2 + wm) * N + c] = w;
            }
        }
    }
}

template<int MODE>
__global__ __launch_bounds__(256)
void gemm_scan_k(const u16* __restrict__ Ah, const u16* __restrict__ Al,
                 const u16* __restrict__ Wh, const u16* __restrict__ Wl,
                 float* __restrict__ C, u16* __restrict__ Chi, u16* __restrict__ Clo,
                 u16* __restrict__ ChiT, u16* __restrict__ CloT,
                 const float* __restrict__ Zf, const float* __restrict__ add,
                 const float* __restrict__ bias, float* __restrict__ CP,
                 int M, int N, int K, float alpha)
{
    __shared__ u16 lds[2][32768];
    int bx, by; xcd_swizzle(bx, by);
    scan_body<MODE>(&lds[0][0], bx, by, Ah, Al, Wh, Wl, C, Chi, Clo, ChiT, CloT,
                    Zf, add, bias, CP, M, N, K, alpha);
}

// merged launch: gW2 (MODE3, 4x8 tiles at by<8) || dh (MODE4, 4x2 tiles at by>=8)
__global__ __launch_bounds__(256)
void gemm_scan_pair_k(const u16* __restrict__ rTh, const u16* __restrict__ rTl,
                      const u16* __restrict__ hTh, const u16* __restrict__ hTl,
                      float* __restrict__ gW2,
                      const u16* __restrict__ rh_, const u16* __restrict__ rl_,
                      const u16* __restrict__ w2th, const u16* __restrict__ w2tl,
                      u16* __restrict__ dhTh, u16* __restrict__ dhTl,
                      const float* __restrict__ z1, float* __restrict__ cp1, float cs)
{
    __shared__ u16 lds[2][32768];
    if (blockIdx.y < 8) {
        scan_body<3>(&lds[0][0], blockIdx.x, blockIdx.y, rTh, rTl, hTh, hTl,
                     gW2, nullptr, nullptr, nullptr, nullptr, nullptr, nullptr,
                     nullptr, nullptr, 1024, 512, 256, cs);
    } else {
        scan_body<4>(&lds[0][0], blockIdx.x, blockIdx.y - 8, rh_, rl_, w2th, w2tl,
                     nullptr, nullptr, nullptr, dhTh, dhTl, z1, nullptr,
                     nullptr, cp1, 256, 512, 1024, cs);
    }
}

// ---------------- small kernels ----------------
__global__ void cvt_split_k(const float* __restrict__ in, u16* __restrict__ hi,
                            u16* __restrict__ lo, int n4) {
    int i = blockIdx.x * 256 + threadIdx.x;
    if (i >= n4) return;
    float4 v = *(const float4*)&in[(size_t)i * 4];
    u16 h0,l0,h1,l1,h2,l2,h3,l3;
    split2(v.x,h0,l0); split2(v.y,h1,l1); split2(v.z,h2,l2); split2(v.w,h3,l3);
    ushort4 hv = {h0,h1,h2,h3}, lv = {l0,l1,l2,l3};
    *(ushort4*)&hi[(size_t)i * 4] = hv;
    *(ushort4*)&lo[(size_t)i * 4] = lv;
}
__global__ void transpose_split_k(const float* __restrict__ in, u16* __restrict__ outh,
                                  u16* __restrict__ outl, int R, int C) {
    __shared__ float t[32][33];
    const int c0 = blockIdx.x * 32, r0 = blockIdx.y * 32;
    const size_t zoff = (size_t)blockIdx.z * R * C;
    const int tx = threadIdx.x & 31, ty = threadIdx.x >> 5;
    #pragma unroll
    for (int p = 0; p < 4; ++p) {
        int r = ty + p * 8;
        t[r][tx] = in[zoff + (size_t)(r0 + r) * C + c0 + tx];
    }
    __syncthreads();
    #pragma unroll
    for (int p = 0; p < 4; ++p) {
        int cc = ty + p * 8;
        float v = t[tx][cc];
        u16 h, l; split2(v, h, l);
        size_t o = zoff + (size_t)(c0 + cc) * R + r0 + tx;
        outh[o] = h; outl[o] = l;
    }
}
// momentum update; bias grads from col-partials; maintain W1/W2/W2T split forms
__global__ void update3_k(float* __restrict__ p, float* __restrict__ mo,
                          const float* __restrict__ g,
                          const float* __restrict__ cp1, const float* __restrict__ cp2,
                          u16* __restrict__ w1h, u16* __restrict__ w1l,
                          u16* __restrict__ w2h, u16* __restrict__ w2l,
                          u16* __restrict__ w2th, u16* __restrict__ w2tl, int n) {
    int i = blockIdx.x * 256 + threadIdx.x;
    if (i >= n) return;
    float gi;
    if (i < 524288) gi = g[i];
    else if (i < 524800) {
        int j = i - 524288;
        gi = cp1[j] + cp1[512 + j] + cp1[1024 + j] + cp1[1536 + j];
    } else if (i < 1049088) gi = g[i];
    else {
        int j = i - 1049088;
        gi = cp2[j] + cp2[1024 + j] + cp2[2048 + j] + cp2[3072 + j];
    }
    float m = ETA_C * mo[i] - THETA_C * gi;
    mo[i] = m;
    float pv = (1.f - ALPHA_C) * p[i] + m;
    p[i] = pv;
    if (i < 524288) {
        u16 h, l; split2(pv, h, l); w1h[i] = h; w1l[i] = l;
    } else if (i >= 524800 && i < 1049088) {
        int j = i - 524800;
        u16 h, l; split2(pv, h, l);
        w2h[j] = h; w2l[j] = l;
        int tj = (j & 511) * 1024 + (j >> 9);
        w2th[tj] = h; w2tl[tj] = l;
    }
}
__global__ void extractqkv2_k(const float* __restrict__ qkv, u16* __restrict__ Qh,
                              u16* __restrict__ Ql, float* __restrict__ Kb,
                              float* __restrict__ Vb) {
    size_t idx = (size_t)blockIdx.x * 256 + threadIdx.x;
    int m = (int)(idx / 3072), col = (int)(idx % 3072);
    int b = m >> 10, t = m & 1023;
    float v = qkv[idx];
    if (col < 1024) {
        size_t o = (size_t)m * 1024 + col;
        u16 h, l; split2(v, h, l); Qh[o] = h; Ql[o] = l;
    } else {
        int d = col & 1023;
        int ch = t >> 7, r = t & 127;
        size_t o = ((size_t)((ch * 2 + b) * 128 + r)) * 1024 + d;
        if (col < 2048) Kb[o] = v; else Vb[o] = v;
    }
}
__global__ void tokens_split_k(const float* __restrict__ P, const float* __restrict__ memtok,
                               const float* __restrict__ x, u16* __restrict__ th,
                               u16* __restrict__ tl) {
    size_t idx = (size_t)blockIdx.x * 256 + threadIdx.x;
    int d = (int)(idx & 1023);
    int n = (int)((idx >> 10) % NTOK);
    int b = (int)(idx / ((size_t)NTOK * 1024));
    float v;
    if (n < NPERS)            v = P[(size_t)n * 1024 + d];
    else if (n < NPERS + TSEQ) v = memtok[((size_t)b * TSEQ + (n - NPERS)) * 1024 + d];
    else                      v = x[((size_t)b * TSEQ + (n - NPERS - TSEQ)) * 1024 + d];
    u16 h, l; split2(v, h, l); th[idx] = h; tl[idx] = l;
}
__global__ void mul_k(const float* __restrict__ a, const float* __restrict__ b,
                      float* __restrict__ o, int n) {
    int i = blockIdx.x * 256 + threadIdx.x;
    if (i < n) o[i] = a[i] * b[i];
}

// ---------------- attention prep ----------------
__global__ void prep_q_k(const float* __restrict__ aqkv, u16* __restrict__ Qh,
                         u16* __restrict__ Ql) {
    size_t idx = (size_t)blockIdx.x * 256 + threadIdx.x;
    int d = (int)(idx & 63);
    int row = (int)((idx >> 6) & 1023);
    int h = (int)((idx >> 16) & 15);
    int b = (int)(idx >> 20);
    float v = 0.125f * aqkv[((size_t)b * NTOK + NPERS + TSEQ + row) * 3072 + h * 64 + d];
    u16 hh, ll; split2(v, hh, ll);
    Qh[idx] = hh; Ql[idx] = ll;
}
__global__ void prep_kk_k(const float* __restrict__ aqkv, u16* __restrict__ Kh,
                          u16* __restrict__ Kl) {
    size_t idx = (size_t)blockIdx.x * 256 + threadIdx.x;
    int d = (int)(idx & 63);
    int n = (int)((idx >> 6) % NTOK);
    int t = (int)(idx / (64 * NTOK));
    int h = t & 15, b = t >> 4;
    float v = aqkv[((size_t)b * NTOK + n) * 3072 + 1024 + h * 64 + d];
    u16 hh, ll; split2(v, hh, ll);
    Kh[idx] = hh; Kl[idx] = ll;
}
__global__ void prep_vt_k(const float* __restrict__ aqkv, u16* __restrict__ Vt) {
    __shared__ float t[64][65];
    const int nt = blockIdx.x, h = blockIdx.y, b = blockIdx.z;
    const int j0 = nt * 64;
    const int lx = threadIdx.x & 63, rg = threadIdx.x >> 6;
    #pragma unroll
    for (int p = 0; p < 16; ++p) {
        int r = rg * 16 + p;
        int n = j0 + r;
        t[r][lx] = (n < NTOK) ? aqkv[((size_t)b * NTOK + n) * 3072 + 2048 + h * 64 + lx] : 0.f;
    }
    __syncthreads();
    #pragma unroll
    for (int p = 0; p < 16; ++p) {
        int d = rg * 16 + p;
        int n = j0 + lx;
        if (n < NTOK)
            Vt[((size_t)(b * 16 + h) * 64 + d) * NTOK + n] = f2bf(t[lx][d]);
    }
}

// ---------------- MFMA flash attention: split-KV partial + merge ----------------
__global__ __launch_bounds__(256)
void flash_part_k(const u16* __restrict__ Qsh, const u16* __restrict__ Qsl,
                  const u16* __restrict__ Ksh, const u16* __restrict__ Ksl,
                  const u16* __restrict__ Vts, float* __restrict__ Of,
                  float* __restrict__ Mf, float* __restrict__ Lf)
{
    __shared__ u16 lds[20480];             // KH KL VT | PH PL = 40 KB
    u16* KH = lds;            u16* KL = lds + 4096;
    u16* VT = lds + 8192;
    u16* PH = lds + 12288;    u16* PL = lds + 16384;

    int lid = blockIdx.x + (blockIdx.y << 4) + (blockIdx.z << 8);
    int t1024 = ((lid & 7) << 7) | (lid >> 3);
    const int qt = t1024 & 15, h = (t1024 >> 4) & 15;
    const int zb = t1024 >> 8;
    const int b = zb >> 1, z = zb & 1;

    const int tid = threadIdx.x;
    const int lane = tid & 63, wid = tid >> 6;
    const int fr = lane & 15, kq = lane >> 4;
    const int bh = b * 16 + h;
    const int q0c = qt * 64;
    const int q0a = NPERS + TSEQ + q0c;
    const int ntile = ((q0a + 63) >> 6) + 1;
    const int half = ntile >> 1;
    const int jt0 = z ? half : 0;
    const int jt1 = z ? ntile : half;
    const int l8 = lane & 7, lr8 = lane >> 3;

    auto stageKV = [&](int jt) {
        const int j0 = jt * 64;
        #pragma unroll
        for (int jj = 0; jj < 6; ++jj) {
            int j = wid * 6 + jj;
            int buf = j >> 3, i8 = j & 7;
            if (buf < 2) {
                int row = i8 * 8 + lr8;
                int grow = j0 + row; if (grow > NTOK - 1) grow = NTOK - 1;
                int c = l8 ^ (row & 7);
                const u16* src = (buf == 0 ? Ksh : Ksl) +
                                 (((size_t)bh * NTOK + grow) << 6) + c * 8;
                gload_lds16(src, (buf == 0 ? KH : KL) + i8 * 512);
            } else {
                int d = i8 * 8 + lr8;
                int c = l8 ^ (d & 7);
                int col = j0 + c * 8; if (col > NTOK - 8) col = NTOK - 8;
                const u16* src = Vts + ((size_t)bh * 64 + d) * NTOK + col;
                gload_lds16(src, VT + i8 * 512);
            }
        }
    };

    s16x8 qh[2], ql[2];
    {
        const size_t qrow = ((size_t)bh * 1024 + q0c + wid * 16 + fr) << 6;
        #pragma unroll
        for (int kb = 0; kb < 2; ++kb) {
            qh[kb] = *(const s16x8*)&Qsh[qrow + (size_t)(kb * 4 + kq) * 8];
            ql[kb] = *(const s16x8*)&Qsl[qrow + (size_t)(kb * 4 + kq) * 8];
        }
    }

    f32x4 Oa[4] = {};
    float mrow[4], lrow[4];
    #pragma unroll
    for (int r = 0; r < 4; ++r) { mrow[r] = -INFINITY; lrow[r] = 0.f; }

    for (int jt = jt0; jt < jt1; ++jt) {
        const int j0 = jt * 64;
        stageKV(jt);
        __syncthreads();

        f32x4 sacc[4] = {};
        __builtin_amdgcn_s_setprio(1);
        #pragma unroll
        for (int nt = 0; nt < 4; ++nt) {
            #pragma unroll
            for (int kb = 0; kb < 2; ++kb) {
                int br = nt * 16 + fr;
                int sl = (kb * 4 + kq) ^ (fr & 7);
                s16x8 kh = *(const s16x8*)&KH[br * 64 + sl * 8];
                s16x8 kl = *(const s16x8*)&KL[br * 64 + sl * 8];
                sacc[nt] = __builtin_amdgcn_mfma_f32_16x16x32_bf16(qh[kb], kh, sacc[nt], 0, 0, 0);
                sacc[nt] = __builtin_amdgcn_mfma_f32_16x16x32_bf16(ql[kb], kh, sacc[nt], 0, 0, 0);
                sacc[nt] = __builtin_amdgcn_mfma_f32_16x16x32_bf16(qh[kb], kl, sacc[nt], 0, 0, 0);
            }
        }
        __builtin_amdgcn_s_setprio(0);

        #pragma unroll
        for (int r = 0; r < 4; ++r) {
            const int qloc = kq * 4 + r;
            const int qi = q0a + wid * 16 + qloc;
            float sv[4], tmax = -INFINITY;
            #pragma unroll
            for (int nt = 0; nt < 4; ++nt) {
                int kj = j0 + nt * 16 + fr;
                sv[nt] = (kj <= qi) ? sacc[nt][r] : -INFINITY;
                tmax = fmaxf(tmax, sv[nt]);
            }
            #pragma unroll
            for (int off = 1; off < 16; off <<= 1)
                tmax = fmaxf(tmax, __shfl_xor(tmax, off));
            float mnew = fmaxf(mrow[r], tmax);
            float scale = __expf(mrow[r] - mnew);
            float psum = 0.f;
            float p4[4];
            #pragma unroll
            for (int nt = 0; nt < 4; ++nt) { p4[nt] = __expf(sv[nt] - mnew); psum += p4[nt]; }
            #pragma unroll
            for (int off = 1; off < 16; off <<= 1)
                psum += __shfl_xor(psum, off);
            lrow[r] = lrow[r] * scale + psum;
            mrow[r] = mnew;
            #pragma unroll
            for (int dt = 0; dt < 4; ++dt) Oa[dt][r] *= scale;
            const int prow = wid * 16 + qloc;
            #pragma unroll
            for (int nt = 0; nt < 4; ++nt) {
                u16 ph, pl; split2(p4[nt], ph, pl);
                int col = nt * 16 + fr;
                int sl = (col >> 3) ^ (qloc & 7);
                int off = prow * 64 + sl * 8 + (col & 7);
                PH[off] = ph; PL[off] = pl;
            }
        }

        __builtin_amdgcn_s_setprio(1);
        #pragma unroll
        for (int kb = 0; kb < 2; ++kb) {
            int pr = wid * 16 + fr;
            int sl = (kb * 4 + kq) ^ (fr & 7);
            s16x8 pa = *(const s16x8*)&PH[pr * 64 + sl * 8];
            s16x8 pb = *(const s16x8*)&PL[pr * 64 + sl * 8];
            #pragma unroll
            for (int dt = 0; dt < 4; ++dt) {
                int vr = dt * 16 + fr;
                s16x8 vb = *(const s16x8*)&VT[vr * 64 + sl * 8];
                Oa[dt] = __builtin_amdgcn_mfma_f32_16x16x32_bf16(pa, vb, Oa[dt], 0, 0, 0);
                Oa[dt] = __builtin_amdgcn_mfma_f32_16x16x32_bf16(pb, vb, Oa[dt], 0, 0, 0);
            }
        }
        __builtin_amdgcn_s_setprio(0);
        __syncthreads();
    }

    const size_t obase = ((((size_t)z * 2 + b) * 16 + h) * 16 + qt) * 4096;
    const size_t mlb   = ((((size_t)z * 2 + b) * 16 + h) * 16 + qt) * 64;
    #pragma unroll
    for (int r = 0; r < 4; ++r) {
        int rl = wid * 16 + kq * 4 + r;
        if (fr == 0) { Mf[mlb + rl] = mrow[r]; Lf[mlb + rl] = lrow[r]; }
        #pragma unroll
        for (int dt = 0; dt < 4; ++dt)
            Of[obase + (size_t)rl * 64 + dt * 16 + fr] = Oa[dt][r];
    }
}

__global__ __launch_bounds__(256)
void flash_merge_k(const float* __restrict__ Of, const float* __restrict__ Mf,
                   const float* __restrict__ Lf, u16* __restrict__ oh, u16* __restrict__ ol)
{
    const int qt = blockIdx.x, h = blockIdx.y, b = blockIdx.z;
    const int tid = threadIdx.x;
    const int row = tid >> 2, quad = tid & 3;
    const size_t b0 = ((((size_t)0 * 2 + b) * 16 + h) * 16 + qt) * 4096 + (size_t)row * 64;
    const size_t b1 = ((((size_t)1 * 2 + b) * 16 + h) * 16 + qt) * 4096 + (size_t)row * 64;
    const size_t m0i = ((((size_t)0 * 2 + b) * 16 + h) * 16 + qt) * 64 + row;
    const size_t m1i = ((((size_t)1 * 2 + b) * 16 + h) * 16 + qt) * 64 + row;
    float m0 = Mf[m0i], m1 = Mf[m1i], l0 = Lf[m0i], l1 = Lf[m1i];
    float m = fmaxf(m0, m1);
    float e0 = __expf(m0 - m), e1 = __expf(m1 - m);
    float inv = 1.f / (l0 * e0 + l1 * e1);
    const size_t orow = ((size_t)(b * 1024 + qt * 64 + row)) * 1024 + h * 64;
    #pragma unroll
    for (int i = 0; i < 4; ++i) {
        int col = quad * 16 + i * 4;
        float4 v0 = *(const float4*)&Of[b0 + col];
        float4 v1 = *(const float4*)&Of[b1 + col];
        float o0 = (v0.x * e0 + v1.x * e1) * inv;
        float o1 = (v0.y * e0 + v1.y * e1) * inv;
        float o2 = (v0.z * e0 + v1.z * e1) * inv;
        float o3 = (v0.w * e0 + v1.w * e1) * inv;
        u16 h0,l0_,h1,l1_,h2,l2_,h3,l3_;
        split2(o0,h0,l0_); split2(o1,h1,l1_); split2(o2,h2,l2_); split2(o3,h3,l3_);
        ushort4 hv = {h0,h1,h2,h3}, lv = {l0_,l1_,l2_,l3_};
        *(ushort4*)&oh[orow + col] = hv;
        *(ushort4*)&ol[orow + col] = lv;
    }
}

// ---------------- launch ----------------
extern "C" void kernel_launch(void* const* d_in, const int* in_sizes, int n_in,
                              void* d_out, int out_size, void* d_ws, size_t ws_size,
                              hipStream_t stream)
{
    const float* x     = (const float*)d_in[0];
    const float* Wqkv  = (const float*)d_in[1];
    const float* mW1   = (const float*)d_in[2];
    const float* mb1   = (const float*)d_in[3];
    const float* mW2   = (const float*)d_in[4];
    const float* mb2   = (const float*)d_in[5];
    const float* Pp    = (const float*)d_in[6];
    const float* Wqa   = (const float*)d_in[7];
    const float* Wo    = (const float*)d_in[8];
    const float* ffW1  = (const float*)d_in[9];
    const float* ffb1  = (const float*)d_in[10];
    const float* ffW2  = (const float*)d_in[11];
    const float* ffb2  = (const float*)d_in[12];
    char* wsb = (char*)d_ws;
    float* outp = (float*)d_out;

    // region A (multiplexed)
    float* qkv   = (float*)(wsb + oRA);
    float* z1    = (float*)(wsb + oRA);
    float* grd   = (float*)(wsb + oRA + 3145728);
    float* cp2   = (float*)(wsb + oRA + 7346176);
    float* cp1   = (float*)(wsb + oRA + 7362560);
    u16* hh_     = (u16*)(wsb + oRA + 8388608);
    u16* hl_     = (u16*)(wsb + oRA + 8650752);
    u16* hTh     = (u16*)(wsb + oRA + 9437184);
    u16* hTl     = (u16*)(wsb + oRA + 9699328);
    u16* rh_     = (u16*)(wsb + oRA + 10485760);
    u16* rl_     = (u16*)(wsb + oRA + 11010048);
    u16* rTh     = (u16*)(wsb + oRA + 11534336);
    u16* rTl     = (u16*)(wsb + oRA + 12058624);
    u16* dhTh    = (u16*)(wsb + oRA + 12582912);
    u16* dhTl    = (u16*)(wsb + oRA + 12845056);
    u16* kcTh    = (u16*)(wsb + oRA + 16777216);
    u16* kcTl    = (u16*)(wsb + oRA + 20971520);
    float* aqkv  = (float*)(wsb + oRA);
    float* Of    = (float*)(wsb + oRA);                  // flash partials 33.5 MB
    float* Mf    = (float*)(wsb + oRA + 33554432);
    float* Lf    = (float*)(wsb + oRA + 34078720);
    u16* Woh     = (u16*)(wsb + oRA);
    u16* Wol     = (u16*)(wsb + oRA + 2097152);
    u16* ffhh    = (u16*)(wsb + oRA);
    u16* ffhl    = (u16*)(wsb + oRA + 16777216);
    u16* outbh   = (u16*)(wsb + oRA + 33554432);
    u16* outbl   = (u16*)(wsb + oRA + 37748736);
    u16* newQh   = (u16*)(wsb + oRA);
    u16* newQl   = (u16*)(wsb + oRA + 4194304);
    u16* hzh     = (u16*)(wsb + oRA + 8388608);
    u16* hzl     = (u16*)(wsb + oRA + 10485760);
    float* memq  = (float*)(wsb + oRA + 12582912);
    float* partA0 = (float*)(wsb + oRA);
    float* partA1 = (float*)(wsb + oRA + 4194304);
    float* partA2 = (float*)(wsb + oRA + 16777216);
    // region B
    float* Kb    = (float*)(wsb + oRB);
    float* Vb    = (float*)(wsb + oRB + 8388608);
    u16* tokh    = (u16*)(wsb + oRB);
    u16* tokl    = (u16*)(wsb + oRB + 8454144);
    u16* oh      = (u16*)(wsb + oRB);
    u16* ol      = (u16*)(wsb + oRB + 4194304);
    u16* fVth    = (u16*)(wsb + oRB + 8388608);
    u16* y1h     = (u16*)(wsb + oRB + 8388608);
    u16* y1l     = (u16*)(wsb + oRB + 12582912);
    float* partB = (float*)(wsb + oRB);
    // region C
    u16* xh      = (u16*)(wsb + oRC);
    u16* xl      = (u16*)(wsb + oRC + 4194304);
    float* mom   = (float*)(wsb + oRC);
    u16* pW2Th   = (u16*)(wsb + oRC + 5242880);
    u16* pW2Tl   = (u16*)(wsb + oRC + 6291456);
    u16* Wqah    = (u16*)(wsb + oRC);
    u16* Wqal    = (u16*)(wsb + oRC + 6291456);
    u16* fKl     = (u16*)(wsb + oRC);
    // region D
    u16* Qh      = (u16*)(wsb + oRD);
    u16* Ql      = (u16*)(wsb + oRD + 4194304);
    u16* kchh    = (u16*)(wsb + oRD + 8388608);
    u16* kchl    = (u16*)(wsb + oRD + 12582912);
    u16* t1h     = (u16*)(wsb + oRD + 8388608);
    u16* t1l     = (u16*)(wsb + oRD + 10485760);
    float* memtok= (float*)(wsb + oRD);
    u16* fKh     = (u16*)(wsb + oRD);
    u16* ffW1h   = (u16*)(wsb + oRD);
    u16* ffW1l   = (u16*)(wsb + oRD + 8388608);
    u16* ffW2h   = (u16*)(wsb + oRD);
    u16* ffW2l   = (u16*)(wsb + oRD + 8388608);
    // persistent
    u16* Wqkvh   = (u16*)(wsb + oRE);
    u16* Wqkvl   = (u16*)(wsb + oRE + 6291456);
    u16* pW1h    = (u16*)(wsb + oRF);
    u16* pW1l    = (u16*)(wsb + oRF + 1048576);
    u16* pW2h    = (u16*)(wsb + oRF + 2097152);
    u16* pW2l    = (u16*)(wsb + oRF + 3145728);
    float* par   = (float*)(wsb + oRG);
    float* outb  = (float*)(wsb + oRH);
    u16* fQh     = (u16*)(wsb + oRH);
    u16* fQl     = (u16*)(wsb + oRH + 4194304);

    // init memory-MLP params
    hipMemcpyAsync(par + PW1, mW1, 524288 * sizeof(float), hipMemcpyDeviceToDevice, stream);
    hipMemcpyAsync(par + PB1, mb1, 512 * sizeof(float), hipMemcpyDeviceToDevice, stream);
    hipMemcpyAsync(par + PW2, mW2, 524288 * sizeof(float), hipMemcpyDeviceToDevice, stream);
    hipMemcpyAsync(par + PB2, mb2, 1024 * sizeof(float), hipMemcpyDeviceToDevice, stream);

    // qkv = x @ Wqkv^T
    cvt_split_k<<<2048, 256, 0, stream>>>(x, xh, xl, 524288);
    cvt_split_k<<<3072, 256, 0, stream>>>(Wqkv, Wqkvh, Wqkvl, 786432);
    gemm_mfma(stream, 0, 1, 0, xh, xl, Wqkvh, Wqkvl, qkv, nullptr, nullptr, 2048, 3072, 1024, nullptr);
    extractqkv2_k<<<24576, 256, 0, stream>>>(qkv, Qh, Ql, Kb, Vb);

    // scan prep
    hipMemsetAsync(mom, 0, PSZ * sizeof(float), stream);
    cvt_split_k<<<2048, 256, 0, stream>>>(Kb, kchh, kchl, 524288);
    transpose_split_k<<<dim3(32, 8, 8), 256, 0, stream>>>(Kb, kcTh, kcTl, 256, 1024);
    cvt_split_k<<<512, 256, 0, stream>>>(par + PW1, pW1h, pW1l, 131072);
    cvt_split_k<<<512, 256, 0, stream>>>(par + PW2, pW2h, pW2l, 131072);
    transpose_split_k<<<dim3(16, 32, 1), 256, 0, stream>>>(par + PW2, pW2Th, pW2Tl, 1024, 512);

    // memory scan: z1 -> r -> {gW2 || dh} -> gW1 -> update  (BK=64 dbuf GEMMs)
    const float cs = 2.f / (float)(BATCH * 128 * DIMD);
    for (int c = 0; c < NCH; ++c) {
        const u16* kch = kchh + (size_t)c * 262144;
        const u16* kcl = kchl + (size_t)c * 262144;
        const u16* kth = kcTh + (size_t)c * 262144;
        const u16* ktl = kcTl + (size_t)c * 262144;
        const float* vc = Vb + (size_t)c * 262144;
        gemm_scan_k<1><<<dim3(4, 2), 256, 0, stream>>>(kch, kcl, pW1h, pW1l,
            z1, hh_, hl_, hTh, hTl, nullptr, nullptr, par + PB1, nullptr, 256, 512, 1024, 1.f);
        gemm_scan_k<2><<<dim3(8, 2), 256, 0, stream>>>(hh_, hl_, pW2h, pW2l,
            nullptr, rh_, rl_, rTh, rTl, nullptr, vc, par + PB2, cp2, 256, 1024, 512, cs);
        gemm_scan_pair_k<<<dim3(4, 10), 256, 0, stream>>>(rTh, rTl, hTh, hTl, grd + PW2,
            rh_, rl_, pW2Th, pW2Tl, dhTh, dhTl, z1, cp1, cs);
        gemm_scan_k<3><<<dim3(8, 4), 256, 0, stream>>>(dhTh, dhTl, kth, ktl,
            grd + PW1, nullptr, nullptr, nullptr, nullptr, nullptr, nullptr, nullptr, nullptr,
            512, 1024, 256, 1.f);
        update3_k<<<4102, 256, 0, stream>>>(par, mom, grd, cp1, cp2,
            pW1h, pW1l, pW2h, pW2l, pW2Th, pW2Tl, (int)PSZ);
    }

    // memory readout (split-K: t1 S=4 part@A2, memtok S=2 part@A0)
    gemm_mfma_sk(stream, 1, 0, 1, Qh, Ql, pW1h, pW1l, nullptr, t1h, t1l,
                 2048, 512, 1024, par + PB1, 4, partA2);
    gemm_mfma_sk(stream, 0, 1, 0, t1h, t1l, pW2h, pW2l, memtok, nullptr, nullptr,
                 2048, 1024, 512, par + PB2, 2, partA0);

    // tokens + attention qkv
    tokens_split_k<<<16512, 256, 0, stream>>>(Pp, memtok, x, tokh, tokl);
    cvt_split_k<<<3072, 256, 0, stream>>>(Wqa, Wqah, Wqal, 786432);
    gemm_mfma(stream, 0, 1, 0, tokh, tokl, Wqah, Wqal, aqkv, nullptr, nullptr, 4128, 3072, 1024, nullptr);

    // attention prep
    prep_q_k<<<8192, 256, 0, stream>>>(aqkv, fQh, fQl);
    prep_kk_k<<<16512, 256, 0, stream>>>(aqkv, fKh, fKl);
    prep_vt_k<<<dim3(33, 16, 2), 256, 0, stream>>>(aqkv, fVth);

    // MFMA flash attention: split-KV partials + merge
    flash_part_k<<<dim3(16, 16, 4), 256, 0, stream>>>(fQh, fQl, fKh, fKl, fVth, Of, Mf, Lf);
    flash_merge_k<<<dim3(16, 16, 2), 256, 0, stream>>>(Of, Mf, Lf, oh, ol);

    // Wo projection + FFN (split-K on grid-starved GEMMs)
    cvt_split_k<<<1024, 256, 0, stream>>>(Wo, Woh, Wol, 262144);
    gemm_mfma_sk(stream, 0, 0, 1, oh, ol, Woh, Wol, nullptr, y1h, y1l,
                 2048, 1024, 1024, nullptr, 2, partA1);
    cvt_split_k<<<4096, 256, 0, stream>>>(ffW1, ffW1h, ffW1l, 1048576);
    gemm_mfma(stream, 2, 0, 1, y1h, y1l, ffW1h, ffW1l, nullptr, ffhh, ffhl, 2048, 4096, 1024, ffb1);
    cvt_split_k<<<4096, 256, 0, stream>>>(ffW2, ffW2h, ffW2l, 1048576);
    gemm_mfma_sk(stream, 0, 1, 1, ffhh, ffhl, ffW2h, ffW2l, outb, outbh, outbl,
                 2048, 1024, 4096, ffb2, 2, partB);

    // gate
    gemm_mfma_sk(stream, 0, 0, 1, outbh, outbl, Wqkvh, Wqkvl, nullptr, newQh, newQl,
                 2048, 1024, 1024, nullptr, 2, partB);
    gemm_mfma_sk(stream, 1, 0, 1, newQh, newQl, pW1h, pW1l, nullptr, hzh, hzl,
                 2048, 512, 1024, par + PB1, 4, partB);
    gemm_mfma_sk(stream, 0, 1, 0, hzh, hzl, pW2h, pW2l, memq, nullptr, nullptr,
                 2048, 1024, 512, par + PB2, 2, partB);
    mul_k<<<8192, 256, 0, stream>>>(outb, memq, outp, 2097152);
}

// Round 13
// 1395.936 us; speedup vs baseline: 1.2005x; 1.0225x over previous
//
#include <hip/hip_runtime.h>
#include <math.h>

// ---------------- problem constants ----------------
#define BATCH 2
#define TSEQ 1024
#define DIMD 1024
#define NPERS 16
#define NCH 8
#define NTOK 2064
#define ETA_C 0.9f
#define THETA_C 0.1f
#define ALPHA_C 0.02f

typedef __attribute__((ext_vector_type(4))) float f32x4;
typedef __attribute__((ext_vector_type(8))) short s16x8;
typedef unsigned short u16;

// ---------------- bf16 helpers ----------------
__device__ __forceinline__ u16 f2bf(float f) {
    unsigned int u = __float_as_uint(f);
    return (u16)((u + 0x7fffu + ((u >> 16) & 1u)) >> 16);
}
__device__ __forceinline__ float bf2f(u16 h) { return __uint_as_float(((unsigned)h) << 16); }
__device__ __forceinline__ void split2(float v, u16& h, u16& l) {
    h = f2bf(v); l = f2bf(v - bf2f(h));
}

// ---------------- workspace layout (byte offsets) ----------------
static const size_t oRA = 0;                       // 50,724,864 multiplexed
static const size_t oRB = 50724864;                // 16,908,288
static const size_t oRC = 67633152;                // 12,582,912
static const size_t oRD = 80216064;                // 16,777,216
static const size_t oRE = 96993280;                // 12,582,912 Wqkv h/l (persistent)
static const size_t oRF = 109576192;               //  4,194,304 parW h/l (persistent)
static const size_t oRG = 113770496;               //  4,200,448 par (persistent)
static const size_t oRH = 117970944;               //  8,388,608 outb f32 / fQ split
// total 126,359,552 bytes

static const size_t PW1 = 0, PB1 = 524288, PW2 = 524800, PB2 = 1049088, PSZ = 1050112;

// ---------------- async global->LDS ----------------
__device__ __forceinline__ void gload_lds16(const u16* g, u16* l) {
    __builtin_amdgcn_global_load_lds(
        (const __attribute__((address_space(1))) unsigned int*)g,
        (__attribute__((address_space(3))) unsigned int*)l, 16, 0, 0);
}

// XCD-chunked block swizzle (bijective when nwg % 8 == 0; identity fallback).
__device__ __forceinline__ void xcd_swizzle(int& bx, int& by) {
    int gx = gridDim.x, nwg = gx * gridDim.y;
    int lid = blockIdx.y * gx + blockIdx.x;
    int t = lid;
    if ((nwg & 7) == 0) {
        int q = nwg >> 3;
        t = (lid & 7) * q + (lid >> 3);
    }
    bx = t % gx; by = t / gx;
}

// stage one 128x32 bf16 tile (this wave's quarter) into buf + wid*4096
__device__ __forceinline__ void stage_tile(const u16* sp, u16* buf, int rbase,
                                           int M, int clampM, int K, int k0,
                                           int wid, int lane) {
    const int lr = lane >> 2, lc = lane & 3;
    #pragma unroll
    for (int i = 0; i < 8; ++i) {
        int r = i * 16 + lr;
        int gr = rbase + r;
        if (clampM && gr >= M) gr = M - 1;
        int g = lc ^ ((r >> 1) & 3);
        gload_lds16(sp + (size_t)gr * K + k0 + g * 8, buf + wid * 4096 + i * 512);
    }
}

// stage one 128x64 bf16 tile into buf + wid*8192 (scan path, BK=64)
__device__ __forceinline__ void stage_tile64(const u16* sp, u16* buf, int rbase,
                                             int K, int k0, int wid, int lane) {
    const int lr = lane >> 3, lc = lane & 7;
    #pragma unroll
    for (int i = 0; i < 16; ++i) {
        int r = i * 8 + lr;
        int gr = rbase + r;
        int g = lc ^ (r & 7);
        gload_lds16(sp + (size_t)gr * K + k0 + g * 8, buf + wid * 8192 + i * 512);
    }
}

// shared BK=32 dbuf main loop: accumulates into acc[4][4]
__device__ __forceinline__ void mm_loop32(u16 lds[2][16384],
                const u16* sp, int rbase, int M, int clampM, int K,
                int kbeg, int kend, int wid, int lane, int wm, int wn,
                f32x4 acc[4][4]) {
    const int frow = lane & 15, kblk = lane >> 4;
    const int nt = (kend - kbeg) >> 5;
    stage_tile(sp, lds[0], rbase, M, clampM, K, kbeg, wid, lane);
    for (int t = 0; t < nt; ++t) {
        __syncthreads();
        if (t + 1 < nt)
            stage_tile(sp, lds[(t + 1) & 1], rbase, M, clampM, K, kbeg + ((t + 1) << 5), wid, lane);
        const u16* cb = lds[t & 1];
        s16x8 bh[4], bl[4];
        #pragma unroll
        for (int ni = 0; ni < 4; ++ni) {
            int br = wn * 64 + ni * 16 + frow;
            int pc = kblk ^ ((br >> 1) & 3);
            bh[ni] = *(const s16x8*)&cb[2 * 4096 + br * 32 + pc * 8];
            bl[ni] = *(const s16x8*)&cb[3 * 4096 + br * 32 + pc * 8];
        }
        #pragma unroll
        for (int mi = 0; mi < 4; ++mi) {
            int ar = wm * 64 + mi * 16 + frow;
            int pc = kblk ^ ((ar >> 1) & 3);
            s16x8 ah = *(const s16x8*)&cb[0 * 4096 + ar * 32 + pc * 8];
            s16x8 al = *(const s16x8*)&cb[1 * 4096 + ar * 32 + pc * 8];
            #pragma unroll
            for (int ni = 0; ni < 4; ++ni) {
                acc[mi][ni] = __builtin_amdgcn_mfma_f32_16x16x32_bf16(ah, bh[ni], acc[mi][ni], 0, 0, 0);
                acc[mi][ni] = __builtin_amdgcn_mfma_f32_16x16x32_bf16(ah, bl[ni], acc[mi][ni], 0, 0, 0);
                acc[mi][ni] = __builtin_amdgcn_mfma_f32_16x16x32_bf16(al, bh[ni], acc[mi][ni], 0, 0, 0);
            }
        }
    }
}

// ---------------- split-bf16 MFMA GEMM:  C = act(A @ W^T + bias) ----------------
template<int ACTF, int WF32, int WSPLIT, int PARTIAL>
__global__ __launch_bounds__(256)
void gemm_mfma_k(const u16* __restrict__ Ah, const u16* __restrict__ Al,
                 const u16* __restrict__ Wh, const u16* __restrict__ Wl,
                 float* __restrict__ C, u16* __restrict__ Chi, u16* __restrict__ Clo,
                 int M, int N, int K, const float* __restrict__ bias)
{
    __shared__ u16 lds[2][16384];
    const int tid = threadIdx.x;
    const int lane = tid & 63, wid = tid >> 6;
    const int wm = wid >> 1, wn = wid & 1;
    int bx, by; xcd_swizzle(bx, by);
    const int row0 = by * 128, col0 = bx * 128;
    const u16* sp = (wid == 0) ? Ah : (wid == 1) ? Al : (wid == 2) ? Wh : Wl;
    const int rbase = (wid < 2) ? row0 : col0;
    const int clampM = (wid < 2) ? 1 : 0;
    f32x4 acc[4][4] = {};
    int kbeg = 0, kend = K;
    if (PARTIAL) {
        int Kseg = K / gridDim.z;
        kbeg = blockIdx.z * Kseg;
        kend = kbeg + Kseg;
    }
    mm_loop32(lds, sp, rbase, M, clampM, K, kbeg, kend, wid, lane, wm, wn, acc);

    const int erow = (lane >> 4) * 4, ecol = lane & 15;
    #pragma unroll
    for (int mi = 0; mi < 4; ++mi) {
        #pragma unroll
        for (int ni = 0; ni < 4; ++ni) {
            int c = col0 + wn * 64 + ni * 16 + ecol;
            float bv = (!PARTIAL && bias) ? bias[c] : 0.f;
            #pragma unroll
            for (int reg = 0; reg < 4; ++reg) {
                int r = row0 + wm * 64 + mi * 16 + erow + reg;
                if (r >= M) continue;
                float v = acc[mi][ni][reg] + bv;
                if (PARTIAL) {
                    C[((size_t)blockIdx.z * M + r) * N + c] = v;
                    continue;
                }
                if (ACTF == 1) v = v / (1.f + __expf(-v));
                else if (ACTF == 2) {
                    float u = 0.7978845608028654f * (v + 0.044715f * v * v * v);
                    v = 0.5f * v * (1.f + tanhf(u));
                }
                size_t o = (size_t)r * N + c;
                if (WF32) C[o] = v;
                if (WSPLIT) { u16 h, l; split2(v, h, l); Chi[o] = h; Clo[o] = l; }
            }
        }
    }
}

// fused qkv GEMM: writes Q split, kc split, kcT split, V f32 directly (M=2048,N=3072)
__global__ __launch_bounds__(256)
void gemm_qkv_k(const u16* __restrict__ Ah, const u16* __restrict__ Al,
                const u16* __restrict__ Wh, const u16* __restrict__ Wl,
                u16* __restrict__ Qh, u16* __restrict__ Ql,
                u16* __restrict__ kch, u16* __restrict__ kcl,
                u16* __restrict__ kcTh, u16* __restrict__ kcTl,
                float* __restrict__ Vb, int M, int N, int K)
{
    __shared__ u16 lds[2][16384];
    const int tid = threadIdx.x;
    const int lane = tid & 63, wid = tid >> 6;
    const int wm = wid >> 1, wn = wid & 1;
    int bx, by; xcd_swizzle(bx, by);
    const int row0 = by * 128, col0 = bx * 128;
    const u16* sp = (wid == 0) ? Ah : (wid == 1) ? Al : (wid == 2) ? Wh : Wl;
    const int rbase = (wid < 2) ? row0 : col0;
    f32x4 acc[4][4] = {};
    mm_loop32(lds, sp, rbase, M, 0, K, 0, K, wid, lane, wm, wn, acc);

    const int erow = (lane >> 4) * 4, ecol = lane & 15;
    #pragma unroll
    for (int mi = 0; mi < 4; ++mi) {
        #pragma unroll
        for (int ni = 0; ni < 4; ++ni) {
            int c = col0 + wn * 64 + ni * 16 + ecol;
            #pragma unroll
            for (int reg = 0; reg < 4; ++reg) {
                int r = row0 + wm * 64 + mi * 16 + erow + reg;
                float v = acc[mi][ni][reg];
                int b = r >> 10, t = r & 1023;
                if (c < 1024) {
                    size_t o = (size_t)r * 1024 + c;
                    u16 h, l; split2(v, h, l); Qh[o] = h; Ql[o] = l;
                } else if (c < 2048) {
                    int d = c - 1024;
                    int ch = t >> 7, rr = t & 127;
                    size_t o = ((size_t)((ch * 2 + b) * 128 + rr)) * 1024 + d;
                    u16 h, l; split2(v, h, l);
                    kch[o] = h; kcl[o] = l;
                    size_t ot = (size_t)ch * 262144 + (size_t)d * 256 + b * 128 + rr;
                    kcTh[ot] = h; kcTl[ot] = l;
                } else {
                    int d = c - 2048;
                    int ch = t >> 7, rr = t & 127;
                    Vb[((size_t)((ch * 2 + b) * 128 + rr)) * 1024 + d] = v;
                }
            }
        }
    }
}

// fused attention-qkv GEMM: writes fQ (0.125-scaled, kept rows), fK split, fV^T hi
__global__ __launch_bounds__(256)
void gemm_aqkv_k(const u16* __restrict__ Ah, const u16* __restrict__ Al,
                 const u16* __restrict__ Wh, const u16* __restrict__ Wl,
                 u16* __restrict__ fQh, u16* __restrict__ fQl,
                 u16* __restrict__ fKh, u16* __restrict__ fKl,
                 u16* __restrict__ fVt, int M, int N, int K)
{
    __shared__ u16 lds[2][16384];
    const int tid = threadIdx.x;
    const int lane = tid & 63, wid = tid >> 6;
    const int wm = wid >> 1, wn = wid & 1;
    int bx, by; xcd_swizzle(bx, by);
    const int row0 = by * 128, col0 = bx * 128;
    const u16* sp = (wid == 0) ? Ah : (wid == 1) ? Al : (wid == 2) ? Wh : Wl;
    const int rbase = (wid < 2) ? row0 : col0;
    const int clampM = (wid < 2) ? 1 : 0;
    f32x4 acc[4][4] = {};
    mm_loop32(lds, sp, rbase, M, clampM, K, 0, K, wid, lane, wm, wn, acc);

    const int erow = (lane >> 4) * 4, ecol = lane & 15;
    #pragma unroll
    for (int mi = 0; mi < 4; ++mi) {
        #pragma unroll
        for (int ni = 0; ni < 4; ++ni) {
            int c = col0 + wn * 64 + ni * 16 + ecol;
            #pragma unroll
            for (int reg = 0; reg < 4; ++reg) {
                int r = row0 + wm * 64 + mi * 16 + erow + reg;
                if (r >= M) continue;
                float v = acc[mi][ni][reg];
                int b = (r >= 2064) ? 1 : 0;
                int n = r - b * 2064;
                if (c < 1024) {
                    if (n >= NPERS + TSEQ) {
                        int h = c >> 6, d = c & 63;
                        int row = n - (NPERS + TSEQ);
                        size_t o = (((size_t)(b * 16 + h)) * 1024 + row) * 64 + d;
                        u16 hh, ll; split2(0.125f * v, hh, ll);
                        fQh[o] = hh; fQl[o] = ll;
                    }
                } else if (c < 2048) {
                    int cc = c - 1024;
                    int h = cc >> 6, d = cc & 63;
                    size_t o = (((size_t)(b * 16 + h)) * NTOK + n) * 64 + d;
                    u16 hh, ll; split2(v, hh, ll);
                    fKh[o] = hh; fKl[o] = ll;
                } else {
                    int cc = c - 2048;
                    int h = cc >> 6, d = cc & 63;
                    fVt[(((size_t)(b * 16 + h)) * 64 + d) * NTOK + n] = f2bf(v);
                }
            }
        }
    }
}

// split-K reduce + epilogue
template<int ACTF, int WF32, int WSPLIT>
__global__ __launch_bounds__(256)
void reduce_k(const float* __restrict__ Cp, int S,
              float* __restrict__ C, u16* __restrict__ Chi, u16* __restrict__ Clo,
              const float* __restrict__ bias, int M, int N)
{
    int i = blockIdx.x * 256 + threadIdx.x;
    int n4 = (int)((size_t)M * N / 4);
    if (i >= n4) return;
    size_t off = (size_t)i * 4;
    float4 v = *(const float4*)&Cp[off];
    for (int z = 1; z < S; ++z) {
        float4 u = *(const float4*)&Cp[(size_t)z * M * N + off];
        v.x += u.x; v.y += u.y; v.z += u.z; v.w += u.w;
    }
    int c = (int)(off % N);
    float vv[4] = {v.x, v.y, v.z, v.w};
    #pragma unroll
    for (int j = 0; j < 4; ++j) {
        float w = vv[j];
        if (bias) w += bias[c + j];
        if (ACTF == 1) w = w / (1.f + __expf(-w));
        else if (ACTF == 2) {
            float u = 0.7978845608028654f * (w + 0.044715f * w * w * w);
            w = 0.5f * w * (1.f + tanhf(u));
        }
        if (WF32) C[off + j] = w;
        if (WSPLIT) { u16 h, l; split2(w, h, l); Chi[off + j] = h; Clo[off + j] = l; }
    }
}

static void gemm_mfma(hipStream_t s, int act, int wf32, int wsplit,
                      const u16* Ah, const u16* Al, const u16* Wh, const u16* Wl,
                      float* C, u16* Ch, u16* Cl, int M, int N, int K, const float* bias)
{
    dim3 g(N / 128, (M + 127) / 128), b(256);
    if (act == 0 && wf32 == 1 && wsplit == 0)
        gemm_mfma_k<0,1,0,0><<<g,b,0,s>>>(Ah,Al,Wh,Wl,C,Ch,Cl,M,N,K,bias);
    else if (act == 0 && wf32 == 1 && wsplit == 1)
        gemm_mfma_k<0,1,1,0><<<g,b,0,s>>>(Ah,Al,Wh,Wl,C,Ch,Cl,M,N,K,bias);
    else if (act == 0 && wf32 == 0 && wsplit == 1)
        gemm_mfma_k<0,0,1,0><<<g,b,0,s>>>(Ah,Al,Wh,Wl,C,Ch,Cl,M,N,K,bias);
    else if (act == 1)
        gemm_mfma_k<1,0,1,0><<<g,b,0,s>>>(Ah,Al,Wh,Wl,C,Ch,Cl,M,N,K,bias);
    else
        gemm_mfma_k<2,0,1,0><<<g,b,0,s>>>(Ah,Al,Wh,Wl,C,Ch,Cl,M,N,K,bias);
}

static void gemm_mfma_sk(hipStream_t s, int act, int wf32, int wsplit,
                         const u16* Ah, const u16* Al, const u16* Wh, const u16* Wl,
                         float* C, u16* Ch, u16* Cl, int M, int N, int K,
                         const float* bias, int S, float* part)
{
    if (S <= 1) { gemm_mfma(s, act, wf32, wsplit, Ah, Al, Wh, Wl, C, Ch, Cl, M, N, K, bias); return; }
    dim3 g(N / 128, (M + 127) / 128, S), b(256);
    gemm_mfma_k<0,0,0,1><<<g,b,0,s>>>(Ah,Al,Wh,Wl,part,nullptr,nullptr,M,N,K,nullptr);
    int n4 = (int)((size_t)M * N / 4);
    dim3 rg((n4 + 255) / 256), rb(256);
    if (act == 0 && wf32 == 1 && wsplit == 0)
        reduce_k<0,1,0><<<rg,rb,0,s>>>(part, S, C, Ch, Cl, bias, M, N);
    else if (act == 0 && wf32 == 1 && wsplit == 1)
        reduce_k<0,1,1><<<rg,rb,0,s>>>(part, S, C, Ch, Cl, bias, M, N);
    else if (act == 0 && wf32 == 0 && wsplit == 1)
        reduce_k<0,0,1><<<rg,rb,0,s>>>(part, S, C, Ch, Cl, bias, M, N);
    else if (act == 1)
        reduce_k<1,0,1><<<rg,rb,0,s>>>(part, S, C, Ch, Cl, bias, M, N);
    else
        reduce_k<2,0,1><<<rg,rb,0,s>>>(part, S, C, Ch, Cl, bias, M, N);
}

// ---------------- scan-specialized split-bf16 MFMA GEMM body (BK=64 dbuf) -------
template<int MODE>
__device__ __forceinline__ void scan_body(u16* lds, int bx, int by,
                 const u16* __restrict__ Ah, const u16* __restrict__ Al,
                 const u16* __restrict__ Wh, const u16* __restrict__ Wl,
                 float* __restrict__ C, u16* __restrict__ Chi, u16* __restrict__ Clo,
                 u16* __restrict__ ChiT, u16* __restrict__ CloT,
                 const float* __restrict__ Zf, const float* __restrict__ add,
                 const float* __restrict__ bias, float* __restrict__ CP,
                 int M, int N, int K, float alpha)
{
    const int tid = threadIdx.x;
    const int lane = tid & 63, wid = tid >> 6;
    const int wm = wid >> 1, wn = wid & 1;
    const int row0 = by * 128, col0 = bx * 128;

    const u16* sp = (wid == 0) ? Ah : (wid == 1) ? Al : (wid == 2) ? Wh : Wl;
    const int rbase = (wid < 2) ? row0 : col0;

    f32x4 acc[4][4] = {};
    const int frow = lane & 15, kblk = lane >> 4;
    const int nt = K >> 6;

    stage_tile64(sp, lds, rbase, K, 0, wid, lane);

    for (int t = 0; t < nt; ++t) {
        __syncthreads();
        if (t + 1 < nt)
            stage_tile64(sp, lds + (((t + 1) & 1) << 15), rbase, K, (t + 1) << 6, wid, lane);
        const u16* cb = lds + ((t & 1) << 15);

        #pragma unroll
        for (int s = 0; s < 2; ++s) {
            s16x8 bh[4], bl[4];
            #pragma unroll
            for (int ni = 0; ni < 4; ++ni) {
                int br = wn * 64 + ni * 16 + frow;
                int pc = (s * 4 + kblk) ^ (br & 7);
                bh[ni] = *(const s16x8*)&cb[2 * 8192 + br * 64 + pc * 8];
                bl[ni] = *(const s16x8*)&cb[3 * 8192 + br * 64 + pc * 8];
            }
            #pragma unroll
            for (int mi = 0; mi < 4; ++mi) {
                int ar = wm * 64 + mi * 16 + frow;
                int pc = (s * 4 + kblk) ^ (ar & 7);
                s16x8 ah = *(const s16x8*)&cb[0 * 8192 + ar * 64 + pc * 8];
                s16x8 al = *(const s16x8*)&cb[1 * 8192 + ar * 64 + pc * 8];
                #pragma unroll
                for (int ni = 0; ni < 4; ++ni) {
                    acc[mi][ni] = __builtin_amdgcn_mfma_f32_16x16x32_bf16(ah, bh[ni], acc[mi][ni], 0, 0, 0);
                    acc[mi][ni] = __builtin_amdgcn_mfma_f32_16x16x32_bf16(ah, bl[ni], acc[mi][ni], 0, 0, 0);
                    acc[mi][ni] = __builtin_amdgcn_mfma_f32_16x16x32_bf16(al, bh[ni], acc[mi][ni], 0, 0, 0);
                }
            }
        }
    }

    const int erow = (lane >> 4) * 4, ecol = lane & 15;
    float csum[4] = {0.f, 0.f, 0.f, 0.f};
    #pragma unroll
    for (int mi = 0; mi < 4; ++mi) {
        #pragma unroll
        for (int ni = 0; ni < 4; ++ni) {
            int c = col0 + wn * 64 + ni * 16 + ecol;
            #pragma unroll
            for (int reg = 0; reg < 4; ++reg) {
                int r = row0 + wm * 64 + mi * 16 + erow + reg;
                float v = acc[mi][ni][reg];
                size_t o = (size_t)r * N + c;
                if (MODE == 1) {
                    v += bias[c];
                    C[o] = v;
                    float hv = v / (1.f + __expf(-v));
                    u16 h, l; split2(hv, h, l);
                    Chi[o] = h; Clo[o] = l;
                    size_t ot = (size_t)c * M + r;
                    ChiT[ot] = h; CloT[ot] = l;
                } else if (MODE == 2) {
                    v += bias[c] - add[o];
                    u16 h, l; split2(v, h, l);
                    Chi[o] = h; Clo[o] = l;
                    size_t ot = (size_t)c * M + r;
                    ChiT[ot] = h; CloT[ot] = l;
                    csum[ni] += v;
                } else if (MODE == 3) {
                    C[o] = alpha * v;
                } else {
                    v *= alpha;
                    float z = Zf[o];
                    float sg = 1.f / (1.f + __expf(-z));
                    v *= sg * (1.f + z * (1.f - sg));
                    u16 h, l; split2(v, h, l);
                    size_t ot = (size_t)c * M + r;
                    ChiT[ot] = h; CloT[ot] = l;
                    csum[ni] += v;
                }
            }
        }
    }
    if (MODE == 2 || MODE == 4) {
        #pragma unroll
        for (int ni = 0; ni < 4; ++ni) {
            float s = csum[ni];
            s += __shfl_xor(s, 16);
            s += __shfl_xor(s, 32);
            if ((lane >> 4) == 0) {
                int c = col0 + wn * 64 + ni * 16 + ecol;
                float w = (MODE == 2) ? alpha * s : s;
                CP[(size_t)(by * 2 + wm) * N + c] = w;
            }
        }
    }
}

template<int MODE>
__global__ __launch_bounds__(256)
void gemm_scan_k(const u16* __restrict__ Ah, const u16* __restrict__ Al,
                 const u16* __restrict__ Wh, const u16* __restrict__ Wl,
                 float* __restrict__ C, u16* __restrict__ Chi, u16* __restrict__ Clo,
                 u16* __restrict__ ChiT, u16* __restrict__ CloT,
                 const float* __restrict__ Zf, const float* __restrict__ add,
                 const float* __restrict__ bias, float* __restrict__ CP,
                 int M, int N, int K, float alpha)
{
    __shared__ u16 lds[2][32768];
    int bx, by; xcd_swizzle(bx, by);
    scan_body<MODE>(&lds[0][0], bx, by, Ah, Al, Wh, Wl, C, Chi, Clo, ChiT, CloT,
                    Zf, add, bias, CP, M, N, K, alpha);
}

// merged launch: gW2 (MODE3, 4x8 tiles at by<8) || dh (MODE4, 4x2 tiles at by>=8)
__global__ __launch_bounds__(256)
void gemm_scan_pair_k(const u16* __restrict__ rTh, const u16* __restrict__ rTl,
                      const u16* __restrict__ hTh, const u16* __restrict__ hTl,
                      float* __restrict__ gW2,
                      const u16* __restrict__ rh_, const u16* __restrict__ rl_,
                      const u16* __restrict__ w2th, const u16* __restrict__ w2tl,
                      u16* __restrict__ dhTh, u16* __restrict__ dhTl,
                      const float* __restrict__ z1, float* __restrict__ cp1, float cs)
{
    __shared__ u16 lds[2][32768];
    if (blockIdx.y < 8) {
        scan_body<3>(&lds[0][0], blockIdx.x, blockIdx.y, rTh, rTl, hTh, hTl,
                     gW2, nullptr, nullptr, nullptr, nullptr, nullptr, nullptr,
                     nullptr, nullptr, 1024, 512, 256, cs);
    } else {
        scan_body<4>(&lds[0][0], blockIdx.x, blockIdx.y - 8, rh_, rl_, w2th, w2tl,
                     nullptr, nullptr, nullptr, dhTh, dhTl, z1, nullptr,
                     nullptr, cp1, 256, 512, 1024, cs);
    }
}

// ---------------- small kernels ----------------
__global__ void cvt_split_k(const float* __restrict__ in, u16* __restrict__ hi,
                            u16* __restrict__ lo, int n4) {
    int i = blockIdx.x * 256 + threadIdx.x;
    if (i >= n4) return;
    float4 v = *(const float4*)&in[(size_t)i * 4];
    u16 h0,l0,h1,l1,h2,l2,h3,l3;
    split2(v.x,h0,l0); split2(v.y,h1,l1); split2(v.z,h2,l2); split2(v.w,h3,l3);
    ushort4 hv = {h0,h1,h2,h3}, lv = {l0,l1,l2,l3};
    *(ushort4*)&hi[(size_t)i * 4] = hv;
    *(ushort4*)&lo[(size_t)i * 4] = lv;
}
__global__ void transpose_split_k(const float* __restrict__ in, u16* __restrict__ outh,
                                  u16* __restrict__ outl, int R, int C) {
    __shared__ float t[32][33];
    const int c0 = blockIdx.x * 32, r0 = blockIdx.y * 32;
    const size_t zoff = (size_t)blockIdx.z * R * C;
    const int tx = threadIdx.x & 31, ty = threadIdx.x >> 5;
    #pragma unroll
    for (int p = 0; p < 4; ++p) {
        int r = ty + p * 8;
        t[r][tx] = in[zoff + (size_t)(r0 + r) * C + c0 + tx];
    }
    __syncthreads();
    #pragma unroll
    for (int p = 0; p < 4; ++p) {
        int cc = ty + p * 8;
        float v = t[tx][cc];
        u16 h, l; split2(v, h, l);
        size_t o = zoff + (size_t)(c0 + cc) * R + r0 + tx;
        outh[o] = h; outl[o] = l;
    }
}
__global__ void update3_k(float* __restrict__ p, float* __restrict__ mo,
                          const float* __restrict__ g,
                          const float* __restrict__ cp1, const float* __restrict__ cp2,
                          u16* __restrict__ w1h, u16* __restrict__ w1l,
                          u16* __restrict__ w2h, u16* __restrict__ w2l,
                          u16* __restrict__ w2th, u16* __restrict__ w2tl, int n) {
    int i = blockIdx.x * 256 + threadIdx.x;
    if (i >= n) return;
    float gi;
    if (i < 524288) gi = g[i];
    else if (i < 524800) {
        int j = i - 524288;
        gi = cp1[j] + cp1[512 + j] + cp1[1024 + j] + cp1[1536 + j];
    } else if (i < 1049088) gi = g[i];
    else {
        int j = i - 1049088;
        gi = cp2[j] + cp2[1024 + j] + cp2[2048 + j] + cp2[3072 + j];
    }
    float m = ETA_C * mo[i] - THETA_C * gi;
    mo[i] = m;
    float pv = (1.f - ALPHA_C) * p[i] + m;
    p[i] = pv;
    if (i < 524288) {
        u16 h, l; split2(pv, h, l); w1h[i] = h; w1l[i] = l;
    } else if (i >= 524800 && i < 1049088) {
        int j = i - 524800;
        u16 h, l; split2(pv, h, l);
        w2h[j] = h; w2l[j] = l;
        int tj = (j & 511) * 1024 + (j >> 9);
        w2th[tj] = h; w2tl[tj] = l;
    }
}
__global__ void tokens_split_k(const float* __restrict__ P, const float* __restrict__ memtok,
                               const float* __restrict__ x, u16* __restrict__ th,
                               u16* __restrict__ tl) {
    size_t idx = (size_t)blockIdx.x * 256 + threadIdx.x;
    int d = (int)(idx & 1023);
    int n = (int)((idx >> 10) % NTOK);
    int b = (int)(idx / ((size_t)NTOK * 1024));
    float v;
    if (n < NPERS)            v = P[(size_t)n * 1024 + d];
    else if (n < NPERS + TSEQ) v = memtok[((size_t)b * TSEQ + (n - NPERS)) * 1024 + d];
    else                      v = x[((size_t)b * TSEQ + (n - NPERS - TSEQ)) * 1024 + d];
    u16 h, l; split2(v, h, l); th[idx] = h; tl[idx] = l;
}
__global__ void mul_k(const float* __restrict__ a, const float* __restrict__ b,
                      float* __restrict__ o, int n) {
    int i = blockIdx.x * 256 + threadIdx.x;
    if (i < n) o[i] = a[i] * b[i];
}

// ---------------- MFMA flash attention: split-KV partial + merge ----------------
__global__ __launch_bounds__(256)
void flash_part_k(const u16* __restrict__ Qsh, const u16* __restrict__ Qsl,
                  const u16* __restrict__ Ksh, const u16* __restrict__ Ksl,
                  const u16* __restrict__ Vts, float* __restrict__ Of,
                  float* __restrict__ Mf, float* __restrict__ Lf)
{
    __shared__ u16 lds[20480];
    u16* KH = lds;            u16* KL = lds + 4096;
    u16* VT = lds + 8192;
    u16* PH = lds + 12288;    u16* PL = lds + 16384;

    int lid = blockIdx.x + (blockIdx.y << 4) + (blockIdx.z << 8);
    int t1024 = ((lid & 7) << 7) | (lid >> 3);
    const int qt = t1024 & 15, h = (t1024 >> 4) & 15;
    const int zb = t1024 >> 8;
    const int b = zb >> 1, z = zb & 1;

    const int tid = threadIdx.x;
    const int lane = tid & 63, wid = tid >> 6;
    const int fr = lane & 15, kq = lane >> 4;
    const int bh = b * 16 + h;
    const int q0c = qt * 64;
    const int q0a = NPERS + TSEQ + q0c;
    const int ntile = ((q0a + 63) >> 6) + 1;
    const int half = ntile >> 1;
    const int jt0 = z ? half : 0;
    const int jt1 = z ? ntile : half;
    const int l8 = lane & 7, lr8 = lane >> 3;

    auto stageKV = [&](int jt) {
        const int j0 = jt * 64;
        #pragma unroll
        for (int jj = 0; jj < 6; ++jj) {
            int j = wid * 6 + jj;
            int buf = j >> 3, i8 = j & 7;
            if (buf < 2) {
                int row = i8 * 8 + lr8;
                int grow = j0 + row; if (grow > NTOK - 1) grow = NTOK - 1;
                int c = l8 ^ (row & 7);
                const u16* src = (buf == 0 ? Ksh : Ksl) +
                                 (((size_t)bh * NTOK + grow) << 6) + c * 8;
                gload_lds16(src, (buf == 0 ? KH : KL) + i8 * 512);
            } else {
                int d = i8 * 8 + lr8;
                int c = l8 ^ (d & 7);
                int col = j0 + c * 8; if (col > NTOK - 8) col = NTOK - 8;
                const u16* src = Vts + ((size_t)bh * 64 + d) * NTOK + col;
                gload_lds16(src, VT + i8 * 512);
            }
        }
    };

    s16x8 qh[2], ql[2];
    {
        const size_t qrow = ((size_t)bh * 1024 + q0c + wid * 16 + fr) << 6;
        #pragma unroll
        for (int kb = 0; kb < 2; ++kb) {
            qh[kb] = *(const s16x8*)&Qsh[qrow + (size_t)(kb * 4 + kq) * 8];
            ql[kb] = *(const s16x8*)&Qsl[qrow + (size_t)(kb * 4 + kq) * 8];
        }
    }

    f32x4 Oa[4] = {};
    float mrow[4], lrow[4];
    #pragma unroll
    for (int r = 0; r < 4; ++r) { mrow[r] = -INFINITY; lrow[r] = 0.f; }

    for (int jt = jt0; jt < jt1; ++jt) {
        const int j0 = jt * 64;
        stageKV(jt);
        __syncthreads();

        f32x4 sacc[4] = {};
        __builtin_amdgcn_s_setprio(1);
        #pragma unroll
        for (int nt = 0; nt < 4; ++nt) {
            #pragma unroll
            for (int kb = 0; kb < 2; ++kb) {
                int br = nt * 16 + fr;
                int sl = (kb * 4 + kq) ^ (fr & 7);
                s16x8 kh = *(const s16x8*)&KH[br * 64 + sl * 8];
                s16x8 kl = *(const s16x8*)&KL[br * 64 + sl * 8];
                sacc[nt] = __builtin_amdgcn_mfma_f32_16x16x32_bf16(qh[kb], kh, sacc[nt], 0, 0, 0);
                sacc[nt] = __builtin_amdgcn_mfma_f32_16x16x32_bf16(ql[kb], kh, sacc[nt], 0, 0, 0);
                sacc[nt] = __builtin_amdgcn_mfma_f32_16x16x32_bf16(qh[kb], kl, sacc[nt], 0, 0, 0);
            }
        }
        __builtin_amdgcn_s_setprio(0);

        #pragma unroll
        for (int r = 0; r < 4; ++r) {
            const int qloc = kq * 4 + r;
            const int qi = q0a + wid * 16 + qloc;
            float sv[4], tmax = -INFINITY;
            #pragma unroll
            for (int nt = 0; nt < 4; ++nt) {
                int kj = j0 + nt * 16 + fr;
                sv[nt] = (kj <= qi) ? sacc[nt][r] : -INFINITY;
                tmax = fmaxf(tmax, sv[nt]);
            }
            #pragma unroll
            for (int off = 1; off < 16; off <<= 1)
                tmax = fmaxf(tmax, __shfl_xor(tmax, off));
            float mnew = fmaxf(mrow[r], tmax);
            float scale = __expf(mrow[r] - mnew);
            float psum = 0.f;
            float p4[4];
            #pragma unroll
            for (int nt = 0; nt < 4; ++nt) { p4[nt] = __expf(sv[nt] - mnew); psum += p4[nt]; }
            #pragma unroll
            for (int off = 1; off < 16; off <<= 1)
                psum += __shfl_xor(psum, off);
            lrow[r] = lrow[r] * scale + psum;
            mrow[r] = mnew;
            #pragma unroll
            for (int dt = 0; dt < 4; ++dt) Oa[dt][r] *= scale;
            const int prow = wid * 16 + qloc;
            #pragma unroll
            for (int nt = 0; nt < 4; ++nt) {
                u16 ph, pl; split2(p4[nt], ph, pl);
                int col = nt * 16 + fr;
                int sl = (col >> 3) ^ (qloc & 7);
                int off = prow * 64 + sl * 8 + (col & 7);
                PH[off] = ph; PL[off] = pl;
            }
        }

        __builtin_amdgcn_s_setprio(1);
        #pragma unroll
        for (int kb = 0; kb < 2; ++kb) {
            int pr = wid * 16 + fr;
            int sl = (kb * 4 + kq) ^ (fr & 7);
            s16x8 pa = *(const s16x8*)&PH[pr * 64 + sl * 8];
            s16x8 pb = *(const s16x8*)&PL[pr * 64 + sl * 8];
            #pragma unroll
            for (int dt = 0; dt < 4; ++dt) {
                int vr = dt * 16 + fr;
                s16x8 vb = *(const s16x8*)&VT[vr * 64 + sl * 8];
                Oa[dt] = __builtin_amdgcn_mfma_f32_16x16x32_bf16(pa, vb, Oa[dt], 0, 0, 0);
                Oa[dt] = __builtin_amdgcn_mfma_f32_16x16x32_bf16(pb, vb, Oa[dt], 0, 0, 0);
            }
        }
        __builtin_amdgcn_s_setprio(0);
        __syncthreads();
    }

    const size_t obase = ((((size_t)z * 2 + b) * 16 + h) * 16 + qt) * 4096;
    const size_t mlb   = ((((size_t)z * 2 + b) * 16 + h) * 16 + qt) * 64;
    #pragma unroll
    for (int r = 0; r < 4; ++r) {
        int rl = wid * 16 + kq * 4 + r;
        if (fr == 0) { Mf[mlb + rl] = mrow[r]; Lf[mlb + rl] = lrow[r]; }
        #pragma unroll
        for (int dt = 0; dt < 4; ++dt)
            Of[obase + (size_t)rl * 64 + dt * 16 + fr] = Oa[dt][r];
    }
}

__global__ __launch_bounds__(256)
void flash_merge_k(const float* __restrict__ Of, const float* __restrict__ Mf,
                   const float* __restrict__ Lf, u16* __restrict__ oh, u16* __restrict__ ol)
{
    const int qt = blockIdx.x, h = blockIdx.y, b = blockIdx.z;
    const int tid = threadIdx.x;
    const int row = tid >> 2, quad = tid & 3;
    const size_t b0 = ((((size_t)0 * 2 + b) * 16 + h) * 16 + qt) * 4096 + (size_t)row * 64;
    const size_t b1 = ((((size_t)1 * 2 + b) * 16 + h) * 16 + qt) * 4096 + (size_t)row * 64;
    const size_t m0i = ((((size_t)0 * 2 + b) * 16 + h) * 16 + qt) * 64 + row;
    const size_t m1i = ((((size_t)1 * 2 + b) * 16 + h) * 16 + qt) * 64 + row;
    float m0 = Mf[m0i], m1 = Mf[m1i], l0 = Lf[m0i], l1 = Lf[m1i];
    float m = fmaxf(m0, m1);
    float e0 = __expf(m0 - m), e1 = __expf(m1 - m);
    float inv = 1.f / (l0 * e0 + l1 * e1);
    const size_t orow = ((size_t)(b * 1024 + qt * 64 + row)) * 1024 + h * 64;
    #pragma unroll
    for (int i = 0; i < 4; ++i) {
        int col = quad * 16 + i * 4;
        float4 v0 = *(const float4*)&Of[b0 + col];
        float4 v1 = *(const float4*)&Of[b1 + col];
        float o0 = (v0.x * e0 + v1.x * e1) * inv;
        float o1 = (v0.y * e0 + v1.y * e1) * inv;
        float o2 = (v0.z * e0 + v1.z * e1) * inv;
        float o3 = (v0.w * e0 + v1.w * e1) * inv;
        u16 h0,l0_,h1,l1_,h2,l2_,h3,l3_;
        split2(o0,h0,l0_); split2(o1,h1,l1_); split2(o2,h2,l2_); split2(o3,h3,l3_);
        ushort4 hv = {h0,h1,h2,h3}, lv = {l0_,l1_,l2_,l3_};
        *(ushort4*)&oh[orow + col] = hv;
        *(ushort4*)&ol[orow + col] = lv;
    }
}

// ---------------- launch ----------------
extern "C" void kernel_launch(void* const* d_in, const int* in_sizes, int n_in,
                              void* d_out, int out_size, void* d_ws, size_t ws_size,
                              hipStream_t stream)
{
    const float* x     = (const float*)d_in[0];
    const float* Wqkv  = (const float*)d_in[1];
    const float* mW1   = (const float*)d_in[2];
    const float* mb1   = (const float*)d_in[3];
    const float* mW2   = (const float*)d_in[4];
    const float* mb2   = (const float*)d_in[5];
    const float* Pp    = (const float*)d_in[6];
    const float* Wqa   = (const float*)d_in[7];
    const float* Wo    = (const float*)d_in[8];
    const float* ffW1  = (const float*)d_in[9];
    const float* ffb1  = (const float*)d_in[10];
    const float* ffW2  = (const float*)d_in[11];
    const float* ffb2  = (const float*)d_in[12];
    char* wsb = (char*)d_ws;
    float* outp = (float*)d_out;

    // region A (multiplexed)
    float* z1    = (float*)(wsb + oRA);
    float* grd   = (float*)(wsb + oRA + 3145728);
    float* cp2   = (float*)(wsb + oRA + 7346176);
    float* cp1   = (float*)(wsb + oRA + 7362560);
    u16* hh_     = (u16*)(wsb + oRA + 8388608);
    u16* hl_     = (u16*)(wsb + oRA + 8650752);
    u16* hTh     = (u16*)(wsb + oRA + 9437184);
    u16* hTl     = (u16*)(wsb + oRA + 9699328);
    u16* rh_     = (u16*)(wsb + oRA + 10485760);
    u16* rl_     = (u16*)(wsb + oRA + 11010048);
    u16* rTh     = (u16*)(wsb + oRA + 11534336);
    u16* rTl     = (u16*)(wsb + oRA + 12058624);
    u16* dhTh    = (u16*)(wsb + oRA + 12582912);
    u16* dhTl    = (u16*)(wsb + oRA + 12845056);
    u16* kcTh    = (u16*)(wsb + oRA + 16777216);
    u16* kcTl    = (u16*)(wsb + oRA + 20971520);
    // flash partials + attn operands (region A is dead between scan and FFN)
    float* Of    = (float*)(wsb + oRA);                   // 16.78 MB
    float* Mf    = (float*)(wsb + oRA + 16777216);        // 0.26 MB
    float* Lf    = (float*)(wsb + oRA + 17039360);        // 0.26 MB
    u16* fVth    = (u16*)(wsb + oRA + 17825792);          // 8.45 MB
    u16* fKl     = (u16*)(wsb + oRA + 26279936);          // 8.45 MB (ends 34.73 MB)
    u16* Woh     = (u16*)(wsb + oRA);
    u16* Wol     = (u16*)(wsb + oRA + 2097152);
    u16* ffhh    = (u16*)(wsb + oRA);
    u16* ffhl    = (u16*)(wsb + oRA + 16777216);
    u16* outbh   = (u16*)(wsb + oRA + 33554432);
    u16* outbl   = (u16*)(wsb + oRA + 37748736);
    u16* newQh   = (u16*)(wsb + oRA);
    u16* newQl   = (u16*)(wsb + oRA + 4194304);
    u16* hzh     = (u16*)(wsb + oRA + 8388608);
    u16* hzl     = (u16*)(wsb + oRA + 10485760);
    float* memq  = (float*)(wsb + oRA + 12582912);
    float* partA0 = (float*)(wsb + oRA);
    float* partA1 = (float*)(wsb + oRA + 4194304);
    float* partA2 = (float*)(wsb + oRA + 16777216);
    // region B
    float* Vb    = (float*)(wsb + oRB + 8388608);
    u16* tokh    = (u16*)(wsb + oRB);
    u16* tokl    = (u16*)(wsb + oRB + 8454144);
    u16* oh      = (u16*)(wsb + oRB);
    u16* ol      = (u16*)(wsb + oRB + 4194304);
    u16* y1h     = (u16*)(wsb + oRB + 8388608);
    u16* y1l     = (u16*)(wsb + oRB + 12582912);
    float* partB = (float*)(wsb + oRB);
    // region C
    u16* xh      = (u16*)(wsb + oRC);
    u16* xl      = (u16*)(wsb + oRC + 4194304);
    float* mom   = (float*)(wsb + oRC);
    u16* pW2Th   = (u16*)(wsb + oRC + 5242880);
    u16* pW2Tl   = (u16*)(wsb + oRC + 6291456);
    u16* Wqah    = (u16*)(wsb + oRC);
    u16* Wqal    = (u16*)(wsb + oRC + 6291456);
    // region D
    u16* Qh      = (u16*)(wsb + oRD);
    u16* Ql      = (u16*)(wsb + oRD + 4194304);
    u16* kchh    = (u16*)(wsb + oRD + 8388608);
    u16* kchl    = (u16*)(wsb + oRD + 12582912);
    u16* t1h     = (u16*)(wsb + oRD + 8388608);
    u16* t1l     = (u16*)(wsb + oRD + 10485760);
    float* memtok= (float*)(wsb + oRD);
    u16* fKh     = (u16*)(wsb + oRD);                     // 8.45 MB during attn
    u16* ffW1h   = (u16*)(wsb + oRD);
    u16* ffW1l   = (u16*)(wsb + oRD + 8388608);
    u16* ffW2h   = (u16*)(wsb + oRD);
    u16* ffW2l   = (u16*)(wsb + oRD + 8388608);
    // persistent
    u16* Wqkvh   = (u16*)(wsb + oRE);
    u16* Wqkvl   = (u16*)(wsb + oRE + 6291456);
    u16* pW1h    = (u16*)(wsb + oRF);
    u16* pW1l    = (u16*)(wsb + oRF + 1048576);
    u16* pW2h    = (u16*)(wsb + oRF + 2097152);
    u16* pW2l    = (u16*)(wsb + oRF + 3145728);
    float* par   = (float*)(wsb + oRG);
    float* outb  = (float*)(wsb + oRH);
    u16* fQh     = (u16*)(wsb + oRH);
    u16* fQl     = (u16*)(wsb + oRH + 4194304);

    // init memory-MLP params
    hipMemcpyAsync(par + PW1, mW1, 524288 * sizeof(float), hipMemcpyDeviceToDevice, stream);
    hipMemcpyAsync(par + PB1, mb1, 512 * sizeof(float), hipMemcpyDeviceToDevice, stream);
    hipMemcpyAsync(par + PW2, mW2, 524288 * sizeof(float), hipMemcpyDeviceToDevice, stream);
    hipMemcpyAsync(par + PB2, mb2, 1024 * sizeof(float), hipMemcpyDeviceToDevice, stream);

    // qkv = x @ Wqkv^T (fused epilogue: Q split, kc split, kcT split, V f32)
    cvt_split_k<<<2048, 256, 0, stream>>>(x, xh, xl, 524288);
    cvt_split_k<<<3072, 256, 0, stream>>>(Wqkv, Wqkvh, Wqkvl, 786432);
    gemm_qkv_k<<<dim3(24, 16), 256, 0, stream>>>(xh, xl, Wqkvh, Wqkvl,
        Qh, Ql, kchh, kchl, kcTh, kcTl, Vb, 2048, 3072, 1024);

    // scan prep (xh/xl dead now)
    hipMemsetAsync(mom, 0, PSZ * sizeof(float), stream);
    cvt_split_k<<<512, 256, 0, stream>>>(par + PW1, pW1h, pW1l, 131072);
    cvt_split_k<<<512, 256, 0, stream>>>(par + PW2, pW2h, pW2l, 131072);
    transpose_split_k<<<dim3(16, 32, 1), 256, 0, stream>>>(par + PW2, pW2Th, pW2Tl, 1024, 512);

    // memory scan: z1 -> r -> {gW2 || dh} -> gW1 -> update  (BK=64 dbuf GEMMs)
    const float cs = 2.f / (float)(BATCH * 128 * DIMD);
    for (int c = 0; c < NCH; ++c) {
        const u16* kch = kchh + (size_t)c * 262144;
        const u16* kcl = kchl + (size_t)c * 262144;
        const u16* kth = kcTh + (size_t)c * 262144;
        const u16* ktl = kcTl + (size_t)c * 262144;
        const float* vc = Vb + (size_t)c * 262144;
        gemm_scan_k<1><<<dim3(4, 2), 256, 0, stream>>>(kch, kcl, pW1h, pW1l,
            z1, hh_, hl_, hTh, hTl, nullptr, nullptr, par + PB1, nullptr, 256, 512, 1024, 1.f);
        gemm_scan_k<2><<<dim3(8, 2), 256, 0, stream>>>(hh_, hl_, pW2h, pW2l,
            nullptr, rh_, rl_, rTh, rTl, nullptr, vc, par + PB2, cp2, 256, 1024, 512, cs);
        gemm_scan_pair_k<<<dim3(4, 10), 256, 0, stream>>>(rTh, rTl, hTh, hTl, grd + PW2,
            rh_, rl_, pW2Th, pW2Tl, dhTh, dhTl, z1, cp1, cs);
        gemm_scan_k<3><<<dim3(8, 4), 256, 0, stream>>>(dhTh, dhTl, kth, ktl,
            grd + PW1, nullptr, nullptr, nullptr, nullptr, nullptr, nullptr, nullptr, nullptr,
            512, 1024, 256, 1.f);
        update3_k<<<4102, 256, 0, stream>>>(par, mom, grd, cp1, cp2,
            pW1h, pW1l, pW2h, pW2l, pW2Th, pW2Tl, (int)PSZ);
    }

    // memory readout (split-K: t1 S=4 part@A2, memtok S=2 part@A0)
    gemm_mfma_sk(stream, 1, 0, 1, Qh, Ql, pW1h, pW1l, nullptr, t1h, t1l,
                 2048, 512, 1024, par + PB1, 4, partA2);
    gemm_mfma_sk(stream, 0, 1, 0, t1h, t1l, pW2h, pW2l, memtok, nullptr, nullptr,
                 2048, 1024, 512, par + PB2, 2, partA0);

    // tokens + fused attention qkv (writes fQ/fK/fVt directly)
    tokens_split_k<<<16512, 256, 0, stream>>>(Pp, memtok, x, tokh, tokl);
    cvt_split_k<<<3072, 256, 0, stream>>>(Wqa, Wqah, Wqal, 786432);
    gemm_aqkv_k<<<dim3(24, 33), 256, 0, stream>>>(tokh, tokl, Wqah, Wqal,
        fQh, fQl, fKh, fKl, fVth, 4128, 3072, 1024);

    // MFMA flash attention: split-KV partials + merge
    flash_part_k<<<dim3(16, 16, 4), 256, 0, stream>>>(fQh, fQl, fKh, fKl, fVth, Of, Mf, Lf);
    flash_merge_k<<<dim3(16, 16, 2), 256, 0, stream>>>(Of, Mf, Lf, oh, ol);

    // Wo projection + FFN (split-K on grid-starved GEMMs)
    cvt_split_k<<<1024, 256, 0, stream>>>(Wo, Woh, Wol, 262144);
    gemm_mfma_sk(stream, 0, 0, 1, oh, ol, Woh, Wol, nullptr, y1h, y1l,
                 2048, 1024, 1024, nullptr, 2, partA1);
    cvt_split_k<<<4096, 256, 0, stream>>>(ffW1, ffW1h, ffW1l, 1048576);
    gemm_mfma(stream, 2, 0, 1, y1h, y1l, ffW1h, ffW1l, nullptr, ffhh, ffhl, 2048, 4096, 1024, ffb1);
    cvt_split_k<<<4096, 256, 0, stream>>>(ffW2, ffW2h, ffW2l, 1048576);
    gemm_mfma_sk(stream, 0, 1, 1, ffhh, ffhl, ffW2h, ffW2l, outb, outbh, outbl,
                 2048, 1024, 4096, ffb2, 2, partB);

    // gate
    gemm_mfma_sk(stream, 0, 0, 1, outbh, outbl, Wqkvh, Wqkvl, nullptr, newQh, newQl,
                 2048, 1024, 1024, nullptr, 2, partB);
    gemm_mfma_sk(stream, 1, 0, 1, newQh, newQl, pW1h, pW1l, nullptr, hzh, hzl,
                 2048, 512, 1024, par + PB1, 4, partB);
    gemm_mfma_sk(stream, 0, 1, 0, hzh, hzl, pW2h, pW2l, memq, nullptr, nullptr,
                 2048, 1024, 512, par + PB2, 2, partB);
    mul_k<<<8192, 256, 0, stream>>>(outb, memq, outp, 2097152);
}

// Round 14
// 1360.662 us; speedup vs baseline: 1.2316x; 1.0259x over previous
//
#include <hip/hip_runtime.h>
#include <math.h>

// ---------------- problem constants ----------------
#define BATCH 2
#define TSEQ 1024
#define DIMD 1024
#define NPERS 16
#define NCH 8
#define NTOK 2064
#define ETA_C 0.9f
#define THETA_C 0.1f
#define ALPHA_C 0.02f

typedef __attribute__((ext_vector_type(4))) float f32x4;
typedef __attribute__((ext_vector_type(8))) short s16x8;
typedef unsigned short u16;

// ---------------- bf16 helpers ----------------
__device__ __forceinline__ u16 f2bf(float f) {
    unsigned int u = __float_as_uint(f);
    return (u16)((u + 0x7fffu + ((u >> 16) & 1u)) >> 16);
}
__device__ __forceinline__ float bf2f(u16 h) { return __uint_as_float(((unsigned)h) << 16); }
__device__ __forceinline__ void split2(float v, u16& h, u16& l) {
    h = f2bf(v); l = f2bf(v - bf2f(h));
}

// ---------------- workspace layout (byte offsets) ----------------
static const size_t oRA = 0;                       // 50,724,864 multiplexed
static const size_t oRB = 50724864;                // 16,908,288
static const size_t oRC = 67633152;                // 12,582,912
static const size_t oRD = 80216064;                // 16,777,216
static const size_t oRE = 96993280;                // 12,582,912 Wqkv h/l (persistent)
static const size_t oRF = 109576192;               //  4,194,304 parW h/l (persistent)
static const size_t oRG = 113770496;               //  4,200,448 par (persistent)
static const size_t oRH = 117970944;               //  8,388,608 outb f32 / fQ split
// total 126,359,552 bytes

static const size_t PW1 = 0, PB1 = 524288, PW2 = 524800, PB2 = 1049088, PSZ = 1050112;

// ---------------- async global->LDS ----------------
__device__ __forceinline__ void gload_lds16(const u16* g, u16* l) {
    __builtin_amdgcn_global_load_lds(
        (const __attribute__((address_space(1))) unsigned int*)g,
        (__attribute__((address_space(3))) unsigned int*)l, 16, 0, 0);
}

// XCD-chunked block swizzle (bijective when nwg % 8 == 0; identity fallback).
__device__ __forceinline__ void xcd_swizzle(int& bx, int& by) {
    int gx = gridDim.x, nwg = gx * gridDim.y;
    int lid = blockIdx.y * gx + blockIdx.x;
    int t = lid;
    if ((nwg & 7) == 0) {
        int q = nwg >> 3;
        t = (lid & 7) * q + (lid >> 3);
    }
    bx = t % gx; by = t / gx;
}

// stage one 128x32 bf16 tile (this wave's quarter) into buf + wid*4096
__device__ __forceinline__ void stage_tile(const u16* sp, u16* buf, int rbase,
                                           int M, int clampM, int K, int k0,
                                           int wid, int lane) {
    const int lr = lane >> 2, lc = lane & 3;
    #pragma unroll
    for (int i = 0; i < 8; ++i) {
        int r = i * 16 + lr;
        int gr = rbase + r;
        if (clampM && gr >= M) gr = M - 1;
        int g = lc ^ ((r >> 1) & 3);
        gload_lds16(sp + (size_t)gr * K + k0 + g * 8, buf + wid * 4096 + i * 512);
    }
}

// stage one 128x64 bf16 tile into buf + wid*8192 (scan path, BK=64)
__device__ __forceinline__ void stage_tile64(const u16* sp, u16* buf, int rbase,
                                             int K, int k0, int wid, int lane) {
    const int lr = lane >> 3, lc = lane & 7;
    #pragma unroll
    for (int i = 0; i < 16; ++i) {
        int r = i * 8 + lr;
        int gr = rbase + r;
        int g = lc ^ (r & 7);
        gload_lds16(sp + (size_t)gr * K + k0 + g * 8, buf + wid * 8192 + i * 512);
    }
}

// shared BK=32 dbuf main loop: accumulates into acc[4][4].
// NPROD=3: hh+hl+lh (fp32-quality). NPROD=2: hh+hl (drops al term, ~2^-9 rel err).
template<int NPROD>
__device__ __forceinline__ void mm_loop32(u16 lds[2][16384],
                const u16* sp, int rbase, int M, int clampM, int K,
                int kbeg, int kend, int wid, int lane, int wm, int wn,
                f32x4 acc[4][4]) {
    const int frow = lane & 15, kblk = lane >> 4;
    const int nt = (kend - kbeg) >> 5;
    const int doStage = (NPROD == 3) || (wid != 1);   // skip unused A-low staging
    if (doStage) stage_tile(sp, lds[0], rbase, M, clampM, K, kbeg, wid, lane);
    for (int t = 0; t < nt; ++t) {
        __syncthreads();
        if (t + 1 < nt && doStage)
            stage_tile(sp, lds[(t + 1) & 1], rbase, M, clampM, K, kbeg + ((t + 1) << 5), wid, lane);
        const u16* cb = lds[t & 1];
        s16x8 bh[4], bl[4];
        #pragma unroll
        for (int ni = 0; ni < 4; ++ni) {
            int br = wn * 64 + ni * 16 + frow;
            int pc = kblk ^ ((br >> 1) & 3);
            bh[ni] = *(const s16x8*)&cb[2 * 4096 + br * 32 + pc * 8];
            bl[ni] = *(const s16x8*)&cb[3 * 4096 + br * 32 + pc * 8];
        }
        #pragma unroll
        for (int mi = 0; mi < 4; ++mi) {
            int ar = wm * 64 + mi * 16 + frow;
            int pc = kblk ^ ((ar >> 1) & 3);
            s16x8 ah = *(const s16x8*)&cb[0 * 4096 + ar * 32 + pc * 8];
            s16x8 al;
            if (NPROD == 3) al = *(const s16x8*)&cb[1 * 4096 + ar * 32 + pc * 8];
            #pragma unroll
            for (int ni = 0; ni < 4; ++ni) {
                acc[mi][ni] = __builtin_amdgcn_mfma_f32_16x16x32_bf16(ah, bh[ni], acc[mi][ni], 0, 0, 0);
                acc[mi][ni] = __builtin_amdgcn_mfma_f32_16x16x32_bf16(ah, bl[ni], acc[mi][ni], 0, 0, 0);
                if (NPROD == 3)
                    acc[mi][ni] = __builtin_amdgcn_mfma_f32_16x16x32_bf16(al, bh[ni], acc[mi][ni], 0, 0, 0);
            }
        }
    }
}

// ---------------- split-bf16 MFMA GEMM:  C = act(A @ W^T + bias) ----------------
template<int ACTF, int WF32, int WSPLIT, int PARTIAL, int NPROD>
__global__ __launch_bounds__(256)
void gemm_mfma_k(const u16* __restrict__ Ah, const u16* __restrict__ Al,
                 const u16* __restrict__ Wh, const u16* __restrict__ Wl,
                 float* __restrict__ C, u16* __restrict__ Chi, u16* __restrict__ Clo,
                 int M, int N, int K, const float* __restrict__ bias)
{
    __shared__ u16 lds[2][16384];
    const int tid = threadIdx.x;
    const int lane = tid & 63, wid = tid >> 6;
    const int wm = wid >> 1, wn = wid & 1;
    int bx, by; xcd_swizzle(bx, by);
    const int row0 = by * 128, col0 = bx * 128;
    const u16* sp = (wid == 0) ? Ah : (wid == 1) ? Al : (wid == 2) ? Wh : Wl;
    const int rbase = (wid < 2) ? row0 : col0;
    const int clampM = (wid < 2) ? 1 : 0;
    f32x4 acc[4][4] = {};
    int kbeg = 0, kend = K;
    if (PARTIAL) {
        int Kseg = K / gridDim.z;
        kbeg = blockIdx.z * Kseg;
        kend = kbeg + Kseg;
    }
    mm_loop32<NPROD>(lds, sp, rbase, M, clampM, K, kbeg, kend, wid, lane, wm, wn, acc);

    const int erow = (lane >> 4) * 4, ecol = lane & 15;
    #pragma unroll
    for (int mi = 0; mi < 4; ++mi) {
        #pragma unroll
        for (int ni = 0; ni < 4; ++ni) {
            int c = col0 + wn * 64 + ni * 16 + ecol;
            float bv = (!PARTIAL && bias) ? bias[c] : 0.f;
            #pragma unroll
            for (int reg = 0; reg < 4; ++reg) {
                int r = row0 + wm * 64 + mi * 16 + erow + reg;
                if (r >= M) continue;
                float v = acc[mi][ni][reg] + bv;
                if (PARTIAL) {
                    C[((size_t)blockIdx.z * M + r) * N + c] = v;
                    continue;
                }
                if (ACTF == 1) v = v / (1.f + __expf(-v));
                else if (ACTF == 2) {
                    float u = 0.7978845608028654f * (v + 0.044715f * v * v * v);
                    v = 0.5f * v * (1.f + tanhf(u));
                }
                size_t o = (size_t)r * N + c;
                if (WF32) C[o] = v;
                if (WSPLIT) { u16 h, l; split2(v, h, l); Chi[o] = h; Clo[o] = l; }
            }
        }
    }
}

// fused qkv GEMM: writes Q split, kc split, kcT split, V f32 directly (M=2048,N=3072)
__global__ __launch_bounds__(256)
void gemm_qkv_k(const u16* __restrict__ Ah, const u16* __restrict__ Al,
                const u16* __restrict__ Wh, const u16* __restrict__ Wl,
                u16* __restrict__ Qh, u16* __restrict__ Ql,
                u16* __restrict__ kch, u16* __restrict__ kcl,
                u16* __restrict__ kcTh, u16* __restrict__ kcTl,
                float* __restrict__ Vb, int M, int N, int K)
{
    __shared__ u16 lds[2][16384];
    const int tid = threadIdx.x;
    const int lane = tid & 63, wid = tid >> 6;
    const int wm = wid >> 1, wn = wid & 1;
    int bx, by; xcd_swizzle(bx, by);
    const int row0 = by * 128, col0 = bx * 128;
    const u16* sp = (wid == 0) ? Ah : (wid == 1) ? Al : (wid == 2) ? Wh : Wl;
    const int rbase = (wid < 2) ? row0 : col0;
    f32x4 acc[4][4] = {};
    mm_loop32<3>(lds, sp, rbase, M, 0, K, 0, K, wid, lane, wm, wn, acc);

    const int erow = (lane >> 4) * 4, ecol = lane & 15;
    #pragma unroll
    for (int mi = 0; mi < 4; ++mi) {
        #pragma unroll
        for (int ni = 0; ni < 4; ++ni) {
            int c = col0 + wn * 64 + ni * 16 + ecol;
            #pragma unroll
            for (int reg = 0; reg < 4; ++reg) {
                int r = row0 + wm * 64 + mi * 16 + erow + reg;
                float v = acc[mi][ni][reg];
                int b = r >> 10, t = r & 1023;
                if (c < 1024) {
                    size_t o = (size_t)r * 1024 + c;
                    u16 h, l; split2(v, h, l); Qh[o] = h; Ql[o] = l;
                } else if (c < 2048) {
                    int d = c - 1024;
                    int ch = t >> 7, rr = t & 127;
                    size_t o = ((size_t)((ch * 2 + b) * 128 + rr)) * 1024 + d;
                    u16 h, l; split2(v, h, l);
                    kch[o] = h; kcl[o] = l;
                    size_t ot = (size_t)ch * 262144 + (size_t)d * 256 + b * 128 + rr;
                    kcTh[ot] = h; kcTl[ot] = l;
                } else {
                    int d = c - 2048;
                    int ch = t >> 7, rr = t & 127;
                    Vb[((size_t)((ch * 2 + b) * 128 + rr)) * 1024 + d] = v;
                }
            }
        }
    }
}

// fused attention-qkv GEMM (2-product): fQ (0.125-scaled, kept rows), fK split, fV^T hi
__global__ __launch_bounds__(256)
void gemm_aqkv_k(const u16* __restrict__ Ah, const u16* __restrict__ Al,
                 const u16* __restrict__ Wh, const u16* __restrict__ Wl,
                 u16* __restrict__ fQh, u16* __restrict__ fQl,
                 u16* __restrict__ fKh, u16* __restrict__ fKl,
                 u16* __restrict__ fVt, int M, int N, int K)
{
    __shared__ u16 lds[2][16384];
    const int tid = threadIdx.x;
    const int lane = tid & 63, wid = tid >> 6;
    const int wm = wid >> 1, wn = wid & 1;
    int bx, by; xcd_swizzle(bx, by);
    // dead Q tiles: cols<1024 only used for query rows n>=1040
    if (bx < 8 && ((by <= 7) || (by >= 17 && by <= 23))) return;
    const int row0 = by * 128, col0 = bx * 128;
    const u16* sp = (wid == 0) ? Ah : (wid == 1) ? Al : (wid == 2) ? Wh : Wl;
    const int rbase = (wid < 2) ? row0 : col0;
    const int clampM = (wid < 2) ? 1 : 0;
    f32x4 acc[4][4] = {};
    mm_loop32<2>(lds, sp, rbase, M, clampM, K, 0, K, wid, lane, wm, wn, acc);

    const int erow = (lane >> 4) * 4, ecol = lane & 15;
    #pragma unroll
    for (int mi = 0; mi < 4; ++mi) {
        #pragma unroll
        for (int ni = 0; ni < 4; ++ni) {
            int c = col0 + wn * 64 + ni * 16 + ecol;
            #pragma unroll
            for (int reg = 0; reg < 4; ++reg) {
                int r = row0 + wm * 64 + mi * 16 + erow + reg;
                if (r >= M) continue;
                float v = acc[mi][ni][reg];
                int b = (r >= 2064) ? 1 : 0;
                int n = r - b * 2064;
                if (c < 1024) {
                    if (n >= NPERS + TSEQ) {
                        int h = c >> 6, d = c & 63;
                        int row = n - (NPERS + TSEQ);
                        size_t o = (((size_t)(b * 16 + h)) * 1024 + row) * 64 + d;
                        u16 hh, ll; split2(0.125f * v, hh, ll);
                        fQh[o] = hh; fQl[o] = ll;
                    }
                } else if (c < 2048) {
                    int cc = c - 1024;
                    int h = cc >> 6, d = cc & 63;
                    size_t o = (((size_t)(b * 16 + h)) * NTOK + n) * 64 + d;
                    u16 hh, ll; split2(v, hh, ll);
                    fKh[o] = hh; fKl[o] = ll;
                } else {
                    int cc = c - 2048;
                    int h = cc >> 6, d = cc & 63;
                    fVt[(((size_t)(b * 16 + h)) * 64 + d) * NTOK + n] = f2bf(v);
                }
            }
        }
    }
}

// split-K reduce + epilogue
template<int ACTF, int WF32, int WSPLIT>
__global__ __launch_bounds__(256)
void reduce_k(const float* __restrict__ Cp, int S,
              float* __restrict__ C, u16* __restrict__ Chi, u16* __restrict__ Clo,
              const float* __restrict__ bias, int M, int N)
{
    int i = blockIdx.x * 256 + threadIdx.x;
    int n4 = (int)((size_t)M * N / 4);
    if (i >= n4) return;
    size_t off = (size_t)i * 4;
    float4 v = *(const float4*)&Cp[off];
    for (int z = 1; z < S; ++z) {
        float4 u = *(const float4*)&Cp[(size_t)z * M * N + off];
        v.x += u.x; v.y += u.y; v.z += u.z; v.w += u.w;
    }
    int c = (int)(off % N);
    float vv[4] = {v.x, v.y, v.z, v.w};
    #pragma unroll
    for (int j = 0; j < 4; ++j) {
        float w = vv[j];
        if (bias) w += bias[c + j];
        if (ACTF == 1) w = w / (1.f + __expf(-w));
        else if (ACTF == 2) {
            float u = 0.7978845608028654f * (w + 0.044715f * w * w * w);
            w = 0.5f * w * (1.f + tanhf(u));
        }
        if (WF32) C[off + j] = w;
        if (WSPLIT) { u16 h, l; split2(w, h, l); Chi[off + j] = h; Clo[off + j] = l; }
    }
}

static void gemm_mfma(hipStream_t s, int act, int wf32, int wsplit,
                      const u16* Ah, const u16* Al, const u16* Wh, const u16* Wl,
                      float* C, u16* Ch, u16* Cl, int M, int N, int K,
                      const float* bias, int nprod = 3)
{
    dim3 g(N / 128, (M + 127) / 128), b(256);
    if (act == 0 && wf32 == 1 && wsplit == 0)
        gemm_mfma_k<0,1,0,0,3><<<g,b,0,s>>>(Ah,Al,Wh,Wl,C,Ch,Cl,M,N,K,bias);
    else if (act == 0 && wf32 == 1 && wsplit == 1)
        gemm_mfma_k<0,1,1,0,3><<<g,b,0,s>>>(Ah,Al,Wh,Wl,C,Ch,Cl,M,N,K,bias);
    else if (act == 0 && wf32 == 0 && wsplit == 1)
        gemm_mfma_k<0,0,1,0,3><<<g,b,0,s>>>(Ah,Al,Wh,Wl,C,Ch,Cl,M,N,K,bias);
    else if (act == 1)
        gemm_mfma_k<1,0,1,0,3><<<g,b,0,s>>>(Ah,Al,Wh,Wl,C,Ch,Cl,M,N,K,bias);
    else if (nprod == 2)
        gemm_mfma_k<2,0,1,0,2><<<g,b,0,s>>>(Ah,Al,Wh,Wl,C,Ch,Cl,M,N,K,bias);
    else
        gemm_mfma_k<2,0,1,0,3><<<g,b,0,s>>>(Ah,Al,Wh,Wl,C,Ch,Cl,M,N,K,bias);
}

static void gemm_mfma_sk(hipStream_t s, int act, int wf32, int wsplit,
                         const u16* Ah, const u16* Al, const u16* Wh, const u16* Wl,
                         float* C, u16* Ch, u16* Cl, int M, int N, int K,
                         const float* bias, int S, float* part, int nprod = 3)
{
    if (S <= 1) { gemm_mfma(s, act, wf32, wsplit, Ah, Al, Wh, Wl, C, Ch, Cl, M, N, K, bias, nprod); return; }
    dim3 g(N / 128, (M + 127) / 128, S), b(256);
    if (nprod == 2)
        gemm_mfma_k<0,0,0,1,2><<<g,b,0,s>>>(Ah,Al,Wh,Wl,part,nullptr,nullptr,M,N,K,nullptr);
    else
        gemm_mfma_k<0,0,0,1,3><<<g,b,0,s>>>(Ah,Al,Wh,Wl,part,nullptr,nullptr,M,N,K,nullptr);
    int n4 = (int)((size_t)M * N / 4);
    dim3 rg((n4 + 255) / 256), rb(256);
    if (act == 0 && wf32 == 1 && wsplit == 0)
        reduce_k<0,1,0><<<rg,rb,0,s>>>(part, S, C, Ch, Cl, bias, M, N);
    else if (act == 0 && wf32 == 1 && wsplit == 1)
        reduce_k<0,1,1><<<rg,rb,0,s>>>(part, S, C, Ch, Cl, bias, M, N);
    else if (act == 0 && wf32 == 0 && wsplit == 1)
        reduce_k<0,0,1><<<rg,rb,0,s>>>(part, S, C, Ch, Cl, bias, M, N);
    else if (act == 1)
        reduce_k<1,0,1><<<rg,rb,0,s>>>(part, S, C, Ch, Cl, bias, M, N);
    else
        reduce_k<2,0,1><<<rg,rb,0,s>>>(part, S, C, Ch, Cl, bias, M, N);
}

// ---------------- scan-specialized split-bf16 MFMA GEMM body (BK=64 dbuf) -------
template<int MODE>
__device__ __forceinline__ void scan_body(u16* lds, int bx, int by,
                 const u16* __restrict__ Ah, const u16* __restrict__ Al,
                 const u16* __restrict__ Wh, const u16* __restrict__ Wl,
                 float* __restrict__ C, u16* __restrict__ Chi, u16* __restrict__ Clo,
                 u16* __restrict__ ChiT, u16* __restrict__ CloT,
                 const float* __restrict__ Zf, const float* __restrict__ add,
                 const float* __restrict__ bias, float* __restrict__ CP,
                 int M, int N, int K, float alpha)
{
    const int tid = threadIdx.x;
    const int lane = tid & 63, wid = tid >> 6;
    const int wm = wid >> 1, wn = wid & 1;
    const int row0 = by * 128, col0 = bx * 128;

    const u16* sp = (wid == 0) ? Ah : (wid == 1) ? Al : (wid == 2) ? Wh : Wl;
    const int rbase = (wid < 2) ? row0 : col0;

    f32x4 acc[4][4] = {};
    const int frow = lane & 15, kblk = lane >> 4;
    const int nt = K >> 6;

    stage_tile64(sp, lds, rbase, K, 0, wid, lane);

    for (int t = 0; t < nt; ++t) {
        __syncthreads();
        if (t + 1 < nt)
            stage_tile64(sp, lds + (((t + 1) & 1) << 15), rbase, K, (t + 1) << 6, wid, lane);
        const u16* cb = lds + ((t & 1) << 15);

        #pragma unroll
        for (int s = 0; s < 2; ++s) {
            s16x8 bh[4], bl[4];
            #pragma unroll
            for (int ni = 0; ni < 4; ++ni) {
                int br = wn * 64 + ni * 16 + frow;
                int pc = (s * 4 + kblk) ^ (br & 7);
                bh[ni] = *(const s16x8*)&cb[2 * 8192 + br * 64 + pc * 8];
                bl[ni] = *(const s16x8*)&cb[3 * 8192 + br * 64 + pc * 8];
            }
            #pragma unroll
            for (int mi = 0; mi < 4; ++mi) {
                int ar = wm * 64 + mi * 16 + frow;
                int pc = (s * 4 + kblk) ^ (ar & 7);
                s16x8 ah = *(const s16x8*)&cb[0 * 8192 + ar * 64 + pc * 8];
                s16x8 al = *(const s16x8*)&cb[1 * 8192 + ar * 64 + pc * 8];
                #pragma unroll
                for (int ni = 0; ni < 4; ++ni) {
                    acc[mi][ni] = __builtin_amdgcn_mfma_f32_16x16x32_bf16(ah, bh[ni], acc[mi][ni], 0, 0, 0);
                    acc[mi][ni] = __builtin_amdgcn_mfma_f32_16x16x32_bf16(ah, bl[ni], acc[mi][ni], 0, 0, 0);
                    acc[mi][ni] = __builtin_amdgcn_mfma_f32_16x16x32_bf16(al, bh[ni], acc[mi][ni], 0, 0, 0);
                }
            }
        }
    }

    const int erow = (lane >> 4) * 4, ecol = lane & 15;
    float csum[4] = {0.f, 0.f, 0.f, 0.f};
    #pragma unroll
    for (int mi = 0; mi < 4; ++mi) {
        #pragma unroll
        for (int ni = 0; ni < 4; ++ni) {
            int c = col0 + wn * 64 + ni * 16 + ecol;
            #pragma unroll
            for (int reg = 0; reg < 4; ++reg) {
                int r = row0 + wm * 64 + mi * 16 + erow + reg;
                float v = acc[mi][ni][reg];
                size_t o = (size_t)r * N + c;
                if (MODE == 1) {
                    v += bias[c];
                    C[o] = v;
                    float hv = v / (1.f + __expf(-v));
                    u16 h, l; split2(hv, h, l);
                    Chi[o] = h; Clo[o] = l;
                    size_t ot = (size_t)c * M + r;
                    ChiT[ot] = h; CloT[ot] = l;
                } else if (MODE == 2) {
                    v += bias[c] - add[o];
                    u16 h, l; split2(v, h, l);
                    Chi[o] = h; Clo[o] = l;
                    size_t ot = (size_t)c * M + r;
                    ChiT[ot] = h; CloT[ot] = l;
                    csum[ni] += v;
                } else if (MODE == 3) {
                    C[o] = alpha * v;
                } else {
                    v *= alpha;
                    float z = Zf[o];
                    float sg = 1.f / (1.f + __expf(-z));
                    v *= sg * (1.f + z * (1.f - sg));
                    u16 h, l; split2(v, h, l);
                    size_t ot = (size_t)c * M + r;
                    ChiT[ot] = h; CloT[ot] = l;
                    csum[ni] += v;
                }
            }
        }
    }
    if (MODE == 2 || MODE == 4) {
        #pragma unroll
        for (int ni = 0; ni < 4; ++ni) {
            float s = csum[ni];
            s += __shfl_xor(s, 16);
            s += __shfl_xor(s, 32);
            if ((lane >> 4) == 0) {
                int c = col0 + wn * 64 + ni * 16 + ecol;
                float w = (MODE == 2) ? alpha * s : s;
                CP[(size_t)(by * 2 + wm) * N + c] = w;
            }
        }
    }
}

template<int MODE>
__global__ __launch_bounds__(256)
void gemm_scan_k(const u16* __restrict__ Ah, const u16* __restrict__ Al,
                 const u16* __restrict__ Wh, const u16* __restrict__ Wl,
                 float* __restrict__ C, u16* __restrict__ Chi, u16* __restrict__ Clo,
                 u16* __restrict__ ChiT, u16* __restrict__ CloT,
                 const float* __restrict__ Zf, const float* __restrict__ add,
                 const float* __restrict__ bias, float* __restrict__ CP,
                 int M, int N, int K, float alpha)
{
    __shared__ u16 lds[2][32768];
    int bx, by; xcd_swizzle(bx, by);
    scan_body<MODE>(&lds[0][0], bx, by, Ah, Al, Wh, Wl, C, Chi, Clo, ChiT, CloT,
                    Zf, add, bias, CP, M, N, K, alpha);
}

// merged launch: gW2 (MODE3, 4x8 tiles at by<8) || dh (MODE4, 4x2 tiles at by>=8)
__global__ __launch_bounds__(256)
void gemm_scan_pair_k(const u16* __restrict__ rTh, const u16* __restrict__ rTl,
                      const u16* __restrict__ hTh, const u16* __restrict__ hTl,
                      float* __restrict__ gW2,
                      const u16* __restrict__ rh_, const u16* __restrict__ rl_,
                      const u16* __restrict__ w2th, const u16* __restrict__ w2tl,
                      u16* __restrict__ dhTh, u16* __restrict__ dhTl,
                      const float* __restrict__ z1, float* __restrict__ cp1, float cs)
{
    __shared__ u16 lds[2][32768];
    if (blockIdx.y < 8) {
        scan_body<3>(&lds[0][0], blockIdx.x, blockIdx.y, rTh, rTl, hTh, hTl,
                     gW2, nullptr, nullptr, nullptr, nullptr, nullptr, nullptr,
                     nullptr, nullptr, 1024, 512, 256, cs);
    } else {
        scan_body<4>(&lds[0][0], blockIdx.x, blockIdx.y - 8, rh_, rl_, w2th, w2tl,
                     nullptr, nullptr, nullptr, dhTh, dhTl, z1, nullptr,
                     nullptr, cp1, 256, 512, 1024, cs);
    }
}

// ---------------- small kernels ----------------
__global__ void cvt_split_k(const float* __restrict__ in, u16* __restrict__ hi,
                            u16* __restrict__ lo, int n4) {
    int i = blockIdx.x * 256 + threadIdx.x;
    if (i >= n4) return;
    float4 v = *(const float4*)&in[(size_t)i * 4];
    u16 h0,l0,h1,l1,h2,l2,h3,l3;
    split2(v.x,h0,l0); split2(v.y,h1,l1); split2(v.z,h2,l2); split2(v.w,h3,l3);
    ushort4 hv = {h0,h1,h2,h3}, lv = {l0,l1,l2,l3};
    *(ushort4*)&hi[(size_t)i * 4] = hv;
    *(ushort4*)&lo[(size_t)i * 4] = lv;
}
__global__ void transpose_split_k(const float* __restrict__ in, u16* __restrict__ outh,
                                  u16* __restrict__ outl, int R, int C) {
    __shared__ float t[32][33];
    const int c0 = blockIdx.x * 32, r0 = blockIdx.y * 32;
    const size_t zoff = (size_t)blockIdx.z * R * C;
    const int tx = threadIdx.x & 31, ty = threadIdx.x >> 5;
    #pragma unroll
    for (int p = 0; p < 4; ++p) {
        int r = ty + p * 8;
        t[r][tx] = in[zoff + (size_t)(r0 + r) * C + c0 + tx];
    }
    __syncthreads();
    #pragma unroll
    for (int p = 0; p < 4; ++p) {
        int cc = ty + p * 8;
        float v = t[tx][cc];
        u16 h, l; split2(v, h, l);
        size_t o = zoff + (size_t)(c0 + cc) * R + r0 + tx;
        outh[o] = h; outl[o] = l;
    }
}
__global__ void update3_k(float* __restrict__ p, float* __restrict__ mo,
                          const float* __restrict__ g,
                          const float* __restrict__ cp1, const float* __restrict__ cp2,
                          u16* __restrict__ w1h, u16* __restrict__ w1l,
                          u16* __restrict__ w2h, u16* __restrict__ w2l,
                          u16* __restrict__ w2th, u16* __restrict__ w2tl, int n) {
    int i = blockIdx.x * 256 + threadIdx.x;
    if (i >= n) return;
    float gi;
    if (i < 524288) gi = g[i];
    else if (i < 524800) {
        int j = i - 524288;
        gi = cp1[j] + cp1[512 + j] + cp1[1024 + j] + cp1[1536 + j];
    } else if (i < 1049088) gi = g[i];
    else {
        int j = i - 1049088;
        gi = cp2[j] + cp2[1024 + j] + cp2[2048 + j] + cp2[3072 + j];
    }
    float m = ETA_C * mo[i] - THETA_C * gi;
    mo[i] = m;
    float pv = (1.f - ALPHA_C) * p[i] + m;
    p[i] = pv;
    if (i < 524288) {
        u16 h, l; split2(pv, h, l); w1h[i] = h; w1l[i] = l;
    } else if (i >= 524800 && i < 1049088) {
        int j = i - 524800;
        u16 h, l; split2(pv, h, l);
        w2h[j] = h; w2l[j] = l;
        int tj = (j & 511) * 1024 + (j >> 9);
        w2th[tj] = h; w2tl[tj] = l;
    }
}
__global__ void tokens_split_k(const float* __restrict__ P, const float* __restrict__ memtok,
                               const float* __restrict__ x, u16* __restrict__ th,
                               u16* __restrict__ tl) {
    size_t idx = (size_t)blockIdx.x * 256 + threadIdx.x;
    int d = (int)(idx & 1023);
    int n = (int)((idx >> 10) % NTOK);
    int b = (int)(idx / ((size_t)NTOK * 1024));
    float v;
    if (n < NPERS)            v = P[(size_t)n * 1024 + d];
    else if (n < NPERS + TSEQ) v = memtok[((size_t)b * TSEQ + (n - NPERS)) * 1024 + d];
    else                      v = x[((size_t)b * TSEQ + (n - NPERS - TSEQ)) * 1024 + d];
    u16 h, l; split2(v, h, l); th[idx] = h; tl[idx] = l;
}
__global__ void mul_k(const float* __restrict__ a, const float* __restrict__ b,
                      float* __restrict__ o, int n) {
    int i = blockIdx.x * 256 + threadIdx.x;
    if (i < n) o[i] = a[i] * b[i];
}

// ---------------- MFMA flash attention: split-KV partial + merge ----------------
__global__ __launch_bounds__(256)
void flash_part_k(const u16* __restrict__ Qsh, const u16* __restrict__ Qsl,
                  const u16* __restrict__ Ksh, const u16* __restrict__ Ksl,
                  const u16* __restrict__ Vts, float* __restrict__ Of,
                  float* __restrict__ Mf, float* __restrict__ Lf)
{
    __shared__ u16 lds[20480];
    u16* KH = lds;            u16* KL = lds + 4096;
    u16* VT = lds + 8192;
    u16* PH = lds + 12288;    u16* PL = lds + 16384;

    int lid = blockIdx.x + (blockIdx.y << 4) + (blockIdx.z << 8);
    int t1024 = ((lid & 7) << 7) | (lid >> 3);
    const int qt = t1024 & 15, h = (t1024 >> 4) & 15;
    const int zb = t1024 >> 8;
    const int b = zb >> 1, z = zb & 1;

    const int tid = threadIdx.x;
    const int lane = tid & 63, wid = tid >> 6;
    const int fr = lane & 15, kq = lane >> 4;
    const int bh = b * 16 + h;
    const int q0c = qt * 64;
    const int q0a = NPERS + TSEQ + q0c;
    const int ntile = ((q0a + 63) >> 6) + 1;
    const int half = ntile >> 1;
    const int jt0 = z ? half : 0;
    const int jt1 = z ? ntile : half;
    const int l8 = lane & 7, lr8 = lane >> 3;

    auto stageKV = [&](int jt) {
        const int j0 = jt * 64;
        #pragma unroll
        for (int jj = 0; jj < 6; ++jj) {
            int j = wid * 6 + jj;
            int buf = j >> 3, i8 = j & 7;
            if (buf < 2) {
                int row = i8 * 8 + lr8;
                int grow = j0 + row; if (grow > NTOK - 1) grow = NTOK - 1;
                int c = l8 ^ (row & 7);
                const u16* src = (buf == 0 ? Ksh : Ksl) +
                                 (((size_t)bh * NTOK + grow) << 6) + c * 8;
                gload_lds16(src, (buf == 0 ? KH : KL) + i8 * 512);
            } else {
                int d = i8 * 8 + lr8;
                int c = l8 ^ (d & 7);
                int col = j0 + c * 8; if (col > NTOK - 8) col = NTOK - 8;
                const u16* src = Vts + ((size_t)bh * 64 + d) * NTOK + col;
                gload_lds16(src, VT + i8 * 512);
            }
        }
    };

    s16x8 qh[2], ql[2];
    {
        const size_t qrow = ((size_t)bh * 1024 + q0c + wid * 16 + fr) << 6;
        #pragma unroll
        for (int kb = 0; kb < 2; ++kb) {
            qh[kb] = *(const s16x8*)&Qsh[qrow + (size_t)(kb * 4 + kq) * 8];
            ql[kb] = *(const s16x8*)&Qsl[qrow + (size_t)(kb * 4 + kq) * 8];
        }
    }

    f32x4 Oa[4] = {};
    float mrow[4], lrow[4];
    #pragma unroll
    for (int r = 0; r < 4; ++r) { mrow[r] = -INFINITY; lrow[r] = 0.f; }

    for (int jt = jt0; jt < jt1; ++jt) {
        const int j0 = jt * 64;
        stageKV(jt);
        __syncthreads();

        f32x4 sacc[4] = {};
        __builtin_amdgcn_s_setprio(1);
        #pragma unroll
        for (int nt = 0; nt < 4; ++nt) {
            #pragma unroll
            for (int kb = 0; kb < 2; ++kb) {
                int br = nt * 16 + fr;
                int sl = (kb * 4 + kq) ^ (fr & 7);
                s16x8 kh = *(const s16x8*)&KH[br * 64 + sl * 8];
                s16x8 kl = *(const s16x8*)&KL[br * 64 + sl * 8];
                sacc[nt] = __builtin_amdgcn_mfma_f32_16x16x32_bf16(qh[kb], kh, sacc[nt], 0, 0, 0);
                sacc[nt] = __builtin_amdgcn_mfma_f32_16x16x32_bf16(ql[kb], kh, sacc[nt], 0, 0, 0);
                sacc[nt] = __builtin_amdgcn_mfma_f32_16x16x32_bf16(qh[kb], kl, sacc[nt], 0, 0, 0);
            }
        }
        __builtin_amdgcn_s_setprio(0);

        #pragma unroll
        for (int r = 0; r < 4; ++r) {
            const int qloc = kq * 4 + r;
            const int qi = q0a + wid * 16 + qloc;
            float sv[4], tmax = -INFINITY;
            #pragma unroll
            for (int nt = 0; nt < 4; ++nt) {
                int kj = j0 + nt * 16 + fr;
                sv[nt] = (kj <= qi) ? sacc[nt][r] : -INFINITY;
                tmax = fmaxf(tmax, sv[nt]);
            }
            #pragma unroll
            for (int off = 1; off < 16; off <<= 1)
                tmax = fmaxf(tmax, __shfl_xor(tmax, off));
            float mnew = fmaxf(mrow[r], tmax);
            float scale = __expf(mrow[r] - mnew);
            float psum = 0.f;
            float p4[4];
            #pragma unroll
            for (int nt = 0; nt < 4; ++nt) { p4[nt] = __expf(sv[nt] - mnew); psum += p4[nt]; }
            #pragma unroll
            for (int off = 1; off < 16; off <<= 1)
                psum += __shfl_xor(psum, off);
            lrow[r] = lrow[r] * scale + psum;
            mrow[r] = mnew;
            #pragma unroll
            for (int dt = 0; dt < 4; ++dt) Oa[dt][r] *= scale;
            const int prow = wid * 16 + qloc;
            #pragma unroll
            for (int nt = 0; nt < 4; ++nt) {
                u16 ph, pl; split2(p4[nt], ph, pl);
                int col = nt * 16 + fr;
                int sl = (col >> 3) ^ (qloc & 7);
                int off = prow * 64 + sl * 8 + (col & 7);
                PH[off] = ph; PL[off] = pl;
            }
        }

        __builtin_amdgcn_s_setprio(1);
        #pragma unroll
        for (int kb = 0; kb < 2; ++kb) {
            int pr = wid * 16 + fr;
            int sl = (kb * 4 + kq) ^ (fr & 7);
            s16x8 pa = *(const s16x8*)&PH[pr * 64 + sl * 8];
            s16x8 pb = *(const s16x8*)&PL[pr * 64 + sl * 8];
            #pragma unroll
            for (int dt = 0; dt < 4; ++dt) {
                int vr = dt * 16 + fr;
                s16x8 vb = *(const s16x8*)&VT[vr * 64 + sl * 8];
                Oa[dt] = __builtin_amdgcn_mfma_f32_16x16x32_bf16(pa, vb, Oa[dt], 0, 0, 0);
                Oa[dt] = __builtin_amdgcn_mfma_f32_16x16x32_bf16(pb, vb, Oa[dt], 0, 0, 0);
            }
        }
        __builtin_amdgcn_s_setprio(0);
        __syncthreads();
    }

    const size_t obase = ((((size_t)z * 2 + b) * 16 + h) * 16 + qt) * 4096;
    const size_t mlb   = ((((size_t)z * 2 + b) * 16 + h) * 16 + qt) * 64;
    #pragma unroll
    for (int r = 0; r < 4; ++r) {
        int rl = wid * 16 + kq * 4 + r;
        if (fr == 0) { Mf[mlb + rl] = mrow[r]; Lf[mlb + rl] = lrow[r]; }
        #pragma unroll
        for (int dt = 0; dt < 4; ++dt)
            Of[obase + (size_t)rl * 64 + dt * 16 + fr] = Oa[dt][r];
    }
}

__global__ __launch_bounds__(256)
void flash_merge_k(const float* __restrict__ Of, const float* __restrict__ Mf,
                   const float* __restrict__ Lf, u16* __restrict__ oh, u16* __restrict__ ol)
{
    const int qt = blockIdx.x, h = blockIdx.y, b = blockIdx.z;
    const int tid = threadIdx.x;
    const int row = tid >> 2, quad = tid & 3;
    const size_t b0 = ((((size_t)0 * 2 + b) * 16 + h) * 16 + qt) * 4096 + (size_t)row * 64;
    const size_t b1 = ((((size_t)1 * 2 + b) * 16 + h) * 16 + qt) * 4096 + (size_t)row * 64;
    const size_t m0i = ((((size_t)0 * 2 + b) * 16 + h) * 16 + qt) * 64 + row;
    const size_t m1i = ((((size_t)1 * 2 + b) * 16 + h) * 16 + qt) * 64 + row;
    float m0 = Mf[m0i], m1 = Mf[m1i], l0 = Lf[m0i], l1 = Lf[m1i];
    float m = fmaxf(m0, m1);
    float e0 = __expf(m0 - m), e1 = __expf(m1 - m);
    float inv = 1.f / (l0 * e0 + l1 * e1);
    const size_t orow = ((size_t)(b * 1024 + qt * 64 + row)) * 1024 + h * 64;
    #pragma unroll
    for (int i = 0; i < 4; ++i) {
        int col = quad * 16 + i * 4;
        float4 v0 = *(const float4*)&Of[b0 + col];
        float4 v1 = *(const float4*)&Of[b1 + col];
        float o0 = (v0.x * e0 + v1.x * e1) * inv;
        float o1 = (v0.y * e0 + v1.y * e1) * inv;
        float o2 = (v0.z * e0 + v1.z * e1) * inv;
        float o3 = (v0.w * e0 + v1.w * e1) * inv;
        u16 h0,l0_,h1,l1_,h2,l2_,h3,l3_;
        split2(o0,h0,l0_); split2(o1,h1,l1_); split2(o2,h2,l2_); split2(o3,h3,l3_);
        ushort4 hv = {h0,h1,h2,h3}, lv = {l0_,l1_,l2_,l3_};
        *(ushort4*)&oh[orow + col] = hv;
        *(ushort4*)&ol[orow + col] = lv;
    }
}

// ---------------- launch ----------------
extern "C" void kernel_launch(void* const* d_in, const int* in_sizes, int n_in,
                              void* d_out, int out_size, void* d_ws, size_t ws_size,
                              hipStream_t stream)
{
    const float* x     = (const float*)d_in[0];
    const float* Wqkv  = (const float*)d_in[1];
    const float* mW1   = (const float*)d_in[2];
    const float* mb1   = (const float*)d_in[3];
    const float* mW2   = (const float*)d_in[4];
    const float* mb2   = (const float*)d_in[5];
    const float* Pp    = (const float*)d_in[6];
    const float* Wqa   = (const float*)d_in[7];
    const float* Wo    = (const float*)d_in[8];
    const float* ffW1  = (const float*)d_in[9];
    const float* ffb1  = (const float*)d_in[10];
    const float* ffW2  = (const float*)d_in[11];
    const float* ffb2  = (const float*)d_in[12];
    char* wsb = (char*)d_ws;
    float* outp = (float*)d_out;

    // region A (multiplexed)
    float* z1    = (float*)(wsb + oRA);
    float* grd   = (float*)(wsb + oRA + 3145728);
    float* cp2   = (float*)(wsb + oRA + 7346176);
    float* cp1   = (float*)(wsb + oRA + 7362560);
    u16* hh_     = (u16*)(wsb + oRA + 8388608);
    u16* hl_     = (u16*)(wsb + oRA + 8650752);
    u16* hTh     = (u16*)(wsb + oRA + 9437184);
    u16* hTl     = (u16*)(wsb + oRA + 9699328);
    u16* rh_     = (u16*)(wsb + oRA + 10485760);
    u16* rl_     = (u16*)(wsb + oRA + 11010048);
    u16* rTh     = (u16*)(wsb + oRA + 11534336);
    u16* rTl     = (u16*)(wsb + oRA + 12058624);
    u16* dhTh    = (u16*)(wsb + oRA + 12582912);
    u16* dhTl    = (u16*)(wsb + oRA + 12845056);
    u16* kcTh    = (u16*)(wsb + oRA + 16777216);
    u16* kcTl    = (u16*)(wsb + oRA + 20971520);
    // flash partials + attn operands (region A is dead between scan and FFN)
    float* Of    = (float*)(wsb + oRA);                   // 16.78 MB
    float* Mf    = (float*)(wsb + oRA + 16777216);        // 0.26 MB
    float* Lf    = (float*)(wsb + oRA + 17039360);        // 0.26 MB
    u16* fVth    = (u16*)(wsb + oRA + 17825792);          // 8.45 MB
    u16* fKl     = (u16*)(wsb + oRA + 26279936);          // 8.45 MB (ends 34.73 MB)
    u16* Woh     = (u16*)(wsb + oRA);
    u16* Wol     = (u16*)(wsb + oRA + 2097152);
    u16* ffhh    = (u16*)(wsb + oRA);
    u16* ffhl    = (u16*)(wsb + oRA + 16777216);
    u16* outbh   = (u16*)(wsb + oRA + 33554432);
    u16* outbl   = (u16*)(wsb + oRA + 37748736);
    u16* newQh   = (u16*)(wsb + oRA);
    u16* newQl   = (u16*)(wsb + oRA + 4194304);
    u16* hzh     = (u16*)(wsb + oRA + 8388608);
    u16* hzl     = (u16*)(wsb + oRA + 10485760);
    float* memq  = (float*)(wsb + oRA + 12582912);
    float* partA0 = (float*)(wsb + oRA);
    float* partA1 = (float*)(wsb + oRA + 4194304);
    float* partA2 = (float*)(wsb + oRA + 16777216);
    // region B
    float* Vb    = (float*)(wsb + oRB + 8388608);
    u16* tokh    = (u16*)(wsb + oRB);
    u16* tokl    = (u16*)(wsb + oRB + 8454144);
    u16* oh      = (u16*)(wsb + oRB);
    u16* ol      = (u16*)(wsb + oRB + 4194304);
    u16* y1h     = (u16*)(wsb + oRB + 8388608);
    u16* y1l     = (u16*)(wsb + oRB + 12582912);
    float* partB = (float*)(wsb + oRB);
    // region C
    u16* xh      = (u16*)(wsb + oRC);
    u16* xl      = (u16*)(wsb + oRC + 4194304);
    float* mom   = (float*)(wsb + oRC);
    u16* pW2Th   = (u16*)(wsb + oRC + 5242880);
    u16* pW2Tl   = (u16*)(wsb + oRC + 6291456);
    u16* Wqah    = (u16*)(wsb + oRC);
    u16* Wqal    = (u16*)(wsb + oRC + 6291456);
    // region D
    u16* Qh      = (u16*)(wsb + oRD);
    u16* Ql      = (u16*)(wsb + oRD + 4194304);
    u16* kchh    = (u16*)(wsb + oRD + 8388608);
    u16* kchl    = (u16*)(wsb + oRD + 12582912);
    u16* t1h     = (u16*)(wsb + oRD + 8388608);
    u16* t1l     = (u16*)(wsb + oRD + 10485760);
    float* memtok= (float*)(wsb + oRD);
    u16* fKh     = (u16*)(wsb + oRD);                     // 8.45 MB during attn
    u16* ffW1h   = (u16*)(wsb + oRD);
    u16* ffW1l   = (u16*)(wsb + oRD + 8388608);
    u16* ffW2h   = (u16*)(wsb + oRD);
    u16* ffW2l   = (u16*)(wsb + oRD + 8388608);
    // persistent
    u16* Wqkvh   = (u16*)(wsb + oRE);
    u16* Wqkvl   = (u16*)(wsb + oRE + 6291456);
    u16* pW1h    = (u16*)(wsb + oRF);
    u16* pW1l    = (u16*)(wsb + oRF + 1048576);
    u16* pW2h    = (u16*)(wsb + oRF + 2097152);
    u16* pW2l    = (u16*)(wsb + oRF + 3145728);
    float* par   = (float*)(wsb + oRG);
    float* outb  = (float*)(wsb + oRH);
    u16* fQh     = (u16*)(wsb + oRH);
    u16* fQl     = (u16*)(wsb + oRH + 4194304);

    // init memory-MLP params
    hipMemcpyAsync(par + PW1, mW1, 524288 * sizeof(float), hipMemcpyDeviceToDevice, stream);
    hipMemcpyAsync(par + PB1, mb1, 512 * sizeof(float), hipMemcpyDeviceToDevice, stream);
    hipMemcpyAsync(par + PW2, mW2, 524288 * sizeof(float), hipMemcpyDeviceToDevice, stream);
    hipMemcpyAsync(par + PB2, mb2, 1024 * sizeof(float), hipMemcpyDeviceToDevice, stream);

    // qkv = x @ Wqkv^T (fused epilogue: Q split, kc split, kcT split, V f32)
    cvt_split_k<<<2048, 256, 0, stream>>>(x, xh, xl, 524288);
    cvt_split_k<<<3072, 256, 0, stream>>>(Wqkv, Wqkvh, Wqkvl, 786432);
    gemm_qkv_k<<<dim3(24, 16), 256, 0, stream>>>(xh, xl, Wqkvh, Wqkvl,
        Qh, Ql, kchh, kchl, kcTh, kcTl, Vb, 2048, 3072, 1024);

    // scan prep (xh/xl dead now)
    hipMemsetAsync(mom, 0, PSZ * sizeof(float), stream);
    cvt_split_k<<<512, 256, 0, stream>>>(par + PW1, pW1h, pW1l, 131072);
    cvt_split_k<<<512, 256, 0, stream>>>(par + PW2, pW2h, pW2l, 131072);
    transpose_split_k<<<dim3(16, 32, 1), 256, 0, stream>>>(par + PW2, pW2Th, pW2Tl, 1024, 512);

    // memory scan: z1 -> r -> {gW2 || dh} -> gW1 -> update  (BK=64 dbuf GEMMs)
    const float cs = 2.f / (float)(BATCH * 128 * DIMD);
    for (int c = 0; c < NCH; ++c) {
        const u16* kch = kchh + (size_t)c * 262144;
        const u16* kcl = kchl + (size_t)c * 262144;
        const u16* kth = kcTh + (size_t)c * 262144;
        const u16* ktl = kcTl + (size_t)c * 262144;
        const float* vc = Vb + (size_t)c * 262144;
        gemm_scan_k<1><<<dim3(4, 2), 256, 0, stream>>>(kch, kcl, pW1h, pW1l,
            z1, hh_, hl_, hTh, hTl, nullptr, nullptr, par + PB1, nullptr, 256, 512, 1024, 1.f);
        gemm_scan_k<2><<<dim3(8, 2), 256, 0, stream>>>(hh_, hl_, pW2h, pW2l,
            nullptr, rh_, rl_, rTh, rTl, nullptr, vc, par + PB2, cp2, 256, 1024, 512, cs);
        gemm_scan_pair_k<<<dim3(4, 10), 256, 0, stream>>>(rTh, rTl, hTh, hTl, grd + PW2,
            rh_, rl_, pW2Th, pW2Tl, dhTh, dhTl, z1, cp1, cs);
        gemm_scan_k<3><<<dim3(8, 4), 256, 0, stream>>>(dhTh, dhTl, kth, ktl,
            grd + PW1, nullptr, nullptr, nullptr, nullptr, nullptr, nullptr, nullptr, nullptr,
            512, 1024, 256, 1.f);
        update3_k<<<4102, 256, 0, stream>>>(par, mom, grd, cp1, cp2,
            pW1h, pW1l, pW2h, pW2l, pW2Th, pW2Tl, (int)PSZ);
    }

    // memory readout (split-K: t1 S=4 part@A2, memtok S=2 part@A0)
    gemm_mfma_sk(stream, 1, 0, 1, Qh, Ql, pW1h, pW1l, nullptr, t1h, t1l,
                 2048, 512, 1024, par + PB1, 4, partA2);
    gemm_mfma_sk(stream, 0, 1, 0, t1h, t1l, pW2h, pW2l, memtok, nullptr, nullptr,
                 2048, 1024, 512, par + PB2, 2, partA0);

    // tokens + fused attention qkv (2-product, dead-Q-tile skip)
    tokens_split_k<<<16512, 256, 0, stream>>>(Pp, memtok, x, tokh, tokl);
    cvt_split_k<<<3072, 256, 0, stream>>>(Wqa, Wqah, Wqal, 786432);
    gemm_aqkv_k<<<dim3(24, 33), 256, 0, stream>>>(tokh, tokl, Wqah, Wqal,
        fQh, fQl, fKh, fKl, fVth, 4128, 3072, 1024);

    // MFMA flash attention: split-KV partials + merge
    flash_part_k<<<dim3(16, 16, 4), 256, 0, stream>>>(fQh, fQl, fKh, fKl, fVth, Of, Mf, Lf);
    flash_merge_k<<<dim3(16, 16, 2), 256, 0, stream>>>(Of, Mf, Lf, oh, ol);

    // Wo projection + FFN (split-K; FF1/FF2 2-product)
    cvt_split_k<<<1024, 256, 0, stream>>>(Wo, Woh, Wol, 262144);
    gemm_mfma_sk(stream, 0, 0, 1, oh, ol, Woh, Wol, nullptr, y1h, y1l,
                 2048, 1024, 1024, nullptr, 2, partA1);
    cvt_split_k<<<4096, 256, 0, stream>>>(ffW1, ffW1h, ffW1l, 1048576);
    gemm_mfma(stream, 2, 0, 1, y1h, y1l, ffW1h, ffW1l, nullptr, ffhh, ffhl,
              2048, 4096, 1024, ffb1, 2);
    cvt_split_k<<<4096, 256, 0, stream>>>(ffW2, ffW2h, ffW2l, 1048576);
    gemm_mfma_sk(stream, 0, 1, 1, ffhh, ffhl, ffW2h, ffW2l, outb, outbh, outbl,
                 2048, 1024, 4096, ffb2, 2, partB, 2);

    // gate (full 3-product for endpoint precision)
    gemm_mfma_sk(stream, 0, 0, 1, outbh, outbl, Wqkvh, Wqkvl, nullptr, newQh, newQl,
                 2048, 1024, 1024, nullptr, 2, partB);
    gemm_mfma_sk(stream, 1, 0, 1, newQh, newQl, pW1h, pW1l, nullptr, hzh, hzl,
                 2048, 512, 1024, par + PB1, 4, partB);
    gemm_mfma_sk(stream, 0, 1, 0, hzh, hzl, pW2h, pW2l, memq, nullptr, nullptr,
                 2048, 1024, 512, par + PB2, 2, partB);
    mul_k<<<8192, 256, 0, stream>>>(outb, memq, outp, 2097152);
}

// Round 15
// 1358.347 us; speedup vs baseline: 1.2337x; 1.0017x over previous
//
#include <hip/hip_runtime.h>
#include <math.h>

// ---------------- problem constants ----------------
#define BATCH 2
#define TSEQ 1024
#define DIMD 1024
#define NPERS 16
#define NCH 8
#define NTOK 2064
#define ETA_C 0.9f
#define THETA_C 0.1f
#define ALPHA_C 0.02f

typedef __attribute__((ext_vector_type(4))) float f32x4;
typedef __attribute__((ext_vector_type(8))) short s16x8;
typedef unsigned short u16;

// ---------------- bf16 helpers ----------------
__device__ __forceinline__ u16 f2bf(float f) {
    unsigned int u = __float_as_uint(f);
    return (u16)((u + 0x7fffu + ((u >> 16) & 1u)) >> 16);
}
__device__ __forceinline__ float bf2f(u16 h) { return __uint_as_float(((unsigned)h) << 16); }
__device__ __forceinline__ void split2(float v, u16& h, u16& l) {
    h = f2bf(v); l = f2bf(v - bf2f(h));
}

// ---------------- workspace layout (byte offsets) ----------------
static const size_t oRA = 0;                       // 50,724,864 multiplexed
static const size_t oRB = 50724864;                // 16,908,288
static const size_t oRC = 67633152;                // 12,582,912
static const size_t oRD = 80216064;                // 16,777,216
static const size_t oRE = 96993280;                // 12,582,912 Wqkv h/l (persistent)
static const size_t oRF = 109576192;               //  4,194,304 parW h/l (persistent)
static const size_t oRG = 113770496;               //  4,200,448 par (persistent)
static const size_t oRH = 117970944;               //  8,388,608 outb f32 / fQ split
// total 126,359,552 bytes

static const size_t PW1 = 0, PB1 = 524288, PW2 = 524800, PB2 = 1049088, PSZ = 1050112;

// ---------------- async global->LDS ----------------
__device__ __forceinline__ void gload_lds16(const u16* g, u16* l) {
    __builtin_amdgcn_global_load_lds(
        (const __attribute__((address_space(1))) unsigned int*)g,
        (__attribute__((address_space(3))) unsigned int*)l, 16, 0, 0);
}

// XCD-chunked block swizzle (bijective when nwg % 8 == 0; identity fallback).
__device__ __forceinline__ void xcd_swizzle(int& bx, int& by) {
    int gx = gridDim.x, nwg = gx * gridDim.y;
    int lid = blockIdx.y * gx + blockIdx.x;
    int t = lid;
    if ((nwg & 7) == 0) {
        int q = nwg >> 3;
        t = (lid & 7) * q + (lid >> 3);
    }
    bx = t % gx; by = t / gx;
}

// stage one 128x32 bf16 tile (this wave's quarter) into buf + wid*4096
__device__ __forceinline__ void stage_tile(const u16* sp, u16* buf, int rbase,
                                           int M, int clampM, int K, int k0,
                                           int wid, int lane) {
    const int lr = lane >> 2, lc = lane & 3;
    #pragma unroll
    for (int i = 0; i < 8; ++i) {
        int r = i * 16 + lr;
        int gr = rbase + r;
        if (clampM && gr >= M) gr = M - 1;
        int g = lc ^ ((r >> 1) & 3);
        gload_lds16(sp + (size_t)gr * K + k0 + g * 8, buf + wid * 4096 + i * 512);
    }
}

// stage one 128x64 bf16 tile into buf + wid*8192 (scan path, BK=64)
__device__ __forceinline__ void stage_tile64(const u16* sp, u16* buf, int rbase,
                                             int K, int k0, int wid, int lane) {
    const int lr = lane >> 3, lc = lane & 7;
    #pragma unroll
    for (int i = 0; i < 16; ++i) {
        int r = i * 8 + lr;
        int gr = rbase + r;
        int g = lc ^ (r & 7);
        gload_lds16(sp + (size_t)gr * K + k0 + g * 8, buf + wid * 8192 + i * 512);
    }
}

// shared BK=32 dbuf main loop: accumulates into acc[4][4].
// NPROD=3: hh+hl+lh (fp32-quality). NPROD=2: hh+hl (drops al term, ~2^-9 rel err).
template<int NPROD>
__device__ __forceinline__ void mm_loop32(u16 lds[2][16384],
                const u16* sp, int rbase, int M, int clampM, int K,
                int kbeg, int kend, int wid, int lane, int wm, int wn,
                f32x4 acc[4][4]) {
    const int frow = lane & 15, kblk = lane >> 4;
    const int nt = (kend - kbeg) >> 5;
    const int doStage = (NPROD == 3) || (wid != 1);   // skip unused A-low staging
    if (doStage) stage_tile(sp, lds[0], rbase, M, clampM, K, kbeg, wid, lane);
    for (int t = 0; t < nt; ++t) {
        __syncthreads();
        if (t + 1 < nt && doStage)
            stage_tile(sp, lds[(t + 1) & 1], rbase, M, clampM, K, kbeg + ((t + 1) << 5), wid, lane);
        const u16* cb = lds[t & 1];
        s16x8 bh[4], bl[4];
        #pragma unroll
        for (int ni = 0; ni < 4; ++ni) {
            int br = wn * 64 + ni * 16 + frow;
            int pc = kblk ^ ((br >> 1) & 3);
            bh[ni] = *(const s16x8*)&cb[2 * 4096 + br * 32 + pc * 8];
            bl[ni] = *(const s16x8*)&cb[3 * 4096 + br * 32 + pc * 8];
        }
        #pragma unroll
        for (int mi = 0; mi < 4; ++mi) {
            int ar = wm * 64 + mi * 16 + frow;
            int pc = kblk ^ ((ar >> 1) & 3);
            s16x8 ah = *(const s16x8*)&cb[0 * 4096 + ar * 32 + pc * 8];
            s16x8 al;
            if (NPROD == 3) al = *(const s16x8*)&cb[1 * 4096 + ar * 32 + pc * 8];
            #pragma unroll
            for (int ni = 0; ni < 4; ++ni) {
                acc[mi][ni] = __builtin_amdgcn_mfma_f32_16x16x32_bf16(ah, bh[ni], acc[mi][ni], 0, 0, 0);
                acc[mi][ni] = __builtin_amdgcn_mfma_f32_16x16x32_bf16(ah, bl[ni], acc[mi][ni], 0, 0, 0);
                if (NPROD == 3)
                    acc[mi][ni] = __builtin_amdgcn_mfma_f32_16x16x32_bf16(al, bh[ni], acc[mi][ni], 0, 0, 0);
            }
        }
    }
}

// ---------------- split-bf16 MFMA GEMM:  C = act(A @ W^T + bias) ----------------
template<int ACTF, int WF32, int WSPLIT, int PARTIAL, int NPROD>
__global__ __launch_bounds__(256)
void gemm_mfma_k(const u16* __restrict__ Ah, const u16* __restrict__ Al,
                 const u16* __restrict__ Wh, const u16* __restrict__ Wl,
                 float* __restrict__ C, u16* __restrict__ Chi, u16* __restrict__ Clo,
                 int M, int N, int K, const float* __restrict__ bias)
{
    __shared__ u16 lds[2][16384];
    const int tid = threadIdx.x;
    const int lane = tid & 63, wid = tid >> 6;
    const int wm = wid >> 1, wn = wid & 1;
    int bx, by; xcd_swizzle(bx, by);
    const int row0 = by * 128, col0 = bx * 128;
    const u16* sp = (wid == 0) ? Ah : (wid == 1) ? Al : (wid == 2) ? Wh : Wl;
    const int rbase = (wid < 2) ? row0 : col0;
    const int clampM = (wid < 2) ? 1 : 0;
    f32x4 acc[4][4] = {};
    int kbeg = 0, kend = K;
    if (PARTIAL) {
        int Kseg = K / gridDim.z;
        kbeg = blockIdx.z * Kseg;
        kend = kbeg + Kseg;
    }
    mm_loop32<NPROD>(lds, sp, rbase, M, clampM, K, kbeg, kend, wid, lane, wm, wn, acc);

    const int erow = (lane >> 4) * 4, ecol = lane & 15;
    #pragma unroll
    for (int mi = 0; mi < 4; ++mi) {
        #pragma unroll
        for (int ni = 0; ni < 4; ++ni) {
            int c = col0 + wn * 64 + ni * 16 + ecol;
            float bv = (!PARTIAL && bias) ? bias[c] : 0.f;
            #pragma unroll
            for (int reg = 0; reg < 4; ++reg) {
                int r = row0 + wm * 64 + mi * 16 + erow + reg;
                if (r >= M) continue;
                float v = acc[mi][ni][reg] + bv;
                if (PARTIAL) {
                    C[((size_t)blockIdx.z * M + r) * N + c] = v;
                    continue;
                }
                if (ACTF == 1) v = v / (1.f + __expf(-v));
                else if (ACTF == 2) {
                    float u = 0.7978845608028654f * (v + 0.044715f * v * v * v);
                    v = 0.5f * v * (1.f + tanhf(u));
                }
                size_t o = (size_t)r * N + c;
                if (WF32) C[o] = v;
                if (WSPLIT) { u16 h, l; split2(v, h, l); Chi[o] = h; Clo[o] = l; }
            }
        }
    }
}

// fused qkv GEMM: writes Q split, kc split, kcT split, V f32 directly (M=2048,N=3072)
__global__ __launch_bounds__(256)
void gemm_qkv_k(const u16* __restrict__ Ah, const u16* __restrict__ Al,
                const u16* __restrict__ Wh, const u16* __restrict__ Wl,
                u16* __restrict__ Qh, u16* __restrict__ Ql,
                u16* __restrict__ kch, u16* __restrict__ kcl,
                u16* __restrict__ kcTh, u16* __restrict__ kcTl,
                float* __restrict__ Vb, int M, int N, int K)
{
    __shared__ u16 lds[2][16384];
    const int tid = threadIdx.x;
    const int lane = tid & 63, wid = tid >> 6;
    const int wm = wid >> 1, wn = wid & 1;
    int bx, by; xcd_swizzle(bx, by);
    const int row0 = by * 128, col0 = bx * 128;
    const u16* sp = (wid == 0) ? Ah : (wid == 1) ? Al : (wid == 2) ? Wh : Wl;
    const int rbase = (wid < 2) ? row0 : col0;
    f32x4 acc[4][4] = {};
    mm_loop32<3>(lds, sp, rbase, M, 0, K, 0, K, wid, lane, wm, wn, acc);

    const int erow = (lane >> 4) * 4, ecol = lane & 15;
    #pragma unroll
    for (int mi = 0; mi < 4; ++mi) {
        #pragma unroll
        for (int ni = 0; ni < 4; ++ni) {
            int c = col0 + wn * 64 + ni * 16 + ecol;
            #pragma unroll
            for (int reg = 0; reg < 4; ++reg) {
                int r = row0 + wm * 64 + mi * 16 + erow + reg;
                float v = acc[mi][ni][reg];
                int b = r >> 10, t = r & 1023;
                if (c < 1024) {
                    size_t o = (size_t)r * 1024 + c;
                    u16 h, l; split2(v, h, l); Qh[o] = h; Ql[o] = l;
                } else if (c < 2048) {
                    int d = c - 1024;
                    int ch = t >> 7, rr = t & 127;
                    size_t o = ((size_t)((ch * 2 + b) * 128 + rr)) * 1024 + d;
                    u16 h, l; split2(v, h, l);
                    kch[o] = h; kcl[o] = l;
                    size_t ot = (size_t)ch * 262144 + (size_t)d * 256 + b * 128 + rr;
                    kcTh[ot] = h; kcTl[ot] = l;
                } else {
                    int d = c - 2048;
                    int ch = t >> 7, rr = t & 127;
                    Vb[((size_t)((ch * 2 + b) * 128 + rr)) * 1024 + d] = v;
                }
            }
        }
    }
}

// fused attention-qkv GEMM (2-product): fQ (0.125-scaled, kept rows), fK split, fV^T hi
__global__ __launch_bounds__(256)
void gemm_aqkv_k(const u16* __restrict__ Ah, const u16* __restrict__ Al,
                 const u16* __restrict__ Wh, const u16* __restrict__ Wl,
                 u16* __restrict__ fQh, u16* __restrict__ fQl,
                 u16* __restrict__ fKh, u16* __restrict__ fKl,
                 u16* __restrict__ fVt, int M, int N, int K)
{
    __shared__ u16 lds[2][16384];
    const int tid = threadIdx.x;
    const int lane = tid & 63, wid = tid >> 6;
    const int wm = wid >> 1, wn = wid & 1;
    int bx, by; xcd_swizzle(bx, by);
    // dead Q tiles: cols<1024 only used for query rows n>=1040
    if (bx < 8 && ((by <= 7) || (by >= 17 && by <= 23))) return;
    const int row0 = by * 128, col0 = bx * 128;
    const u16* sp = (wid == 0) ? Ah : (wid == 1) ? Al : (wid == 2) ? Wh : Wl;
    const int rbase = (wid < 2) ? row0 : col0;
    const int clampM = (wid < 2) ? 1 : 0;
    f32x4 acc[4][4] = {};
    mm_loop32<2>(lds, sp, rbase, M, clampM, K, 0, K, wid, lane, wm, wn, acc);

    const int erow = (lane >> 4) * 4, ecol = lane & 15;
    #pragma unroll
    for (int mi = 0; mi < 4; ++mi) {
        #pragma unroll
        for (int ni = 0; ni < 4; ++ni) {
            int c = col0 + wn * 64 + ni * 16 + ecol;
            #pragma unroll
            for (int reg = 0; reg < 4; ++reg) {
                int r = row0 + wm * 64 + mi * 16 + erow + reg;
                if (r >= M) continue;
                float v = acc[mi][ni][reg];
                int b = (r >= 2064) ? 1 : 0;
                int n = r - b * 2064;
                if (c < 1024) {
                    if (n >= NPERS + TSEQ) {
                        int h = c >> 6, d = c & 63;
                        int row = n - (NPERS + TSEQ);
                        size_t o = (((size_t)(b * 16 + h)) * 1024 + row) * 64 + d;
                        u16 hh, ll; split2(0.125f * v, hh, ll);
                        fQh[o] = hh; fQl[o] = ll;
                    }
                } else if (c < 2048) {
                    int cc = c - 1024;
                    int h = cc >> 6, d = cc & 63;
                    size_t o = (((size_t)(b * 16 + h)) * NTOK + n) * 64 + d;
                    u16 hh, ll; split2(v, hh, ll);
                    fKh[o] = hh; fKl[o] = ll;
                } else {
                    int cc = c - 2048;
                    int h = cc >> 6, d = cc & 63;
                    fVt[(((size_t)(b * 16 + h)) * 64 + d) * NTOK + n] = f2bf(v);
                }
            }
        }
    }
}

// split-K reduce + epilogue
template<int ACTF, int WF32, int WSPLIT>
__global__ __launch_bounds__(256)
void reduce_k(const float* __restrict__ Cp, int S,
              float* __restrict__ C, u16* __restrict__ Chi, u16* __restrict__ Clo,
              const float* __restrict__ bias, int M, int N)
{
    int i = blockIdx.x * 256 + threadIdx.x;
    int n4 = (int)((size_t)M * N / 4);
    if (i >= n4) return;
    size_t off = (size_t)i * 4;
    float4 v = *(const float4*)&Cp[off];
    for (int z = 1; z < S; ++z) {
        float4 u = *(const float4*)&Cp[(size_t)z * M * N + off];
        v.x += u.x; v.y += u.y; v.z += u.z; v.w += u.w;
    }
    int c = (int)(off % N);
    float vv[4] = {v.x, v.y, v.z, v.w};
    #pragma unroll
    for (int j = 0; j < 4; ++j) {
        float w = vv[j];
        if (bias) w += bias[c + j];
        if (ACTF == 1) w = w / (1.f + __expf(-w));
        else if (ACTF == 2) {
            float u = 0.7978845608028654f * (w + 0.044715f * w * w * w);
            w = 0.5f * w * (1.f + tanhf(u));
        }
        if (WF32) C[off + j] = w;
        if (WSPLIT) { u16 h, l; split2(w, h, l); Chi[off + j] = h; Clo[off + j] = l; }
    }
}

// memtok reduce: sum S=2 partials [z][2048][1024] + b2, write split DIRECTLY into
// token buffer rows b*2064 + 16 + t  (memtok rows of the token sequence)
__global__ __launch_bounds__(256)
void reduce_tok_k(const float* __restrict__ Cp, const float* __restrict__ bias,
                  u16* __restrict__ th, u16* __restrict__ tl)
{
    int i = blockIdx.x * 256 + threadIdx.x;           // < 524288 (2048*1024/4)
    if (i >= 524288) return;
    size_t off = (size_t)i * 4;
    float4 v = *(const float4*)&Cp[off];
    float4 u = *(const float4*)&Cp[2097152 + off];
    v.x += u.x; v.y += u.y; v.z += u.z; v.w += u.w;
    int r = (int)(off >> 10), c = (int)(off & 1023);
    int b = r >> 10, t = r & 1023;
    size_t orow = (((size_t)(b * NTOK + NPERS + t)) << 10) + c;
    float vv[4] = {v.x + bias[c], v.y + bias[c + 1], v.z + bias[c + 2], v.w + bias[c + 3]};
    u16 h0,l0,h1,l1,h2,l2,h3,l3;
    split2(vv[0],h0,l0); split2(vv[1],h1,l1); split2(vv[2],h2,l2); split2(vv[3],h3,l3);
    ushort4 hv = {h0,h1,h2,h3}, lv = {l0,l1,l2,l3};
    *(ushort4*)&th[orow] = hv;
    *(ushort4*)&tl[orow] = lv;
}

static void gemm_mfma(hipStream_t s, int act, int wf32, int wsplit,
                      const u16* Ah, const u16* Al, const u16* Wh, const u16* Wl,
                      float* C, u16* Ch, u16* Cl, int M, int N, int K,
                      const float* bias, int nprod = 3)
{
    dim3 g(N / 128, (M + 127) / 128), b(256);
    if (act == 0 && wf32 == 1 && wsplit == 0)
        gemm_mfma_k<0,1,0,0,3><<<g,b,0,s>>>(Ah,Al,Wh,Wl,C,Ch,Cl,M,N,K,bias);
    else if (act == 0 && wf32 == 1 && wsplit == 1)
        gemm_mfma_k<0,1,1,0,3><<<g,b,0,s>>>(Ah,Al,Wh,Wl,C,Ch,Cl,M,N,K,bias);
    else if (act == 0 && wf32 == 0 && wsplit == 1)
        gemm_mfma_k<0,0,1,0,3><<<g,b,0,s>>>(Ah,Al,Wh,Wl,C,Ch,Cl,M,N,K,bias);
    else if (act == 1)
        gemm_mfma_k<1,0,1,0,3><<<g,b,0,s>>>(Ah,Al,Wh,Wl,C,Ch,Cl,M,N,K,bias);
    else if (nprod == 2)
        gemm_mfma_k<2,0,1,0,2><<<g,b,0,s>>>(Ah,Al,Wh,Wl,C,Ch,Cl,M,N,K,bias);
    else
        gemm_mfma_k<2,0,1,0,3><<<g,b,0,s>>>(Ah,Al,Wh,Wl,C,Ch,Cl,M,N,K,bias);
}

static void gemm_mfma_sk(hipStream_t s, int act, int wf32, int wsplit,
                         const u16* Ah, const u16* Al, const u16* Wh, const u16* Wl,
                         float* C, u16* Ch, u16* Cl, int M, int N, int K,
                         const float* bias, int S, float* part, int nprod = 3)
{
    if (S <= 1) { gemm_mfma(s, act, wf32, wsplit, Ah, Al, Wh, Wl, C, Ch, Cl, M, N, K, bias, nprod); return; }
    dim3 g(N / 128, (M + 127) / 128, S), b(256);
    if (nprod == 2)
        gemm_mfma_k<0,0,0,1,2><<<g,b,0,s>>>(Ah,Al,Wh,Wl,part,nullptr,nullptr,M,N,K,nullptr);
    else
        gemm_mfma_k<0,0,0,1,3><<<g,b,0,s>>>(Ah,Al,Wh,Wl,part,nullptr,nullptr,M,N,K,nullptr);
    int n4 = (int)((size_t)M * N / 4);
    dim3 rg((n4 + 255) / 256), rb(256);
    if (act == 0 && wf32 == 1 && wsplit == 0)
        reduce_k<0,1,0><<<rg,rb,0,s>>>(part, S, C, Ch, Cl, bias, M, N);
    else if (act == 0 && wf32 == 1 && wsplit == 1)
        reduce_k<0,1,1><<<rg,rb,0,s>>>(part, S, C, Ch, Cl, bias, M, N);
    else if (act == 0 && wf32 == 0 && wsplit == 1)
        reduce_k<0,0,1><<<rg,rb,0,s>>>(part, S, C, Ch, Cl, bias, M, N);
    else if (act == 1)
        reduce_k<1,0,1><<<rg,rb,0,s>>>(part, S, C, Ch, Cl, bias, M, N);
    else
        reduce_k<2,0,1><<<rg,rb,0,s>>>(part, S, C, Ch, Cl, bias, M, N);
}

// ---------------- scan-specialized split-bf16 MFMA GEMM body (BK=64 dbuf) -------
template<int MODE>
__device__ __forceinline__ void scan_body(u16* lds, int bx, int by,
                 const u16* __restrict__ Ah, const u16* __restrict__ Al,
                 const u16* __restrict__ Wh, const u16* __restrict__ Wl,
                 float* __restrict__ C, u16* __restrict__ Chi, u16* __restrict__ Clo,
                 u16* __restrict__ ChiT, u16* __restrict__ CloT,
                 const float* __restrict__ Zf, const float* __restrict__ add,
                 const float* __restrict__ bias, float* __restrict__ CP,
                 int M, int N, int K, float alpha)
{
    const int tid = threadIdx.x;
    const int lane = tid & 63, wid = tid >> 6;
    const int wm = wid >> 1, wn = wid & 1;
    const int row0 = by * 128, col0 = bx * 128;

    const u16* sp = (wid == 0) ? Ah : (wid == 1) ? Al : (wid == 2) ? Wh : Wl;
    const int rbase = (wid < 2) ? row0 : col0;

    f32x4 acc[4][4] = {};
    const int frow = lane & 15, kblk = lane >> 4;
    const int nt = K >> 6;

    stage_tile64(sp, lds, rbase, K, 0, wid, lane);

    for (int t = 0; t < nt; ++t) {
        __syncthreads();
        if (t + 1 < nt)
            stage_tile64(sp, lds + (((t + 1) & 1) << 15), rbase, K, (t + 1) << 6, wid, lane);
        const u16* cb = lds + ((t & 1) << 15);

        #pragma unroll
        for (int s = 0; s < 2; ++s) {
            s16x8 bh[4], bl[4];
            #pragma unroll
            for (int ni = 0; ni < 4; ++ni) {
                int br = wn * 64 + ni * 16 + frow;
                int pc = (s * 4 + kblk) ^ (br & 7);
                bh[ni] = *(const s16x8*)&cb[2 * 8192 + br * 64 + pc * 8];
                bl[ni] = *(const s16x8*)&cb[3 * 8192 + br * 64 + pc * 8];
            }
            #pragma unroll
            for (int mi = 0; mi < 4; ++mi) {
                int ar = wm * 64 + mi * 16 + frow;
                int pc = (s * 4 + kblk) ^ (ar & 7);
                s16x8 ah = *(const s16x8*)&cb[0 * 8192 + ar * 64 + pc * 8];
                s16x8 al = *(const s16x8*)&cb[1 * 8192 + ar * 64 + pc * 8];
                #pragma unroll
                for (int ni = 0; ni < 4; ++ni) {
                    acc[mi][ni] = __builtin_amdgcn_mfma_f32_16x16x32_bf16(ah, bh[ni], acc[mi][ni], 0, 0, 0);
                    acc[mi][ni] = __builtin_amdgcn_mfma_f32_16x16x32_bf16(ah, bl[ni], acc[mi][ni], 0, 0, 0);
                    acc[mi][ni] = __builtin_amdgcn_mfma_f32_16x16x32_bf16(al, bh[ni], acc[mi][ni], 0, 0, 0);
                }
            }
        }
    }

    const int erow = (lane >> 4) * 4, ecol = lane & 15;
    float csum[4] = {0.f, 0.f, 0.f, 0.f};
    #pragma unroll
    for (int mi = 0; mi < 4; ++mi) {
        #pragma unroll
        for (int ni = 0; ni < 4; ++ni) {
            int c = col0 + wn * 64 + ni * 16 + ecol;
            #pragma unroll
            for (int reg = 0; reg < 4; ++reg) {
                int r = row0 + wm * 64 + mi * 16 + erow + reg;
                float v = acc[mi][ni][reg];
                size_t o = (size_t)r * N + c;
                if (MODE == 1) {
                    v += bias[c];
                    C[o] = v;
                    float hv = v / (1.f + __expf(-v));
                    u16 h, l; split2(hv, h, l);
                    Chi[o] = h; Clo[o] = l;
                    size_t ot = (size_t)c * M + r;
                    ChiT[ot] = h; CloT[ot] = l;
                } else if (MODE == 2) {
                    v += bias[c] - add[o];
                    u16 h, l; split2(v, h, l);
                    Chi[o] = h; Clo[o] = l;
                    size_t ot = (size_t)c * M + r;
                    ChiT[ot] = h; CloT[ot] = l;
                    csum[ni] += v;
                } else if (MODE == 3) {
                    C[o] = alpha * v;
                } else {
                    v *= alpha;
                    float z = Zf[o];
                    float sg = 1.f / (1.f + __expf(-z));
                    v *= sg * (1.f + z * (1.f - sg));
                    u16 h, l; split2(v, h, l);
                    size_t ot = (size_t)c * M + r;
                    ChiT[ot] = h; CloT[ot] = l;
                    csum[ni] += v;
                }
            }
        }
    }
    if (MODE == 2 || MODE == 4) {
        #pragma unroll
        for (int ni = 0; ni < 4; ++ni) {
            float s = csum[ni];
            s += __shfl_xor(s, 16);
            s += __shfl_xor(s, 32);
            if ((lane >> 4) == 0) {
                int c = col0 + wn * 64 + ni * 16 + ecol;
                float w = (MODE == 2) ? alpha * s : s;
                CP[(size_t)(by * 2 + wm) * N + c] = w;
            }
        }
    }
}

template<int MODE>
__global__ __launch_bounds__(256)
void gemm_scan_k(const u16* __restrict__ Ah, const u16* __restrict__ Al,
                 const u16* __restrict__ Wh, const u16* __restrict__ Wl,
                 float* __restrict__ C, u16* __restrict__ Chi, u16* __restrict__ Clo,
                 u16* __restrict__ ChiT, u16* __restrict__ CloT,
                 const float* __restrict__ Zf, const float* __restrict__ add,
                 const float* __restrict__ bias, float* __restrict__ CP,
                 int M, int N, int K, float alpha)
{
    __shared__ u16 lds[2][32768];
    int bx, by; xcd_swizzle(bx, by);
    scan_body<MODE>(&lds[0][0], bx, by, Ah, Al, Wh, Wl, C, Chi, Clo, ChiT, CloT,
                    Zf, add, bias, CP, M, N, K, alpha);
}

// merged launch: gW2 (MODE3, 4x8 tiles at by<8) || dh (MODE4, 4x2 tiles at by>=8)
__global__ __launch_bounds__(256)
void gemm_scan_pair_k(const u16* __restrict__ rTh, const u16* __restrict__ rTl,
                      const u16* __restrict__ hTh, const u16* __restrict__ hTl,
                      float* __restrict__ gW2,
                      const u16* __restrict__ rh_, const u16* __restrict__ rl_,
                      const u16* __restrict__ w2th, const u16* __restrict__ w2tl,
                      u16* __restrict__ dhTh, u16* __restrict__ dhTl,
                      const float* __restrict__ z1, float* __restrict__ cp1, float cs)
{
    __shared__ u16 lds[2][32768];
    if (blockIdx.y < 8) {
        scan_body<3>(&lds[0][0], blockIdx.x, blockIdx.y, rTh, rTl, hTh, hTl,
                     gW2, nullptr, nullptr, nullptr, nullptr, nullptr, nullptr,
                     nullptr, nullptr, 1024, 512, 256, cs);
    } else {
        scan_body<4>(&lds[0][0], blockIdx.x, blockIdx.y - 8, rh_, rl_, w2th, w2tl,
                     nullptr, nullptr, nullptr, dhTh, dhTl, z1, nullptr,
                     nullptr, cp1, 256, 512, 1024, cs);
    }
}

// ---------------- small kernels ----------------
__global__ void cvt_split_k(const float* __restrict__ in, u16* __restrict__ hi,
                            u16* __restrict__ lo, int n4) {
    int i = blockIdx.x * 256 + threadIdx.x;
    if (i >= n4) return;
    float4 v = *(const float4*)&in[(size_t)i * 4];
    u16 h0,l0,h1,l1,h2,l2,h3,l3;
    split2(v.x,h0,l0); split2(v.y,h1,l1); split2(v.z,h2,l2); split2(v.w,h3,l3);
    ushort4 hv = {h0,h1,h2,h3}, lv = {l0,l1,l2,l3};
    *(ushort4*)&hi[(size_t)i * 4] = hv;
    *(ushort4*)&lo[(size_t)i * 4] = lv;
}
__global__ void transpose_split_k(const float* __restrict__ in, u16* __restrict__ outh,
                                  u16* __restrict__ outl, int R, int C) {
    __shared__ float t[32][33];
    const int c0 = blockIdx.x * 32, r0 = blockIdx.y * 32;
    const size_t zoff = (size_t)blockIdx.z * R * C;
    const int tx = threadIdx.x & 31, ty = threadIdx.x >> 5;
    #pragma unroll
    for (int p = 0; p < 4; ++p) {
        int r = ty + p * 8;
        t[r][tx] = in[zoff + (size_t)(r0 + r) * C + c0 + tx];
    }
    __syncthreads();
    #pragma unroll
    for (int p = 0; p < 4; ++p) {
        int cc = ty + p * 8;
        float v = t[tx][cc];
        u16 h, l; split2(v, h, l);
        size_t o = zoff + (size_t)(c0 + cc) * R + r0 + tx;
        outh[o] = h; outl[o] = l;
    }
}
__global__ void update3_k(float* __restrict__ p, float* __restrict__ mo,
                          const float* __restrict__ g,
                          const float* __restrict__ cp1, const float* __restrict__ cp2,
                          u16* __restrict__ w1h, u16* __restrict__ w1l,
                          u16* __restrict__ w2h, u16* __restrict__ w2l,
                          u16* __restrict__ w2th, u16* __restrict__ w2tl, int n) {
    int i = blockIdx.x * 256 + threadIdx.x;
    if (i >= n) return;
    float gi;
    if (i < 524288) gi = g[i];
    else if (i < 524800) {
        int j = i - 524288;
        gi = cp1[j] + cp1[512 + j] + cp1[1024 + j] + cp1[1536 + j];
    } else if (i < 1049088) gi = g[i];
    else {
        int j = i - 1049088;
        gi = cp2[j] + cp2[1024 + j] + cp2[2048 + j] + cp2[3072 + j];
    }
    float m = ETA_C * mo[i] - THETA_C * gi;
    mo[i] = m;
    float pv = (1.f - ALPHA_C) * p[i] + m;
    p[i] = pv;
    if (i < 524288) {
        u16 h, l; split2(pv, h, l); w1h[i] = h; w1l[i] = l;
    } else if (i >= 524800 && i < 1049088) {
        int j = i - 524800;
        u16 h, l; split2(pv, h, l);
        w2h[j] = h; w2l[j] = l;
        int tj = (j & 511) * 1024 + (j >> 9);
        w2th[tj] = h; w2tl[tj] = l;
    }
}
// fill ONLY persist (P) and x rows of the token split buffers
// (memtok rows are written directly by reduce_tok_k)
__global__ void tokens_px_k(const float* __restrict__ P, const float* __restrict__ x,
                            u16* __restrict__ th, u16* __restrict__ tl) {
    size_t idx = (size_t)blockIdx.x * 256 + threadIdx.x;   // 2*1040*1024
    if (idx >= (size_t)2 * 1040 * 1024) return;
    int d = (int)(idx & 1023);
    int rl = (int)((idx >> 10) % 1040);
    int b = (int)(idx / ((size_t)1040 * 1024));
    float v; int n;
    if (rl < NPERS) { v = P[(size_t)rl * 1024 + d]; n = rl; }
    else { int t = rl - NPERS; v = x[((size_t)b * TSEQ + t) * 1024 + d]; n = NPERS + TSEQ + t; }
    size_t o = (((size_t)(b * NTOK + n)) << 10) + d;
    u16 h, l; split2(v, h, l); th[o] = h; tl[o] = l;
}
__global__ void mul_k(const float* __restrict__ a, const float* __restrict__ b,
                      float* __restrict__ o, int n) {
    int i = blockIdx.x * 256 + threadIdx.x;
    if (i < n) o[i] = a[i] * b[i];
}

// ---------------- MFMA flash attention: split-KV partial (KV dbuf) + merge ------
__global__ __launch_bounds__(256)
void flash_part_k(const u16* __restrict__ Qsh, const u16* __restrict__ Qsl,
                  const u16* __restrict__ Ksh, const u16* __restrict__ Ksl,
                  const u16* __restrict__ Vts, float* __restrict__ Of,
                  float* __restrict__ Mf, float* __restrict__ Lf)
{
    __shared__ u16 lds[32768];             // kv0{KH KL VT} kv1{...} | PH PL = 64 KB
    u16* KV0 = lds;           u16* KV1 = lds + 12288;
    u16* PH = lds + 24576;    u16* PL = lds + 28672;

    int lid = blockIdx.x + (blockIdx.y << 4) + (blockIdx.z << 8);
    int t1024 = ((lid & 7) << 7) | (lid >> 3);
    const int qt = t1024 & 15, h = (t1024 >> 4) & 15;
    const int zb = t1024 >> 8;
    const int b = zb >> 1, z = zb & 1;

    const int tid = threadIdx.x;
    const int lane = tid & 63, wid = tid >> 6;
    const int fr = lane & 15, kq = lane >> 4;
    const int bh = b * 16 + h;
    const int q0c = qt * 64;
    const int q0a = NPERS + TSEQ + q0c;
    const int ntile = ((q0a + 63) >> 6) + 1;
    const int half = ntile >> 1;
    const int jt0 = z ? half : 0;
    const int jt1 = z ? ntile : half;
    const int l8 = lane & 7, lr8 = lane >> 3;

    auto stageKV = [&](int jt, u16* kvb) {
        const int j0 = jt * 64;
        #pragma unroll
        for (int jj = 0; jj < 6; ++jj) {
            int j = wid * 6 + jj;
            int buf = j >> 3, i8 = j & 7;
            if (buf < 2) {
                int row = i8 * 8 + lr8;
                int grow = j0 + row; if (grow > NTOK - 1) grow = NTOK - 1;
                int c = l8 ^ (row & 7);
                const u16* src = (buf == 0 ? Ksh : Ksl) +
                                 (((size_t)bh * NTOK + grow) << 6) + c * 8;
                gload_lds16(src, kvb + buf * 4096 + i8 * 512);
            } else {
                int d = i8 * 8 + lr8;
                int c = l8 ^ (d & 7);
                int col = j0 + c * 8; if (col > NTOK - 8) col = NTOK - 8;
                const u16* src = Vts + ((size_t)bh * 64 + d) * NTOK + col;
                gload_lds16(src, kvb + 8192 + i8 * 512);
            }
        }
    };

    // Q fragments direct from global
    s16x8 qh[2], ql[2];
    {
        const size_t qrow = ((size_t)bh * 1024 + q0c + wid * 16 + fr) << 6;
        #pragma unroll
        for (int kb = 0; kb < 2; ++kb) {
            qh[kb] = *(const s16x8*)&Qsh[qrow + (size_t)(kb * 4 + kq) * 8];
            ql[kb] = *(const s16x8*)&Qsl[qrow + (size_t)(kb * 4 + kq) * 8];
        }
    }

    f32x4 Oa[4] = {};
    float mrow[4], lrow[4];
    #pragma unroll
    for (int r = 0; r < 4; ++r) { mrow[r] = -INFINITY; lrow[r] = 0.f; }

    stageKV(jt0, KV0);
    __syncthreads();                        // KV(jt0) landed

    for (int jt = jt0; jt < jt1; ++jt) {
        const int j0 = jt * 64;
        const int idx = jt - jt0;
        if (idx) __syncthreads();           // KV(idx) landed; compute(idx-1) done
        if (jt + 1 < jt1) stageKV(jt + 1, (idx & 1) ? KV0 : KV1);
        u16* kvb = (idx & 1) ? KV1 : KV0;
        u16* KH = kvb; u16* KL = kvb + 4096; u16* VT = kvb + 8192;

        f32x4 sacc[4] = {};
        __builtin_amdgcn_s_setprio(1);
        #pragma unroll
        for (int nt = 0; nt < 4; ++nt) {
            #pragma unroll
            for (int kb = 0; kb < 2; ++kb) {
                int br = nt * 16 + fr;
                int sl = (kb * 4 + kq) ^ (fr & 7);
                s16x8 kh = *(const s16x8*)&KH[br * 64 + sl * 8];
                s16x8 kl = *(const s16x8*)&KL[br * 64 + sl * 8];
                sacc[nt] = __builtin_amdgcn_mfma_f32_16x16x32_bf16(qh[kb], kh, sacc[nt], 0, 0, 0);
                sacc[nt] = __builtin_amdgcn_mfma_f32_16x16x32_bf16(ql[kb], kh, sacc[nt], 0, 0, 0);
                sacc[nt] = __builtin_amdgcn_mfma_f32_16x16x32_bf16(qh[kb], kl, sacc[nt], 0, 0, 0);
            }
        }
        __builtin_amdgcn_s_setprio(0);

        #pragma unroll
        for (int r = 0; r < 4; ++r) {
            const int qloc = kq * 4 + r;
            const int qi = q0a + wid * 16 + qloc;
            float sv[4], tmax = -INFINITY;
            #pragma unroll
            for (int nt = 0; nt < 4; ++nt) {
                int kj = j0 + nt * 16 + fr;
                sv[nt] = (kj <= qi) ? sacc[nt][r] : -INFINITY;
                tmax = fmaxf(tmax, sv[nt]);
            }
            #pragma unroll
            for (int off = 1; off < 16; off <<= 1)
                tmax = fmaxf(tmax, __shfl_xor(tmax, off));
            float mnew = fmaxf(mrow[r], tmax);
            float scale = __expf(mrow[r] - mnew);
            float psum = 0.f;
            float p4[4];
            #pragma unroll
            for (int nt = 0; nt < 4; ++nt) { p4[nt] = __expf(sv[nt] - mnew); psum += p4[nt]; }
            #pragma unroll
            for (int off = 1; off < 16; off <<= 1)
                psum += __shfl_xor(psum, off);
            lrow[r] = lrow[r] * scale + psum;
            mrow[r] = mnew;
            #pragma unroll
            for (int dt = 0; dt < 4; ++dt) Oa[dt][r] *= scale;
            const int prow = wid * 16 + qloc;
            #pragma unroll
            for (int nt = 0; nt < 4; ++nt) {
                u16 ph, pl; split2(p4[nt], ph, pl);
                int col = nt * 16 + fr;
                int sl = (col >> 3) ^ (qloc & 7);
                int off = prow * 64 + sl * 8 + (col & 7);
                PH[off] = ph; PL[off] = pl;
            }
        }

        __builtin_amdgcn_s_setprio(1);
        #pragma unroll
        for (int kb = 0; kb < 2; ++kb) {
            int pr = wid * 16 + fr;
            int sl = (kb * 4 + kq) ^ (fr & 7);
            s16x8 pa = *(const s16x8*)&PH[pr * 64 + sl * 8];
            s16x8 pb = *(const s16x8*)&PL[pr * 64 + sl * 8];
            #pragma unroll
            for (int dt = 0; dt < 4; ++dt) {
                int vr = dt * 16 + fr;
                s16x8 vb = *(const s16x8*)&VT[vr * 64 + sl * 8];
                Oa[dt] = __builtin_amdgcn_mfma_f32_16x16x32_bf16(pa, vb, Oa[dt], 0, 0, 0);
                Oa[dt] = __builtin_amdgcn_mfma_f32_16x16x32_bf16(pb, vb, Oa[dt], 0, 0, 0);
            }
        }
        __builtin_amdgcn_s_setprio(0);
    }

    const size_t obase = ((((size_t)z * 2 + b) * 16 + h) * 16 + qt) * 4096;
    const size_t mlb   = ((((size_t)z * 2 + b) * 16 + h) * 16 + qt) * 64;
    #pragma unroll
    for (int r = 0; r < 4; ++r) {
        int rl = wid * 16 + kq * 4 + r;
        if (fr == 0) { Mf[mlb + rl] = mrow[r]; Lf[mlb + rl] = lrow[r]; }
        #pragma unroll
        for (int dt = 0; dt < 4; ++dt)
            Of[obase + (size_t)rl * 64 + dt * 16 + fr] = Oa[dt][r];
    }
}

__global__ __launch_bounds__(256)
void flash_merge_k(const float* __restrict__ Of, const float* __restrict__ Mf,
                   const float* __restrict__ Lf, u16* __restrict__ oh, u16* __restrict__ ol)
{
    const int qt = blockIdx.x, h = blockIdx.y, b = blockIdx.z;
    const int tid = threadIdx.x;
    const int row = tid >> 2, quad = tid & 3;
    const size_t b0 = ((((size_t)0 * 2 + b) * 16 + h) * 16 + qt) * 4096 + (size_t)row * 64;
    const size_t b1 = ((((size_t)1 * 2 + b) * 16 + h) * 16 + qt) * 4096 + (size_t)row * 64;
    const size_t m0i = ((((size_t)0 * 2 + b) * 16 + h) * 16 + qt) * 64 + row;
    const size_t m1i = ((((size_t)1 * 2 + b) * 16 + h) * 16 + qt) * 64 + row;
    float m0 = Mf[m0i], m1 = Mf[m1i], l0 = Lf[m0i], l1 = Lf[m1i];
    float m = fmaxf(m0, m1);
    float e0 = __expf(m0 - m), e1 = __expf(m1 - m);
    float inv = 1.f / (l0 * e0 + l1 * e1);
    const size_t orow = ((size_t)(b * 1024 + qt * 64 + row)) * 1024 + h * 64;
    #pragma unroll
    for (int i = 0; i < 4; ++i) {
        int col = quad * 16 + i * 4;
        float4 v0 = *(const float4*)&Of[b0 + col];
        float4 v1 = *(const float4*)&Of[b1 + col];
        float o0 = (v0.x * e0 + v1.x * e1) * inv;
        float o1 = (v0.y * e0 + v1.y * e1) * inv;
        float o2 = (v0.z * e0 + v1.z * e1) * inv;
        float o3 = (v0.w * e0 + v1.w * e1) * inv;
        u16 h0,l0_,h1,l1_,h2,l2_,h3,l3_;
        split2(o0,h0,l0_); split2(o1,h1,l1_); split2(o2,h2,l2_); split2(o3,h3,l3_);
        ushort4 hv = {h0,h1,h2,h3}, lv = {l0_,l1_,l2_,l3_};
        *(ushort4*)&oh[orow + col] = hv;
        *(ushort4*)&ol[orow + col] = lv;
    }
}

// ---------------- launch ----------------
extern "C" void kernel_launch(void* const* d_in, const int* in_sizes, int n_in,
                              void* d_out, int out_size, void* d_ws, size_t ws_size,
                              hipStream_t stream)
{
    const float* x     = (const float*)d_in[0];
    const float* Wqkv  = (const float*)d_in[1];
    const float* mW1   = (const float*)d_in[2];
    const float* mb1   = (const float*)d_in[3];
    const float* mW2   = (const float*)d_in[4];
    const float* mb2   = (const float*)d_in[5];
    const float* Pp    = (const float*)d_in[6];
    const float* Wqa   = (const float*)d_in[7];
    const float* Wo    = (const float*)d_in[8];
    const float* ffW1  = (const float*)d_in[9];
    const float* ffb1  = (const float*)d_in[10];
    const float* ffW2  = (const float*)d_in[11];
    const float* ffb2  = (const float*)d_in[12];
    char* wsb = (char*)d_ws;
    float* outp = (float*)d_out;

    // region A (multiplexed)
    float* z1    = (float*)(wsb + oRA);
    float* grd   = (float*)(wsb + oRA + 3145728);
    float* cp2   = (float*)(wsb + oRA + 7346176);
    float* cp1   = (float*)(wsb + oRA + 7362560);
    u16* hh_     = (u16*)(wsb + oRA + 8388608);
    u16* hl_     = (u16*)(wsb + oRA + 8650752);
    u16* hTh     = (u16*)(wsb + oRA + 9437184);
    u16* hTl     = (u16*)(wsb + oRA + 9699328);
    u16* rh_     = (u16*)(wsb + oRA + 10485760);
    u16* rl_     = (u16*)(wsb + oRA + 11010048);
    u16* rTh     = (u16*)(wsb + oRA + 11534336);
    u16* rTl     = (u16*)(wsb + oRA + 12058624);
    u16* dhTh    = (u16*)(wsb + oRA + 12582912);
    u16* dhTl    = (u16*)(wsb + oRA + 12845056);
    u16* kcTh    = (u16*)(wsb + oRA + 16777216);
    u16* kcTl    = (u16*)(wsb + oRA + 20971520);
    // flash partials + attn operands (region A dead between scan and FFN)
    float* Of    = (float*)(wsb + oRA);                   // 16.78 MB
    float* Mf    = (float*)(wsb + oRA + 16777216);
    float* Lf    = (float*)(wsb + oRA + 17039360);
    u16* fVth    = (u16*)(wsb + oRA + 17825792);          // 8.45 MB
    u16* fKl     = (u16*)(wsb + oRA + 26279936);          // 8.45 MB
    u16* Woh     = (u16*)(wsb + oRA);
    u16* Wol     = (u16*)(wsb + oRA + 2097152);
    u16* ffhh    = (u16*)(wsb + oRA);
    u16* ffhl    = (u16*)(wsb + oRA + 16777216);
    u16* outbh   = (u16*)(wsb + oRA + 33554432);
    u16* outbl   = (u16*)(wsb + oRA + 37748736);
    u16* newQh   = (u16*)(wsb + oRA);
    u16* newQl   = (u16*)(wsb + oRA + 4194304);
    u16* hzh     = (u16*)(wsb + oRA + 8388608);
    u16* hzl     = (u16*)(wsb + oRA + 10485760);
    float* memq  = (float*)(wsb + oRA + 12582912);
    float* partA0 = (float*)(wsb + oRA);
    float* partA1 = (float*)(wsb + oRA + 4194304);
    float* partA2 = (float*)(wsb + oRA + 16777216);
    // region B
    float* Vb    = (float*)(wsb + oRB + 8388608);
    u16* tokh    = (u16*)(wsb + oRB);
    u16* tokl    = (u16*)(wsb + oRB + 8454144);
    u16* oh      = (u16*)(wsb + oRB);
    u16* ol      = (u16*)(wsb + oRB + 4194304);
    u16* y1h     = (u16*)(wsb + oRB + 8388608);
    u16* y1l     = (u16*)(wsb + oRB + 12582912);
    float* partB = (float*)(wsb + oRB);
    // region C
    u16* xh      = (u16*)(wsb + oRC);
    u16* xl      = (u16*)(wsb + oRC + 4194304);
    float* mom   = (float*)(wsb + oRC);
    u16* pW2Th   = (u16*)(wsb + oRC + 5242880);
    u16* pW2Tl   = (u16*)(wsb + oRC + 6291456);
    u16* Wqah    = (u16*)(wsb + oRC);
    u16* Wqal    = (u16*)(wsb + oRC + 6291456);
    // region D
    u16* Qh      = (u16*)(wsb + oRD);
    u16* Ql      = (u16*)(wsb + oRD + 4194304);
    u16* kchh    = (u16*)(wsb + oRD + 8388608);
    u16* kchl    = (u16*)(wsb + oRD + 12582912);
    u16* t1h     = (u16*)(wsb + oRD + 8388608);
    u16* t1l     = (u16*)(wsb + oRD + 10485760);
    u16* fKh     = (u16*)(wsb + oRD);
    u16* ffW1h   = (u16*)(wsb + oRD);
    u16* ffW1l   = (u16*)(wsb + oRD + 8388608);
    u16* ffW2h   = (u16*)(wsb + oRD);
    u16* ffW2l   = (u16*)(wsb + oRD + 8388608);
    // persistent
    u16* Wqkvh   = (u16*)(wsb + oRE);
    u16* Wqkvl   = (u16*)(wsb + oRE + 6291456);
    u16* pW1h    = (u16*)(wsb + oRF);
    u16* pW1l    = (u16*)(wsb + oRF + 1048576);
    u16* pW2h    = (u16*)(wsb + oRF + 2097152);
    u16* pW2l    = (u16*)(wsb + oRF + 3145728);
    float* par   = (float*)(wsb + oRG);
    float* outb  = (float*)(wsb + oRH);
    u16* fQh     = (u16*)(wsb + oRH);
    u16* fQl     = (u16*)(wsb + oRH + 4194304);

    // init memory-MLP params
    hipMemcpyAsync(par + PW1, mW1, 524288 * sizeof(float), hipMemcpyDeviceToDevice, stream);
    hipMemcpyAsync(par + PB1, mb1, 512 * sizeof(float), hipMemcpyDeviceToDevice, stream);
    hipMemcpyAsync(par + PW2, mW2, 524288 * sizeof(float), hipMemcpyDeviceToDevice, stream);
    hipMemcpyAsync(par + PB2, mb2, 1024 * sizeof(float), hipMemcpyDeviceToDevice, stream);

    // qkv = x @ Wqkv^T (fused epilogue: Q split, kc split, kcT split, V f32)
    cvt_split_k<<<2048, 256, 0, stream>>>(x, xh, xl, 524288);
    cvt_split_k<<<3072, 256, 0, stream>>>(Wqkv, Wqkvh, Wqkvl, 786432);
    gemm_qkv_k<<<dim3(24, 16), 256, 0, stream>>>(xh, xl, Wqkvh, Wqkvl,
        Qh, Ql, kchh, kchl, kcTh, kcTl, Vb, 2048, 3072, 1024);

    // scan prep (xh/xl dead now)
    hipMemsetAsync(mom, 0, PSZ * sizeof(float), stream);
    cvt_split_k<<<512, 256, 0, stream>>>(par + PW1, pW1h, pW1l, 131072);
    cvt_split_k<<<512, 256, 0, stream>>>(par + PW2, pW2h, pW2l, 131072);
    transpose_split_k<<<dim3(16, 32, 1), 256, 0, stream>>>(par + PW2, pW2Th, pW2Tl, 1024, 512);

    // memory scan: z1 -> r -> {gW2 || dh} -> gW1 -> update  (BK=64 dbuf GEMMs)
    const float cs = 2.f / (float)(BATCH * 128 * DIMD);
    for (int c = 0; c < NCH; ++c) {
        const u16* kch = kchh + (size_t)c * 262144;
        const u16* kcl = kchl + (size_t)c * 262144;
        const u16* kth = kcTh + (size_t)c * 262144;
        const u16* ktl = kcTl + (size_t)c * 262144;
        const float* vc = Vb + (size_t)c * 262144;
        gemm_scan_k<1><<<dim3(4, 2), 256, 0, stream>>>(kch, kcl, pW1h, pW1l,
            z1, hh_, hl_, hTh, hTl, nullptr, nullptr, par + PB1, nullptr, 256, 512, 1024, 1.f);
        gemm_scan_k<2><<<dim3(8, 2), 256, 0, stream>>>(hh_, hl_, pW2h, pW2l,
            nullptr, rh_, rl_, rTh, rTl, nullptr, vc, par + PB2, cp2, 256, 1024, 512, cs);
        gemm_scan_pair_k<<<dim3(4, 10), 256, 0, stream>>>(rTh, rTl, hTh, hTl, grd + PW2,
            rh_, rl_, pW2Th, pW2Tl, dhTh, dhTl, z1, cp1, cs);
        gemm_scan_k<3><<<dim3(8, 4), 256, 0, stream>>>(dhTh, dhTl, kth, ktl,
            grd + PW1, nullptr, nullptr, nullptr, nullptr, nullptr, nullptr, nullptr, nullptr,
            512, 1024, 256, 1.f);
        update3_k<<<4102, 256, 0, stream>>>(par, mom, grd, cp1, cp2,
            pW1h, pW1l, pW2h, pW2l, pW2Th, pW2Tl, (int)PSZ);
    }

    // memory readout: t1 (split-K S=4), memtok partial -> reduce directly into tok rows
    gemm_mfma_sk(stream, 1, 0, 1, Qh, Ql, pW1h, pW1l, nullptr, t1h, t1l,
                 2048, 512, 1024, par + PB1, 4, partA2);
    {
        dim3 g(8, 16, 2), b(256);
        gemm_mfma_k<0,0,0,1,3><<<g, b, 0, stream>>>(t1h, t1l, pW2h, pW2l,
            partA0, nullptr, nullptr, 2048, 1024, 512, nullptr);
        reduce_tok_k<<<2048, 256, 0, stream>>>(partA0, par + PB2, tokh, tokl);
    }

    // P + x token rows, weights, fused attention qkv (2-product, dead-Q-tile skip)
    tokens_px_k<<<8320, 256, 0, stream>>>(Pp, x, tokh, tokl);
    cvt_split_k<<<3072, 256, 0, stream>>>(Wqa, Wqah, Wqal, 786432);
    gemm_aqkv_k<<<dim3(24, 33), 256, 0, stream>>>(tokh, tokl, Wqah, Wqal,
        fQh, fQl, fKh, fKl, fVth, 4128, 3072, 1024);

    // MFMA flash attention: split-KV partials (KV dbuf) + merge
    flash_part_k<<<dim3(16, 16, 4), 256, 0, stream>>>(fQh, fQl, fKh, fKl, fVth, Of, Mf, Lf);
    flash_merge_k<<<dim3(16, 16, 2), 256, 0, stream>>>(Of, Mf, Lf, oh, ol);

    // Wo projection + FFN (split-K; FF1/FF2 2-product)
    cvt_split_k<<<1024, 256, 0, stream>>>(Wo, Woh, Wol, 262144);
    gemm_mfma_sk(stream, 0, 0, 1, oh, ol, Woh, Wol, nullptr, y1h, y1l,
                 2048, 1024, 1024, nullptr, 2, partA1);
    cvt_split_k<<<4096, 256, 0, stream>>>(ffW1, ffW1h, ffW1l, 1048576);
    gemm_mfma(stream, 2, 0, 1, y1h, y1l, ffW1h, ffW1l, nullptr, ffhh, ffhl,
              2048, 4096, 1024, ffb1, 2);
    cvt_split_k<<<4096, 256, 0, stream>>>(ffW2, ffW2h, ffW2l, 1048576);
    gemm_mfma_sk(stream, 0, 1, 1, ffhh, ffhl, ffW2h, ffW2l, outb, outbh, outbl,
                 2048, 1024, 4096, ffb2, 2, partB, 2);

    // gate (full 3-product for endpoint precision)
    gemm_mfma_sk(stream, 0, 0, 1, outbh, outbl, Wqkvh, Wqkvl, nullptr, newQh, newQl,
                 2048, 1024, 1024, nullptr, 2, partB);
    gemm_mfma_sk(stream, 1, 0, 1, newQh, newQl, pW1h, pW1l, nullptr, hzh, hzl,
                 2048, 512, 1024, par + PB1, 4, partB);
    gemm_mfma_sk(stream, 0, 1, 0, hzh, hzl, pW2h, pW2l, memq, nullptr, nullptr,
                 2048, 1024, 512, par + PB2, 2, partB);
    mul_k<<<8192, 256, 0, stream>>>(outb, memq, outp, 2097152);
}

// Round 16
// 1335.205 us; speedup vs baseline: 1.2551x; 1.0173x over previous
//
#include <hip/hip_runtime.h>
#include <math.h>

// ---------------- problem constants ----------------
#define BATCH 2
#define TSEQ 1024
#define DIMD 1024
#define NPERS 16
#define NCH 8
#define NTOK 2064
#define ETA_C 0.9f
#define THETA_C 0.1f
#define ALPHA_C 0.02f

typedef __attribute__((ext_vector_type(4))) float f32x4;
typedef __attribute__((ext_vector_type(8))) short s16x8;
typedef unsigned short u16;

// ---------------- bf16 helpers ----------------
__device__ __forceinline__ u16 f2bf(float f) {
    unsigned int u = __float_as_uint(f);
    return (u16)((u + 0x7fffu + ((u >> 16) & 1u)) >> 16);
}
__device__ __forceinline__ float bf2f(u16 h) { return __uint_as_float(((unsigned)h) << 16); }
__device__ __forceinline__ void split2(float v, u16& h, u16& l) {
    h = f2bf(v); l = f2bf(v - bf2f(h));
}

// ---------------- workspace layout (byte offsets) ----------------
static const size_t oRA = 0;                       // 50,724,864 multiplexed
static const size_t oRB = 50724864;                // 16,908,288
static const size_t oRC = 67633152;                // 12,582,912
static const size_t oRD = 80216064;                // 16,777,216
static const size_t oRE = 96993280;                // 12,582,912 Wqkv h/l (persistent)
static const size_t oRF = 109576192;               //  4,194,304 parW h/l (persistent)
static const size_t oRG = 113770496;               //  4,200,448 par (persistent)
static const size_t oRH = 117970944;               //  8,388,608 outb f32 / fQ split
// total 126,359,552 bytes

static const size_t PW1 = 0, PB1 = 524288, PW2 = 524800, PB2 = 1049088, PSZ = 1050112;

// ---------------- async global->LDS ----------------
__device__ __forceinline__ void gload_lds16(const u16* g, u16* l) {
    __builtin_amdgcn_global_load_lds(
        (const __attribute__((address_space(1))) unsigned int*)g,
        (__attribute__((address_space(3))) unsigned int*)l, 16, 0, 0);
}

// XCD-chunked block swizzle (bijective when nwg % 8 == 0; identity fallback).
__device__ __forceinline__ void xcd_swizzle(int& bx, int& by) {
    int gx = gridDim.x, nwg = gx * gridDim.y;
    int lid = blockIdx.y * gx + blockIdx.x;
    int t = lid;
    if ((nwg & 7) == 0) {
        int q = nwg >> 3;
        t = (lid & 7) * q + (lid >> 3);
    }
    bx = t % gx; by = t / gx;
}

// stage one 128x32 bf16 tile (this wave's quarter) into buf + wid*4096
__device__ __forceinline__ void stage_tile(const u16* sp, u16* buf, int rbase,
                                           int M, int clampM, int K, int k0,
                                           int wid, int lane) {
    const int lr = lane >> 2, lc = lane & 3;
    #pragma unroll
    for (int i = 0; i < 8; ++i) {
        int r = i * 16 + lr;
        int gr = rbase + r;
        if (clampM && gr >= M) gr = M - 1;
        int g = lc ^ ((r >> 1) & 3);
        gload_lds16(sp + (size_t)gr * K + k0 + g * 8, buf + wid * 4096 + i * 512);
    }
}

// stage one 128x64 bf16 tile into buf + wid*8192 (scan path, BK=64)
__device__ __forceinline__ void stage_tile64(const u16* sp, u16* buf, int rbase,
                                             int K, int k0, int wid, int lane) {
    const int lr = lane >> 3, lc = lane & 7;
    #pragma unroll
    for (int i = 0; i < 16; ++i) {
        int r = i * 8 + lr;
        int gr = rbase + r;
        int g = lc ^ (r & 7);
        gload_lds16(sp + (size_t)gr * K + k0 + g * 8, buf + wid * 8192 + i * 512);
    }
}

// shared BK=32 dbuf main loop: accumulates into acc[4][4].
// NPROD=3: hh+hl+lh (fp32-quality). NPROD=2: hh+hl (drops al term, ~2^-9 rel err).
template<int NPROD>
__device__ __forceinline__ void mm_loop32(u16 lds[2][16384],
                const u16* sp, int rbase, int M, int clampM, int K,
                int kbeg, int kend, int wid, int lane, int wm, int wn,
                f32x4 acc[4][4]) {
    const int frow = lane & 15, kblk = lane >> 4;
    const int nt = (kend - kbeg) >> 5;
    const int doStage = (NPROD == 3) || (wid != 1);   // skip unused A-low staging
    if (doStage) stage_tile(sp, lds[0], rbase, M, clampM, K, kbeg, wid, lane);
    for (int t = 0; t < nt; ++t) {
        __syncthreads();
        if (t + 1 < nt && doStage)
            stage_tile(sp, lds[(t + 1) & 1], rbase, M, clampM, K, kbeg + ((t + 1) << 5), wid, lane);
        const u16* cb = lds[t & 1];
        s16x8 bh[4], bl[4];
        #pragma unroll
        for (int ni = 0; ni < 4; ++ni) {
            int br = wn * 64 + ni * 16 + frow;
            int pc = kblk ^ ((br >> 1) & 3);
            bh[ni] = *(const s16x8*)&cb[2 * 4096 + br * 32 + pc * 8];
            bl[ni] = *(const s16x8*)&cb[3 * 4096 + br * 32 + pc * 8];
        }
        #pragma unroll
        for (int mi = 0; mi < 4; ++mi) {
            int ar = wm * 64 + mi * 16 + frow;
            int pc = kblk ^ ((ar >> 1) & 3);
            s16x8 ah = *(const s16x8*)&cb[0 * 4096 + ar * 32 + pc * 8];
            s16x8 al;
            if (NPROD == 3) al = *(const s16x8*)&cb[1 * 4096 + ar * 32 + pc * 8];
            #pragma unroll
            for (int ni = 0; ni < 4; ++ni) {
                acc[mi][ni] = __builtin_amdgcn_mfma_f32_16x16x32_bf16(ah, bh[ni], acc[mi][ni], 0, 0, 0);
                acc[mi][ni] = __builtin_amdgcn_mfma_f32_16x16x32_bf16(ah, bl[ni], acc[mi][ni], 0, 0, 0);
                if (NPROD == 3)
                    acc[mi][ni] = __builtin_amdgcn_mfma_f32_16x16x32_bf16(al, bh[ni], acc[mi][ni], 0, 0, 0);
            }
        }
    }
}

// ---------------- split-bf16 MFMA GEMM:  C = act(A @ W^T + bias) ----------------
template<int ACTF, int WF32, int WSPLIT, int PARTIAL, int NPROD>
__global__ __launch_bounds__(256)
void gemm_mfma_k(const u16* __restrict__ Ah, const u16* __restrict__ Al,
                 const u16* __restrict__ Wh, const u16* __restrict__ Wl,
                 float* __restrict__ C, u16* __restrict__ Chi, u16* __restrict__ Clo,
                 int M, int N, int K, const float* __restrict__ bias)
{
    __shared__ u16 lds[2][16384];
    const int tid = threadIdx.x;
    const int lane = tid & 63, wid = tid >> 6;
    const int wm = wid >> 1, wn = wid & 1;
    int bx, by; xcd_swizzle(bx, by);
    const int row0 = by * 128, col0 = bx * 128;
    const u16* sp = (wid == 0) ? Ah : (wid == 1) ? Al : (wid == 2) ? Wh : Wl;
    const int rbase = (wid < 2) ? row0 : col0;
    const int clampM = (wid < 2) ? 1 : 0;
    f32x4 acc[4][4] = {};
    int kbeg = 0, kend = K;
    if (PARTIAL) {
        int Kseg = K / gridDim.z;
        kbeg = blockIdx.z * Kseg;
        kend = kbeg + Kseg;
    }
    mm_loop32<NPROD>(lds, sp, rbase, M, clampM, K, kbeg, kend, wid, lane, wm, wn, acc);

    const int erow = (lane >> 4) * 4, ecol = lane & 15;
    #pragma unroll
    for (int mi = 0; mi < 4; ++mi) {
        #pragma unroll
        for (int ni = 0; ni < 4; ++ni) {
            int c = col0 + wn * 64 + ni * 16 + ecol;
            float bv = (!PARTIAL && bias) ? bias[c] : 0.f;
            #pragma unroll
            for (int reg = 0; reg < 4; ++reg) {
                int r = row0 + wm * 64 + mi * 16 + erow + reg;
                if (r >= M) continue;
                float v = acc[mi][ni][reg] + bv;
                if (PARTIAL) {
                    C[((size_t)blockIdx.z * M + r) * N + c] = v;
                    continue;
                }
                if (ACTF == 1) v = v / (1.f + __expf(-v));
                else if (ACTF == 2) {
                    float u = 0.7978845608028654f * (v + 0.044715f * v * v * v);
                    v = 0.5f * v * (1.f + tanhf(u));
                }
                size_t o = (size_t)r * N + c;
                if (WF32) C[o] = v;
                if (WSPLIT) { u16 h, l; split2(v, h, l); Chi[o] = h; Clo[o] = l; }
            }
        }
    }
}

// fused qkv GEMM: writes Q split, kc split, kcT split, V f32 directly (M=2048,N=3072)
__global__ __launch_bounds__(256)
void gemm_qkv_k(const u16* __restrict__ Ah, const u16* __restrict__ Al,
                const u16* __restrict__ Wh, const u16* __restrict__ Wl,
                u16* __restrict__ Qh, u16* __restrict__ Ql,
                u16* __restrict__ kch, u16* __restrict__ kcl,
                u16* __restrict__ kcTh, u16* __restrict__ kcTl,
                float* __restrict__ Vb, int M, int N, int K)
{
    __shared__ u16 lds[2][16384];
    const int tid = threadIdx.x;
    const int lane = tid & 63, wid = tid >> 6;
    const int wm = wid >> 1, wn = wid & 1;
    int bx, by; xcd_swizzle(bx, by);
    const int row0 = by * 128, col0 = bx * 128;
    const u16* sp = (wid == 0) ? Ah : (wid == 1) ? Al : (wid == 2) ? Wh : Wl;
    const int rbase = (wid < 2) ? row0 : col0;
    f32x4 acc[4][4] = {};
    mm_loop32<3>(lds, sp, rbase, M, 0, K, 0, K, wid, lane, wm, wn, acc);

    const int erow = (lane >> 4) * 4, ecol = lane & 15;
    #pragma unroll
    for (int mi = 0; mi < 4; ++mi) {
        #pragma unroll
        for (int ni = 0; ni < 4; ++ni) {
            int c = col0 + wn * 64 + ni * 16 + ecol;
            #pragma unroll
            for (int reg = 0; reg < 4; ++reg) {
                int r = row0 + wm * 64 + mi * 16 + erow + reg;
                float v = acc[mi][ni][reg];
                int b = r >> 10, t = r & 1023;
                if (c < 1024) {
                    size_t o = (size_t)r * 1024 + c;
                    u16 h, l; split2(v, h, l); Qh[o] = h; Ql[o] = l;
                } else if (c < 2048) {
                    int d = c - 1024;
                    int ch = t >> 7, rr = t & 127;
                    size_t o = ((size_t)((ch * 2 + b) * 128 + rr)) * 1024 + d;
                    u16 h, l; split2(v, h, l);
                    kch[o] = h; kcl[o] = l;
                    size_t ot = (size_t)ch * 262144 + (size_t)d * 256 + b * 128 + rr;
                    kcTh[ot] = h; kcTl[ot] = l;
                } else {
                    int d = c - 2048;
                    int ch = t >> 7, rr = t & 127;
                    Vb[((size_t)((ch * 2 + b) * 128 + rr)) * 1024 + d] = v;
                }
            }
        }
    }
}

// fused attention-qkv GEMM (2-product): fQ (0.125-scaled, kept rows), fK split, fV^T hi
__global__ __launch_bounds__(256)
void gemm_aqkv_k(const u16* __restrict__ Ah, const u16* __restrict__ Al,
                 const u16* __restrict__ Wh, const u16* __restrict__ Wl,
                 u16* __restrict__ fQh, u16* __restrict__ fQl,
                 u16* __restrict__ fKh, u16* __restrict__ fKl,
                 u16* __restrict__ fVt, int M, int N, int K)
{
    __shared__ u16 lds[2][16384];
    const int tid = threadIdx.x;
    const int lane = tid & 63, wid = tid >> 6;
    const int wm = wid >> 1, wn = wid & 1;
    int bx, by; xcd_swizzle(bx, by);
    // dead Q tiles: cols<1024 only used for query rows n>=1040
    if (bx < 8 && ((by <= 7) || (by >= 17 && by <= 23))) return;
    const int row0 = by * 128, col0 = bx * 128;
    const u16* sp = (wid == 0) ? Ah : (wid == 1) ? Al : (wid == 2) ? Wh : Wl;
    const int rbase = (wid < 2) ? row0 : col0;
    const int clampM = (wid < 2) ? 1 : 0;
    f32x4 acc[4][4] = {};
    mm_loop32<2>(lds, sp, rbase, M, clampM, K, 0, K, wid, lane, wm, wn, acc);

    const int erow = (lane >> 4) * 4, ecol = lane & 15;
    #pragma unroll
    for (int mi = 0; mi < 4; ++mi) {
        #pragma unroll
        for (int ni = 0; ni < 4; ++ni) {
            int c = col0 + wn * 64 + ni * 16 + ecol;
            #pragma unroll
            for (int reg = 0; reg < 4; ++reg) {
                int r = row0 + wm * 64 + mi * 16 + erow + reg;
                if (r >= M) continue;
                float v = acc[mi][ni][reg];
                int b = (r >= 2064) ? 1 : 0;
                int n = r - b * 2064;
                if (c < 1024) {
                    if (n >= NPERS + TSEQ) {
                        int h = c >> 6, d = c & 63;
                        int row = n - (NPERS + TSEQ);
                        size_t o = (((size_t)(b * 16 + h)) * 1024 + row) * 64 + d;
                        u16 hh, ll; split2(0.125f * v, hh, ll);
                        fQh[o] = hh; fQl[o] = ll;
                    }
                } else if (c < 2048) {
                    int cc = c - 1024;
                    int h = cc >> 6, d = cc & 63;
                    size_t o = (((size_t)(b * 16 + h)) * NTOK + n) * 64 + d;
                    u16 hh, ll; split2(v, hh, ll);
                    fKh[o] = hh; fKl[o] = ll;
                } else {
                    int cc = c - 2048;
                    int h = cc >> 6, d = cc & 63;
                    fVt[(((size_t)(b * 16 + h)) * 64 + d) * NTOK + n] = f2bf(v);
                }
            }
        }
    }
}

// split-K reduce + epilogue
template<int ACTF, int WF32, int WSPLIT>
__global__ __launch_bounds__(256)
void reduce_k(const float* __restrict__ Cp, int S,
              float* __restrict__ C, u16* __restrict__ Chi, u16* __restrict__ Clo,
              const float* __restrict__ bias, int M, int N)
{
    int i = blockIdx.x * 256 + threadIdx.x;
    int n4 = (int)((size_t)M * N / 4);
    if (i >= n4) return;
    size_t off = (size_t)i * 4;
    float4 v = *(const float4*)&Cp[off];
    for (int z = 1; z < S; ++z) {
        float4 u = *(const float4*)&Cp[(size_t)z * M * N + off];
        v.x += u.x; v.y += u.y; v.z += u.z; v.w += u.w;
    }
    int c = (int)(off % N);
    float vv[4] = {v.x, v.y, v.z, v.w};
    #pragma unroll
    for (int j = 0; j < 4; ++j) {
        float w = vv[j];
        if (bias) w += bias[c + j];
        if (ACTF == 1) w = w / (1.f + __expf(-w));
        else if (ACTF == 2) {
            float u = 0.7978845608028654f * (w + 0.044715f * w * w * w);
            w = 0.5f * w * (1.f + tanhf(u));
        }
        if (WF32) C[off + j] = w;
        if (WSPLIT) { u16 h, l; split2(w, h, l); Chi[off + j] = h; Clo[off + j] = l; }
    }
}

// memtok reduce: sum S=2 partials [z][2048][1024] + b2, write split DIRECTLY into
// token buffer rows b*2064 + 16 + t
__global__ __launch_bounds__(256)
void reduce_tok_k(const float* __restrict__ Cp, const float* __restrict__ bias,
                  u16* __restrict__ th, u16* __restrict__ tl)
{
    int i = blockIdx.x * 256 + threadIdx.x;
    if (i >= 524288) return;
    size_t off = (size_t)i * 4;
    float4 v = *(const float4*)&Cp[off];
    float4 u = *(const float4*)&Cp[2097152 + off];
    v.x += u.x; v.y += u.y; v.z += u.z; v.w += u.w;
    int r = (int)(off >> 10), c = (int)(off & 1023);
    int b = r >> 10, t = r & 1023;
    size_t orow = (((size_t)(b * NTOK + NPERS + t)) << 10) + c;
    float vv[4] = {v.x + bias[c], v.y + bias[c + 1], v.z + bias[c + 2], v.w + bias[c + 3]};
    u16 h0,l0,h1,l1,h2,l2,h3,l3;
    split2(vv[0],h0,l0); split2(vv[1],h1,l1); split2(vv[2],h2,l2); split2(vv[3],h3,l3);
    ushort4 hv = {h0,h1,h2,h3}, lv = {l0,l1,l2,l3};
    *(ushort4*)&th[orow] = hv;
    *(ushort4*)&tl[orow] = lv;
}

static void gemm_mfma(hipStream_t s, int act, int wf32, int wsplit,
                      const u16* Ah, const u16* Al, const u16* Wh, const u16* Wl,
                      float* C, u16* Ch, u16* Cl, int M, int N, int K,
                      const float* bias, int nprod = 3)
{
    dim3 g(N / 128, (M + 127) / 128), b(256);
    if (act == 0 && wf32 == 1 && wsplit == 0)
        gemm_mfma_k<0,1,0,0,3><<<g,b,0,s>>>(Ah,Al,Wh,Wl,C,Ch,Cl,M,N,K,bias);
    else if (act == 0 && wf32 == 1 && wsplit == 1)
        gemm_mfma_k<0,1,1,0,3><<<g,b,0,s>>>(Ah,Al,Wh,Wl,C,Ch,Cl,M,N,K,bias);
    else if (act == 0 && wf32 == 0 && wsplit == 1)
        gemm_mfma_k<0,0,1,0,3><<<g,b,0,s>>>(Ah,Al,Wh,Wl,C,Ch,Cl,M,N,K,bias);
    else if (act == 1)
        gemm_mfma_k<1,0,1,0,3><<<g,b,0,s>>>(Ah,Al,Wh,Wl,C,Ch,Cl,M,N,K,bias);
    else if (nprod == 2)
        gemm_mfma_k<2,0,1,0,2><<<g,b,0,s>>>(Ah,Al,Wh,Wl,C,Ch,Cl,M,N,K,bias);
    else
        gemm_mfma_k<2,0,1,0,3><<<g,b,0,s>>>(Ah,Al,Wh,Wl,C,Ch,Cl,M,N,K,bias);
}

static void gemm_mfma_sk(hipStream_t s, int act, int wf32, int wsplit,
                         const u16* Ah, const u16* Al, const u16* Wh, const u16* Wl,
                         float* C, u16* Ch, u16* Cl, int M, int N, int K,
                         const float* bias, int S, float* part, int nprod = 3)
{
    if (S <= 1) { gemm_mfma(s, act, wf32, wsplit, Ah, Al, Wh, Wl, C, Ch, Cl, M, N, K, bias, nprod); return; }
    dim3 g(N / 128, (M + 127) / 128, S), b(256);
    if (nprod == 2)
        gemm_mfma_k<0,0,0,1,2><<<g,b,0,s>>>(Ah,Al,Wh,Wl,part,nullptr,nullptr,M,N,K,nullptr);
    else
        gemm_mfma_k<0,0,0,1,3><<<g,b,0,s>>>(Ah,Al,Wh,Wl,part,nullptr,nullptr,M,N,K,nullptr);
    int n4 = (int)((size_t)M * N / 4);
    dim3 rg((n4 + 255) / 256), rb(256);
    if (act == 0 && wf32 == 1 && wsplit == 0)
        reduce_k<0,1,0><<<rg,rb,0,s>>>(part, S, C, Ch, Cl, bias, M, N);
    else if (act == 0 && wf32 == 1 && wsplit == 1)
        reduce_k<0,1,1><<<rg,rb,0,s>>>(part, S, C, Ch, Cl, bias, M, N);
    else if (act == 0 && wf32 == 0 && wsplit == 1)
        reduce_k<0,0,1><<<rg,rb,0,s>>>(part, S, C, Ch, Cl, bias, M, N);
    else if (act == 1)
        reduce_k<1,0,1><<<rg,rb,0,s>>>(part, S, C, Ch, Cl, bias, M, N);
    else
        reduce_k<2,0,1><<<rg,rb,0,s>>>(part, S, C, Ch, Cl, bias, M, N);
}

// ---------------- scan-specialized split-bf16 MFMA GEMM body (BK=64 dbuf) -------
template<int MODE>
__device__ __forceinline__ void scan_body(u16* lds, int bx, int by,
                 const u16* __restrict__ Ah, const u16* __restrict__ Al,
                 const u16* __restrict__ Wh, const u16* __restrict__ Wl,
                 float* __restrict__ C, u16* __restrict__ Chi, u16* __restrict__ Clo,
                 u16* __restrict__ ChiT, u16* __restrict__ CloT,
                 const float* __restrict__ Zf, const float* __restrict__ add,
                 const float* __restrict__ bias, float* __restrict__ CP,
                 int M, int N, int K, float alpha)
{
    const int tid = threadIdx.x;
    const int lane = tid & 63, wid = tid >> 6;
    const int wm = wid >> 1, wn = wid & 1;
    const int row0 = by * 128, col0 = bx * 128;

    const u16* sp = (wid == 0) ? Ah : (wid == 1) ? Al : (wid == 2) ? Wh : Wl;
    const int rbase = (wid < 2) ? row0 : col0;

    f32x4 acc[4][4] = {};
    const int frow = lane & 15, kblk = lane >> 4;
    const int nt = K >> 6;

    stage_tile64(sp, lds, rbase, K, 0, wid, lane);

    for (int t = 0; t < nt; ++t) {
        __syncthreads();
        if (t + 1 < nt)
            stage_tile64(sp, lds + (((t + 1) & 1) << 15), rbase, K, (t + 1) << 6, wid, lane);
        const u16* cb = lds + ((t & 1) << 15);

        #pragma unroll
        for (int s = 0; s < 2; ++s) {
            s16x8 bh[4], bl[4];
            #pragma unroll
            for (int ni = 0; ni < 4; ++ni) {
                int br = wn * 64 + ni * 16 + frow;
                int pc = (s * 4 + kblk) ^ (br & 7);
                bh[ni] = *(const s16x8*)&cb[2 * 8192 + br * 64 + pc * 8];
                bl[ni] = *(const s16x8*)&cb[3 * 8192 + br * 64 + pc * 8];
            }
            #pragma unroll
            for (int mi = 0; mi < 4; ++mi) {
                int ar = wm * 64 + mi * 16 + frow;
                int pc = (s * 4 + kblk) ^ (ar & 7);
                s16x8 ah = *(const s16x8*)&cb[0 * 8192 + ar * 64 + pc * 8];
                s16x8 al = *(const s16x8*)&cb[1 * 8192 + ar * 64 + pc * 8];
                #pragma unroll
                for (int ni = 0; ni < 4; ++ni) {
                    acc[mi][ni] = __builtin_amdgcn_mfma_f32_16x16x32_bf16(ah, bh[ni], acc[mi][ni], 0, 0, 0);
                    acc[mi][ni] = __builtin_amdgcn_mfma_f32_16x16x32_bf16(ah, bl[ni], acc[mi][ni], 0, 0, 0);
                    acc[mi][ni] = __builtin_amdgcn_mfma_f32_16x16x32_bf16(al, bh[ni], acc[mi][ni], 0, 0, 0);
                }
            }
        }
    }

    const int erow = (lane >> 4) * 4, ecol = lane & 15;
    float csum[4] = {0.f, 0.f, 0.f, 0.f};
    #pragma unroll
    for (int mi = 0; mi < 4; ++mi) {
        #pragma unroll
        for (int ni = 0; ni < 4; ++ni) {
            int c = col0 + wn * 64 + ni * 16 + ecol;
            #pragma unroll
            for (int reg = 0; reg < 4; ++reg) {
                int r = row0 + wm * 64 + mi * 16 + erow + reg;
                float v = acc[mi][ni][reg];
                size_t o = (size_t)r * N + c;
                if (MODE == 1) {
                    v += bias[c];
                    C[o] = v;
                    float hv = v / (1.f + __expf(-v));
                    u16 h, l; split2(hv, h, l);
                    Chi[o] = h; Clo[o] = l;
                    size_t ot = (size_t)c * M + r;
                    ChiT[ot] = h; CloT[ot] = l;
                } else if (MODE == 2) {
                    v += bias[c] - add[o];
                    u16 h, l; split2(v, h, l);
                    Chi[o] = h; Clo[o] = l;
                    size_t ot = (size_t)c * M + r;
                    ChiT[ot] = h; CloT[ot] = l;
                    csum[ni] += v;
                } else if (MODE == 3) {
                    C[o] = alpha * v;
                } else {
                    v *= alpha;
                    float z = Zf[o];
                    float sg = 1.f / (1.f + __expf(-z));
                    v *= sg * (1.f + z * (1.f - sg));
                    u16 h, l; split2(v, h, l);
                    size_t ot = (size_t)c * M + r;
                    ChiT[ot] = h; CloT[ot] = l;
                    csum[ni] += v;
                }
            }
        }
    }
    if (MODE == 2 || MODE == 4) {
        #pragma unroll
        for (int ni = 0; ni < 4; ++ni) {
            float s = csum[ni];
            s += __shfl_xor(s, 16);
            s += __shfl_xor(s, 32);
            if ((lane >> 4) == 0) {
                int c = col0 + wn * 64 + ni * 16 + ecol;
                float w = (MODE == 2) ? alpha * s : s;
                CP[(size_t)(by * 2 + wm) * N + c] = w;
            }
        }
    }
}

template<int MODE>
__global__ __launch_bounds__(256)
void gemm_scan_k(const u16* __restrict__ Ah, const u16* __restrict__ Al,
                 const u16* __restrict__ Wh, const u16* __restrict__ Wl,
                 float* __restrict__ C, u16* __restrict__ Chi, u16* __restrict__ Clo,
                 u16* __restrict__ ChiT, u16* __restrict__ CloT,
                 const float* __restrict__ Zf, const float* __restrict__ add,
                 const float* __restrict__ bias, float* __restrict__ CP,
                 int M, int N, int K, float alpha)
{
    __shared__ u16 lds[2][32768];
    int bx, by; xcd_swizzle(bx, by);
    scan_body<MODE>(&lds[0][0], bx, by, Ah, Al, Wh, Wl, C, Chi, Clo, ChiT, CloT,
                    Zf, add, bias, CP, M, N, K, alpha);
}

// merged launch: gW2 (MODE3, 4x8 tiles at by<8) || dh (MODE4, 4x2 tiles at by>=8)
__global__ __launch_bounds__(256)
void gemm_scan_pair_k(const u16* __restrict__ rTh, const u16* __restrict__ rTl,
                      const u16* __restrict__ hTh, const u16* __restrict__ hTl,
                      float* __restrict__ gW2,
                      const u16* __restrict__ rh_, const u16* __restrict__ rl_,
                      const u16* __restrict__ w2th, const u16* __restrict__ w2tl,
                      u16* __restrict__ dhTh, u16* __restrict__ dhTl,
                      const float* __restrict__ z1, float* __restrict__ cp1, float cs)
{
    __shared__ u16 lds[2][32768];
    if (blockIdx.y < 8) {
        scan_body<3>(&lds[0][0], blockIdx.x, blockIdx.y, rTh, rTl, hTh, hTl,
                     gW2, nullptr, nullptr, nullptr, nullptr, nullptr, nullptr,
                     nullptr, nullptr, 1024, 512, 256, cs);
    } else {
        scan_body<4>(&lds[0][0], blockIdx.x, blockIdx.y - 8, rh_, rl_, w2th, w2tl,
                     nullptr, nullptr, nullptr, dhTh, dhTl, z1, nullptr,
                     nullptr, cp1, 256, 512, 1024, cs);
    }
}

// ---------------- small kernels ----------------
__global__ void cvt_split_k(const float* __restrict__ in, u16* __restrict__ hi,
                            u16* __restrict__ lo, int n4) {
    int i = blockIdx.x * 256 + threadIdx.x;
    if (i >= n4) return;
    float4 v = *(const float4*)&in[(size_t)i * 4];
    u16 h0,l0,h1,l1,h2,l2,h3,l3;
    split2(v.x,h0,l0); split2(v.y,h1,l1); split2(v.z,h2,l2); split2(v.w,h3,l3);
    ushort4 hv = {h0,h1,h2,h3}, lv = {l0,l1,l2,l3};
    *(ushort4*)&hi[(size_t)i * 4] = hv;
    *(ushort4*)&lo[(size_t)i * 4] = lv;
}
__global__ void transpose_split_k(const float* __restrict__ in, u16* __restrict__ outh,
                                  u16* __restrict__ outl, int R, int C) {
    __shared__ float t[32][33];
    const int c0 = blockIdx.x * 32, r0 = blockIdx.y * 32;
    const size_t zoff = (size_t)blockIdx.z * R * C;
    const int tx = threadIdx.x & 31, ty = threadIdx.x >> 5;
    #pragma unroll
    for (int p = 0; p < 4; ++p) {
        int r = ty + p * 8;
        t[r][tx] = in[zoff + (size_t)(r0 + r) * C + c0 + tx];
    }
    __syncthreads();
    #pragma unroll
    for (int p = 0; p < 4; ++p) {
        int cc = ty + p * 8;
        float v = t[tx][cc];
        u16 h, l; split2(v, h, l);
        size_t o = zoff + (size_t)(c0 + cc) * R + r0 + tx;
        outh[o] = h; outl[o] = l;
    }
}
__global__ void update3_k(float* __restrict__ p, float* __restrict__ mo,
                          const float* __restrict__ g,
                          const float* __restrict__ cp1, const float* __restrict__ cp2,
                          u16* __restrict__ w1h, u16* __restrict__ w1l,
                          u16* __restrict__ w2h, u16* __restrict__ w2l,
                          u16* __restrict__ w2th, u16* __restrict__ w2tl, int n) {
    int i = blockIdx.x * 256 + threadIdx.x;
    if (i >= n) return;
    float gi;
    if (i < 524288) gi = g[i];
    else if (i < 524800) {
        int j = i - 524288;
        gi = cp1[j] + cp1[512 + j] + cp1[1024 + j] + cp1[1536 + j];
    } else if (i < 1049088) gi = g[i];
    else {
        int j = i - 1049088;
        gi = cp2[j] + cp2[1024 + j] + cp2[2048 + j] + cp2[3072 + j];
    }
    float m = ETA_C * mo[i] - THETA_C * gi;
    mo[i] = m;
    float pv = (1.f - ALPHA_C) * p[i] + m;
    p[i] = pv;
    if (i < 524288) {
        u16 h, l; split2(pv, h, l); w1h[i] = h; w1l[i] = l;
    } else if (i >= 524800 && i < 1049088) {
        int j = i - 524800;
        u16 h, l; split2(pv, h, l);
        w2h[j] = h; w2l[j] = l;
        int tj = (j & 511) * 1024 + (j >> 9);
        w2th[tj] = h; w2tl[tj] = l;
    }
}
// fill ONLY persist (P) and x rows of the token split buffers
__global__ void tokens_px_k(const float* __restrict__ P, const float* __restrict__ x,
                            u16* __restrict__ th, u16* __restrict__ tl) {
    size_t idx = (size_t)blockIdx.x * 256 + threadIdx.x;   // 2*1040*1024
    if (idx >= (size_t)2 * 1040 * 1024) return;
    int d = (int)(idx & 1023);
    int rl = (int)((idx >> 10) % 1040);
    int b = (int)(idx / ((size_t)1040 * 1024));
    float v; int n;
    if (rl < NPERS) { v = P[(size_t)rl * 1024 + d]; n = rl; }
    else { int t = rl - NPERS; v = x[((size_t)b * TSEQ + t) * 1024 + d]; n = NPERS + TSEQ + t; }
    size_t o = (((size_t)(b * NTOK + n)) << 10) + d;
    u16 h, l; split2(v, h, l); th[o] = h; tl[o] = l;
}
__global__ void mul_k(const float* __restrict__ a, const float* __restrict__ b,
                      float* __restrict__ o, int n) {
    int i = blockIdx.x * 256 + threadIdx.x;
    if (i < n) o[i] = a[i] * b[i];
}

// ---------------- MFMA flash attention: split-KV partial + merge ----------------
// Fixed-shift softmax (m == 0): softmax is shift-invariant; logits are bounded
// (|s| << 88) so exp(s) cannot overflow. No running max, no O rescale.
__global__ __launch_bounds__(256)
void flash_part_k(const u16* __restrict__ Qsh, const u16* __restrict__ Qsl,
                  const u16* __restrict__ Ksh, const u16* __restrict__ Ksl,
                  const u16* __restrict__ Vts, float* __restrict__ Of,
                  float* __restrict__ Lf)
{
    __shared__ u16 lds[20480];             // KH KL VT | PH PL = 40 KB
    u16* KH = lds;            u16* KL = lds + 4096;
    u16* VT = lds + 8192;
    u16* PH = lds + 12288;    u16* PL = lds + 16384;

    int lid = blockIdx.x + (blockIdx.y << 4) + (blockIdx.z << 8);
    int t1024 = ((lid & 7) << 7) | (lid >> 3);
    const int qt = t1024 & 15, h = (t1024 >> 4) & 15;
    const int zb = t1024 >> 8;
    const int b = zb >> 1, z = zb & 1;

    const int tid = threadIdx.x;
    const int lane = tid & 63, wid = tid >> 6;
    const int fr = lane & 15, kq = lane >> 4;
    const int bh = b * 16 + h;
    const int q0c = qt * 64;
    const int q0a = NPERS + TSEQ + q0c;
    const int ntile = ((q0a + 63) >> 6) + 1;
    const int half = ntile >> 1;
    const int jt0 = z ? half : 0;
    const int jt1 = z ? ntile : half;
    const int l8 = lane & 7, lr8 = lane >> 3;

    auto stageKV = [&](int jt) {
        const int j0 = jt * 64;
        #pragma unroll
        for (int jj = 0; jj < 6; ++jj) {
            int j = wid * 6 + jj;
            int buf = j >> 3, i8 = j & 7;
            if (buf < 2) {
                int row = i8 * 8 + lr8;
                int grow = j0 + row; if (grow > NTOK - 1) grow = NTOK - 1;
                int c = l8 ^ (row & 7);
                const u16* src = (buf == 0 ? Ksh : Ksl) +
                                 (((size_t)bh * NTOK + grow) << 6) + c * 8;
                gload_lds16(src, (buf == 0 ? KH : KL) + i8 * 512);
            } else {
                int d = i8 * 8 + lr8;
                int c = l8 ^ (d & 7);
                int col = j0 + c * 8; if (col > NTOK - 8) col = NTOK - 8;
                const u16* src = Vts + ((size_t)bh * 64 + d) * NTOK + col;
                gload_lds16(src, VT + i8 * 512);
            }
        }
    };

    // Q fragments direct from global
    s16x8 qh[2], ql[2];
    {
        const size_t qrow = ((size_t)bh * 1024 + q0c + wid * 16 + fr) << 6;
        #pragma unroll
        for (int kb = 0; kb < 2; ++kb) {
            qh[kb] = *(const s16x8*)&Qsh[qrow + (size_t)(kb * 4 + kq) * 8];
            ql[kb] = *(const s16x8*)&Qsl[qrow + (size_t)(kb * 4 + kq) * 8];
        }
    }

    f32x4 Oa[4] = {};
    float lrow[4] = {0.f, 0.f, 0.f, 0.f};

    for (int jt = jt0; jt < jt1; ++jt) {
        const int j0 = jt * 64;
        stageKV(jt);
        __syncthreads();                    // KV landed

        f32x4 sacc[4] = {};
        __builtin_amdgcn_s_setprio(1);
        #pragma unroll
        for (int nt = 0; nt < 4; ++nt) {
            #pragma unroll
            for (int kb = 0; kb < 2; ++kb) {
                int br = nt * 16 + fr;
                int sl = (kb * 4 + kq) ^ (fr & 7);
                s16x8 kh = *(const s16x8*)&KH[br * 64 + sl * 8];
                s16x8 kl = *(const s16x8*)&KL[br * 64 + sl * 8];
                sacc[nt] = __builtin_amdgcn_mfma_f32_16x16x32_bf16(qh[kb], kh, sacc[nt], 0, 0, 0);
                sacc[nt] = __builtin_amdgcn_mfma_f32_16x16x32_bf16(ql[kb], kh, sacc[nt], 0, 0, 0);
                sacc[nt] = __builtin_amdgcn_mfma_f32_16x16x32_bf16(qh[kb], kl, sacc[nt], 0, 0, 0);
            }
        }
        __builtin_amdgcn_s_setprio(0);

        // fixed-shift softmax accumulation (no max tracking, no rescale)
        #pragma unroll
        for (int r = 0; r < 4; ++r) {
            const int qloc = kq * 4 + r;
            const int qi = q0a + wid * 16 + qloc;
            float p4[4], psum = 0.f;
            #pragma unroll
            for (int nt = 0; nt < 4; ++nt) {
                int kj = j0 + nt * 16 + fr;
                float e = (kj <= qi) ? __expf(sacc[nt][r]) : 0.f;
                p4[nt] = e; psum += e;
            }
            #pragma unroll
            for (int off = 1; off < 16; off <<= 1)
                psum += __shfl_xor(psum, off);
            lrow[r] += psum;
            const int prow = wid * 16 + qloc;
            #pragma unroll
            for (int nt = 0; nt < 4; ++nt) {
                u16 ph, pl; split2(p4[nt], ph, pl);
                int col = nt * 16 + fr;
                int sl = (col >> 3) ^ (qloc & 7);
                int off = prow * 64 + sl * 8 + (col & 7);
                PH[off] = ph; PL[off] = pl;
            }
        }

        __builtin_amdgcn_s_setprio(1);
        #pragma unroll
        for (int kb = 0; kb < 2; ++kb) {
            int pr = wid * 16 + fr;
            int sl = (kb * 4 + kq) ^ (fr & 7);
            s16x8 pa = *(const s16x8*)&PH[pr * 64 + sl * 8];
            s16x8 pb = *(const s16x8*)&PL[pr * 64 + sl * 8];
            #pragma unroll
            for (int dt = 0; dt < 4; ++dt) {
                int vr = dt * 16 + fr;
                s16x8 vb = *(const s16x8*)&VT[vr * 64 + sl * 8];
                Oa[dt] = __builtin_amdgcn_mfma_f32_16x16x32_bf16(pa, vb, Oa[dt], 0, 0, 0);
                Oa[dt] = __builtin_amdgcn_mfma_f32_16x16x32_bf16(pb, vb, Oa[dt], 0, 0, 0);
            }
        }
        __builtin_amdgcn_s_setprio(0);
        __syncthreads();                    // compute done before next stage overwrites
    }

    const size_t obase = ((((size_t)z * 2 + b) * 16 + h) * 16 + qt) * 4096;
    const size_t mlb   = ((((size_t)z * 2 + b) * 16 + h) * 16 + qt) * 64;
    #pragma unroll
    for (int r = 0; r < 4; ++r) {
        int rl = wid * 16 + kq * 4 + r;
        if (fr == 0) Lf[mlb + rl] = lrow[r];
        #pragma unroll
        for (int dt = 0; dt < 4; ++dt)
            Of[obase + (size_t)rl * 64 + dt * 16 + fr] = Oa[dt][r];
    }
}

// merge: O = (O0 + O1) / (l0 + l1)  (both halves share the fixed shift m == 0)
__global__ __launch_bounds__(256)
void flash_merge_k(const float* __restrict__ Of, const float* __restrict__ Lf,
                   u16* __restrict__ oh, u16* __restrict__ ol)
{
    const int qt = blockIdx.x, h = blockIdx.y, b = blockIdx.z;
    const int tid = threadIdx.x;
    const int row = tid >> 2, quad = tid & 3;
    const size_t b0 = ((((size_t)0 * 2 + b) * 16 + h) * 16 + qt) * 4096 + (size_t)row * 64;
    const size_t b1 = ((((size_t)1 * 2 + b) * 16 + h) * 16 + qt) * 4096 + (size_t)row * 64;
    const size_t m0i = ((((size_t)0 * 2 + b) * 16 + h) * 16 + qt) * 64 + row;
    const size_t m1i = ((((size_t)1 * 2 + b) * 16 + h) * 16 + qt) * 64 + row;
    float inv = 1.f / (Lf[m0i] + Lf[m1i]);
    const size_t orow = ((size_t)(b * 1024 + qt * 64 + row)) * 1024 + h * 64;
    #pragma unroll
    for (int i = 0; i < 4; ++i) {
        int col = quad * 16 + i * 4;
        float4 v0 = *(const float4*)&Of[b0 + col];
        float4 v1 = *(const float4*)&Of[b1 + col];
        float o0 = (v0.x + v1.x) * inv;
        float o1 = (v0.y + v1.y) * inv;
        float o2 = (v0.z + v1.z) * inv;
        float o3 = (v0.w + v1.w) * inv;
        u16 h0,l0_,h1,l1_,h2,l2_,h3,l3_;
        split2(o0,h0,l0_); split2(o1,h1,l1_); split2(o2,h2,l2_); split2(o3,h3,l3_);
        ushort4 hv = {h0,h1,h2,h3}, lv = {l0_,l1_,l2_,l3_};
        *(ushort4*)&oh[orow + col] = hv;
        *(ushort4*)&ol[orow + col] = lv;
    }
}

// ---------------- launch ----------------
extern "C" void kernel_launch(void* const* d_in, const int* in_sizes, int n_in,
                              void* d_out, int out_size, void* d_ws, size_t ws_size,
                              hipStream_t stream)
{
    const float* x     = (const float*)d_in[0];
    const float* Wqkv  = (const float*)d_in[1];
    const float* mW1   = (const float*)d_in[2];
    const float* mb1   = (const float*)d_in[3];
    const float* mW2   = (const float*)d_in[4];
    const float* mb2   = (const float*)d_in[5];
    const float* Pp    = (const float*)d_in[6];
    const float* Wqa   = (const float*)d_in[7];
    const float* Wo    = (const float*)d_in[8];
    const float* ffW1  = (const float*)d_in[9];
    const float* ffb1  = (const float*)d_in[10];
    const float* ffW2  = (const float*)d_in[11];
    const float* ffb2  = (const float*)d_in[12];
    char* wsb = (char*)d_ws;
    float* outp = (float*)d_out;

    // region A (multiplexed)
    float* z1    = (float*)(wsb + oRA);
    float* grd   = (float*)(wsb + oRA + 3145728);
    float* cp2   = (float*)(wsb + oRA + 7346176);
    float* cp1   = (float*)(wsb + oRA + 7362560);
    u16* hh_     = (u16*)(wsb + oRA + 8388608);
    u16* hl_     = (u16*)(wsb + oRA + 8650752);
    u16* hTh     = (u16*)(wsb + oRA + 9437184);
    u16* hTl     = (u16*)(wsb + oRA + 9699328);
    u16* rh_     = (u16*)(wsb + oRA + 10485760);
    u16* rl_     = (u16*)(wsb + oRA + 11010048);
    u16* rTh     = (u16*)(wsb + oRA + 11534336);
    u16* rTl     = (u16*)(wsb + oRA + 12058624);
    u16* dhTh    = (u16*)(wsb + oRA + 12582912);
    u16* dhTl    = (u16*)(wsb + oRA + 12845056);
    u16* kcTh    = (u16*)(wsb + oRA + 16777216);
    u16* kcTl    = (u16*)(wsb + oRA + 20971520);
    // flash partials + attn operands (region A dead between scan and FFN)
    float* Of    = (float*)(wsb + oRA);                   // 16.78 MB
    float* Lf    = (float*)(wsb + oRA + 16777216);        // 0.26 MB
    u16* fVth    = (u16*)(wsb + oRA + 17825792);          // 8.45 MB
    u16* fKl     = (u16*)(wsb + oRA + 26279936);          // 8.45 MB
    u16* Woh     = (u16*)(wsb + oRA);
    u16* Wol     = (u16*)(wsb + oRA + 2097152);
    u16* ffhh    = (u16*)(wsb + oRA);
    u16* ffhl    = (u16*)(wsb + oRA + 16777216);
    u16* outbh   = (u16*)(wsb + oRA + 33554432);
    u16* outbl   = (u16*)(wsb + oRA + 37748736);
    u16* newQh   = (u16*)(wsb + oRA);
    u16* newQl   = (u16*)(wsb + oRA + 4194304);
    u16* hzh     = (u16*)(wsb + oRA + 8388608);
    u16* hzl     = (u16*)(wsb + oRA + 10485760);
    float* memq  = (float*)(wsb + oRA + 12582912);
    float* partA0 = (float*)(wsb + oRA);
    float* partA1 = (float*)(wsb + oRA + 4194304);
    float* partA2 = (float*)(wsb + oRA + 16777216);
    // region B
    float* Vb    = (float*)(wsb + oRB + 8388608);
    u16* tokh    = (u16*)(wsb + oRB);
    u16* tokl    = (u16*)(wsb + oRB + 8454144);
    u16* oh      = (u16*)(wsb + oRB);
    u16* ol      = (u16*)(wsb + oRB + 4194304);
    u16* y1h     = (u16*)(wsb + oRB + 8388608);
    u16* y1l     = (u16*)(wsb + oRB + 12582912);
    float* partB = (float*)(wsb + oRB);
    // region C
    u16* xh      = (u16*)(wsb + oRC);
    u16* xl      = (u16*)(wsb + oRC + 4194304);
    float* mom   = (float*)(wsb + oRC);
    u16* pW2Th   = (u16*)(wsb + oRC + 5242880);
    u16* pW2Tl   = (u16*)(wsb + oRC + 6291456);
    u16* Wqah    = (u16*)(wsb + oRC);
    u16* Wqal    = (u16*)(wsb + oRC + 6291456);
    // region D
    u16* Qh      = (u16*)(wsb + oRD);
    u16* Ql      = (u16*)(wsb + oRD + 4194304);
    u16* kchh    = (u16*)(wsb + oRD + 8388608);
    u16* kchl    = (u16*)(wsb + oRD + 12582912);
    u16* t1h     = (u16*)(wsb + oRD + 8388608);
    u16* t1l     = (u16*)(wsb + oRD + 10485760);
    u16* fKh     = (u16*)(wsb + oRD);
    u16* ffW1h   = (u16*)(wsb + oRD);
    u16* ffW1l   = (u16*)(wsb + oRD + 8388608);
    u16* ffW2h   = (u16*)(wsb + oRD);
    u16* ffW2l   = (u16*)(wsb + oRD + 8388608);
    // persistent
    u16* Wqkvh   = (u16*)(wsb + oRE);
    u16* Wqkvl   = (u16*)(wsb + oRE + 6291456);
    u16* pW1h    = (u16*)(wsb + oRF);
    u16* pW1l    = (u16*)(wsb + oRF + 1048576);
    u16* pW2h    = (u16*)(wsb + oRF + 2097152);
    u16* pW2l    = (u16*)(wsb + oRF + 3145728);
    float* par   = (float*)(wsb + oRG);
    float* outb  = (float*)(wsb + oRH);
    u16* fQh     = (u16*)(wsb + oRH);
    u16* fQl     = (u16*)(wsb + oRH + 4194304);

    // init memory-MLP params
    hipMemcpyAsync(par + PW1, mW1, 524288 * sizeof(float), hipMemcpyDeviceToDevice, stream);
    hipMemcpyAsync(par + PB1, mb1, 512 * sizeof(float), hipMemcpyDeviceToDevice, stream);
    hipMemcpyAsync(par + PW2, mW2, 524288 * sizeof(float), hipMemcpyDeviceToDevice, stream);
    hipMemcpyAsync(par + PB2, mb2, 1024 * sizeof(float), hipMemcpyDeviceToDevice, stream);

    // qkv = x @ Wqkv^T (fused epilogue: Q split, kc split, kcT split, V f32)
    cvt_split_k<<<2048, 256, 0, stream>>>(x, xh, xl, 524288);
    cvt_split_k<<<3072, 256, 0, stream>>>(Wqkv, Wqkvh, Wqkvl, 786432);
    gemm_qkv_k<<<dim3(24, 16), 256, 0, stream>>>(xh, xl, Wqkvh, Wqkvl,
        Qh, Ql, kchh, kchl, kcTh, kcTl, Vb, 2048, 3072, 1024);

    // scan prep (xh/xl dead now)
    hipMemsetAsync(mom, 0, PSZ * sizeof(float), stream);
    cvt_split_k<<<512, 256, 0, stream>>>(par + PW1, pW1h, pW1l, 131072);
    cvt_split_k<<<512, 256, 0, stream>>>(par + PW2, pW2h, pW2l, 131072);
    transpose_split_k<<<dim3(16, 32, 1), 256, 0, stream>>>(par + PW2, pW2Th, pW2Tl, 1024, 512);

    // memory scan: z1 -> r -> {gW2 || dh} -> gW1 -> update  (BK=64 dbuf GEMMs)
    const float cs = 2.f / (float)(BATCH * 128 * DIMD);
    for (int c = 0; c < NCH; ++c) {
        const u16* kch = kchh + (size_t)c * 262144;
        const u16* kcl = kchl + (size_t)c * 262144;
        const u16* kth = kcTh + (size_t)c * 262144;
        const u16* ktl = kcTl + (size_t)c * 262144;
        const float* vc = Vb + (size_t)c * 262144;
        gemm_scan_k<1><<<dim3(4, 2), 256, 0, stream>>>(kch, kcl, pW1h, pW1l,
            z1, hh_, hl_, hTh, hTl, nullptr, nullptr, par + PB1, nullptr, 256, 512, 1024, 1.f);
        gemm_scan_k<2><<<dim3(8, 2), 256, 0, stream>>>(hh_, hl_, pW2h, pW2l,
            nullptr, rh_, rl_, rTh, rTl, nullptr, vc, par + PB2, cp2, 256, 1024, 512, cs);
        gemm_scan_pair_k<<<dim3(4, 10), 256, 0, stream>>>(rTh, rTl, hTh, hTl, grd + PW2,
            rh_, rl_, pW2Th, pW2Tl, dhTh, dhTl, z1, cp1, cs);
        gemm_scan_k<3><<<dim3(8, 4), 256, 0, stream>>>(dhTh, dhTl, kth, ktl,
            grd + PW1, nullptr, nullptr, nullptr, nullptr, nullptr, nullptr, nullptr, nullptr,
            512, 1024, 256, 1.f);
        update3_k<<<4102, 256, 0, stream>>>(par, mom, grd, cp1, cp2,
            pW1h, pW1l, pW2h, pW2l, pW2Th, pW2Tl, (int)PSZ);
    }

    // memory readout: t1 (split-K S=4), memtok partial -> reduce directly into tok rows
    gemm_mfma_sk(stream, 1, 0, 1, Qh, Ql, pW1h, pW1l, nullptr, t1h, t1l,
                 2048, 512, 1024, par + PB1, 4, partA2);
    {
        dim3 g(8, 16, 2), b(256);
        gemm_mfma_k<0,0,0,1,3><<<g, b, 0, stream>>>(t1h, t1l, pW2h, pW2l,
            partA0, nullptr, nullptr, 2048, 1024, 512, nullptr);
        reduce_tok_k<<<2048, 256, 0, stream>>>(partA0, par + PB2, tokh, tokl);
    }

    // P + x token rows, weights, fused attention qkv (2-product, dead-Q-tile skip)
    tokens_px_k<<<8320, 256, 0, stream>>>(Pp, x, tokh, tokl);
    cvt_split_k<<<3072, 256, 0, stream>>>(Wqa, Wqah, Wqal, 786432);
    gemm_aqkv_k<<<dim3(24, 33), 256, 0, stream>>>(tokh, tokl, Wqah, Wqal,
        fQh, fQl, fKh, fKl, fVth, 4128, 3072, 1024);

    // MFMA flash attention: fixed-shift softmax, split-KV partials + merge
    flash_part_k<<<dim3(16, 16, 4), 256, 0, stream>>>(fQh, fQl, fKh, fKl, fVth, Of, Lf);
    flash_merge_k<<<dim3(16, 16, 2), 256, 0, stream>>>(Of, Lf, oh, ol);

    // Wo projection + FFN (split-K; FF1/FF2 2-product)
    cvt_split_k<<<1024, 256, 0, stream>>>(Wo, Woh, Wol, 262144);
    gemm_mfma_sk(stream, 0, 0, 1, oh, ol, Woh, Wol, nullptr, y1h, y1l,
                 2048, 1024, 1024, nullptr, 2, partA1);
    cvt_split_k<<<4096, 256, 0, stream>>>(ffW1, ffW1h, ffW1l, 1048576);
    gemm_mfma(stream, 2, 0, 1, y1h, y1l, ffW1h, ffW1l, nullptr, ffhh, ffhl,
              2048, 4096, 1024, ffb1, 2);
    cvt_split_k<<<4096, 256, 0, stream>>>(ffW2, ffW2h, ffW2l, 1048576);
    gemm_mfma_sk(stream, 0, 1, 1, ffhh, ffhl, ffW2h, ffW2l, outb, outbh, outbl,
                 2048, 1024, 4096, ffb2, 2, partB, 2);

    // gate (full 3-product for endpoint precision)
    gemm_mfma_sk(stream, 0, 0, 1, outbh, outbl, Wqkvh, Wqkvl, nullptr, newQh, newQl,
                 2048, 1024, 1024, nullptr, 2, partB);
    gemm_mfma_sk(stream, 1, 0, 1, newQh, newQl, pW1h, pW1l, nullptr, hzh, hzl,
                 2048, 512, 1024, par + PB1, 4, partB);
    gemm_mfma_sk(stream, 0, 1, 0, hzh, hzl, pW2h, pW2l, memq, nullptr, nullptr,
                 2048, 1024, 512, par + PB2, 2, partB);
    mul_k<<<8192, 256, 0, stream>>>(outb, memq, outp, 2097152);
}

// Round 17
// 1332.688 us; speedup vs baseline: 1.2574x; 1.0019x over previous
//
#include <hip/hip_runtime.h>
#include <math.h>

// ---------------- problem constants ----------------
#define BATCH 2
#define TSEQ 1024
#define DIMD 1024
#define NPERS 16
#define NCH 8
#define NTOK 2064
#define ETA_C 0.9f
#define THETA_C 0.1f
#define ALPHA_C 0.02f

typedef __attribute__((ext_vector_type(4))) float f32x4;
typedef __attribute__((ext_vector_type(8))) short s16x8;
typedef unsigned short u16;

// ---------------- bf16 helpers ----------------
__device__ __forceinline__ u16 f2bf(float f) {
    unsigned int u = __float_as_uint(f);
    return (u16)((u + 0x7fffu + ((u >> 16) & 1u)) >> 16);
}
__device__ __forceinline__ float bf2f(u16 h) { return __uint_as_float(((unsigned)h) << 16); }
__device__ __forceinline__ void split2(float v, u16& h, u16& l) {
    h = f2bf(v); l = f2bf(v - bf2f(h));
}

// ---------------- workspace layout (byte offsets) ----------------
static const size_t oRA = 0;                       // 50,724,864 multiplexed
static const size_t oRB = 50724864;                // 16,908,288
static const size_t oRC = 67633152;                // 12,582,912
static const size_t oRD = 80216064;                // 16,777,216
static const size_t oRE = 96993280;                // 12,582,912 Wqkv h/l (persistent)
static const size_t oRF = 109576192;               //  4,194,304 parW h/l (persistent)
static const size_t oRG = 113770496;               //  4,200,448 par (persistent)
static const size_t oRH = 117970944;               //  8,388,608 outb f32 / fQ split
// total 126,359,552 bytes

static const size_t PW1 = 0, PB1 = 524288, PW2 = 524800, PB2 = 1049088, PSZ = 1050112;

// ---------------- async global->LDS ----------------
__device__ __forceinline__ void gload_lds16(const u16* g, u16* l) {
    __builtin_amdgcn_global_load_lds(
        (const __attribute__((address_space(1))) unsigned int*)g,
        (__attribute__((address_space(3))) unsigned int*)l, 16, 0, 0);
}

// XCD-chunked block swizzle (bijective when nwg % 8 == 0; identity fallback).
// cmaj=0: consecutive blocks in an XCD share a tile ROW (A panel hot, W swept).
// cmaj=1: consecutive blocks share a tile COLUMN (W panel hot, A swept) -- use
// when the weight matrix exceeds L2 but one column-panel fits.
__device__ __forceinline__ void xcd_swz2(int cmaj, int& bx, int& by) {
    int gx = gridDim.x, gy = gridDim.y, nwg = gx * gy;
    int lid = cmaj ? (blockIdx.x * gy + blockIdx.y) : (blockIdx.y * gx + blockIdx.x);
    int t = lid;
    if ((nwg & 7) == 0) {
        int q = nwg >> 3;
        t = (lid & 7) * q + (lid >> 3);
    }
    if (cmaj) { by = t % gy; bx = t / gy; }
    else      { bx = t % gx; by = t / gx; }
}
__device__ __forceinline__ void xcd_swizzle(int& bx, int& by) { xcd_swz2(0, bx, by); }

// stage one 128x32 bf16 tile (this wave's quarter) into buf + wid*4096
__device__ __forceinline__ void stage_tile(const u16* sp, u16* buf, int rbase,
                                           int M, int clampM, int K, int k0,
                                           int wid, int lane) {
    const int lr = lane >> 2, lc = lane & 3;
    #pragma unroll
    for (int i = 0; i < 8; ++i) {
        int r = i * 16 + lr;
        int gr = rbase + r;
        if (clampM && gr >= M) gr = M - 1;
        int g = lc ^ ((r >> 1) & 3);
        gload_lds16(sp + (size_t)gr * K + k0 + g * 8, buf + wid * 4096 + i * 512);
    }
}

// stage one 128x64 bf16 tile into buf + wid*8192 (scan path, BK=64)
__device__ __forceinline__ void stage_tile64(const u16* sp, u16* buf, int rbase,
                                             int K, int k0, int wid, int lane) {
    const int lr = lane >> 3, lc = lane & 7;
    #pragma unroll
    for (int i = 0; i < 16; ++i) {
        int r = i * 8 + lr;
        int gr = rbase + r;
        int g = lc ^ (r & 7);
        gload_lds16(sp + (size_t)gr * K + k0 + g * 8, buf + wid * 8192 + i * 512);
    }
}

// shared BK=32 dbuf main loop: accumulates into acc[4][4].
// NPROD=3: hh+hl+lh (fp32-quality). NPROD=2: hh+hl (drops al term, ~2^-9 rel err).
template<int NPROD>
__device__ __forceinline__ void mm_loop32(u16 lds[2][16384],
                const u16* sp, int rbase, int M, int clampM, int K,
                int kbeg, int kend, int wid, int lane, int wm, int wn,
                f32x4 acc[4][4]) {
    const int frow = lane & 15, kblk = lane >> 4;
    const int nt = (kend - kbeg) >> 5;
    const int doStage = (NPROD == 3) || (wid != 1);   // skip unused A-low staging
    if (doStage) stage_tile(sp, lds[0], rbase, M, clampM, K, kbeg, wid, lane);
    for (int t = 0; t < nt; ++t) {
        __syncthreads();
        if (t + 1 < nt && doStage)
            stage_tile(sp, lds[(t + 1) & 1], rbase, M, clampM, K, kbeg + ((t + 1) << 5), wid, lane);
        const u16* cb = lds[t & 1];
        s16x8 bh[4], bl[4];
        #pragma unroll
        for (int ni = 0; ni < 4; ++ni) {
            int br = wn * 64 + ni * 16 + frow;
            int pc = kblk ^ ((br >> 1) & 3);
            bh[ni] = *(const s16x8*)&cb[2 * 4096 + br * 32 + pc * 8];
            bl[ni] = *(const s16x8*)&cb[3 * 4096 + br * 32 + pc * 8];
        }
        #pragma unroll
        for (int mi = 0; mi < 4; ++mi) {
            int ar = wm * 64 + mi * 16 + frow;
            int pc = kblk ^ ((ar >> 1) & 3);
            s16x8 ah = *(const s16x8*)&cb[0 * 4096 + ar * 32 + pc * 8];
            s16x8 al;
            if (NPROD == 3) al = *(const s16x8*)&cb[1 * 4096 + ar * 32 + pc * 8];
            #pragma unroll
            for (int ni = 0; ni < 4; ++ni) {
                acc[mi][ni] = __builtin_amdgcn_mfma_f32_16x16x32_bf16(ah, bh[ni], acc[mi][ni], 0, 0, 0);
                acc[mi][ni] = __builtin_amdgcn_mfma_f32_16x16x32_bf16(ah, bl[ni], acc[mi][ni], 0, 0, 0);
                if (NPROD == 3)
                    acc[mi][ni] = __builtin_amdgcn_mfma_f32_16x16x32_bf16(al, bh[ni], acc[mi][ni], 0, 0, 0);
            }
        }
    }
}

// ---------------- split-bf16 MFMA GEMM:  C = act(A @ W^T + bias) ----------------
template<int ACTF, int WF32, int WSPLIT, int PARTIAL, int NPROD>
__global__ __launch_bounds__(256)
void gemm_mfma_k(const u16* __restrict__ Ah, const u16* __restrict__ Al,
                 const u16* __restrict__ Wh, const u16* __restrict__ Wl,
                 float* __restrict__ C, u16* __restrict__ Chi, u16* __restrict__ Clo,
                 int M, int N, int K, const float* __restrict__ bias, int cmaj)
{
    __shared__ u16 lds[2][16384];
    const int tid = threadIdx.x;
    const int lane = tid & 63, wid = tid >> 6;
    const int wm = wid >> 1, wn = wid & 1;
    int bx, by; xcd_swz2(cmaj, bx, by);
    const int row0 = by * 128, col0 = bx * 128;
    const u16* sp = (wid == 0) ? Ah : (wid == 1) ? Al : (wid == 2) ? Wh : Wl;
    const int rbase = (wid < 2) ? row0 : col0;
    const int clampM = (wid < 2) ? 1 : 0;
    f32x4 acc[4][4] = {};
    int kbeg = 0, kend = K;
    if (PARTIAL) {
        int Kseg = K / gridDim.z;
        kbeg = blockIdx.z * Kseg;
        kend = kbeg + Kseg;
    }
    mm_loop32<NPROD>(lds, sp, rbase, M, clampM, K, kbeg, kend, wid, lane, wm, wn, acc);

    const int erow = (lane >> 4) * 4, ecol = lane & 15;
    #pragma unroll
    for (int mi = 0; mi < 4; ++mi) {
        #pragma unroll
        for (int ni = 0; ni < 4; ++ni) {
            int c = col0 + wn * 64 + ni * 16 + ecol;
            float bv = (!PARTIAL && bias) ? bias[c] : 0.f;
            #pragma unroll
            for (int reg = 0; reg < 4; ++reg) {
                int r = row0 + wm * 64 + mi * 16 + erow + reg;
                if (r >= M) continue;
                float v = acc[mi][ni][reg] + bv;
                if (PARTIAL) {
                    C[((size_t)blockIdx.z * M + r) * N + c] = v;
                    continue;
                }
                if (ACTF == 1) v = v / (1.f + __expf(-v));
                else if (ACTF == 2) {
                    float u = 0.7978845608028654f * (v + 0.044715f * v * v * v);
                    v = 0.5f * v * (1.f + tanhf(u));
                }
                size_t o = (size_t)r * N + c;
                if (WF32) C[o] = v;
                if (WSPLIT) { u16 h, l; split2(v, h, l); Chi[o] = h; Clo[o] = l; }
            }
        }
    }
}

// fused qkv GEMM: writes Q split, kc split, kcT split, V f32 directly (M=2048,N=3072)
__global__ __launch_bounds__(256)
void gemm_qkv_k(const u16* __restrict__ Ah, const u16* __restrict__ Al,
                const u16* __restrict__ Wh, const u16* __restrict__ Wl,
                u16* __restrict__ Qh, u16* __restrict__ Ql,
                u16* __restrict__ kch, u16* __restrict__ kcl,
                u16* __restrict__ kcTh, u16* __restrict__ kcTl,
                float* __restrict__ Vb, int M, int N, int K)
{
    __shared__ u16 lds[2][16384];
    const int tid = threadIdx.x;
    const int lane = tid & 63, wid = tid >> 6;
    const int wm = wid >> 1, wn = wid & 1;
    int bx, by; xcd_swz2(1, bx, by);
    const int row0 = by * 128, col0 = bx * 128;
    const u16* sp = (wid == 0) ? Ah : (wid == 1) ? Al : (wid == 2) ? Wh : Wl;
    const int rbase = (wid < 2) ? row0 : col0;
    f32x4 acc[4][4] = {};
    mm_loop32<3>(lds, sp, rbase, M, 0, K, 0, K, wid, lane, wm, wn, acc);

    const int erow = (lane >> 4) * 4, ecol = lane & 15;
    #pragma unroll
    for (int mi = 0; mi < 4; ++mi) {
        #pragma unroll
        for (int ni = 0; ni < 4; ++ni) {
            int c = col0 + wn * 64 + ni * 16 + ecol;
            #pragma unroll
            for (int reg = 0; reg < 4; ++reg) {
                int r = row0 + wm * 64 + mi * 16 + erow + reg;
                float v = acc[mi][ni][reg];
                int b = r >> 10, t = r & 1023;
                if (c < 1024) {
                    size_t o = (size_t)r * 1024 + c;
                    u16 h, l; split2(v, h, l); Qh[o] = h; Ql[o] = l;
                } else if (c < 2048) {
                    int d = c - 1024;
                    int ch = t >> 7, rr = t & 127;
                    size_t o = ((size_t)((ch * 2 + b) * 128 + rr)) * 1024 + d;
                    u16 h, l; split2(v, h, l);
                    kch[o] = h; kcl[o] = l;
                    size_t ot = (size_t)ch * 262144 + (size_t)d * 256 + b * 128 + rr;
                    kcTh[ot] = h; kcTl[ot] = l;
                } else {
                    int d = c - 2048;
                    int ch = t >> 7, rr = t & 127;
                    Vb[((size_t)((ch * 2 + b) * 128 + rr)) * 1024 + d] = v;
                }
            }
        }
    }
}

// fused attention-qkv GEMM (2-product): fQ (0.125-scaled, kept rows), fK split, fV^T hi
__global__ __launch_bounds__(256)
void gemm_aqkv_k(const u16* __restrict__ Ah, const u16* __restrict__ Al,
                 const u16* __restrict__ Wh, const u16* __restrict__ Wl,
                 u16* __restrict__ fQh, u16* __restrict__ fQl,
                 u16* __restrict__ fKh, u16* __restrict__ fKl,
                 u16* __restrict__ fVt, int M, int N, int K)
{
    __shared__ u16 lds[2][16384];
    const int tid = threadIdx.x;
    const int lane = tid & 63, wid = tid >> 6;
    const int wm = wid >> 1, wn = wid & 1;
    int bx, by; xcd_swz2(1, bx, by);
    // dead Q tiles: cols<1024 only used for query rows n>=1040
    if (bx < 8 && ((by <= 7) || (by >= 17 && by <= 23))) return;
    const int row0 = by * 128, col0 = bx * 128;
    const u16* sp = (wid == 0) ? Ah : (wid == 1) ? Al : (wid == 2) ? Wh : Wl;
    const int rbase = (wid < 2) ? row0 : col0;
    const int clampM = (wid < 2) ? 1 : 0;
    f32x4 acc[4][4] = {};
    mm_loop32<2>(lds, sp, rbase, M, clampM, K, 0, K, wid, lane, wm, wn, acc);

    const int erow = (lane >> 4) * 4, ecol = lane & 15;
    #pragma unroll
    for (int mi = 0; mi < 4; ++mi) {
        #pragma unroll
        for (int ni = 0; ni < 4; ++ni) {
            int c = col0 + wn * 64 + ni * 16 + ecol;
            #pragma unroll
            for (int reg = 0; reg < 4; ++reg) {
                int r = row0 + wm * 64 + mi * 16 + erow + reg;
                if (r >= M) continue;
                float v = acc[mi][ni][reg];
                int b = (r >= 2064) ? 1 : 0;
                int n = r - b * 2064;
                if (c < 1024) {
                    if (n >= NPERS + TSEQ) {
                        int h = c >> 6, d = c & 63;
                        int row = n - (NPERS + TSEQ);
                        size_t o = (((size_t)(b * 16 + h)) * 1024 + row) * 64 + d;
                        u16 hh, ll; split2(0.125f * v, hh, ll);
                        fQh[o] = hh; fQl[o] = ll;
                    }
                } else if (c < 2048) {
                    int cc = c - 1024;
                    int h = cc >> 6, d = cc & 63;
                    size_t o = (((size_t)(b * 16 + h)) * NTOK + n) * 64 + d;
                    u16 hh, ll; split2(v, hh, ll);
                    fKh[o] = hh; fKl[o] = ll;
                } else {
                    int cc = c - 2048;
                    int h = cc >> 6, d = cc & 63;
                    fVt[(((size_t)(b * 16 + h)) * 64 + d) * NTOK + n] = f2bf(v);
                }
            }
        }
    }
}

// split-K reduce + epilogue
template<int ACTF, int WF32, int WSPLIT>
__global__ __launch_bounds__(256)
void reduce_k(const float* __restrict__ Cp, int S,
              float* __restrict__ C, u16* __restrict__ Chi, u16* __restrict__ Clo,
              const float* __restrict__ bias, int M, int N)
{
    int i = blockIdx.x * 256 + threadIdx.x;
    int n4 = (int)((size_t)M * N / 4);
    if (i >= n4) return;
    size_t off = (size_t)i * 4;
    float4 v = *(const float4*)&Cp[off];
    for (int z = 1; z < S; ++z) {
        float4 u = *(const float4*)&Cp[(size_t)z * M * N + off];
        v.x += u.x; v.y += u.y; v.z += u.z; v.w += u.w;
    }
    int c = (int)(off % N);
    float vv[4] = {v.x, v.y, v.z, v.w};
    #pragma unroll
    for (int j = 0; j < 4; ++j) {
        float w = vv[j];
        if (bias) w += bias[c + j];
        if (ACTF == 1) w = w / (1.f + __expf(-w));
        else if (ACTF == 2) {
            float u = 0.7978845608028654f * (w + 0.044715f * w * w * w);
            w = 0.5f * w * (1.f + tanhf(u));
        }
        if (WF32) C[off + j] = w;
        if (WSPLIT) { u16 h, l; split2(w, h, l); Chi[off + j] = h; Clo[off + j] = l; }
    }
}

// memtok reduce: sum S=2 partials [z][2048][1024] + b2, write split DIRECTLY into
// token buffer rows b*2064 + 16 + t
__global__ __launch_bounds__(256)
void reduce_tok_k(const float* __restrict__ Cp, const float* __restrict__ bias,
                  u16* __restrict__ th, u16* __restrict__ tl)
{
    int i = blockIdx.x * 256 + threadIdx.x;
    if (i >= 524288) return;
    size_t off = (size_t)i * 4;
    float4 v = *(const float4*)&Cp[off];
    float4 u = *(const float4*)&Cp[2097152 + off];
    v.x += u.x; v.y += u.y; v.z += u.z; v.w += u.w;
    int r = (int)(off >> 10), c = (int)(off & 1023);
    int b = r >> 10, t = r & 1023;
    size_t orow = (((size_t)(b * NTOK + NPERS + t)) << 10) + c;
    float vv[4] = {v.x + bias[c], v.y + bias[c + 1], v.z + bias[c + 2], v.w + bias[c + 3]};
    u16 h0,l0,h1,l1,h2,l2,h3,l3;
    split2(vv[0],h0,l0); split2(vv[1],h1,l1); split2(vv[2],h2,l2); split2(vv[3],h3,l3);
    ushort4 hv = {h0,h1,h2,h3}, lv = {l0,l1,l2,l3};
    *(ushort4*)&th[orow] = hv;
    *(ushort4*)&tl[orow] = lv;
}

static void gemm_mfma(hipStream_t s, int act, int wf32, int wsplit,
                      const u16* Ah, const u16* Al, const u16* Wh, const u16* Wl,
                      float* C, u16* Ch, u16* Cl, int M, int N, int K,
                      const float* bias, int nprod = 3, int cmaj = 0)
{
    dim3 g(N / 128, (M + 127) / 128), b(256);
    if (act == 0 && wf32 == 1 && wsplit == 0)
        gemm_mfma_k<0,1,0,0,3><<<g,b,0,s>>>(Ah,Al,Wh,Wl,C,Ch,Cl,M,N,K,bias,cmaj);
    else if (act == 0 && wf32 == 1 && wsplit == 1)
        gemm_mfma_k<0,1,1,0,3><<<g,b,0,s>>>(Ah,Al,Wh,Wl,C,Ch,Cl,M,N,K,bias,cmaj);
    else if (act == 0 && wf32 == 0 && wsplit == 1)
        gemm_mfma_k<0,0,1,0,3><<<g,b,0,s>>>(Ah,Al,Wh,Wl,C,Ch,Cl,M,N,K,bias,cmaj);
    else if (act == 1)
        gemm_mfma_k<1,0,1,0,3><<<g,b,0,s>>>(Ah,Al,Wh,Wl,C,Ch,Cl,M,N,K,bias,cmaj);
    else if (nprod == 2)
        gemm_mfma_k<2,0,1,0,2><<<g,b,0,s>>>(Ah,Al,Wh,Wl,C,Ch,Cl,M,N,K,bias,cmaj);
    else
        gemm_mfma_k<2,0,1,0,3><<<g,b,0,s>>>(Ah,Al,Wh,Wl,C,Ch,Cl,M,N,K,bias,cmaj);
}

static void gemm_mfma_sk(hipStream_t s, int act, int wf32, int wsplit,
                         const u16* Ah, const u16* Al, const u16* Wh, const u16* Wl,
                         float* C, u16* Ch, u16* Cl, int M, int N, int K,
                         const float* bias, int S, float* part, int nprod = 3,
                         int cmaj = 0)
{
    if (S <= 1) { gemm_mfma(s, act, wf32, wsplit, Ah, Al, Wh, Wl, C, Ch, Cl, M, N, K, bias, nprod, cmaj); return; }
    dim3 g(N / 128, (M + 127) / 128, S), b(256);
    if (nprod == 2)
        gemm_mfma_k<0,0,0,1,2><<<g,b,0,s>>>(Ah,Al,Wh,Wl,part,nullptr,nullptr,M,N,K,nullptr,cmaj);
    else
        gemm_mfma_k<0,0,0,1,3><<<g,b,0,s>>>(Ah,Al,Wh,Wl,part,nullptr,nullptr,M,N,K,nullptr,cmaj);
    int n4 = (int)((size_t)M * N / 4);
    dim3 rg((n4 + 255) / 256), rb(256);
    if (act == 0 && wf32 == 1 && wsplit == 0)
        reduce_k<0,1,0><<<rg,rb,0,s>>>(part, S, C, Ch, Cl, bias, M, N);
    else if (act == 0 && wf32 == 1 && wsplit == 1)
        reduce_k<0,1,1><<<rg,rb,0,s>>>(part, S, C, Ch, Cl, bias, M, N);
    else if (act == 0 && wf32 == 0 && wsplit == 1)
        reduce_k<0,0,1><<<rg,rb,0,s>>>(part, S, C, Ch, Cl, bias, M, N);
    else if (act == 1)
        reduce_k<1,0,1><<<rg,rb,0,s>>>(part, S, C, Ch, Cl, bias, M, N);
    else
        reduce_k<2,0,1><<<rg,rb,0,s>>>(part, S, C, Ch, Cl, bias, M, N);
}

// ---------------- scan-specialized split-bf16 MFMA GEMM body (BK=64 dbuf) -------
template<int MODE>
__device__ __forceinline__ void scan_body(u16* lds, int bx, int by,
                 const u16* __restrict__ Ah, const u16* __restrict__ Al,
                 const u16* __restrict__ Wh, const u16* __restrict__ Wl,
                 float* __restrict__ C, u16* __restrict__ Chi, u16* __restrict__ Clo,
                 u16* __restrict__ ChiT, u16* __restrict__ CloT,
                 const float* __restrict__ Zf, const float* __restrict__ add,
                 const float* __restrict__ bias, float* __restrict__ CP,
                 int M, int N, int K, float alpha)
{
    const int tid = threadIdx.x;
    const int lane = tid & 63, wid = tid >> 6;
    const int wm = wid >> 1, wn = wid & 1;
    const int row0 = by * 128, col0 = bx * 128;

    const u16* sp = (wid == 0) ? Ah : (wid == 1) ? Al : (wid == 2) ? Wh : Wl;
    const int rbase = (wid < 2) ? row0 : col0;

    f32x4 acc[4][4] = {};
    const int frow = lane & 15, kblk = lane >> 4;
    const int nt = K >> 6;

    stage_tile64(sp, lds, rbase, K, 0, wid, lane);

    for (int t = 0; t < nt; ++t) {
        __syncthreads();
        if (t + 1 < nt)
            stage_tile64(sp, lds + (((t + 1) & 1) << 15), rbase, K, (t + 1) << 6, wid, lane);
        const u16* cb = lds + ((t & 1) << 15);

        #pragma unroll
        for (int s = 0; s < 2; ++s) {
            s16x8 bh[4], bl[4];
            #pragma unroll
            for (int ni = 0; ni < 4; ++ni) {
                int br = wn * 64 + ni * 16 + frow;
                int pc = (s * 4 + kblk) ^ (br & 7);
                bh[ni] = *(const s16x8*)&cb[2 * 8192 + br * 64 + pc * 8];
                bl[ni] = *(const s16x8*)&cb[3 * 8192 + br * 64 + pc * 8];
            }
            #pragma unroll
            for (int mi = 0; mi < 4; ++mi) {
                int ar = wm * 64 + mi * 16 + frow;
                int pc = (s * 4 + kblk) ^ (ar & 7);
                s16x8 ah = *(const s16x8*)&cb[0 * 8192 + ar * 64 + pc * 8];
                s16x8 al = *(const s16x8*)&cb[1 * 8192 + ar * 64 + pc * 8];
                #pragma unroll
                for (int ni = 0; ni < 4; ++ni) {
                    acc[mi][ni] = __builtin_amdgcn_mfma_f32_16x16x32_bf16(ah, bh[ni], acc[mi][ni], 0, 0, 0);
                    acc[mi][ni] = __builtin_amdgcn_mfma_f32_16x16x32_bf16(ah, bl[ni], acc[mi][ni], 0, 0, 0);
                    acc[mi][ni] = __builtin_amdgcn_mfma_f32_16x16x32_bf16(al, bh[ni], acc[mi][ni], 0, 0, 0);
                }
            }
        }
    }

    const int erow = (lane >> 4) * 4, ecol = lane & 15;
    float csum[4] = {0.f, 0.f, 0.f, 0.f};
    #pragma unroll
    for (int mi = 0; mi < 4; ++mi) {
        #pragma unroll
        for (int ni = 0; ni < 4; ++ni) {
            int c = col0 + wn * 64 + ni * 16 + ecol;
            #pragma unroll
            for (int reg = 0; reg < 4; ++reg) {
                int r = row0 + wm * 64 + mi * 16 + erow + reg;
                float v = acc[mi][ni][reg];
                size_t o = (size_t)r * N + c;
                if (MODE == 1) {
                    v += bias[c];
                    C[o] = v;
                    float hv = v / (1.f + __expf(-v));
                    u16 h, l; split2(hv, h, l);
                    Chi[o] = h; Clo[o] = l;
                    size_t ot = (size_t)c * M + r;
                    ChiT[ot] = h; CloT[ot] = l;
                } else if (MODE == 2) {
                    v += bias[c] - add[o];
                    u16 h, l; split2(v, h, l);
                    Chi[o] = h; Clo[o] = l;
                    size_t ot = (size_t)c * M + r;
                    ChiT[ot] = h; CloT[ot] = l;
                    csum[ni] += v;
                } else if (MODE == 3) {
                    C[o] = alpha * v;
                } else {
                    v *= alpha;
                    float z = Zf[o];
                    float sg = 1.f / (1.f + __expf(-z));
                    v *= sg * (1.f + z * (1.f - sg));
                    u16 h, l; split2(v, h, l);
                    size_t ot = (size_t)c * M + r;
                    ChiT[ot] = h; CloT[ot] = l;
                    csum[ni] += v;
                }
            }
        }
    }
    if (MODE == 2 || MODE == 4) {
        #pragma unroll
        for (int ni = 0; ni < 4; ++ni) {
            float s = csum[ni];
            s += __shfl_xor(s, 16);
            s += __shfl_xor(s, 32);
            if ((lane >> 4) == 0) {
                int c = col0 + wn * 64 + ni * 16 + ecol;
                float w = (MODE == 2) ? alpha * s : s;
                CP[(size_t)(by * 2 + wm) * N + c] = w;
            }
        }
    }
}

template<int MODE>
__global__ __launch_bounds__(256)
void gemm_scan_k(const u16* __restrict__ Ah, const u16* __restrict__ Al,
                 const u16* __restrict__ Wh, const u16* __restrict__ Wl,
                 float* __restrict__ C, u16* __restrict__ Chi, u16* __restrict__ Clo,
                 u16* __restrict__ ChiT, u16* __restrict__ CloT,
                 const float* __restrict__ Zf, const float* __restrict__ add,
                 const float* __restrict__ bias, float* __restrict__ CP,
                 int M, int N, int K, float alpha)
{
    __shared__ u16 lds[2][32768];
    int bx, by; xcd_swizzle(bx, by);
    scan_body<MODE>(&lds[0][0], bx, by, Ah, Al, Wh, Wl, C, Chi, Clo, ChiT, CloT,
                    Zf, add, bias, CP, M, N, K, alpha);
}

// merged launch: gW2 (MODE3, 4x8 tiles at by<8) || dh (MODE4, 4x2 tiles at by>=8)
__global__ __launch_bounds__(256)
void gemm_scan_pair_k(const u16* __restrict__ rTh, const u16* __restrict__ rTl,
                      const u16* __restrict__ hTh, const u16* __restrict__ hTl,
                      float* __restrict__ gW2,
                      const u16* __restrict__ rh_, const u16* __restrict__ rl_,
                      const u16* __restrict__ w2th, const u16* __restrict__ w2tl,
                      u16* __restrict__ dhTh, u16* __restrict__ dhTl,
                      const float* __restrict__ z1, float* __restrict__ cp1, float cs)
{
    __shared__ u16 lds[2][32768];
    if (blockIdx.y < 8) {
        scan_body<3>(&lds[0][0], blockIdx.x, blockIdx.y, rTh, rTl, hTh, hTl,
                     gW2, nullptr, nullptr, nullptr, nullptr, nullptr, nullptr,
                     nullptr, nullptr, 1024, 512, 256, cs);
    } else {
        scan_body<4>(&lds[0][0], blockIdx.x, blockIdx.y - 8, rh_, rl_, w2th, w2tl,
                     nullptr, nullptr, nullptr, dhTh, dhTl, z1, nullptr,
                     nullptr, cp1, 256, 512, 1024, cs);
    }
}

// ---------------- small kernels ----------------
__global__ void cvt_split_k(const float* __restrict__ in, u16* __restrict__ hi,
                            u16* __restrict__ lo, int n4) {
    int i = blockIdx.x * 256 + threadIdx.x;
    if (i >= n4) return;
    float4 v = *(const float4*)&in[(size_t)i * 4];
    u16 h0,l0,h1,l1,h2,l2,h3,l3;
    split2(v.x,h0,l0); split2(v.y,h1,l1); split2(v.z,h2,l2); split2(v.w,h3,l3);
    ushort4 hv = {h0,h1,h2,h3}, lv = {l0,l1,l2,l3};
    *(ushort4*)&hi[(size_t)i * 4] = hv;
    *(ushort4*)&lo[(size_t)i * 4] = lv;
}
__global__ void transpose_split_k(const float* __restrict__ in, u16* __restrict__ outh,
                                  u16* __restrict__ outl, int R, int C) {
    __shared__ float t[32][33];
    const int c0 = blockIdx.x * 32, r0 = blockIdx.y * 32;
    const size_t zoff = (size_t)blockIdx.z * R * C;
    const int tx = threadIdx.x & 31, ty = threadIdx.x >> 5;
    #pragma unroll
    for (int p = 0; p < 4; ++p) {
        int r = ty + p * 8;
        t[r][tx] = in[zoff + (size_t)(r0 + r) * C + c0 + tx];
    }
    __syncthreads();
    #pragma unroll
    for (int p = 0; p < 4; ++p) {
        int cc = ty + p * 8;
        float v = t[tx][cc];
        u16 h, l; split2(v, h, l);
        size_t o = zoff + (size_t)(c0 + cc) * R + r0 + tx;
        outh[o] = h; outl[o] = l;
    }
}
__global__ void update3_k(float* __restrict__ p, float* __restrict__ mo,
                          const float* __restrict__ g,
                          const float* __restrict__ cp1, const float* __restrict__ cp2,
                          u16* __restrict__ w1h, u16* __restrict__ w1l,
                          u16* __restrict__ w2h, u16* __restrict__ w2l,
                          u16* __restrict__ w2th, u16* __restrict__ w2tl, int n) {
    int i = blockIdx.x * 256 + threadIdx.x;
    if (i >= n) return;
    float gi;
    if (i < 524288) gi = g[i];
    else if (i < 524800) {
        int j = i - 524288;
        gi = cp1[j] + cp1[512 + j] + cp1[1024 + j] + cp1[1536 + j];
    } else if (i < 1049088) gi = g[i];
    else {
        int j = i - 1049088;
        gi = cp2[j] + cp2[1024 + j] + cp2[2048 + j] + cp2[3072 + j];
    }
    float m = ETA_C * mo[i] - THETA_C * gi;
    mo[i] = m;
    float pv = (1.f - ALPHA_C) * p[i] + m;
    p[i] = pv;
    if (i < 524288) {
        u16 h, l; split2(pv, h, l); w1h[i] = h; w1l[i] = l;
    } else if (i >= 524800 && i < 1049088) {
        int j = i - 524800;
        u16 h, l; split2(pv, h, l);
        w2h[j] = h; w2l[j] = l;
        int tj = (j & 511) * 1024 + (j >> 9);
        w2th[tj] = h; w2tl[tj] = l;
    }
}
// fill ONLY persist (P) and x rows of the token split buffers
__global__ void tokens_px_k(const float* __restrict__ P, const float* __restrict__ x,
                            u16* __restrict__ th, u16* __restrict__ tl) {
    size_t idx = (size_t)blockIdx.x * 256 + threadIdx.x;   // 2*1040*1024
    if (idx >= (size_t)2 * 1040 * 1024) return;
    int d = (int)(idx & 1023);
    int rl = (int)((idx >> 10) % 1040);
    int b = (int)(idx / ((size_t)1040 * 1024));
    float v; int n;
    if (rl < NPERS) { v = P[(size_t)rl * 1024 + d]; n = rl; }
    else { int t = rl - NPERS; v = x[((size_t)b * TSEQ + t) * 1024 + d]; n = NPERS + TSEQ + t; }
    size_t o = (((size_t)(b * NTOK + n)) << 10) + d;
    u16 h, l; split2(v, h, l); th[o] = h; tl[o] = l;
}
__global__ void mul_k(const float* __restrict__ a, const float* __restrict__ b,
                      float* __restrict__ o, int n) {
    int i = blockIdx.x * 256 + threadIdx.x;
    if (i < n) o[i] = a[i] * b[i];
}

// ---------------- MFMA flash attention: split-KV partial + merge ----------------
// Fixed-shift softmax (m == 0): softmax is shift-invariant; logits are bounded
// (|s| << 88) so exp(s) cannot overflow. No running max, no O rescale.
__global__ __launch_bounds__(256)
void flash_part_k(const u16* __restrict__ Qsh, const u16* __restrict__ Qsl,
                  const u16* __restrict__ Ksh, const u16* __restrict__ Ksl,
                  const u16* __restrict__ Vts, float* __restrict__ Of,
                  float* __restrict__ Lf)
{
    __shared__ u16 lds[20480];             // KH KL VT | PH PL = 40 KB
    u16* KH = lds;            u16* KL = lds + 4096;
    u16* VT = lds + 8192;
    u16* PH = lds + 12288;    u16* PL = lds + 16384;

    int lid = blockIdx.x + (blockIdx.y << 4) + (blockIdx.z << 8);
    int t1024 = ((lid & 7) << 7) | (lid >> 3);
    const int qt = t1024 & 15, h = (t1024 >> 4) & 15;
    const int zb = t1024 >> 8;
    const int b = zb >> 1, z = zb & 1;

    const int tid = threadIdx.x;
    const int lane = tid & 63, wid = tid >> 6;
    const int fr = lane & 15, kq = lane >> 4;
    const int bh = b * 16 + h;
    const int q0c = qt * 64;
    const int q0a = NPERS + TSEQ + q0c;
    const int ntile = ((q0a + 63) >> 6) + 1;
    const int half = ntile >> 1;
    const int jt0 = z ? half : 0;
    const int jt1 = z ? ntile : half;
    const int l8 = lane & 7, lr8 = lane >> 3;

    auto stageKV = [&](int jt) {
        const int j0 = jt * 64;
        #pragma unroll
        for (int jj = 0; jj < 6; ++jj) {
            int j = wid * 6 + jj;
            int buf = j >> 3, i8 = j & 7;
            if (buf < 2) {
                int row = i8 * 8 + lr8;
                int grow = j0 + row; if (grow > NTOK - 1) grow = NTOK - 1;
                int c = l8 ^ (row & 7);
                const u16* src = (buf == 0 ? Ksh : Ksl) +
                                 (((size_t)bh * NTOK + grow) << 6) + c * 8;
                gload_lds16(src, (buf == 0 ? KH : KL) + i8 * 512);
            } else {
                int d = i8 * 8 + lr8;
                int c = l8 ^ (d & 7);
                int col = j0 + c * 8; if (col > NTOK - 8) col = NTOK - 8;
                const u16* src = Vts + ((size_t)bh * 64 + d) * NTOK + col;
                gload_lds16(src, VT + i8 * 512);
            }
        }
    };

    // Q fragments direct from global
    s16x8 qh[2], ql[2];
    {
        const size_t qrow = ((size_t)bh * 1024 + q0c + wid * 16 + fr) << 6;
        #pragma unroll
        for (int kb = 0; kb < 2; ++kb) {
            qh[kb] = *(const s16x8*)&Qsh[qrow + (size_t)(kb * 4 + kq) * 8];
            ql[kb] = *(const s16x8*)&Qsl[qrow + (size_t)(kb * 4 + kq) * 8];
        }
    }

    f32x4 Oa[4] = {};
    float lrow[4] = {0.f, 0.f, 0.f, 0.f};

    for (int jt = jt0; jt < jt1; ++jt) {
        const int j0 = jt * 64;
        stageKV(jt);
        __syncthreads();                    // KV landed

        f32x4 sacc[4] = {};
        __builtin_amdgcn_s_setprio(1);
        #pragma unroll
        for (int nt = 0; nt < 4; ++nt) {
            #pragma unroll
            for (int kb = 0; kb < 2; ++kb) {
                int br = nt * 16 + fr;
                int sl = (kb * 4 + kq) ^ (fr & 7);
                s16x8 kh = *(const s16x8*)&KH[br * 64 + sl * 8];
                s16x8 kl = *(const s16x8*)&KL[br * 64 + sl * 8];
                sacc[nt] = __builtin_amdgcn_mfma_f32_16x16x32_bf16(qh[kb], kh, sacc[nt], 0, 0, 0);
                sacc[nt] = __builtin_amdgcn_mfma_f32_16x16x32_bf16(ql[kb], kh, sacc[nt], 0, 0, 0);
                sacc[nt] = __builtin_amdgcn_mfma_f32_16x16x32_bf16(qh[kb], kl, sacc[nt], 0, 0, 0);
            }
        }
        __builtin_amdgcn_s_setprio(0);

        // fixed-shift softmax accumulation (no max tracking, no rescale)
        #pragma unroll
        for (int r = 0; r < 4; ++r) {
            const int qloc = kq * 4 + r;
            const int qi = q0a + wid * 16 + qloc;
            float p4[4], psum = 0.f;
            #pragma unroll
            for (int nt = 0; nt < 4; ++nt) {
                int kj = j0 + nt * 16 + fr;
                float e = (kj <= qi) ? __expf(sacc[nt][r]) : 0.f;
                p4[nt] = e; psum += e;
            }
            #pragma unroll
            for (int off = 1; off < 16; off <<= 1)
                psum += __shfl_xor(psum, off);
            lrow[r] += psum;
            const int prow = wid * 16 + qloc;
            #pragma unroll
            for (int nt = 0; nt < 4; ++nt) {
                u16 ph, pl; split2(p4[nt], ph, pl);
                int col = nt * 16 + fr;
                int sl = (col >> 3) ^ (qloc & 7);
                int off = prow * 64 + sl * 8 + (col & 7);
                PH[off] = ph; PL[off] = pl;
            }
        }

        __builtin_amdgcn_s_setprio(1);
        #pragma unroll
        for (int kb = 0; kb < 2; ++kb) {
            int pr = wid * 16 + fr;
            int sl = (kb * 4 + kq) ^ (fr & 7);
            s16x8 pa = *(const s16x8*)&PH[pr * 64 + sl * 8];
            s16x8 pb = *(const s16x8*)&PL[pr * 64 + sl * 8];
            #pragma unroll
            for (int dt = 0; dt < 4; ++dt) {
                int vr = dt * 16 + fr;
                s16x8 vb = *(const s16x8*)&VT[vr * 64 + sl * 8];
                Oa[dt] = __builtin_amdgcn_mfma_f32_16x16x32_bf16(pa, vb, Oa[dt], 0, 0, 0);
                Oa[dt] = __builtin_amdgcn_mfma_f32_16x16x32_bf16(pb, vb, Oa[dt], 0, 0, 0);
            }
        }
        __builtin_amdgcn_s_setprio(0);
        __syncthreads();                    // compute done before next stage overwrites
    }

    const size_t obase = ((((size_t)z * 2 + b) * 16 + h) * 16 + qt) * 4096;
    const size_t mlb   = ((((size_t)z * 2 + b) * 16 + h) * 16 + qt) * 64;
    #pragma unroll
    for (int r = 0; r < 4; ++r) {
        int rl = wid * 16 + kq * 4 + r;
        if (fr == 0) Lf[mlb + rl] = lrow[r];
        #pragma unroll
        for (int dt = 0; dt < 4; ++dt)
            Of[obase + (size_t)rl * 64 + dt * 16 + fr] = Oa[dt][r];
    }
}

// merge: O = (O0 + O1) / (l0 + l1)  (both halves share the fixed shift m == 0)
__global__ __launch_bounds__(256)
void flash_merge_k(const float* __restrict__ Of, const float* __restrict__ Lf,
                   u16* __restrict__ oh, u16* __restrict__ ol)
{
    const int qt = blockIdx.x, h = blockIdx.y, b = blockIdx.z;
    const int tid = threadIdx.x;
    const int row = tid >> 2, quad = tid & 3;
    const size_t b0 = ((((size_t)0 * 2 + b) * 16 + h) * 16 + qt) * 4096 + (size_t)row * 64;
    const size_t b1 = ((((size_t)1 * 2 + b) * 16 + h) * 16 + qt) * 4096 + (size_t)row * 64;
    const size_t m0i = ((((size_t)0 * 2 + b) * 16 + h) * 16 + qt) * 64 + row;
    const size_t m1i = ((((size_t)1 * 2 + b) * 16 + h) * 16 + qt) * 64 + row;
    float inv = 1.f / (Lf[m0i] + Lf[m1i]);
    const size_t orow = ((size_t)(b * 1024 + qt * 64 + row)) * 1024 + h * 64;
    #pragma unroll
    for (int i = 0; i < 4; ++i) {
        int col = quad * 16 + i * 4;
        float4 v0 = *(const float4*)&Of[b0 + col];
        float4 v1 = *(const float4*)&Of[b1 + col];
        float o0 = (v0.x + v1.x) * inv;
        float o1 = (v0.y + v1.y) * inv;
        float o2 = (v0.z + v1.z) * inv;
        float o3 = (v0.w + v1.w) * inv;
        u16 h0,l0_,h1,l1_,h2,l2_,h3,l3_;
        split2(o0,h0,l0_); split2(o1,h1,l1_); split2(o2,h2,l2_); split2(o3,h3,l3_);
        ushort4 hv = {h0,h1,h2,h3}, lv = {l0_,l1_,l2_,l3_};
        *(ushort4*)&oh[orow + col] = hv;
        *(ushort4*)&ol[orow + col] = lv;
    }
}

// ---------------- launch ----------------
extern "C" void kernel_launch(void* const* d_in, const int* in_sizes, int n_in,
                              void* d_out, int out_size, void* d_ws, size_t ws_size,
                              hipStream_t stream)
{
    const float* x     = (const float*)d_in[0];
    const float* Wqkv  = (const float*)d_in[1];
    const float* mW1   = (const float*)d_in[2];
    const float* mb1   = (const float*)d_in[3];
    const float* mW2   = (const float*)d_in[4];
    const float* mb2   = (const float*)d_in[5];
    const float* Pp    = (const float*)d_in[6];
    const float* Wqa   = (const float*)d_in[7];
    const float* Wo    = (const float*)d_in[8];
    const float* ffW1  = (const float*)d_in[9];
    const float* ffb1  = (const float*)d_in[10];
    const float* ffW2  = (const float*)d_in[11];
    const float* ffb2  = (const float*)d_in[12];
    char* wsb = (char*)d_ws;
    float* outp = (float*)d_out;

    // region A (multiplexed)
    float* z1    = (float*)(wsb + oRA);
    float* grd   = (float*)(wsb + oRA + 3145728);
    float* cp2   = (float*)(wsb + oRA + 7346176);
    float* cp1   = (float*)(wsb + oRA + 7362560);
    u16* hh_     = (u16*)(wsb + oRA + 8388608);
    u16* hl_     = (u16*)(wsb + oRA + 8650752);
    u16* hTh     = (u16*)(wsb + oRA + 9437184);
    u16* hTl     = (u16*)(wsb + oRA + 9699328);
    u16* rh_     = (u16*)(wsb + oRA + 10485760);
    u16* rl_     = (u16*)(wsb + oRA + 11010048);
    u16* rTh     = (u16*)(wsb + oRA + 11534336);
    u16* rTl     = (u16*)(wsb + oRA + 12058624);
    u16* dhTh    = (u16*)(wsb + oRA + 12582912);
    u16* dhTl    = (u16*)(wsb + oRA + 12845056);
    u16* kcTh    = (u16*)(wsb + oRA + 16777216);
    u16* kcTl    = (u16*)(wsb + oRA + 20971520);
    // flash partials + attn operands (region A dead between scan and FFN)
    float* Of    = (float*)(wsb + oRA);                   // 16.78 MB
    float* Lf    = (float*)(wsb + oRA + 16777216);        // 0.26 MB
    u16* fVth    = (u16*)(wsb + oRA + 17825792);          // 8.45 MB
    u16* fKl     = (u16*)(wsb + oRA + 26279936);          // 8.45 MB
    u16* Woh     = (u16*)(wsb + oRA);
    u16* Wol     = (u16*)(wsb + oRA + 2097152);
    u16* ffhh    = (u16*)(wsb + oRA);
    u16* ffhl    = (u16*)(wsb + oRA + 16777216);
    u16* outbh   = (u16*)(wsb + oRA + 33554432);
    u16* outbl   = (u16*)(wsb + oRA + 37748736);
    u16* newQh   = (u16*)(wsb + oRA);
    u16* newQl   = (u16*)(wsb + oRA + 4194304);
    u16* hzh     = (u16*)(wsb + oRA + 8388608);
    u16* hzl     = (u16*)(wsb + oRA + 10485760);
    float* memq  = (float*)(wsb + oRA + 12582912);
    float* partA0 = (float*)(wsb + oRA);
    float* partA1 = (float*)(wsb + oRA + 4194304);
    float* partA2 = (float*)(wsb + oRA + 16777216);
    // region B
    float* Vb    = (float*)(wsb + oRB + 8388608);
    u16* tokh    = (u16*)(wsb + oRB);
    u16* tokl    = (u16*)(wsb + oRB + 8454144);
    u16* oh      = (u16*)(wsb + oRB);
    u16* ol      = (u16*)(wsb + oRB + 4194304);
    u16* y1h     = (u16*)(wsb + oRB + 8388608);
    u16* y1l     = (u16*)(wsb + oRB + 12582912);
    float* partB = (float*)(wsb + oRB);
    // region C
    u16* xh      = (u16*)(wsb + oRC);
    u16* xl      = (u16*)(wsb + oRC + 4194304);
    float* mom   = (float*)(wsb + oRC);
    u16* pW2Th   = (u16*)(wsb + oRC + 5242880);
    u16* pW2Tl   = (u16*)(wsb + oRC + 6291456);
    u16* Wqah    = (u16*)(wsb + oRC);
    u16* Wqal    = (u16*)(wsb + oRC + 6291456);
    // region D
    u16* Qh      = (u16*)(wsb + oRD);
    u16* Ql      = (u16*)(wsb + oRD + 4194304);
    u16* kchh    = (u16*)(wsb + oRD + 8388608);
    u16* kchl    = (u16*)(wsb + oRD + 12582912);
    u16* t1h     = (u16*)(wsb + oRD + 8388608);
    u16* t1l     = (u16*)(wsb + oRD + 10485760);
    u16* fKh     = (u16*)(wsb + oRD);
    u16* ffW1h   = (u16*)(wsb + oRD);
    u16* ffW1l   = (u16*)(wsb + oRD + 8388608);
    u16* ffW2h   = (u16*)(wsb + oRD);
    u16* ffW2l   = (u16*)(wsb + oRD + 8388608);
    // persistent
    u16* Wqkvh   = (u16*)(wsb + oRE);
    u16* Wqkvl   = (u16*)(wsb + oRE + 6291456);
    u16* pW1h    = (u16*)(wsb + oRF);
    u16* pW1l    = (u16*)(wsb + oRF + 1048576);
    u16* pW2h    = (u16*)(wsb + oRF + 2097152);
    u16* pW2l    = (u16*)(wsb + oRF + 3145728);
    float* par   = (float*)(wsb + oRG);
    float* outb  = (float*)(wsb + oRH);
    u16* fQh     = (u16*)(wsb + oRH);
    u16* fQl     = (u16*)(wsb + oRH + 4194304);

    // init memory-MLP params
    hipMemcpyAsync(par + PW1, mW1, 524288 * sizeof(float), hipMemcpyDeviceToDevice, stream);
    hipMemcpyAsync(par + PB1, mb1, 512 * sizeof(float), hipMemcpyDeviceToDevice, stream);
    hipMemcpyAsync(par + PW2, mW2, 524288 * sizeof(float), hipMemcpyDeviceToDevice, stream);
    hipMemcpyAsync(par + PB2, mb2, 1024 * sizeof(float), hipMemcpyDeviceToDevice, stream);

    // qkv = x @ Wqkv^T (fused epilogue; column-major XCD chunks: W panel hot)
    cvt_split_k<<<2048, 256, 0, stream>>>(x, xh, xl, 524288);
    cvt_split_k<<<3072, 256, 0, stream>>>(Wqkv, Wqkvh, Wqkvl, 786432);
    gemm_qkv_k<<<dim3(24, 16), 256, 0, stream>>>(xh, xl, Wqkvh, Wqkvl,
        Qh, Ql, kchh, kchl, kcTh, kcTl, Vb, 2048, 3072, 1024);

    // scan prep (xh/xl dead now)
    hipMemsetAsync(mom, 0, PSZ * sizeof(float), stream);
    cvt_split_k<<<512, 256, 0, stream>>>(par + PW1, pW1h, pW1l, 131072);
    cvt_split_k<<<512, 256, 0, stream>>>(par + PW2, pW2h, pW2l, 131072);
    transpose_split_k<<<dim3(16, 32, 1), 256, 0, stream>>>(par + PW2, pW2Th, pW2Tl, 1024, 512);

    // memory scan: z1 -> r -> {gW2 || dh} -> gW1 -> update  (BK=64 dbuf GEMMs)
    const float cs = 2.f / (float)(BATCH * 128 * DIMD);
    for (int c = 0; c < NCH; ++c) {
        const u16* kch = kchh + (size_t)c * 262144;
        const u16* kcl = kchl + (size_t)c * 262144;
        const u16* kth = kcTh + (size_t)c * 262144;
        const u16* ktl = kcTl + (size_t)c * 262144;
        const float* vc = Vb + (size_t)c * 262144;
        gemm_scan_k<1><<<dim3(4, 2), 256, 0, stream>>>(kch, kcl, pW1h, pW1l,
            z1, hh_, hl_, hTh, hTl, nullptr, nullptr, par + PB1, nullptr, 256, 512, 1024, 1.f);
        gemm_scan_k<2><<<dim3(8, 2), 256, 0, stream>>>(hh_, hl_, pW2h, pW2l,
            nullptr, rh_, rl_, rTh, rTl, nullptr, vc, par + PB2, cp2, 256, 1024, 512, cs);
        gemm_scan_pair_k<<<dim3(4, 10), 256, 0, stream>>>(rTh, rTl, hTh, hTl, grd + PW2,
            rh_, rl_, pW2Th, pW2Tl, dhTh, dhTl, z1, cp1, cs);
        gemm_scan_k<3><<<dim3(8, 4), 256, 0, stream>>>(dhTh, dhTl, kth, ktl,
            grd + PW1, nullptr, nullptr, nullptr, nullptr, nullptr, nullptr, nullptr, nullptr,
            512, 1024, 256, 1.f);
        update3_k<<<4102, 256, 0, stream>>>(par, mom, grd, cp1, cp2,
            pW1h, pW1l, pW2h, pW2l, pW2Th, pW2Tl, (int)PSZ);
    }

    // memory readout: t1 (split-K S=4, 2-prod), memtok partial (2-prod) -> tok rows
    gemm_mfma_sk(stream, 1, 0, 1, Qh, Ql, pW1h, pW1l, nullptr, t1h, t1l,
                 2048, 512, 1024, par + PB1, 4, partA2, 2);
    {
        dim3 g(8, 16, 2), b(256);
        gemm_mfma_k<0,0,0,1,2><<<g, b, 0, stream>>>(t1h, t1l, pW2h, pW2l,
            partA0, nullptr, nullptr, 2048, 1024, 512, nullptr, 0);
        reduce_tok_k<<<2048, 256, 0, stream>>>(partA0, par + PB2, tokh, tokl);
    }

    // P + x token rows, weights, fused attention qkv (2-product, dead-Q-tile skip,
    // column-major XCD chunks)
    tokens_px_k<<<8320, 256, 0, stream>>>(Pp, x, tokh, tokl);
    cvt_split_k<<<3072, 256, 0, stream>>>(Wqa, Wqah, Wqal, 786432);
    gemm_aqkv_k<<<dim3(24, 33), 256, 0, stream>>>(tokh, tokl, Wqah, Wqal,
        fQh, fQl, fKh, fKl, fVth, 4128, 3072, 1024);

    // MFMA flash attention: fixed-shift softmax, split-KV partials + merge
    flash_part_k<<<dim3(16, 16, 4), 256, 0, stream>>>(fQh, fQl, fKh, fKl, fVth, Of, Lf);
    flash_merge_k<<<dim3(16, 16, 2), 256, 0, stream>>>(Of, Lf, oh, ol);

    // Wo projection + FFN (split-K; 2-product; FF1 column-major chunks)
    cvt_split_k<<<1024, 256, 0, stream>>>(Wo, Woh, Wol, 262144);
    gemm_mfma_sk(stream, 0, 0, 1, oh, ol, Woh, Wol, nullptr, y1h, y1l,
                 2048, 1024, 1024, nullptr, 2, partA1, 2);
    cvt_split_k<<<4096, 256, 0, stream>>>(ffW1, ffW1h, ffW1l, 1048576);
    gemm_mfma(stream, 2, 0, 1, y1h, y1l, ffW1h, ffW1l, nullptr, ffhh, ffhl,
              2048, 4096, 1024, ffb1, 2, 1);
    cvt_split_k<<<4096, 256, 0, stream>>>(ffW2, ffW2h, ffW2l, 1048576);
    gemm_mfma_sk(stream, 0, 1, 1, ffhh, ffhl, ffW2h, ffW2l, outb, outbh, outbl,
                 2048, 1024, 4096, ffb2, 2, partB, 2);

    // gate (newQ/hz 2-product; memq 3-product endpoint anchor)
    gemm_mfma_sk(stream, 0, 0, 1, outbh, outbl, Wqkvh, Wqkvl, nullptr, newQh, newQl,
                 2048, 1024, 1024, nullptr, 2, partB, 2);
    gemm_mfma_sk(stream, 1, 0, 1, newQh, newQl, pW1h, pW1l, nullptr, hzh, hzl,
                 2048, 512, 1024, par + PB1, 4, partB, 2);
    gemm_mfma_sk(stream, 0, 1, 0, hzh, hzl, pW2h, pW2l, memq, nullptr, nullptr,
                 2048, 1024, 512, par + PB2, 2, partB, 3);
    mul_k<<<8192, 256, 0, stream>>>(outb, memq, outp, 2097152);
}